// Round 2
// baseline (696.716 us; speedup 1.0000x reference)
//
#include <hip/hip_runtime.h>
#include <hip/hip_bf16.h>
#include <math.h>

#define TPB 256

constexpr int   B_  = 256;
constexpr int   C_  = 1024;
constexpr int   N_  = 80;
constexpr int   BNr = B_ * N_;                 // 20480 rows for BN / GEMM M
constexpr int   CN  = C_ * N_;                 // 81920
constexpr long  BCN = (long)B_ * C_ * N_;      // 20971520
constexpr int   NN  = N_ * N_;                 // 6400
constexpr int   BNN = B_ * NN;                 // 1638400
constexpr float EPSf = 1e-5f;

typedef __bf16 bf16x8 __attribute__((ext_vector_type(8)));
typedef float  f32x4  __attribute__((ext_vector_type(4)));

__device__ __forceinline__ float leakyf(float v) { return v >= 0.0f ? v : 0.2f * v; }

__device__ __forceinline__ ushort f2bf(float f) {
  __hip_bfloat16 h = __float2bfloat16(f);
  ushort u; __builtin_memcpy(&u, &h, 2); return u;
}
__device__ __forceinline__ float b2f(ushort u) {
  __hip_bfloat16 h; __builtin_memcpy(&h, &u, 2);
  return __bfloat162float(h);
}

#define GLOBAL_AS __attribute__((address_space(1)))
#define LDS_AS    __attribute__((address_space(3)))
__device__ __forceinline__ void load_lds16(const void* g, void* l) {
  __builtin_amdgcn_global_load_lds((const GLOBAL_AS void*)g, (LDS_AS void*)l, 16, 0, 0);
}

// ---------------------------------------------------------------------------
// K0: sadj = minmax(adj_param); D = rsqrt(rowsum);
// adj_bf[n*96+m] = bf16(D[n]*sadj[m,n]*D[m]) for m<80, 0 for m in [80,96).
// ---------------------------------------------------------------------------
__global__ void k_prep_adj(const float* __restrict__ ap, float* __restrict__ sadj,
                           ushort* __restrict__ adj_bf, float* __restrict__ lossa) {
  __shared__ float s[NN];
  __shared__ float red[TPB];
  __shared__ float s_lo, s_hi;
  __shared__ float sD[N_];
  const int t = threadIdx.x;
  float lo = 3.4e38f, hi = -3.4e38f;
  for (int i = t; i < NN; i += TPB) { float v = ap[i]; s[i] = v; lo = fminf(lo, v); hi = fmaxf(hi, v); }
  red[t] = lo; __syncthreads();
  for (int o = 128; o > 0; o >>= 1) { if (t < o) red[t] = fminf(red[t], red[t + o]); __syncthreads(); }
  if (t == 0) s_lo = red[0];
  __syncthreads();
  red[t] = hi; __syncthreads();
  for (int o = 128; o > 0; o >>= 1) { if (t < o) red[t] = fmaxf(red[t], red[t + o]); __syncthreads(); }
  if (t == 0) s_hi = red[0];
  __syncthreads();
  const float inv = 1.0f / (s_hi - s_lo);
  for (int i = t; i < NN; i += TPB) { float v = (s[i] - s_lo) * inv; s[i] = v; sadj[i] = v; }
  __syncthreads();
  if (t < N_) { float sum = 0.f; for (int m = 0; m < N_; ++m) sum += s[t * N_ + m]; sD[t] = rsqrtf(sum); }
  if (t == 0) *lossa = 0.0f;
  __syncthreads();
  for (int i = t; i < N_ * 96; i += TPB) {
    const int n = i / 96, m = i % 96;
    adj_bf[i] = f2bf((m < N_) ? sD[n] * s[m * N_ + n] * sD[m] : 0.0f);
  }
}

// ---------------------------------------------------------------------------
// KW: Wt[o][c] = bf16(W[c][o]) — transpose + convert, 32x32 LDS tiles.
// ---------------------------------------------------------------------------
__global__ void k_w_bf_t(const float* __restrict__ W, ushort* __restrict__ Wt) {
  __shared__ float s[32][33];
  const int t = threadIdx.x;
  const int tx = t % 32, ty = t / 32;            // 8 rows per pass
  const int r0 = blockIdx.y * 32, c0 = blockIdx.x * 32;
#pragma unroll
  for (int k = 0; k < 4; ++k) s[ty + 8 * k][tx] = W[(size_t)(r0 + ty + 8 * k) * C_ + c0 + tx];
  __syncthreads();
#pragma unroll
  for (int k = 0; k < 4; ++k) Wt[(size_t)(c0 + ty + 8 * k) * C_ + r0 + tx] = f2bf(s[tx][ty + 8 * k]);
}

// ---------------------------------------------------------------------------
// KW2: split Wco (80 x 2048) into two bf16 (80 x 1024) K-major buffers.
// ---------------------------------------------------------------------------
__global__ void k_wco_bf(const float* __restrict__ Wco, ushort* __restrict__ Wco1t,
                         ushort* __restrict__ Wco2t) {
  const int i4 = (blockIdx.x * TPB + threadIdx.x) * 4;   // 80*2048 elems
  const int o = i4 >> 11, k = i4 & 2047;
  float4 v = *(const float4*)&Wco[(size_t)o * 2048 + k];
  ushort4 u;
  u.x = f2bf(v.x); u.y = f2bf(v.y); u.z = f2bf(v.z); u.w = f2bf(v.w);
  if (k < C_) *(ushort4*)&Wco1t[(size_t)o * C_ + k] = u;
  else        *(ushort4*)&Wco2t[(size_t)o * C_ + (k - C_)] = u;
}

// ---------------------------------------------------------------------------
// KW3: plain fp32 -> bf16 elementwise convert (for Wg, already o-major/K-contig).
// ---------------------------------------------------------------------------
__global__ void k_cvt_bf(const float* __restrict__ W, ushort* __restrict__ Wb) {
  const long i4 = ((long)blockIdx.x * TPB + threadIdx.x) * 4;
  float4 v = *(const float4*)&W[i4];
  ushort4 u;
  u.x = f2bf(v.x); u.y = f2bf(v.y); u.z = f2bf(v.z); u.w = f2bf(v.w);
  *(ushort4*)&Wb[i4] = u;
}

// K-zero: go accumulator (20480 floats).
__global__ void k_zero_go(float* __restrict__ go) {
  const int i = (blockIdx.x * TPB + threadIdx.x) * 4;
  float4 z = make_float4(0.f, 0.f, 0.f, 0.f);
  *(float4*)&go[i] = z;
}

// ---------------------------------------------------------------------------
// K1v3: MFMA fold.  out[(b*80+n)*1024 + c] (bf16, B,N,C) =
//   sum_m adj[n,m] * X[b, c, m]       (X fp32 in B,C,N layout)
// mode 0: adjsrc = adj_bf global (80x96 bf16, prepadded).
// mode 1: adjsrc = dadj RAW fp32 (B,80,80); normalized by dmm, tadj in LDS.
// ---------------------------------------------------------------------------
__global__ __launch_bounds__(256) void k_fold_mfma(const float* __restrict__ X,
                                                   const void* __restrict__ adjsrc,
                                                   ushort* __restrict__ outp, int mode,
                                                   const float* __restrict__ dmm) {
  __shared__ __align__(16) ushort sX[128][104];     // rows c, cols m (pad->104, b128 2-way free)
  __shared__ __align__(16) ushort sAdj[80][104];    // rows n, cols m
  __shared__ float sD[N_];
  const int t = threadIdx.x;
  const int b  = blockIdx.x >> 3;
  const int c0 = (blockIdx.x & 7) * 128;

  // ---- adjacency -> sAdj (bf16, m 80..95 zero) ----
  if (mode == 0) {
    const ushort* ab = (const ushort*)adjsrc;
    for (int i = t; i < (N_ * 96) / 4; i += TPB) {
      ushort4 v = *(const ushort4*)&ab[i * 4];
      *(ushort4*)&sAdj[(i * 4) / 96][(i * 4) % 96] = v;
    }
    __syncthreads();
  } else {
    float* sF = (float*)&sX[0][0];                  // 80*80 fp32 = 25.6KB <= sX
    const float* db = (const float*)adjsrc + (size_t)b * NN;
    const float lo = dmm[0], inv = dmm[1];
    for (int i = t; i < NN / 4; i += TPB) {
      float4 v = *(const float4*)&db[i * 4];
      v.x = (v.x - lo) * inv; v.y = (v.y - lo) * inv;
      v.z = (v.z - lo) * inv; v.w = (v.w - lo) * inv;
      *(float4*)&sF[i * 4] = v;
    }
    __syncthreads();
    if (t < N_) { float s = 0.f; for (int m = 0; m < N_; ++m) s += sF[t * N_ + m]; sD[t] = rsqrtf(s); }
    __syncthreads();
    for (int i = t; i < N_ * 96; i += TPB) {
      const int n = i / 96, m = i % 96;
      sAdj[n][m] = f2bf((m < N_) ? sF[m * N_ + n] * sD[n] * sD[m] : 0.0f);
    }
    __syncthreads();                                 // before sX overwrite
  }

  // ---- stage X (128 rows x 80 m) fp32 -> bf16; zero pad m 80..95 ----
  const float* Xb = X + ((size_t)b * C_ + c0) * N_;
  for (int i = t; i < (128 * N_) / 4; i += TPB) {
    float4 v = *(const float4*)&Xb[i * 4];
    const int r = (i * 4) / N_, m = (i * 4) % N_;
    ushort4 u; u.x = f2bf(v.x); u.y = f2bf(v.y); u.z = f2bf(v.z); u.w = f2bf(v.w);
    *(ushort4*)&sX[r][m] = u;
  }
  for (int i = t; i < (128 * 16) / 4; i += TPB) {
    const int r = i / 4, m = 80 + (i % 4) * 4;
    ushort4 z; z.x = 0; z.y = 0; z.z = 0; z.w = 0;
    *(ushort4*)&sX[r][m] = z;
  }
  __syncthreads();

  const int lane = t & 63, wid = t >> 6;
  const int l16 = lane & 15, lq = lane >> 4;
  f32x4 acc[2][5];
#pragma unroll
  for (int i = 0; i < 2; ++i)
#pragma unroll
    for (int j = 0; j < 5; ++j) { f32x4 z = {0.f, 0.f, 0.f, 0.f}; acc[i][j] = z; }
  bf16x8 af[2][3], bfr[5][3];
#pragma unroll
  for (int i = 0; i < 2; ++i)
#pragma unroll
    for (int kk = 0; kk < 3; ++kk)
      af[i][kk] = *(const bf16x8*)&sX[wid * 32 + i * 16 + l16][kk * 32 + lq * 8];
#pragma unroll
  for (int j = 0; j < 5; ++j)
#pragma unroll
    for (int kk = 0; kk < 3; ++kk)
      bfr[j][kk] = *(const bf16x8*)&sAdj[j * 16 + l16][kk * 32 + lq * 8];
#pragma unroll
  for (int i = 0; i < 2; ++i)
#pragma unroll
    for (int j = 0; j < 5; ++j)
#pragma unroll
      for (int kk = 0; kk < 3; ++kk)
        acc[i][j] = __builtin_amdgcn_mfma_f32_16x16x32_bf16(af[i][kk], bfr[j][kk], acc[i][j], 0, 0, 0);

  // ---- epilogue: D[row=c_local (lq*4+reg)][col=n (l16)] -> (B,N,C) ushort4 ----
  ushort* ob = outp + (size_t)b * CN;
#pragma unroll
  for (int i = 0; i < 2; ++i) {
    const int c = c0 + wid * 32 + i * 16 + lq * 4;
#pragma unroll
    for (int j = 0; j < 5; ++j) {
      const int n = j * 16 + l16;
      ushort4 u;
      u.x = f2bf(acc[i][j][0]); u.y = f2bf(acc[i][j][1]);
      u.z = f2bf(acc[i][j][2]); u.w = f2bf(acc[i][j][3]);
      *(ushort4*)&ob[(size_t)n * C_ + c] = u;
    }
  }
}

// ---------------------------------------------------------------------------
// K2: 256x256x64 8-phase counted-vmcnt MFMA GEMM (T3+T4+T5 schedule).
// A: 20480 x 1024 bf16 row-major. Bt: 1024 x 1024 bf16 row-major.
// out[b, o, n] (B,C,N) = sum_k A[m=(b,n)][k] * Bt[o][k];  out_bf: 1 -> bf16.
// 8 waves (2M x 4N), per-wave out 128x64 with split-half fragments so each
// phase (mh,nh) reads exactly one A-half + one B-half; staging re-targets a
// region only after the barrier following its last read; vmcnt(4) at phases
// 4/8 only (3 half-tiles stay in flight across barriers).
// ---------------------------------------------------------------------------
__global__ __launch_bounds__(512, 2) void k_gemm_256(const ushort* __restrict__ A,
                                                     const ushort* __restrict__ Bt,
                                                     void* __restrict__ outp, int out_bf) {
  __shared__ ushort sA[2][256 * 64];   // 64 KB
  __shared__ ushort sB[2][256 * 64];   // 64 KB
  const int t = threadIdx.x;
  const int lane = t & 63, wid = t >> 6;       // 8 waves
  const int wm = wid >> 2, wn = wid & 3;       // 2 x 4
  const int l16 = lane & 15, lq = lane >> 4;

  // XCD-chunked swizzle: 320 blocks, 320%8==0. Each XCD: contiguous tm range, one tn.
  const int lin = blockIdx.x;
  const int v   = (lin & 7) * 40 + (lin >> 3);
  const int tm = v % 80, tn = v / 80;
  const int m0 = tm * 256, o0 = tn * 256;

  // staging coords: thread t stages row (rowbase + t>>3), elem col (t&7)*8
  const int srow = t >> 3;
  const int scol = (t & 7) * 8;

  f32x4 acc[8][4];
#pragma unroll
  for (int i = 0; i < 8; ++i)
#pragma unroll
    for (int j = 0; j < 4; ++j) { f32x4 z = {0.f, 0.f, 0.f, 0.f}; acc[i][j] = z; }

  // one call stages 64 rows x 64 cols (8KB): per-wave linear LDS dest.
#define STA(PAR, ROWB, KT) load_lds16(A  + (size_t)(m0 + (ROWB) + srow) * C_ + (KT) * 64 + scol, \
                                      &sA[PAR][((ROWB) + (wid << 3)) * 64])
#define STB(PAR, ROWB, KT) load_lds16(Bt + (size_t)(o0 + (ROWB) + srow) * C_ + (KT) * 64 + scol, \
                                      &sB[PAR][((ROWB) + (wid << 3)) * 64])
#define STA_H(PAR, H, KT) { STA(PAR, (H)*128, KT); STA(PAR, (H)*128 + 64, KT); }
#define STB_H(PAR, H, KT) { STB(PAR, (H)*128, KT); STB(PAR, (H)*128 + 64, KT); }

#define DSREADS(PAR, MH, NH)                                                       \
  _Pragma("unroll") for (int fi = 0; fi < 4; ++fi) {                               \
    const int row = ((MH) ? 128 : 0) + wm * 64 + fi * 16 + l16;                    \
    _Pragma("unroll") for (int kk = 0; kk < 2; ++kk)                               \
      afr[fi][kk] = *(const bf16x8*)&sA[PAR][row * 64 + kk * 32 + lq * 8];         \
  }                                                                                \
  _Pragma("unroll") for (int gi = 0; gi < 2; ++gi) {                               \
    const int row = ((NH) ? 128 : 0) + wn * 32 + gi * 16 + l16;                    \
    _Pragma("unroll") for (int kk = 0; kk < 2; ++kk)                               \
      bfr[gi][kk] = *(const bf16x8*)&sB[PAR][row * 64 + kk * 32 + lq * 8];         \
  }

#define MFMAS(MH, NH)                                                              \
  _Pragma("unroll") for (int kk = 0; kk < 2; ++kk)                                 \
  _Pragma("unroll") for (int fi = 0; fi < 4; ++fi)                                 \
  _Pragma("unroll") for (int gi = 0; gi < 2; ++gi)                                 \
    acc[(MH) * 4 + fi][(NH) * 2 + gi] = __builtin_amdgcn_mfma_f32_16x16x32_bf16(   \
        afr[fi][kk], bfr[gi][kk], acc[(MH) * 4 + fi][(NH) * 2 + gi], 0, 0, 0);

#define PHASE(PAR, MH, NH, STAGES, VMW)                                            \
  {                                                                                \
    bf16x8 afr[4][2], bfr[2][2];                                                   \
    DSREADS(PAR, MH, NH)                                                           \
    STAGES                                                                         \
    asm volatile("s_barrier" ::: "memory");                                        \
    asm volatile("s_waitcnt lgkmcnt(0)" ::: "memory");                             \
    __builtin_amdgcn_s_setprio(1);                                                 \
    MFMAS(MH, NH)                                                                  \
    __builtin_amdgcn_s_setprio(0);                                                 \
    VMW                                                                            \
    asm volatile("s_barrier" ::: "memory");                                        \
  }

  // prologue: T0 fully (8 calls) + T1's A-half0, B-half1 (4 calls)
  STA_H(0, 0, 0); STA_H(0, 1, 0); STB_H(0, 0, 0); STB_H(0, 1, 0);
  STA_H(1, 0, 1); STB_H(1, 1, 1);
  asm volatile("s_waitcnt vmcnt(4)" ::: "memory");
  asm volatile("s_barrier" ::: "memory");

  for (int i = 0; i < 7; ++i) {
    const int t1 = 2 * i + 1, t2 = 2 * i + 2, t3 = 2 * i + 3;
    PHASE(0, 0, 0, { STA_H(1, 1, t1); }, {})   // stage par1 A1 <- T(2i+1)
    PHASE(0, 0, 1, { STB_H(1, 0, t1); }, {})   // stage par1 B0
    PHASE(0, 1, 1, { STA_H(0, 0, t2); }, {})   // stage par0 A0 <- T(2i+2)
    PHASE(0, 1, 0, { STB_H(0, 1, t2); }, { asm volatile("s_waitcnt vmcnt(4)" ::: "memory"); })
    PHASE(1, 0, 0, { STA_H(0, 1, t2); }, {})   // stage par0 A1
    PHASE(1, 0, 1, { STB_H(0, 0, t2); }, {})   // stage par0 B0
    PHASE(1, 1, 1, { STA_H(1, 0, t3); }, {})   // stage par1 A0 <- T(2i+3)
    PHASE(1, 1, 0, { STB_H(1, 1, t3); }, { asm volatile("s_waitcnt vmcnt(4)" ::: "memory"); })
  }
  // peeled last iter: tiles 14 (par0), 15 (par1); only T15's A1/B0 remain to stage.
  PHASE(0, 0, 0, { STA_H(1, 1, 15); }, {})
  PHASE(0, 0, 1, { STB_H(1, 0, 15); }, {})
  PHASE(0, 1, 1, {}, {})
  PHASE(0, 1, 0, {}, { asm volatile("s_waitcnt vmcnt(0)" ::: "memory"); })
  PHASE(1, 0, 0, {}, {})
  PHASE(1, 0, 1, {}, {})
  PHASE(1, 1, 1, {}, {})
  PHASE(1, 1, 0, {}, {})

  // epilogue: row = lq*4+reg -> m; col = l16 -> o. (B,C,N) store, 4 consecutive n.
#pragma unroll
  for (int f = 0; f < 8; ++f) {
    const int gmb = (f < 4) ? (wm * 64 + f * 16) : (128 + wm * 64 + (f - 4) * 16);
    const int mg = m0 + gmb + lq * 4;
    const int b  = mg / 80;
    const int n0 = mg - b * 80;
#pragma unroll
    for (int gi = 0; gi < 4; ++gi) {
      const int gnb = (gi < 2) ? (wn * 32 + gi * 16) : (128 + wn * 32 + (gi - 2) * 16);
      const int og = o0 + gnb + l16;
      const size_t off = (size_t)b * CN + (size_t)og * N_ + n0;
      if (out_bf) {
        ushort4 u;
        u.x = f2bf(acc[f][gi][0]); u.y = f2bf(acc[f][gi][1]);
        u.z = f2bf(acc[f][gi][2]); u.w = f2bf(acc[f][gi][3]);
        *(ushort4*)((ushort*)outp + off) = u;
      } else {
        *(f32x4*)((float*)outp + off) = acc[f][gi];
      }
    }
  }
#undef STA
#undef STB
#undef STA_H
#undef STB_H
#undef DSREADS
#undef MFMAS
#undef PHASE
}

// ---------------------------------------------------------------------------
// K2b: dadj MFMA GEMM. A: x2t bf16 (M=20480, K=1024). Bw: Wco2t bf16 (80,1024).
// dadj[b,o,n] = go[b,o] + bco[o] + sum_k A[m=(b,n)][k]*Bw[o][k].
// ---------------------------------------------------------------------------
__global__ __launch_bounds__(256) void k_dadj_mfma(const ushort* __restrict__ A,
                                                   const ushort* __restrict__ Bw,
                                                   const float* __restrict__ go,
                                                   const float* __restrict__ bco,
                                                   float* __restrict__ dadj) {
  __shared__ ushort smA[128 * 32];
  __shared__ ushort smB[80 * 32];
  const int t = threadIdx.x;
  const int lane = t & 63, wid = t >> 6;
  const int m0 = blockIdx.x * 128;
  const int rto = t >> 2, ch = t & 3;
  const size_t gA0 = (size_t)(m0 + rto) * C_ + (size_t)ch * 8;
  ushort* ldsA = smA + wid * 512;
  const int l16 = lane & 15, lq = lane >> 4;
  const int wrow = wid * 32;
  f32x4 zero = {0.f, 0.f, 0.f, 0.f};
  f32x4 acc[2][5];
#pragma unroll
  for (int i = 0; i < 2; ++i)
#pragma unroll
    for (int j = 0; j < 5; ++j) acc[i][j] = zero;
  for (int k0 = 0; k0 < C_; k0 += 32) {
    load_lds16(A + gA0 + k0,            ldsA);
    load_lds16(A + gA0 + 64 * C_ + k0,  ldsA + 2048);
    {
      const int idx = t;                               // 320 chunks of 16B
      uint4 v = *(const uint4*)&Bw[(size_t)(idx >> 2) * C_ + k0 + (idx & 3) * 8];
      *(uint4*)&smB[idx * 8] = v;
      if (t < 64) {
        const int idx2 = 256 + t;
        uint4 v2 = *(const uint4*)&Bw[(size_t)(idx2 >> 2) * C_ + k0 + (idx2 & 3) * 8];
        *(uint4*)&smB[idx2 * 8] = v2;
      }
    }
    __syncthreads();
    bf16x8 af[2], bfr[5];
#pragma unroll
    for (int i = 0; i < 2; ++i) af[i]  = *(const bf16x8*)&smA[(wrow + i * 16 + l16) * 32 + lq * 8];
#pragma unroll
    for (int j = 0; j < 5; ++j) bfr[j] = *(const bf16x8*)&smB[(j * 16 + l16) * 32 + lq * 8];
#pragma unroll
    for (int i = 0; i < 2; ++i)
#pragma unroll
      for (int j = 0; j < 5; ++j)
        acc[i][j] = __builtin_amdgcn_mfma_f32_16x16x32_bf16(af[i], bfr[j], acc[i][j], 0, 0, 0);
    __syncthreads();
  }
#pragma unroll
  for (int i = 0; i < 2; ++i) {
    const int mg = m0 + wrow + i * 16 + lq * 4;
    const int b  = mg / 80;
    const int n0 = mg - b * 80;
    const float* gob = go + b * N_;
#pragma unroll
    for (int j = 0; j < 5; ++j) {
      const int o = j * 16 + l16;
      const float g = gob[o] + bco[o];
      f32x4 v = acc[i][j];
      v[0] += g; v[1] += g; v[2] += g; v[3] += g;
      *(f32x4*)&dadj[(size_t)b * NN + (size_t)o * N_ + n0] = v;
    }
  }
}

// ---------------------------------------------------------------------------
// K2c: glb1 MFMA GEMM. A: glb0_bf (256 x 1024). Bw: Wg_bf (1024 x 1024, K-contig).
// ---------------------------------------------------------------------------
__global__ __launch_bounds__(256) void k_glb_mfma(const ushort* __restrict__ A,
                                                  const ushort* __restrict__ Bw,
                                                  const float* __restrict__ bias,
                                                  float* __restrict__ outp) {
  __shared__ ushort smA[2][64 * 32];
  __shared__ ushort smB[2][64 * 32];
  const int t = threadIdx.x;
  const int lane = t & 63, wid = t >> 6;
  const int o0 = blockIdx.x * 64, m0 = blockIdx.y * 64;
  const int rto = t >> 2, ch = t & 3;
  const size_t gA0 = (size_t)(m0 + rto) * C_ + (size_t)ch * 8;
  const size_t gB0 = (size_t)(o0 + rto) * C_ + (size_t)ch * 8;
  const int l16 = lane & 15, lq = lane >> 4;
  const int wm = wid & 1, wn = wid >> 1;
  f32x4 zero = {0.f, 0.f, 0.f, 0.f};
  f32x4 acc[2][2];
#pragma unroll
  for (int i = 0; i < 2; ++i)
#pragma unroll
    for (int j = 0; j < 2; ++j) acc[i][j] = zero;
  for (int k0 = 0; k0 < C_; k0 += 64) {
    load_lds16(A  + gA0 + k0,       smA[0] + wid * 512);
    load_lds16(A  + gA0 + k0 + 32,  smA[1] + wid * 512);
    load_lds16(Bw + gB0 + k0,       smB[0] + wid * 512);
    load_lds16(Bw + gB0 + k0 + 32,  smB[1] + wid * 512);
    __syncthreads();
#pragma unroll
    for (int h = 0; h < 2; ++h) {
      bf16x8 af[2], bfr[2];
#pragma unroll
      for (int i = 0; i < 2; ++i) af[i]  = *(const bf16x8*)&smA[h][(wm * 32 + i * 16 + l16) * 32 + lq * 8];
#pragma unroll
      for (int j = 0; j < 2; ++j) bfr[j] = *(const bf16x8*)&smB[h][(wn * 32 + j * 16 + l16) * 32 + lq * 8];
#pragma unroll
      for (int i = 0; i < 2; ++i)
#pragma unroll
        for (int j = 0; j < 2; ++j)
          acc[i][j] = __builtin_amdgcn_mfma_f32_16x16x32_bf16(af[i], bfr[j], acc[i][j], 0, 0, 0);
    }
    __syncthreads();
  }
#pragma unroll
  for (int i = 0; i < 2; ++i) {
    const int mg = m0 + wm * 32 + i * 16 + lq * 4;
#pragma unroll
    for (int j = 0; j < 2; ++j) {
      const int og = o0 + wn * 32 + j * 16 + l16;
      const float bs = bias[og];
      f32x4 v = acc[i][j];
#pragma unroll
      for (int r = 0; r < 4; ++r) outp[(size_t)(mg + r) * C_ + og] = v[r] + bs;
    }
  }
}

// ---------------------------------------------------------------------------
// K2d: go MFMA GEMM, split-K x8.  A: glbf_bf (256 x 1024). Bw: Wco1t (80 x 1024).
// ---------------------------------------------------------------------------
__global__ __launch_bounds__(256) void k_go_mfma(const ushort* __restrict__ A,
                                                 const ushort* __restrict__ Bw,
                                                 float* __restrict__ go) {
  __shared__ ushort smA[128 * 32];
  __shared__ ushort smB[80 * 32];
  const int t = threadIdx.x;
  const int lane = t & 63, wid = t >> 6;
  const int kbase = blockIdx.x * 128;
  const int m0 = blockIdx.y * 128;
  const int rto = t >> 2, ch = t & 3;
  const size_t gA0 = (size_t)(m0 + rto) * C_ + (size_t)ch * 8;
  ushort* ldsA = smA + wid * 512;
  const int l16 = lane & 15, lq = lane >> 4;
  const int wrow = wid * 32;
  f32x4 zero = {0.f, 0.f, 0.f, 0.f};
  f32x4 acc[2][5];
#pragma unroll
  for (int i = 0; i < 2; ++i)
#pragma unroll
    for (int j = 0; j < 5; ++j) acc[i][j] = zero;
  for (int kk0 = 0; kk0 < 128; kk0 += 32) {
    const int k0 = kbase + kk0;
    load_lds16(A + gA0 + k0,            ldsA);
    load_lds16(A + gA0 + 64 * C_ + k0,  ldsA + 2048);
    {
      const int idx = t;
      uint4 v = *(const uint4*)&Bw[(size_t)(idx >> 2) * C_ + k0 + (idx & 3) * 8];
      *(uint4*)&smB[idx * 8] = v;
      if (t < 64) {
        const int idx2 = 256 + t;
        uint4 v2 = *(const uint4*)&Bw[(size_t)(idx2 >> 2) * C_ + k0 + (idx2 & 3) * 8];
        *(uint4*)&smB[idx2 * 8] = v2;
      }
    }
    __syncthreads();
    bf16x8 af[2], bfr[5];
#pragma unroll
    for (int i = 0; i < 2; ++i) af[i]  = *(const bf16x8*)&smA[(wrow + i * 16 + l16) * 32 + lq * 8];
#pragma unroll
    for (int j = 0; j < 5; ++j) bfr[j] = *(const bf16x8*)&smB[(j * 16 + l16) * 32 + lq * 8];
#pragma unroll
    for (int i = 0; i < 2; ++i)
#pragma unroll
      for (int j = 0; j < 5; ++j)
        acc[i][j] = __builtin_amdgcn_mfma_f32_16x16x32_bf16(af[i], bfr[j], acc[i][j], 0, 0, 0);
    __syncthreads();
  }
#pragma unroll
  for (int i = 0; i < 2; ++i) {
    const int mg = m0 + wrow + i * 16 + lq * 4;
#pragma unroll
    for (int j = 0; j < 5; ++j) {
      const int o = j * 16 + l16;
#pragma unroll
      for (int r = 0; r < 4; ++r)
        atomicAdd(&go[(size_t)(mg + r) * N_ + o], acc[i][j][r]);
    }
  }
}

// ---------------------------------------------------------------------------
// K3: BN stats per channel over (b,n) — fp32 (B,C,N) input, float4 loads.
// ---------------------------------------------------------------------------
__global__ void k_bn_stats(const float* __restrict__ X, float* __restrict__ mu, float* __restrict__ rstd) {
  const int c = blockIdx.x, t = threadIdx.x;
  const float* base = X + (long)c * N_;
  float s = 0.f, sq = 0.f;
  for (int i4 = t; i4 < BNr / 4; i4 += TPB) {
    const int b = i4 / 20, n0 = (i4 % 20) * 4;
    float4 v = *(const float4*)&base[(long)b * CN + n0];
    s += v.x + v.y + v.z + v.w;
    sq += v.x * v.x + v.y * v.y + v.z * v.z + v.w * v.w;
  }
  __shared__ float rs[TPB], rq[TPB];
  rs[t] = s; rq[t] = sq; __syncthreads();
  for (int o = 128; o > 0; o >>= 1) { if (t < o) { rs[t] += rs[t + o]; rq[t] += rq[t + o]; } __syncthreads(); }
  if (t == 0) {
    const float m = rs[0] / BNr;
    const float var = rq[0] / BNr - m * m;
    mu[c] = m;
    rstd[c] = rsqrtf(var + EPSf);
  }
}

// K3b: same, bf16 (B,C,N) input.
__global__ void k_bn_stats_bf(const ushort* __restrict__ X, float* __restrict__ mu, float* __restrict__ rstd) {
  const int c = blockIdx.x, t = threadIdx.x;
  const ushort* base = X + (long)c * N_;
  float s = 0.f, sq = 0.f;
  for (int i4 = t; i4 < BNr / 4; i4 += TPB) {
    const int b = i4 / 20, n0 = (i4 % 20) * 4;
    ushort4 v = *(const ushort4*)&base[(long)b * CN + n0];
    const float f0 = b2f(v.x), f1 = b2f(v.y), f2 = b2f(v.z), f3 = b2f(v.w);
    s += f0 + f1 + f2 + f3;
    sq += f0 * f0 + f1 * f1 + f2 * f2 + f3 * f3;
  }
  __shared__ float rs[TPB], rq[TPB];
  rs[t] = s; rq[t] = sq; __syncthreads();
  for (int o = 128; o > 0; o >>= 1) { if (t < o) { rs[t] += rs[t + o]; rq[t] += rq[t + o]; } __syncthreads(); }
  if (t == 0) {
    const float m = rs[0] / BNr;
    const float var = rq[0] / BNr - m * m;
    mu[c] = m;
    rstd[c] = rsqrtf(var + EPSf);
  }
}

// ---------------------------------------------------------------------------
// K4f: fused x2 = x + leaky(bn(hT)) ; x2t transpose (bf16, B,N,C) ; glb0 mean.
// One block = one b, 64 c-rows, all 80 n.
// ---------------------------------------------------------------------------
__global__ __launch_bounds__(256) void k_x2_fused(
    const float* __restrict__ x, const ushort* __restrict__ hT,
    const float* __restrict__ g, const float* __restrict__ be,
    const float* __restrict__ mu, const float* __restrict__ rstd,
    float* __restrict__ out, ushort* __restrict__ x2t, ushort* __restrict__ glb0b) {
  __shared__ float s[64][84];
  __shared__ float pg[64], pm[64], pb[64];
  const int t = threadIdx.x;
  const long row0 = (long)blockIdx.x * 64;     // row = b*C + c
  const int b = (int)(row0 >> 10), c0 = (int)(row0 & 1023);
  if (t < 64) {
    const int c = c0 + t;
    pg[t] = g[c] * rstd[c]; pm[t] = mu[c]; pb[t] = be[c];
  }
  __syncthreads();
  const float*  xb = x   + row0 * N_;
  const ushort* hb = hT  + row0 * N_;
  float*        ob = out + row0 * N_;
  for (int i4 = t; i4 < (64 * N_) / 4; i4 += TPB) {
    const int e = i4 * 4, r = e / N_, n = e % N_;
    float4 xv = *(const float4*)&xb[e];
    ushort4 hu = *(const ushort4*)&hb[e];
    const float gm = pg[r], m = pm[r], bb = pb[r];
    float4 o;
    o.x = xv.x + leakyf(gm * (b2f(hu.x) - m) + bb);
    o.y = xv.y + leakyf(gm * (b2f(hu.y) - m) + bb);
    o.z = xv.z + leakyf(gm * (b2f(hu.z) - m) + bb);
    o.w = xv.w + leakyf(gm * (b2f(hu.w) - m) + bb);
    *(float4*)&ob[e] = o;
    *(float4*)&s[r][n] = o;
  }
  __syncthreads();
  // transpose to (B,N,C) bf16
  const int tx = t % 16, ty = t / 16;
  ushort* tb = x2t + (size_t)b * CN + c0 + tx * 4;
#pragma unroll
  for (int u = 0; u < 5; ++u) {
    const int n = ty + 16 * u;
    ushort4 v;
    v.x = f2bf(s[tx * 4 + 0][n]); v.y = f2bf(s[tx * 4 + 1][n]);
    v.z = f2bf(s[tx * 4 + 2][n]); v.w = f2bf(s[tx * 4 + 3][n]);
    *(ushort4*)&tb[(size_t)n * C_] = v;
  }
  // glb0 mean over n
  if (t < 64) {
    float sacc = 0.f;
    for (int n = 0; n < N_; ++n) sacc += s[t][n];
    glb0b[(size_t)b * C_ + c0 + t] = f2bf(sacc * (1.0f / N_));
  }
}

// ---------------------------------------------------------------------------
// K7: BN over batch (256 rows) per channel + leaky -> bf16 out.
// ---------------------------------------------------------------------------
__global__ void k_bng(const float* __restrict__ glb1, const float* __restrict__ gg,
                      const float* __restrict__ gb, ushort* __restrict__ glbf) {
  const int c = blockIdx.x, t = threadIdx.x;
  const float v = glb1[(long)t * C_ + c];
  __shared__ float rs[TPB], rq[TPB];
  rs[t] = v; rq[t] = v * v; __syncthreads();
  for (int o = 128; o > 0; o >>= 1) { if (t < o) { rs[t] += rs[t + o]; rq[t] += rq[t + o]; } __syncthreads(); }
  __shared__ float sm, sr;
  if (t == 0) { const float m = rs[0] / B_; const float var = rq[0] / B_ - m * m; sm = m; sr = rsqrtf(var + EPSf); }
  __syncthreads();
  glbf[(long)t * C_ + c] = f2bf(leakyf(gg[c] * (v - sm) * sr + gb[c]));
}

// ---------------------------------------------------------------------------
// K9/K10: global minmax of dadj (2-pass). Normalization folded into consumers.
// ---------------------------------------------------------------------------
__global__ void k_minmax1(const float* __restrict__ d, float* __restrict__ bmin, float* __restrict__ bmax) {
  const int t = threadIdx.x;
  float lo = 3.4e38f, hi = -3.4e38f;
  for (long i = (long)blockIdx.x * TPB + t; i < BNN; i += (long)512 * TPB) {
    const float v = d[i]; lo = fminf(lo, v); hi = fmaxf(hi, v);
  }
  __shared__ float rl[TPB], rh[TPB];
  rl[t] = lo; rh[t] = hi; __syncthreads();
  for (int o = 128; o > 0; o >>= 1) { if (t < o) { rl[t] = fminf(rl[t], rl[t + o]); rh[t] = fmaxf(rh[t], rh[t + o]); } __syncthreads(); }
  if (t == 0) { bmin[blockIdx.x] = rl[0]; bmax[blockIdx.x] = rh[0]; }
}

__global__ void k_minmax2(const float* __restrict__ bmin, const float* __restrict__ bmax, float* __restrict__ dmm) {
  const int t = threadIdx.x;
  float lo = fminf(bmin[t], bmin[t + 256]);
  float hi = fmaxf(bmax[t], bmax[t + 256]);
  __shared__ float rl[TPB], rh[TPB];
  rl[t] = lo; rh[t] = hi; __syncthreads();
  for (int o = 128; o > 0; o >>= 1) { if (t < o) { rl[t] = fminf(rl[t], rl[t + o]); rh[t] = fmaxf(rh[t], rh[t + o]); } __syncthreads(); }
  if (t == 0) { dmm[0] = rl[0]; dmm[1] = 1.0f / (rh[0] - rl[0]); }
}

// ---------------------------------------------------------------------------
// K12: loss per batch; dadj read RAW, normalized inline via dmm.
// ---------------------------------------------------------------------------
__global__ void k_loss(const float* __restrict__ dadj, const float* __restrict__ sadj,
                       const float* __restrict__ out1, float* __restrict__ lossa,
                       const float* __restrict__ dmm) {
  const int b = blockIdx.x, t = threadIdx.x;
  const float* db = dadj + (long)b * NN;
  const float* o1 = out1 + b * N_;
  const float lo = dmm[0], inv = dmm[1];
  float p2 = 0.f;
  for (int i = t; i < NN; i += TPB) { const float d = (db[i] - lo) * inv - sadj[i]; p2 += d * d; }
  float p1 = 0.f;
  if (t < N_) {
    float acc = 0.f;
    for (int n = 0; n < N_; ++n) acc += o1[n] * ((db[n * N_ + t] - lo) * inv);
    const float d = o1[t] - acc * (1.0f / N_);
    p1 = d * d;
  }
  __shared__ float red[TPB];
  __shared__ float s2;
  red[t] = p2; __syncthreads();
  for (int o = 128; o > 0; o >>= 1) { if (t < o) red[t] += red[t + o]; __syncthreads(); }
  if (t == 0) s2 = red[0];
  __syncthreads();
  red[t] = p1; __syncthreads();
  for (int o = 128; o > 0; o >>= 1) { if (t < o) red[t] += red[t + o]; __syncthreads(); }
  if (t == 0) atomicAdd(lossa, sqrtf(s2) + sqrtf(red[0]));
}

// ---------------------------------------------------------------------------
// K14: final BN + leaky in place on d_out (B,C,N); writes loss scalar.
// ---------------------------------------------------------------------------
__global__ void k_final(float* __restrict__ outp, const float* __restrict__ g, const float* __restrict__ be,
                        const float* __restrict__ mu, const float* __restrict__ rstd,
                        const float* __restrict__ lossa) {
  const long i = ((long)blockIdx.x * TPB + threadIdx.x) * 4;
  const int c = (int)((i / N_) % C_);
  float4 v = *(const float4*)&outp[i];
  const float gm = g[c] * rstd[c], m = mu[c], bb = be[c];
  v.x = leakyf(gm * (v.x - m) + bb);
  v.y = leakyf(gm * (v.y - m) + bb);
  v.z = leakyf(gm * (v.z - m) + bb);
  v.w = leakyf(gm * (v.w - m) + bb);
  *(float4*)&outp[i] = v;
  if (blockIdx.x == 0 && threadIdx.x == 0) outp[BCN] = *lossa;
}

// ---------------------------------------------------------------------------
extern "C" void kernel_launch(void* const* d_in, const int* in_sizes, int n_in,
                              void* d_out, int out_size, void* d_ws, size_t ws_size,
                              hipStream_t stream) {
  const float* x    = (const float*)d_in[0];
  const float* out1 = (const float*)d_in[1];
  const float* ap   = (const float*)d_in[2];
  const float* Ws   = (const float*)d_in[3];
  const float* Wd   = (const float*)d_in[4];
  const float* Wg   = (const float*)d_in[5];
  const float* bg   = (const float*)d_in[6];
  const float* Wco  = (const float*)d_in[7];
  const float* bco  = (const float*)d_in[8];
  const float* bn_g  = (const float*)d_in[9];
  const float* bn_b  = (const float*)d_in[10];
  const float* bng_g = (const float*)d_in[11];
  const float* bng_b = (const float*)d_in[12];
  float* out = (float*)d_out;

  float* w = (float*)d_ws;
  float* sadj  = w;                    // 6400
  float* dadj  = sadj + NN;            // 1638400
  float* glb0  = dadj + BNN;           // 262144 (used as bf16 ushorts)
  float* glb1  = glb0 + B_ * C_;       // 262144
  float* glbf  = glb1 + B_ * C_;       // 262144 (used as bf16 ushorts)
  float* go    = glbf + B_ * C_;       // 20480
  float* mu1   = go + BNr;             // 1024
  float* rstd1 = mu1 + C_;             // 1024
  float* mu2   = rstd1 + C_;           // 1024
  float* rstd2 = mu2 + C_;             // 1024
  float* bmin  = rstd2 + C_;           // 512
  float* bmax  = bmin + 512;           // 512
  float* dmm   = bmax + 512;           // 2
  float* lossa = dmm + 2;              // 1
  ushort* ub   = (ushort*)(((uintptr_t)(lossa + 1) + 255) & ~(uintptr_t)255);
  ushort* xa_bf  = ub;                    // BCN bf16 (B,N,C): fold out / x2t / fold2 out
  ushort* hT_bf  = xa_bf + BCN;           // BCN bf16 (B,C,N)
  ushort* Wts    = hT_bf + BCN;           // 1M bf16 (O,C)
  ushort* Wtd    = Wts + (size_t)C_ * C_; // 1M bf16 (O,C)
  ushort* Wco2t  = Wtd + (size_t)C_ * C_; // 80K bf16 (80,1024)
  ushort* adj_bf = Wco2t + (size_t)N_ * C_; // 80x96 bf16 prepadded
  // bf16 aliases in regions dead at time of use:
  ushort* Wg_bf   = (ushort*)dadj;                      // 1M ushorts; dadj written later
  ushort* Wco1t   = (ushort*)dadj + (size_t)C_ * C_;    // 80K ushorts, same region
  ushort* glb0_bf = (ushort*)glb0;
  ushort* glbf_bf = (ushort*)glbf;
  ushort* x2t_bf  = xa_bf;                              // xa dead after GEMM#1; x2t dead before fold#2

  // ---- prep ----
  k_prep_adj<<<1, TPB, 0, stream>>>(ap, sadj, adj_bf, lossa);
  k_w_bf_t<<<dim3(32, 32), TPB, 0, stream>>>(Ws, Wts);
  k_w_bf_t<<<dim3(32, 32), TPB, 0, stream>>>(Wd, Wtd);
  k_wco_bf<<<(N_ * 2 * C_) / (4 * TPB), TPB, 0, stream>>>(Wco, Wco1t, Wco2t);
  k_cvt_bf<<<(C_ * C_) / (4 * TPB), TPB, 0, stream>>>(Wg, Wg_bf);
  k_zero_go<<<BNr / (4 * TPB), TPB, 0, stream>>>(go);

  // ---- static GCN ----
  k_fold_mfma<<<B_ * 8, TPB, 0, stream>>>(x, adj_bf, xa_bf, 0, dmm);
  k_gemm_256<<<320, 512, 0, stream>>>(xa_bf, Wts, hT_bf, 1);
  k_bn_stats_bf<<<C_, TPB, 0, stream>>>(hT_bf, mu1, rstd1);
  k_x2_fused<<<(B_ * C_) / 64, TPB, 0, stream>>>(x, hT_bf, bn_g, bn_b, mu1, rstd1,
                                                 out, x2t_bf, glb0_bf);

  // ---- dynamic graph construction ----
  k_glb_mfma<<<dim3(C_ / 64, B_ / 64), TPB, 0, stream>>>(glb0_bf, Wg_bf, bg, glb1);
  k_bng<<<C_, TPB, 0, stream>>>(glb1, bng_g, bng_b, glbf_bf);
  k_go_mfma<<<dim3(8, B_ / 128), TPB, 0, stream>>>(glbf_bf, Wco1t, go);
  k_dadj_mfma<<<BNr / 128, TPB, 0, stream>>>(x2t_bf, Wco2t, go, bco, dadj);
  k_minmax1<<<512, TPB, 0, stream>>>(dadj, bmin, bmax);
  k_minmax2<<<1, TPB, 0, stream>>>(bmin, bmax, dmm);

  // ---- adjacency loss (reads raw dadj + dmm) ----
  k_loss<<<B_, TPB, 0, stream>>>(dadj, sadj, out1, lossa, dmm);

  // ---- dynamic GCN (fold normalizes dadj inline via dmm) ----
  k_fold_mfma<<<B_ * 8, TPB, 0, stream>>>(out, dadj, xa_bf, 1, dmm);
  k_gemm_256<<<320, 512, 0, stream>>>(xa_bf, Wtd, out, 0);
  k_bn_stats<<<C_, TPB, 0, stream>>>(out, mu2, rstd2);
  k_final<<<(int)(BCN / (4 * TPB)), TPB, 0, stream>>>(out, bn_g, bn_b, mu2, rstd2, lossa);
}

// Round 3
// 598.602 us; speedup vs baseline: 1.1639x; 1.1639x over previous
//
#include <hip/hip_runtime.h>
#include <hip/hip_bf16.h>
#include <math.h>

#define TPB 256

constexpr int   B_  = 256;
constexpr int   C_  = 1024;
constexpr int   N_  = 80;
constexpr int   BNr = B_ * N_;                 // 20480 rows for BN / GEMM M
constexpr int   CN  = C_ * N_;                 // 81920
constexpr long  BCN = (long)B_ * C_ * N_;      // 20971520
constexpr int   NN  = N_ * N_;                 // 6400
constexpr int   BNN = B_ * NN;                 // 1638400
constexpr float EPSf = 1e-5f;

typedef __bf16 bf16x8 __attribute__((ext_vector_type(8)));
typedef float  f32x4  __attribute__((ext_vector_type(4)));

__device__ __forceinline__ float leakyf(float v) { return v >= 0.0f ? v : 0.2f * v; }

__device__ __forceinline__ ushort f2bf(float f) {
  __hip_bfloat16 h = __float2bfloat16(f);
  ushort u; __builtin_memcpy(&u, &h, 2); return u;
}
__device__ __forceinline__ float b2f(ushort u) {
  __hip_bfloat16 h; __builtin_memcpy(&h, &u, 2);
  return __bfloat162float(h);
}

#define GLOBAL_AS __attribute__((address_space(1)))
#define LDS_AS    __attribute__((address_space(3)))
__device__ __forceinline__ void load_lds16(const void* g, void* l) {
  __builtin_amdgcn_global_load_lds((const GLOBAL_AS void*)g, (LDS_AS void*)l, 16, 0, 0);
}

// ---------------------------------------------------------------------------
// K0: sadj = minmax(adj_param); D = rsqrt(rowsum);
// adj_bf[n*96+m] = bf16(D[n]*sadj[m,n]*D[m]) for m<80, 0 for m in [80,96).
// ---------------------------------------------------------------------------
__global__ void k_prep_adj(const float* __restrict__ ap, float* __restrict__ sadj,
                           ushort* __restrict__ adj_bf, float* __restrict__ lossa) {
  __shared__ float s[NN];
  __shared__ float red[TPB];
  __shared__ float s_lo, s_hi;
  __shared__ float sD[N_];
  const int t = threadIdx.x;
  float lo = 3.4e38f, hi = -3.4e38f;
  for (int i = t; i < NN; i += TPB) { float v = ap[i]; s[i] = v; lo = fminf(lo, v); hi = fmaxf(hi, v); }
  red[t] = lo; __syncthreads();
  for (int o = 128; o > 0; o >>= 1) { if (t < o) red[t] = fminf(red[t], red[t + o]); __syncthreads(); }
  if (t == 0) s_lo = red[0];
  __syncthreads();
  red[t] = hi; __syncthreads();
  for (int o = 128; o > 0; o >>= 1) { if (t < o) red[t] = fmaxf(red[t], red[t + o]); __syncthreads(); }
  if (t == 0) s_hi = red[0];
  __syncthreads();
  const float inv = 1.0f / (s_hi - s_lo);
  for (int i = t; i < NN; i += TPB) { float v = (s[i] - s_lo) * inv; s[i] = v; sadj[i] = v; }
  __syncthreads();
  if (t < N_) { float sum = 0.f; for (int m = 0; m < N_; ++m) sum += s[t * N_ + m]; sD[t] = rsqrtf(sum); }
  if (t == 0) *lossa = 0.0f;
  __syncthreads();
  for (int i = t; i < N_ * 96; i += TPB) {
    const int n = i / 96, m = i % 96;
    adj_bf[i] = f2bf((m < N_) ? sD[n] * s[m * N_ + n] * sD[m] : 0.0f);
  }
}

// ---------------------------------------------------------------------------
// KW: Wt[o][c] = bf16(W[c][o]) — transpose + convert, 32x32 LDS tiles.
// ---------------------------------------------------------------------------
__global__ void k_w_bf_t(const float* __restrict__ W, ushort* __restrict__ Wt) {
  __shared__ float s[32][33];
  const int t = threadIdx.x;
  const int tx = t % 32, ty = t / 32;            // 8 rows per pass
  const int r0 = blockIdx.y * 32, c0 = blockIdx.x * 32;
#pragma unroll
  for (int k = 0; k < 4; ++k) s[ty + 8 * k][tx] = W[(size_t)(r0 + ty + 8 * k) * C_ + c0 + tx];
  __syncthreads();
#pragma unroll
  for (int k = 0; k < 4; ++k) Wt[(size_t)(c0 + ty + 8 * k) * C_ + r0 + tx] = f2bf(s[tx][ty + 8 * k]);
}

// ---------------------------------------------------------------------------
// KW2: split Wco (80 x 2048) into two bf16 (80 x 1024) K-major buffers.
// ---------------------------------------------------------------------------
__global__ void k_wco_bf(const float* __restrict__ Wco, ushort* __restrict__ Wco1t,
                         ushort* __restrict__ Wco2t) {
  const int i4 = (blockIdx.x * TPB + threadIdx.x) * 4;   // 80*2048 elems
  const int o = i4 >> 11, k = i4 & 2047;
  float4 v = *(const float4*)&Wco[(size_t)o * 2048 + k];
  ushort4 u;
  u.x = f2bf(v.x); u.y = f2bf(v.y); u.z = f2bf(v.z); u.w = f2bf(v.w);
  if (k < C_) *(ushort4*)&Wco1t[(size_t)o * C_ + k] = u;
  else        *(ushort4*)&Wco2t[(size_t)o * C_ + (k - C_)] = u;
}

// ---------------------------------------------------------------------------
// KW3: plain fp32 -> bf16 elementwise convert (for Wg, already o-major/K-contig).
// ---------------------------------------------------------------------------
__global__ void k_cvt_bf(const float* __restrict__ W, ushort* __restrict__ Wb) {
  const long i4 = ((long)blockIdx.x * TPB + threadIdx.x) * 4;
  float4 v = *(const float4*)&W[i4];
  ushort4 u;
  u.x = f2bf(v.x); u.y = f2bf(v.y); u.z = f2bf(v.z); u.w = f2bf(v.w);
  *(ushort4*)&Wb[i4] = u;
}

// K-zero: go accumulator (20480 floats).
__global__ void k_zero_go(float* __restrict__ go) {
  const int i = (blockIdx.x * TPB + threadIdx.x) * 4;
  float4 z = make_float4(0.f, 0.f, 0.f, 0.f);
  *(float4*)&go[i] = z;
}

// ---------------------------------------------------------------------------
// K1v3: MFMA fold.  out[(b*80+n)*1024 + c] (bf16, B,N,C) =
//   sum_m adj[n,m] * X[b, c, m]       (X fp32 in B,C,N layout)
// mode 0: adjsrc = adj_bf global (80x96 bf16, prepadded).
// mode 1: adjsrc = dadj RAW fp32 (B,80,80); normalized by dmm, tadj in LDS.
// ---------------------------------------------------------------------------
__global__ __launch_bounds__(256) void k_fold_mfma(const float* __restrict__ X,
                                                   const void* __restrict__ adjsrc,
                                                   ushort* __restrict__ outp, int mode,
                                                   const float* __restrict__ dmm) {
  __shared__ __align__(16) ushort sX[128][104];     // rows c, cols m (pad->104, b128 2-way free)
  __shared__ __align__(16) ushort sAdj[80][104];    // rows n, cols m
  __shared__ float sD[N_];
  const int t = threadIdx.x;
  const int b  = blockIdx.x >> 3;
  const int c0 = (blockIdx.x & 7) * 128;

  // ---- adjacency -> sAdj (bf16, m 80..95 zero) ----
  if (mode == 0) {
    const ushort* ab = (const ushort*)adjsrc;
    for (int i = t; i < (N_ * 96) / 4; i += TPB) {
      ushort4 v = *(const ushort4*)&ab[i * 4];
      *(ushort4*)&sAdj[(i * 4) / 96][(i * 4) % 96] = v;
    }
    __syncthreads();
  } else {
    float* sF = (float*)&sX[0][0];                  // 80*80 fp32 = 25.6KB <= sX
    const float* db = (const float*)adjsrc + (size_t)b * NN;
    const float lo = dmm[0], inv = dmm[1];
    for (int i = t; i < NN / 4; i += TPB) {
      float4 v = *(const float4*)&db[i * 4];
      v.x = (v.x - lo) * inv; v.y = (v.y - lo) * inv;
      v.z = (v.z - lo) * inv; v.w = (v.w - lo) * inv;
      *(float4*)&sF[i * 4] = v;
    }
    __syncthreads();
    if (t < N_) { float s = 0.f; for (int m = 0; m < N_; ++m) s += sF[t * N_ + m]; sD[t] = rsqrtf(s); }
    __syncthreads();
    for (int i = t; i < N_ * 96; i += TPB) {
      const int n = i / 96, m = i % 96;
      sAdj[n][m] = f2bf((m < N_) ? sF[m * N_ + n] * sD[n] * sD[m] : 0.0f);
    }
    __syncthreads();                                 // before sX overwrite
  }

  // ---- stage X (128 rows x 80 m) fp32 -> bf16; zero pad m 80..95 ----
  const float* Xb = X + ((size_t)b * C_ + c0) * N_;
  for (int i = t; i < (128 * N_) / 4; i += TPB) {
    float4 v = *(const float4*)&Xb[i * 4];
    const int r = (i * 4) / N_, m = (i * 4) % N_;
    ushort4 u; u.x = f2bf(v.x); u.y = f2bf(v.y); u.z = f2bf(v.z); u.w = f2bf(v.w);
    *(ushort4*)&sX[r][m] = u;
  }
  for (int i = t; i < (128 * 16) / 4; i += TPB) {
    const int r = i / 4, m = 80 + (i % 4) * 4;
    ushort4 z; z.x = 0; z.y = 0; z.z = 0; z.w = 0;
    *(ushort4*)&sX[r][m] = z;
  }
  __syncthreads();

  const int lane = t & 63, wid = t >> 6;
  const int l16 = lane & 15, lq = lane >> 4;
  f32x4 acc[2][5];
#pragma unroll
  for (int i = 0; i < 2; ++i)
#pragma unroll
    for (int j = 0; j < 5; ++j) { f32x4 z = {0.f, 0.f, 0.f, 0.f}; acc[i][j] = z; }
  bf16x8 af[2][3], bfr[5][3];
#pragma unroll
  for (int i = 0; i < 2; ++i)
#pragma unroll
    for (int kk = 0; kk < 3; ++kk)
      af[i][kk] = *(const bf16x8*)&sX[wid * 32 + i * 16 + l16][kk * 32 + lq * 8];
#pragma unroll
  for (int j = 0; j < 5; ++j)
#pragma unroll
    for (int kk = 0; kk < 3; ++kk)
      bfr[j][kk] = *(const bf16x8*)&sAdj[j * 16 + l16][kk * 32 + lq * 8];
#pragma unroll
  for (int i = 0; i < 2; ++i)
#pragma unroll
    for (int j = 0; j < 5; ++j)
#pragma unroll
      for (int kk = 0; kk < 3; ++kk)
        acc[i][j] = __builtin_amdgcn_mfma_f32_16x16x32_bf16(af[i][kk], bfr[j][kk], acc[i][j], 0, 0, 0);

  // ---- epilogue: D[row=c_local (lq*4+reg)][col=n (l16)] -> (B,N,C) ushort4 ----
  ushort* ob = outp + (size_t)b * CN;
#pragma unroll
  for (int i = 0; i < 2; ++i) {
    const int c = c0 + wid * 32 + i * 16 + lq * 4;
#pragma unroll
    for (int j = 0; j < 5; ++j) {
      const int n = j * 16 + l16;
      ushort4 u;
      u.x = f2bf(acc[i][j][0]); u.y = f2bf(acc[i][j][1]);
      u.z = f2bf(acc[i][j][2]); u.w = f2bf(acc[i][j][3]);
      *(ushort4*)&ob[(size_t)n * C_ + c] = u;
    }
  }
}

// ---------------------------------------------------------------------------
// K2: 256x256x64 8-phase counted-vmcnt MFMA GEMM (T2+T3+T4+T5).
// A: 20480 x 1024 bf16 row-major. Bt: 1024 x 1024 bf16 row-major.
// out[b, o, n] (B,C,N) = sum_k A[m=(b,n)][k] * Bt[o][k];  out_bf: 1 -> bf16.
// T2 swizzle (rule 21: both-sides-or-neither with global_load_lds):
//   LDS dest stays LINEAR; global SOURCE 16B-slot is pre-permuted
//   slot ^= (row&7); ds_read applies the same involution
//   slot' = (kk*4+lq) ^ (l16&7).  Each b128 then spreads 64 lanes evenly
//   over all 8 slots (8 lanes / 4-bank quad = the 1024B/instr floor).
// XCD map: xcd gets contiguous 10-tm chunk x all 4 tn (B 2MB + A-panel
//   512KB both L2-resident per XCD).
// ---------------------------------------------------------------------------
__global__ __launch_bounds__(512, 2) void k_gemm_256(const ushort* __restrict__ A,
                                                     const ushort* __restrict__ Bt,
                                                     void* __restrict__ outp, int out_bf) {
  __shared__ ushort sA[2][256 * 64];   // 64 KB
  __shared__ ushort sB[2][256 * 64];   // 64 KB
  const int t = threadIdx.x;
  const int lane = t & 63, wid = t >> 6;       // 8 waves
  const int wm = wid >> 2, wn = wid & 3;       // 2 x 4
  const int l16 = lane & 15, lq = lane >> 4;

  // XCD-chunked swizzle: 320 blocks; each XCD: tm in [xcd*10, xcd*10+10), tn 0..3.
  const int lin = blockIdx.x;
  const int xcd = lin & 7, bi = lin >> 3;      // bi in 0..39
  const int tm = xcd * 10 + (bi >> 2);
  const int tn = bi & 3;
  const int m0 = tm * 256, o0 = tn * 256;

  // staging coords: thread t stages row (rowbase + t>>3); source 16B-slot is
  // pre-swizzled so the linear LDS write lands swizzled data.
  const int srow = t >> 3;
  const int sswz = ((t & 7) ^ ((t >> 3) & 7)) * 8;   // elems

  f32x4 acc[8][4];
#pragma unroll
  for (int i = 0; i < 8; ++i)
#pragma unroll
    for (int j = 0; j < 4; ++j) { f32x4 z = {0.f, 0.f, 0.f, 0.f}; acc[i][j] = z; }

  // one call stages 64 rows x 64 cols (8KB): per-wave linear LDS dest.
#define STA(PAR, ROWB, KT) load_lds16(A  + (size_t)(m0 + (ROWB) + srow) * C_ + (KT) * 64 + sswz, \
                                      &sA[PAR][((ROWB) + (wid << 3)) * 64])
#define STB(PAR, ROWB, KT) load_lds16(Bt + (size_t)(o0 + (ROWB) + srow) * C_ + (KT) * 64 + sswz, \
                                      &sB[PAR][((ROWB) + (wid << 3)) * 64])
#define STA_H(PAR, H, KT) { STA(PAR, (H)*128, KT); STA(PAR, (H)*128 + 64, KT); }
#define STB_H(PAR, H, KT) { STB(PAR, (H)*128, KT); STB(PAR, (H)*128 + 64, KT); }

#define DSREADS(PAR, MH, NH)                                                            \
  _Pragma("unroll") for (int fi = 0; fi < 4; ++fi) {                                    \
    const int row = ((MH) ? 128 : 0) + wm * 64 + fi * 16 + l16;                         \
    _Pragma("unroll") for (int kk = 0; kk < 2; ++kk)                                    \
      afr[fi][kk] = *(const bf16x8*)&sA[PAR][row * 64 + ((kk * 4 + lq) ^ (l16 & 7)) * 8]; \
  }                                                                                     \
  _Pragma("unroll") for (int gi = 0; gi < 2; ++gi) {                                    \
    const int row = ((NH) ? 128 : 0) + wn * 32 + gi * 16 + l16;                         \
    _Pragma("unroll") for (int kk = 0; kk < 2; ++kk)                                    \
      bfr[gi][kk] = *(const bf16x8*)&sB[PAR][row * 64 + ((kk * 4 + lq) ^ (l16 & 7)) * 8]; \
  }

#define MFMAS(MH, NH)                                                              \
  _Pragma("unroll") for (int kk = 0; kk < 2; ++kk)                                 \
  _Pragma("unroll") for (int fi = 0; fi < 4; ++fi)                                 \
  _Pragma("unroll") for (int gi = 0; gi < 2; ++gi)                                 \
    acc[(MH) * 4 + fi][(NH) * 2 + gi] = __builtin_amdgcn_mfma_f32_16x16x32_bf16(   \
        afr[fi][kk], bfr[gi][kk], acc[(MH) * 4 + fi][(NH) * 2 + gi], 0, 0, 0);

#define PHASE(PAR, MH, NH, STAGES, VMW)                                            \
  {                                                                                \
    bf16x8 afr[4][2], bfr[2][2];                                                   \
    DSREADS(PAR, MH, NH)                                                           \
    STAGES                                                                         \
    asm volatile("s_barrier" ::: "memory");                                        \
    asm volatile("s_waitcnt lgkmcnt(0)" ::: "memory");                             \
    __builtin_amdgcn_s_setprio(1);                                                 \
    MFMAS(MH, NH)                                                                  \
    __builtin_amdgcn_s_setprio(0);                                                 \
    VMW                                                                            \
    asm volatile("s_barrier" ::: "memory");                                        \
  }

  // prologue: T0 fully (8 calls) + T1's A-half0, B-half1 (4 calls)
  STA_H(0, 0, 0); STA_H(0, 1, 0); STB_H(0, 0, 0); STB_H(0, 1, 0);
  STA_H(1, 0, 1); STB_H(1, 1, 1);
  asm volatile("s_waitcnt vmcnt(4)" ::: "memory");
  asm volatile("s_barrier" ::: "memory");

  for (int i = 0; i < 7; ++i) {
    const int t1 = 2 * i + 1, t2 = 2 * i + 2, t3 = 2 * i + 3;
    PHASE(0, 0, 0, { STA_H(1, 1, t1); }, {})   // stage par1 A1 <- T(2i+1)
    PHASE(0, 0, 1, { STB_H(1, 0, t1); }, {})   // stage par1 B0
    PHASE(0, 1, 1, { STA_H(0, 0, t2); }, {})   // stage par0 A0 <- T(2i+2)
    PHASE(0, 1, 0, { STB_H(0, 1, t2); }, { asm volatile("s_waitcnt vmcnt(4)" ::: "memory"); })
    PHASE(1, 0, 0, { STA_H(0, 1, t2); }, {})   // stage par0 A1
    PHASE(1, 0, 1, { STB_H(0, 0, t2); }, {})   // stage par0 B0
    PHASE(1, 1, 1, { STA_H(1, 0, t3); }, {})   // stage par1 A0 <- T(2i+3)
    PHASE(1, 1, 0, { STB_H(1, 1, t3); }, { asm volatile("s_waitcnt vmcnt(4)" ::: "memory"); })
  }
  // peeled last iter: tiles 14 (par0), 15 (par1); only T15's A1/B0 remain to stage.
  PHASE(0, 0, 0, { STA_H(1, 1, 15); }, {})
  PHASE(0, 0, 1, { STB_H(1, 0, 15); }, {})
  PHASE(0, 1, 1, {}, {})
  PHASE(0, 1, 0, {}, { asm volatile("s_waitcnt vmcnt(0)" ::: "memory"); })
  PHASE(1, 0, 0, {}, {})
  PHASE(1, 0, 1, {}, {})
  PHASE(1, 1, 1, {}, {})
  PHASE(1, 1, 0, {}, {})

  // epilogue: row = lq*4+reg -> m; col = l16 -> o. (B,C,N) store, 4 consecutive n.
#pragma unroll
  for (int f = 0; f < 8; ++f) {
    const int gmb = (f < 4) ? (wm * 64 + f * 16) : (128 + wm * 64 + (f - 4) * 16);
    const int mg = m0 + gmb + lq * 4;
    const int b  = mg / 80;
    const int n0 = mg - b * 80;
#pragma unroll
    for (int gi = 0; gi < 4; ++gi) {
      const int gnb = (gi < 2) ? (wn * 32 + gi * 16) : (128 + wn * 32 + (gi - 2) * 16);
      const int og = o0 + gnb + l16;
      const size_t off = (size_t)b * CN + (size_t)og * N_ + n0;
      if (out_bf) {
        ushort4 u;
        u.x = f2bf(acc[f][gi][0]); u.y = f2bf(acc[f][gi][1]);
        u.z = f2bf(acc[f][gi][2]); u.w = f2bf(acc[f][gi][3]);
        *(ushort4*)((ushort*)outp + off) = u;
      } else {
        *(f32x4*)((float*)outp + off) = acc[f][gi];
      }
    }
  }
#undef STA
#undef STB
#undef STA_H
#undef STB_H
#undef DSREADS
#undef MFMAS
#undef PHASE
}

// ---------------------------------------------------------------------------
// K2b: dadj MFMA GEMM. A: x2t bf16 (M=20480, K=1024). Bw: Wco2t bf16 (80,1024).
// dadj[b,o,n] = go[b,o] + bco[o] + sum_k A[m=(b,n)][k]*Bw[o][k].
// ---------------------------------------------------------------------------
__global__ __launch_bounds__(256) void k_dadj_mfma(const ushort* __restrict__ A,
                                                   const ushort* __restrict__ Bw,
                                                   const float* __restrict__ go,
                                                   const float* __restrict__ bco,
                                                   float* __restrict__ dadj) {
  __shared__ ushort smA[128 * 32];
  __shared__ ushort smB[80 * 32];
  const int t = threadIdx.x;
  const int lane = t & 63, wid = t >> 6;
  const int m0 = blockIdx.x * 128;
  const int rto = t >> 2, ch = t & 3;
  const size_t gA0 = (size_t)(m0 + rto) * C_ + (size_t)ch * 8;
  ushort* ldsA = smA + wid * 512;
  const int l16 = lane & 15, lq = lane >> 4;
  const int wrow = wid * 32;
  f32x4 zero = {0.f, 0.f, 0.f, 0.f};
  f32x4 acc[2][5];
#pragma unroll
  for (int i = 0; i < 2; ++i)
#pragma unroll
    for (int j = 0; j < 5; ++j) acc[i][j] = zero;
  for (int k0 = 0; k0 < C_; k0 += 32) {
    load_lds16(A + gA0 + k0,            ldsA);
    load_lds16(A + gA0 + 64 * C_ + k0,  ldsA + 2048);
    {
      const int idx = t;                               // 320 chunks of 16B
      uint4 v = *(const uint4*)&Bw[(size_t)(idx >> 2) * C_ + k0 + (idx & 3) * 8];
      *(uint4*)&smB[idx * 8] = v;
      if (t < 64) {
        const int idx2 = 256 + t;
        uint4 v2 = *(const uint4*)&Bw[(size_t)(idx2 >> 2) * C_ + k0 + (idx2 & 3) * 8];
        *(uint4*)&smB[idx2 * 8] = v2;
      }
    }
    __syncthreads();
    bf16x8 af[2], bfr[5];
#pragma unroll
    for (int i = 0; i < 2; ++i) af[i]  = *(const bf16x8*)&smA[(wrow + i * 16 + l16) * 32 + lq * 8];
#pragma unroll
    for (int j = 0; j < 5; ++j) bfr[j] = *(const bf16x8*)&smB[(j * 16 + l16) * 32 + lq * 8];
#pragma unroll
    for (int i = 0; i < 2; ++i)
#pragma unroll
      for (int j = 0; j < 5; ++j)
        acc[i][j] = __builtin_amdgcn_mfma_f32_16x16x32_bf16(af[i], bfr[j], acc[i][j], 0, 0, 0);
    __syncthreads();
  }
#pragma unroll
  for (int i = 0; i < 2; ++i) {
    const int mg = m0 + wrow + i * 16 + lq * 4;
    const int b  = mg / 80;
    const int n0 = mg - b * 80;
    const float* gob = go + b * N_;
#pragma unroll
    for (int j = 0; j < 5; ++j) {
      const int o = j * 16 + l16;
      const float g = gob[o] + bco[o];
      f32x4 v = acc[i][j];
      v[0] += g; v[1] += g; v[2] += g; v[3] += g;
      *(f32x4*)&dadj[(size_t)b * NN + (size_t)o * N_ + n0] = v;
    }
  }
}

// ---------------------------------------------------------------------------
// K2c: glb1 MFMA GEMM. A: glb0_bf (256 x 1024). Bw: Wg_bf (1024 x 1024, K-contig).
// ---------------------------------------------------------------------------
__global__ __launch_bounds__(256) void k_glb_mfma(const ushort* __restrict__ A,
                                                  const ushort* __restrict__ Bw,
                                                  const float* __restrict__ bias,
                                                  float* __restrict__ outp) {
  __shared__ ushort smA[2][64 * 32];
  __shared__ ushort smB[2][64 * 32];
  const int t = threadIdx.x;
  const int lane = t & 63, wid = t >> 6;
  const int o0 = blockIdx.x * 64, m0 = blockIdx.y * 64;
  const int rto = t >> 2, ch = t & 3;
  const size_t gA0 = (size_t)(m0 + rto) * C_ + (size_t)ch * 8;
  const size_t gB0 = (size_t)(o0 + rto) * C_ + (size_t)ch * 8;
  const int l16 = lane & 15, lq = lane >> 4;
  const int wm = wid & 1, wn = wid >> 1;
  f32x4 zero = {0.f, 0.f, 0.f, 0.f};
  f32x4 acc[2][2];
#pragma unroll
  for (int i = 0; i < 2; ++i)
#pragma unroll
    for (int j = 0; j < 2; ++j) acc[i][j] = zero;
  for (int k0 = 0; k0 < C_; k0 += 64) {
    load_lds16(A  + gA0 + k0,       smA[0] + wid * 512);
    load_lds16(A  + gA0 + k0 + 32,  smA[1] + wid * 512);
    load_lds16(Bw + gB0 + k0,       smB[0] + wid * 512);
    load_lds16(Bw + gB0 + k0 + 32,  smB[1] + wid * 512);
    __syncthreads();
#pragma unroll
    for (int h = 0; h < 2; ++h) {
      bf16x8 af[2], bfr[2];
#pragma unroll
      for (int i = 0; i < 2; ++i) af[i]  = *(const bf16x8*)&smA[h][(wm * 32 + i * 16 + l16) * 32 + lq * 8];
#pragma unroll
      for (int j = 0; j < 2; ++j) bfr[j] = *(const bf16x8*)&smB[h][(wn * 32 + j * 16 + l16) * 32 + lq * 8];
#pragma unroll
      for (int i = 0; i < 2; ++i)
#pragma unroll
        for (int j = 0; j < 2; ++j)
          acc[i][j] = __builtin_amdgcn_mfma_f32_16x16x32_bf16(af[i], bfr[j], acc[i][j], 0, 0, 0);
    }
    __syncthreads();
  }
#pragma unroll
  for (int i = 0; i < 2; ++i) {
    const int mg = m0 + wm * 32 + i * 16 + lq * 4;
#pragma unroll
    for (int j = 0; j < 2; ++j) {
      const int og = o0 + wn * 32 + j * 16 + l16;
      const float bs = bias[og];
      f32x4 v = acc[i][j];
#pragma unroll
      for (int r = 0; r < 4; ++r) outp[(size_t)(mg + r) * C_ + og] = v[r] + bs;
    }
  }
}

// ---------------------------------------------------------------------------
// K2d: go MFMA GEMM, split-K x8.  A: glbf_bf (256 x 1024). Bw: Wco1t (80 x 1024).
// ---------------------------------------------------------------------------
__global__ __launch_bounds__(256) void k_go_mfma(const ushort* __restrict__ A,
                                                 const ushort* __restrict__ Bw,
                                                 float* __restrict__ go) {
  __shared__ ushort smA[128 * 32];
  __shared__ ushort smB[80 * 32];
  const int t = threadIdx.x;
  const int lane = t & 63, wid = t >> 6;
  const int kbase = blockIdx.x * 128;
  const int m0 = blockIdx.y * 128;
  const int rto = t >> 2, ch = t & 3;
  const size_t gA0 = (size_t)(m0 + rto) * C_ + (size_t)ch * 8;
  ushort* ldsA = smA + wid * 512;
  const int l16 = lane & 15, lq = lane >> 4;
  const int wrow = wid * 32;
  f32x4 zero = {0.f, 0.f, 0.f, 0.f};
  f32x4 acc[2][5];
#pragma unroll
  for (int i = 0; i < 2; ++i)
#pragma unroll
    for (int j = 0; j < 5; ++j) acc[i][j] = zero;
  for (int kk0 = 0; kk0 < 128; kk0 += 32) {
    const int k0 = kbase + kk0;
    load_lds16(A + gA0 + k0,            ldsA);
    load_lds16(A + gA0 + 64 * C_ + k0,  ldsA + 2048);
    {
      const int idx = t;
      uint4 v = *(const uint4*)&Bw[(size_t)(idx >> 2) * C_ + k0 + (idx & 3) * 8];
      *(uint4*)&smB[idx * 8] = v;
      if (t < 64) {
        const int idx2 = 256 + t;
        uint4 v2 = *(const uint4*)&Bw[(size_t)(idx2 >> 2) * C_ + k0 + (idx2 & 3) * 8];
        *(uint4*)&smB[idx2 * 8] = v2;
      }
    }
    __syncthreads();
    bf16x8 af[2], bfr[5];
#pragma unroll
    for (int i = 0; i < 2; ++i) af[i]  = *(const bf16x8*)&smA[(wrow + i * 16 + l16) * 32 + lq * 8];
#pragma unroll
    for (int j = 0; j < 5; ++j) bfr[j] = *(const bf16x8*)&smB[(j * 16 + l16) * 32 + lq * 8];
#pragma unroll
    for (int i = 0; i < 2; ++i)
#pragma unroll
      for (int j = 0; j < 5; ++j)
        acc[i][j] = __builtin_amdgcn_mfma_f32_16x16x32_bf16(af[i], bfr[j], acc[i][j], 0, 0, 0);
    __syncthreads();
  }
#pragma unroll
  for (int i = 0; i < 2; ++i) {
    const int mg = m0 + wrow + i * 16 + lq * 4;
#pragma unroll
    for (int j = 0; j < 5; ++j) {
      const int o = j * 16 + l16;
#pragma unroll
      for (int r = 0; r < 4; ++r)
        atomicAdd(&go[(size_t)(mg + r) * N_ + o], acc[i][j][r]);
    }
  }
}

// ---------------------------------------------------------------------------
// K3: BN stats per channel over (b,n) — fp32 (B,C,N) input, float4 loads.
// ---------------------------------------------------------------------------
__global__ void k_bn_stats(const float* __restrict__ X, float* __restrict__ mu, float* __restrict__ rstd) {
  const int c = blockIdx.x, t = threadIdx.x;
  const float* base = X + (long)c * N_;
  float s = 0.f, sq = 0.f;
  for (int i4 = t; i4 < BNr / 4; i4 += TPB) {
    const int b = i4 / 20, n0 = (i4 % 20) * 4;
    float4 v = *(const float4*)&base[(long)b * CN + n0];
    s += v.x + v.y + v.z + v.w;
    sq += v.x * v.x + v.y * v.y + v.z * v.z + v.w * v.w;
  }
  __shared__ float rs[TPB], rq[TPB];
  rs[t] = s; rq[t] = sq; __syncthreads();
  for (int o = 128; o > 0; o >>= 1) { if (t < o) { rs[t] += rs[t + o]; rq[t] += rq[t + o]; } __syncthreads(); }
  if (t == 0) {
    const float m = rs[0] / BNr;
    const float var = rq[0] / BNr - m * m;
    mu[c] = m;
    rstd[c] = rsqrtf(var + EPSf);
  }
}

// K3b: same, bf16 (B,C,N) input.
__global__ void k_bn_stats_bf(const ushort* __restrict__ X, float* __restrict__ mu, float* __restrict__ rstd) {
  const int c = blockIdx.x, t = threadIdx.x;
  const ushort* base = X + (long)c * N_;
  float s = 0.f, sq = 0.f;
  for (int i4 = t; i4 < BNr / 4; i4 += TPB) {
    const int b = i4 / 20, n0 = (i4 % 20) * 4;
    ushort4 v = *(const ushort4*)&base[(long)b * CN + n0];
    const float f0 = b2f(v.x), f1 = b2f(v.y), f2 = b2f(v.z), f3 = b2f(v.w);
    s += f0 + f1 + f2 + f3;
    sq += f0 * f0 + f1 * f1 + f2 * f2 + f3 * f3;
  }
  __shared__ float rs[TPB], rq[TPB];
  rs[t] = s; rq[t] = sq; __syncthreads();
  for (int o = 128; o > 0; o >>= 1) { if (t < o) { rs[t] += rs[t + o]; rq[t] += rq[t + o]; } __syncthreads(); }
  if (t == 0) {
    const float m = rs[0] / BNr;
    const float var = rq[0] / BNr - m * m;
    mu[c] = m;
    rstd[c] = rsqrtf(var + EPSf);
  }
}

// ---------------------------------------------------------------------------
// K4f: fused x2 = x + leaky(bn(hT)) ; x2t transpose (bf16, B,N,C) ; glb0 mean.
// One block = one b, 64 c-rows, all 80 n.
// ---------------------------------------------------------------------------
__global__ __launch_bounds__(256) void k_x2_fused(
    const float* __restrict__ x, const ushort* __restrict__ hT,
    const float* __restrict__ g, const float* __restrict__ be,
    const float* __restrict__ mu, const float* __restrict__ rstd,
    float* __restrict__ out, ushort* __restrict__ x2t, ushort* __restrict__ glb0b) {
  __shared__ float s[64][84];
  __shared__ float pg[64], pm[64], pb[64];
  const int t = threadIdx.x;
  const long row0 = (long)blockIdx.x * 64;     // row = b*C + c
  const int b = (int)(row0 >> 10), c0 = (int)(row0 & 1023);
  if (t < 64) {
    const int c = c0 + t;
    pg[t] = g[c] * rstd[c]; pm[t] = mu[c]; pb[t] = be[c];
  }
  __syncthreads();
  const float*  xb = x   + row0 * N_;
  const ushort* hb = hT  + row0 * N_;
  float*        ob = out + row0 * N_;
  for (int i4 = t; i4 < (64 * N_) / 4; i4 += TPB) {
    const int e = i4 * 4, r = e / N_, n = e % N_;
    float4 xv = *(const float4*)&xb[e];
    ushort4 hu = *(const ushort4*)&hb[e];
    const float gm = pg[r], m = pm[r], bb = pb[r];
    float4 o;
    o.x = xv.x + leakyf(gm * (b2f(hu.x) - m) + bb);
    o.y = xv.y + leakyf(gm * (b2f(hu.y) - m) + bb);
    o.z = xv.z + leakyf(gm * (b2f(hu.z) - m) + bb);
    o.w = xv.w + leakyf(gm * (b2f(hu.w) - m) + bb);
    *(float4*)&ob[e] = o;
    *(float4*)&s[r][n] = o;
  }
  __syncthreads();
  // transpose to (B,N,C) bf16
  const int tx = t % 16, ty = t / 16;
  ushort* tb = x2t + (size_t)b * CN + c0 + tx * 4;
#pragma unroll
  for (int u = 0; u < 5; ++u) {
    const int n = ty + 16 * u;
    ushort4 v;
    v.x = f2bf(s[tx * 4 + 0][n]); v.y = f2bf(s[tx * 4 + 1][n]);
    v.z = f2bf(s[tx * 4 + 2][n]); v.w = f2bf(s[tx * 4 + 3][n]);
    *(ushort4*)&tb[(size_t)n * C_] = v;
  }
  // glb0 mean over n
  if (t < 64) {
    float sacc = 0.f;
    for (int n = 0; n < N_; ++n) sacc += s[t][n];
    glb0b[(size_t)b * C_ + c0 + t] = f2bf(sacc * (1.0f / N_));
  }
}

// ---------------------------------------------------------------------------
// K7: BN over batch (256 rows) per channel + leaky -> bf16 out.
// ---------------------------------------------------------------------------
__global__ void k_bng(const float* __restrict__ glb1, const float* __restrict__ gg,
                      const float* __restrict__ gb, ushort* __restrict__ glbf) {
  const int c = blockIdx.x, t = threadIdx.x;
  const float v = glb1[(long)t * C_ + c];
  __shared__ float rs[TPB], rq[TPB];
  rs[t] = v; rq[t] = v * v; __syncthreads();
  for (int o = 128; o > 0; o >>= 1) { if (t < o) { rs[t] += rs[t + o]; rq[t] += rq[t + o]; } __syncthreads(); }
  __shared__ float sm, sr;
  if (t == 0) { const float m = rs[0] / B_; const float var = rq[0] / B_ - m * m; sm = m; sr = rsqrtf(var + EPSf); }
  __syncthreads();
  glbf[(long)t * C_ + c] = f2bf(leakyf(gg[c] * (v - sm) * sr + gb[c]));
}

// ---------------------------------------------------------------------------
// K9/K10: global minmax of dadj (2-pass). Normalization folded into consumers.
// ---------------------------------------------------------------------------
__global__ void k_minmax1(const float* __restrict__ d, float* __restrict__ bmin, float* __restrict__ bmax) {
  const int t = threadIdx.x;
  float lo = 3.4e38f, hi = -3.4e38f;
  for (long i = (long)blockIdx.x * TPB + t; i < BNN; i += (long)512 * TPB) {
    const float v = d[i]; lo = fminf(lo, v); hi = fmaxf(hi, v);
  }
  __shared__ float rl[TPB], rh[TPB];
  rl[t] = lo; rh[t] = hi; __syncthreads();
  for (int o = 128; o > 0; o >>= 1) { if (t < o) { rl[t] = fminf(rl[t], rl[t + o]); rh[t] = fmaxf(rh[t], rh[t + o]); } __syncthreads(); }
  if (t == 0) { bmin[blockIdx.x] = rl[0]; bmax[blockIdx.x] = rh[0]; }
}

__global__ void k_minmax2(const float* __restrict__ bmin, const float* __restrict__ bmax, float* __restrict__ dmm) {
  const int t = threadIdx.x;
  float lo = fminf(bmin[t], bmin[t + 256]);
  float hi = fmaxf(bmax[t], bmax[t + 256]);
  __shared__ float rl[TPB], rh[TPB];
  rl[t] = lo; rh[t] = hi; __syncthreads();
  for (int o = 128; o > 0; o >>= 1) { if (t < o) { rl[t] = fminf(rl[t], rl[t + o]); rh[t] = fmaxf(rh[t], rh[t + o]); } __syncthreads(); }
  if (t == 0) { dmm[0] = rl[0]; dmm[1] = 1.0f / (rh[0] - rl[0]); }
}

// ---------------------------------------------------------------------------
// K12: loss per batch; dadj read RAW, normalized inline via dmm.
// ---------------------------------------------------------------------------
__global__ void k_loss(const float* __restrict__ dadj, const float* __restrict__ sadj,
                       const float* __restrict__ out1, float* __restrict__ lossa,
                       const float* __restrict__ dmm) {
  const int b = blockIdx.x, t = threadIdx.x;
  const float* db = dadj + (long)b * NN;
  const float* o1 = out1 + b * N_;
  const float lo = dmm[0], inv = dmm[1];
  float p2 = 0.f;
  for (int i = t; i < NN; i += TPB) { const float d = (db[i] - lo) * inv - sadj[i]; p2 += d * d; }
  float p1 = 0.f;
  if (t < N_) {
    float acc = 0.f;
    for (int n = 0; n < N_; ++n) acc += o1[n] * ((db[n * N_ + t] - lo) * inv);
    const float d = o1[t] - acc * (1.0f / N_);
    p1 = d * d;
  }
  __shared__ float red[TPB];
  __shared__ float s2;
  red[t] = p2; __syncthreads();
  for (int o = 128; o > 0; o >>= 1) { if (t < o) red[t] += red[t + o]; __syncthreads(); }
  if (t == 0) s2 = red[0];
  __syncthreads();
  red[t] = p1; __syncthreads();
  for (int o = 128; o > 0; o >>= 1) { if (t < o) red[t] += red[t + o]; __syncthreads(); }
  if (t == 0) atomicAdd(lossa, sqrtf(s2) + sqrtf(red[0]));
}

// ---------------------------------------------------------------------------
// K14: final BN + leaky in place on d_out (B,C,N); writes loss scalar.
// ---------------------------------------------------------------------------
__global__ void k_final(float* __restrict__ outp, const float* __restrict__ g, const float* __restrict__ be,
                        const float* __restrict__ mu, const float* __restrict__ rstd,
                        const float* __restrict__ lossa) {
  const long i = ((long)blockIdx.x * TPB + threadIdx.x) * 4;
  const int c = (int)((i / N_) % C_);
  float4 v = *(const float4*)&outp[i];
  const float gm = g[c] * rstd[c], m = mu[c], bb = be[c];
  v.x = leakyf(gm * (v.x - m) + bb);
  v.y = leakyf(gm * (v.y - m) + bb);
  v.z = leakyf(gm * (v.z - m) + bb);
  v.w = leakyf(gm * (v.w - m) + bb);
  *(float4*)&outp[i] = v;
  if (blockIdx.x == 0 && threadIdx.x == 0) outp[BCN] = *lossa;
}

// ---------------------------------------------------------------------------
extern "C" void kernel_launch(void* const* d_in, const int* in_sizes, int n_in,
                              void* d_out, int out_size, void* d_ws, size_t ws_size,
                              hipStream_t stream) {
  const float* x    = (const float*)d_in[0];
  const float* out1 = (const float*)d_in[1];
  const float* ap   = (const float*)d_in[2];
  const float* Ws   = (const float*)d_in[3];
  const float* Wd   = (const float*)d_in[4];
  const float* Wg   = (const float*)d_in[5];
  const float* bg   = (const float*)d_in[6];
  const float* Wco  = (const float*)d_in[7];
  const float* bco  = (const float*)d_in[8];
  const float* bn_g  = (const float*)d_in[9];
  const float* bn_b  = (const float*)d_in[10];
  const float* bng_g = (const float*)d_in[11];
  const float* bng_b = (const float*)d_in[12];
  float* out = (float*)d_out;

  float* w = (float*)d_ws;
  float* sadj  = w;                    // 6400
  float* dadj  = sadj + NN;            // 1638400
  float* glb0  = dadj + BNN;           // 262144 (used as bf16 ushorts)
  float* glb1  = glb0 + B_ * C_;       // 262144
  float* glbf  = glb1 + B_ * C_;       // 262144 (used as bf16 ushorts)
  float* go    = glbf + B_ * C_;       // 20480
  float* mu1   = go + BNr;             // 1024
  float* rstd1 = mu1 + C_;             // 1024
  float* mu2   = rstd1 + C_;           // 1024
  float* rstd2 = mu2 + C_;             // 1024
  float* bmin  = rstd2 + C_;           // 512
  float* bmax  = bmin + 512;           // 512
  float* dmm   = bmax + 512;           // 2
  float* lossa = dmm + 2;              // 1
  ushort* ub   = (ushort*)(((uintptr_t)(lossa + 1) + 255) & ~(uintptr_t)255);
  ushort* xa_bf  = ub;                    // BCN bf16 (B,N,C): fold out / x2t / fold2 out
  ushort* hT_bf  = xa_bf + BCN;           // BCN bf16 (B,C,N)
  ushort* Wts    = hT_bf + BCN;           // 1M bf16 (O,C)
  ushort* Wtd    = Wts + (size_t)C_ * C_; // 1M bf16 (O,C)
  ushort* Wco2t  = Wtd + (size_t)C_ * C_; // 80K bf16 (80,1024)
  ushort* adj_bf = Wco2t + (size_t)N_ * C_; // 80x96 bf16 prepadded
  // bf16 aliases in regions dead at time of use:
  ushort* Wg_bf   = (ushort*)dadj;                      // 1M ushorts; dadj written later
  ushort* Wco1t   = (ushort*)dadj + (size_t)C_ * C_;    // 80K ushorts, same region
  ushort* glb0_bf = (ushort*)glb0;
  ushort* glbf_bf = (ushort*)glbf;
  ushort* x2t_bf  = xa_bf;                              // xa dead after GEMM#1; x2t dead before fold#2

  // ---- prep ----
  k_prep_adj<<<1, TPB, 0, stream>>>(ap, sadj, adj_bf, lossa);
  k_w_bf_t<<<dim3(32, 32), TPB, 0, stream>>>(Ws, Wts);
  k_w_bf_t<<<dim3(32, 32), TPB, 0, stream>>>(Wd, Wtd);
  k_wco_bf<<<(N_ * 2 * C_) / (4 * TPB), TPB, 0, stream>>>(Wco, Wco1t, Wco2t);
  k_cvt_bf<<<(C_ * C_) / (4 * TPB), TPB, 0, stream>>>(Wg, Wg_bf);
  k_zero_go<<<BNr / (4 * TPB), TPB, 0, stream>>>(go);

  // ---- static GCN ----
  k_fold_mfma<<<B_ * 8, TPB, 0, stream>>>(x, adj_bf, xa_bf, 0, dmm);
  k_gemm_256<<<320, 512, 0, stream>>>(xa_bf, Wts, hT_bf, 1);
  k_bn_stats_bf<<<C_, TPB, 0, stream>>>(hT_bf, mu1, rstd1);
  k_x2_fused<<<(B_ * C_) / 64, TPB, 0, stream>>>(x, hT_bf, bn_g, bn_b, mu1, rstd1,
                                                 out, x2t_bf, glb0_bf);

  // ---- dynamic graph construction ----
  k_glb_mfma<<<dim3(C_ / 64, B_ / 64), TPB, 0, stream>>>(glb0_bf, Wg_bf, bg, glb1);
  k_bng<<<C_, TPB, 0, stream>>>(glb1, bng_g, bng_b, glbf_bf);
  k_go_mfma<<<dim3(8, B_ / 128), TPB, 0, stream>>>(glbf_bf, Wco1t, go);
  k_dadj_mfma<<<BNr / 128, TPB, 0, stream>>>(x2t_bf, Wco2t, go, bco, dadj);
  k_minmax1<<<512, TPB, 0, stream>>>(dadj, bmin, bmax);
  k_minmax2<<<1, TPB, 0, stream>>>(bmin, bmax, dmm);

  // ---- adjacency loss (reads raw dadj + dmm) ----
  k_loss<<<B_, TPB, 0, stream>>>(dadj, sadj, out1, lossa, dmm);

  // ---- dynamic GCN (fold normalizes dadj inline via dmm) ----
  k_fold_mfma<<<B_ * 8, TPB, 0, stream>>>(out, dadj, xa_bf, 1, dmm);
  k_gemm_256<<<320, 512, 0, stream>>>(xa_bf, Wtd, out, 0);
  k_bn_stats<<<C_, TPB, 0, stream>>>(out, mu2, rstd2);
  k_final<<<(int)(BCN / (4 * TPB)), TPB, 0, stream>>>(out, bn_g, bn_b, mu2, rstd2, lossa);
}

// Round 4
// 568.795 us; speedup vs baseline: 1.2249x; 1.0524x over previous
//
#include <hip/hip_runtime.h>
#include <hip/hip_bf16.h>
#include <math.h>

#define TPB 256

constexpr int   B_  = 256;
constexpr int   C_  = 1024;
constexpr int   N_  = 80;
constexpr int   BNr = B_ * N_;                 // 20480 rows for BN / GEMM M
constexpr int   CN  = C_ * N_;                 // 81920
constexpr long  BCN = (long)B_ * C_ * N_;      // 20971520
constexpr int   NN  = N_ * N_;                 // 6400
constexpr int   BNN = B_ * NN;                 // 1638400
constexpr float EPSf = 1e-5f;

typedef __bf16 bf16x8 __attribute__((ext_vector_type(8)));
typedef float  f32x4  __attribute__((ext_vector_type(4)));

__device__ __forceinline__ float leakyf(float v) { return v >= 0.0f ? v : 0.2f * v; }

__device__ __forceinline__ ushort f2bf(float f) {
  __hip_bfloat16 h = __float2bfloat16(f);
  ushort u; __builtin_memcpy(&u, &h, 2); return u;
}
__device__ __forceinline__ float b2f(ushort u) {
  __hip_bfloat16 h; __builtin_memcpy(&h, &u, 2);
  return __bfloat162float(h);
}

#define GLOBAL_AS __attribute__((address_space(1)))
#define LDS_AS    __attribute__((address_space(3)))
__device__ __forceinline__ void load_lds16(const void* g, void* l) {
  __builtin_amdgcn_global_load_lds((const GLOBAL_AS void*)g, (LDS_AS void*)l, 16, 0, 0);
}

// ---------------------------------------------------------------------------
// K0: sadj = minmax(adj_param); D = rsqrt(rowsum);
// adj_bf[n*96+m] = bf16(D[n]*sadj[m,n]*D[m]) for m<80, 0 for m in [80,96).
// ---------------------------------------------------------------------------
__global__ void k_prep_adj(const float* __restrict__ ap, float* __restrict__ sadj,
                           ushort* __restrict__ adj_bf, float* __restrict__ lossa) {
  __shared__ float s[NN];
  __shared__ float red[TPB];
  __shared__ float s_lo, s_hi;
  __shared__ float sD[N_];
  const int t = threadIdx.x;
  float lo = 3.4e38f, hi = -3.4e38f;
  for (int i = t; i < NN; i += TPB) { float v = ap[i]; s[i] = v; lo = fminf(lo, v); hi = fmaxf(hi, v); }
  red[t] = lo; __syncthreads();
  for (int o = 128; o > 0; o >>= 1) { if (t < o) red[t] = fminf(red[t], red[t + o]); __syncthreads(); }
  if (t == 0) s_lo = red[0];
  __syncthreads();
  red[t] = hi; __syncthreads();
  for (int o = 128; o > 0; o >>= 1) { if (t < o) red[t] = fmaxf(red[t], red[t + o]); __syncthreads(); }
  if (t == 0) s_hi = red[0];
  __syncthreads();
  const float inv = 1.0f / (s_hi - s_lo);
  for (int i = t; i < NN; i += TPB) { float v = (s[i] - s_lo) * inv; s[i] = v; sadj[i] = v; }
  __syncthreads();
  if (t < N_) { float sum = 0.f; for (int m = 0; m < N_; ++m) sum += s[t * N_ + m]; sD[t] = rsqrtf(sum); }
  if (t == 0) *lossa = 0.0f;
  __syncthreads();
  for (int i = t; i < N_ * 96; i += TPB) {
    const int n = i / 96, m = i % 96;
    adj_bf[i] = f2bf((m < N_) ? sD[n] * s[m * N_ + n] * sD[m] : 0.0f);
  }
}

// ---------------------------------------------------------------------------
// KW: Wt[o][c] = bf16(W[c][o]) — transpose + convert, 32x32 LDS tiles.
// ---------------------------------------------------------------------------
__global__ void k_w_bf_t(const float* __restrict__ W, ushort* __restrict__ Wt) {
  __shared__ float s[32][33];
  const int t = threadIdx.x;
  const int tx = t % 32, ty = t / 32;            // 8 rows per pass
  const int r0 = blockIdx.y * 32, c0 = blockIdx.x * 32;
#pragma unroll
  for (int k = 0; k < 4; ++k) s[ty + 8 * k][tx] = W[(size_t)(r0 + ty + 8 * k) * C_ + c0 + tx];
  __syncthreads();
#pragma unroll
  for (int k = 0; k < 4; ++k) Wt[(size_t)(c0 + ty + 8 * k) * C_ + r0 + tx] = f2bf(s[tx][ty + 8 * k]);
}

// ---------------------------------------------------------------------------
// KW2: split Wco (80 x 2048) into two bf16 (80 x 1024) K-major buffers.
// ---------------------------------------------------------------------------
__global__ void k_wco_bf(const float* __restrict__ Wco, ushort* __restrict__ Wco1t,
                         ushort* __restrict__ Wco2t) {
  const int i4 = (blockIdx.x * TPB + threadIdx.x) * 4;   // 80*2048 elems
  const int o = i4 >> 11, k = i4 & 2047;
  float4 v = *(const float4*)&Wco[(size_t)o * 2048 + k];
  ushort4 u;
  u.x = f2bf(v.x); u.y = f2bf(v.y); u.z = f2bf(v.z); u.w = f2bf(v.w);
  if (k < C_) *(ushort4*)&Wco1t[(size_t)o * C_ + k] = u;
  else        *(ushort4*)&Wco2t[(size_t)o * C_ + (k - C_)] = u;
}

// ---------------------------------------------------------------------------
// KW3: plain fp32 -> bf16 elementwise convert (for Wg, already o-major/K-contig).
// ---------------------------------------------------------------------------
__global__ void k_cvt_bf(const float* __restrict__ W, ushort* __restrict__ Wb) {
  const long i4 = ((long)blockIdx.x * TPB + threadIdx.x) * 4;
  float4 v = *(const float4*)&W[i4];
  ushort4 u;
  u.x = f2bf(v.x); u.y = f2bf(v.y); u.z = f2bf(v.z); u.w = f2bf(v.w);
  *(ushort4*)&Wb[i4] = u;
}

// K-zero: go accumulator (20480 floats).
__global__ void k_zero_go(float* __restrict__ go) {
  const int i = (blockIdx.x * TPB + threadIdx.x) * 4;
  float4 z = make_float4(0.f, 0.f, 0.f, 0.f);
  *(float4*)&go[i] = z;
}

// ---------------------------------------------------------------------------
// K1v3: MFMA fold.  out[(b*80+n)*1024 + c] (bf16, B,N,C) =
//   sum_m adj[n,m] * X[b, c, m]       (X fp32 in B,C,N layout)
// mode 0: adjsrc = adj_bf global (80x96 bf16, prepadded).
// mode 1: adjsrc = dadj RAW fp32 (B,80,80); normalized by dmm, tadj in LDS.
// ---------------------------------------------------------------------------
__global__ __launch_bounds__(256) void k_fold_mfma(const float* __restrict__ X,
                                                   const void* __restrict__ adjsrc,
                                                   ushort* __restrict__ outp, int mode,
                                                   const float* __restrict__ dmm) {
  __shared__ __align__(16) ushort sX[128][104];     // rows c, cols m (pad->104, b128 2-way free)
  __shared__ __align__(16) ushort sAdj[80][104];    // rows n, cols m
  __shared__ float sD[N_];
  const int t = threadIdx.x;
  const int b  = blockIdx.x >> 3;
  const int c0 = (blockIdx.x & 7) * 128;

  // ---- adjacency -> sAdj (bf16, m 80..95 zero) ----
  if (mode == 0) {
    const ushort* ab = (const ushort*)adjsrc;
    for (int i = t; i < (N_ * 96) / 4; i += TPB) {
      ushort4 v = *(const ushort4*)&ab[i * 4];
      *(ushort4*)&sAdj[(i * 4) / 96][(i * 4) % 96] = v;
    }
    __syncthreads();
  } else {
    float* sF = (float*)&sX[0][0];                  // 80*80 fp32 = 25.6KB <= sX
    const float* db = (const float*)adjsrc + (size_t)b * NN;
    const float lo = dmm[0], inv = dmm[1];
    for (int i = t; i < NN / 4; i += TPB) {
      float4 v = *(const float4*)&db[i * 4];
      v.x = (v.x - lo) * inv; v.y = (v.y - lo) * inv;
      v.z = (v.z - lo) * inv; v.w = (v.w - lo) * inv;
      *(float4*)&sF[i * 4] = v;
    }
    __syncthreads();
    if (t < N_) { float s = 0.f; for (int m = 0; m < N_; ++m) s += sF[t * N_ + m]; sD[t] = rsqrtf(s); }
    __syncthreads();
    for (int i = t; i < N_ * 96; i += TPB) {
      const int n = i / 96, m = i % 96;
      sAdj[n][m] = f2bf((m < N_) ? sF[m * N_ + n] * sD[n] * sD[m] : 0.0f);
    }
    __syncthreads();                                 // before sX overwrite
  }

  // ---- stage X (128 rows x 80 m) fp32 -> bf16; zero pad m 80..95 ----
  const float* Xb = X + ((size_t)b * C_ + c0) * N_;
  for (int i = t; i < (128 * N_) / 4; i += TPB) {
    float4 v = *(const float4*)&Xb[i * 4];
    const int r = (i * 4) / N_, m = (i * 4) % N_;
    ushort4 u; u.x = f2bf(v.x); u.y = f2bf(v.y); u.z = f2bf(v.z); u.w = f2bf(v.w);
    *(ushort4*)&sX[r][m] = u;
  }
  for (int i = t; i < (128 * 16) / 4; i += TPB) {
    const int r = i / 4, m = 80 + (i % 4) * 4;
    ushort4 z; z.x = 0; z.y = 0; z.z = 0; z.w = 0;
    *(ushort4*)&sX[r][m] = z;
  }
  __syncthreads();

  const int lane = t & 63, wid = t >> 6;
  const int l16 = lane & 15, lq = lane >> 4;
  f32x4 acc[2][5];
#pragma unroll
  for (int i = 0; i < 2; ++i)
#pragma unroll
    for (int j = 0; j < 5; ++j) { f32x4 z = {0.f, 0.f, 0.f, 0.f}; acc[i][j] = z; }
  bf16x8 af[2][3], bfr[5][3];
#pragma unroll
  for (int i = 0; i < 2; ++i)
#pragma unroll
    for (int kk = 0; kk < 3; ++kk)
      af[i][kk] = *(const bf16x8*)&sX[wid * 32 + i * 16 + l16][kk * 32 + lq * 8];
#pragma unroll
  for (int j = 0; j < 5; ++j)
#pragma unroll
    for (int kk = 0; kk < 3; ++kk)
      bfr[j][kk] = *(const bf16x8*)&sAdj[j * 16 + l16][kk * 32 + lq * 8];
#pragma unroll
  for (int i = 0; i < 2; ++i)
#pragma unroll
    for (int j = 0; j < 5; ++j)
#pragma unroll
      for (int kk = 0; kk < 3; ++kk)
        acc[i][j] = __builtin_amdgcn_mfma_f32_16x16x32_bf16(af[i][kk], bfr[j][kk], acc[i][j], 0, 0, 0);

  // ---- epilogue: D[row=c_local (lq*4+reg)][col=n (l16)] -> (B,N,C) ushort4 ----
  ushort* ob = outp + (size_t)b * CN;
#pragma unroll
  for (int i = 0; i < 2; ++i) {
    const int c = c0 + wid * 32 + i * 16 + lq * 4;
#pragma unroll
    for (int j = 0; j < 5; ++j) {
      const int n = j * 16 + l16;
      ushort4 u;
      u.x = f2bf(acc[i][j][0]); u.y = f2bf(acc[i][j][1]);
      u.z = f2bf(acc[i][j][2]); u.w = f2bf(acc[i][j][3]);
      *(ushort4*)&ob[(size_t)n * C_ + c] = u;
    }
  }
}

// ---------------------------------------------------------------------------
// K2: 256x256x64 8-phase counted-vmcnt MFMA GEMM (T2+T3+T4+T5)
// + gray-code operand carry: phase order (0,0)->(0,1)->(1,1)->(1,0) changes
// one half-operand per step; afr carried across NH changes, both B-halves
// (bfr0,bfr1) held so MH changes re-read nothing. 48 ds_read_b128 per 8
// phases (was 96). Staging/vmcnt/barriers identical to the verified r3 code.
// ---------------------------------------------------------------------------
__global__ __launch_bounds__(512, 2) void k_gemm_256(const ushort* __restrict__ A,
                                                     const ushort* __restrict__ Bt,
                                                     void* __restrict__ outp, int out_bf) {
  __shared__ ushort sA[2][256 * 64];   // 64 KB
  __shared__ ushort sB[2][256 * 64];   // 64 KB
  const int t = threadIdx.x;
  const int lane = t & 63, wid = t >> 6;       // 8 waves
  const int wm = wid >> 2, wn = wid & 3;       // 2 x 4
  const int l16 = lane & 15, lq = lane >> 4;

  // XCD-chunked swizzle: 320 blocks; each XCD: tm in [xcd*10, xcd*10+10), tn 0..3.
  const int lin = blockIdx.x;
  const int xcd = lin & 7, bi = lin >> 3;      // bi in 0..39
  const int tm = xcd * 10 + (bi >> 2);
  const int tn = bi & 3;
  const int m0 = tm * 256, o0 = tn * 256;

  // staging coords: thread t stages row (rowbase + t>>3); source 16B-slot is
  // pre-swizzled so the linear LDS write lands swizzled data.
  const int srow = t >> 3;
  const int sswz = ((t & 7) ^ ((t >> 3) & 7)) * 8;   // elems

  f32x4 acc[8][4];
#pragma unroll
  for (int i = 0; i < 8; ++i)
#pragma unroll
    for (int j = 0; j < 4; ++j) { f32x4 z = {0.f, 0.f, 0.f, 0.f}; acc[i][j] = z; }

  bf16x8 afr[4][2], bfr0[2][2], bfr1[2][2];    // carried fragments

  // one call stages 64 rows x 64 cols (8KB): per-wave linear LDS dest.
#define STA(PAR, ROWB, KT) load_lds16(A  + (size_t)(m0 + (ROWB) + srow) * C_ + (KT) * 64 + sswz, \
                                      &sA[PAR][((ROWB) + (wid << 3)) * 64])
#define STB(PAR, ROWB, KT) load_lds16(Bt + (size_t)(o0 + (ROWB) + srow) * C_ + (KT) * 64 + sswz, \
                                      &sB[PAR][((ROWB) + (wid << 3)) * 64])
#define STA_H(PAR, H, KT) { STA(PAR, (H)*128, KT); STA(PAR, (H)*128 + 64, KT); }
#define STB_H(PAR, H, KT) { STB(PAR, (H)*128, KT); STB(PAR, (H)*128 + 64, KT); }

#define RDA(PAR, MH)                                                                      \
  _Pragma("unroll") for (int fi = 0; fi < 4; ++fi) {                                      \
    const int row = ((MH) ? 128 : 0) + wm * 64 + fi * 16 + l16;                           \
    _Pragma("unroll") for (int kk = 0; kk < 2; ++kk)                                      \
      afr[fi][kk] = *(const bf16x8*)&sA[PAR][row * 64 + ((kk * 4 + lq) ^ (l16 & 7)) * 8]; \
  }
#define RDB(PAR, NH, DST)                                                                 \
  _Pragma("unroll") for (int gi = 0; gi < 2; ++gi) {                                      \
    const int row = ((NH) ? 128 : 0) + wn * 32 + gi * 16 + l16;                           \
    _Pragma("unroll") for (int kk = 0; kk < 2; ++kk)                                      \
      DST[gi][kk] = *(const bf16x8*)&sB[PAR][row * 64 + ((kk * 4 + lq) ^ (l16 & 7)) * 8]; \
  }

#define MFMAS(MH, NH, BF)                                                          \
  _Pragma("unroll") for (int kk = 0; kk < 2; ++kk)                                 \
  _Pragma("unroll") for (int fi = 0; fi < 4; ++fi)                                 \
  _Pragma("unroll") for (int gi = 0; gi < 2; ++gi)                                 \
    acc[(MH) * 4 + fi][(NH) * 2 + gi] = __builtin_amdgcn_mfma_f32_16x16x32_bf16(   \
        afr[fi][kk], BF[gi][kk], acc[(MH) * 4 + fi][(NH) * 2 + gi], 0, 0, 0);

#define PHASE(MH, NH, BF, RD, STAGES, VMW)                                         \
  {                                                                                \
    RD                                                                             \
    STAGES                                                                         \
    asm volatile("s_barrier" ::: "memory");                                        \
    asm volatile("s_waitcnt lgkmcnt(0)" ::: "memory");                             \
    __builtin_amdgcn_s_setprio(1);                                                 \
    MFMAS(MH, NH, BF)                                                              \
    __builtin_amdgcn_s_setprio(0);                                                 \
    VMW                                                                            \
    asm volatile("s_barrier" ::: "memory");                                        \
  }

  // prologue: T0 fully (8 calls) + T1's A-half0, B-half1 (4 calls)
  STA_H(0, 0, 0); STA_H(0, 1, 0); STB_H(0, 0, 0); STB_H(0, 1, 0);
  STA_H(1, 0, 1); STB_H(1, 1, 1);
  asm volatile("s_waitcnt vmcnt(4)" ::: "memory");
  asm volatile("s_barrier" ::: "memory");

  for (int i = 0; i < 7; ++i) {
    const int t1 = 2 * i + 1, t2 = 2 * i + 2, t3 = 2 * i + 3;
    PHASE(0, 0, bfr0, RDA(0, 0) RDB(0, 0, bfr0), { STA_H(1, 1, t1); }, {})
    PHASE(0, 1, bfr1, RDB(0, 1, bfr1),           { STB_H(1, 0, t1); }, {})
    PHASE(1, 1, bfr1, RDA(0, 1),                 { STA_H(0, 0, t2); }, {})
    PHASE(1, 0, bfr0, {},                        { STB_H(0, 1, t2); }, { asm volatile("s_waitcnt vmcnt(4)" ::: "memory"); })
    PHASE(0, 0, bfr0, RDA(1, 0) RDB(1, 0, bfr0), { STA_H(0, 1, t2); }, {})
    PHASE(0, 1, bfr1, RDB(1, 1, bfr1),           { STB_H(0, 0, t2); }, {})
    PHASE(1, 1, bfr1, RDA(1, 1),                 { STA_H(1, 0, t3); }, {})
    PHASE(1, 0, bfr0, {},                        { STB_H(1, 1, t3); }, { asm volatile("s_waitcnt vmcnt(4)" ::: "memory"); })
  }
  // peeled last iter: tiles 14 (par0), 15 (par1); only T15's A1/B0 remain to stage.
  PHASE(0, 0, bfr0, RDA(0, 0) RDB(0, 0, bfr0), { STA_H(1, 1, 15); }, {})
  PHASE(0, 1, bfr1, RDB(0, 1, bfr1),           { STB_H(1, 0, 15); }, {})
  PHASE(1, 1, bfr1, RDA(0, 1),                 {}, {})
  PHASE(1, 0, bfr0, {},                        {}, { asm volatile("s_waitcnt vmcnt(0)" ::: "memory"); })
  PHASE(0, 0, bfr0, RDA(1, 0) RDB(1, 0, bfr0), {}, {})
  PHASE(0, 1, bfr1, RDB(1, 1, bfr1),           {}, {})
  PHASE(1, 1, bfr1, RDA(1, 1),                 {}, {})
  PHASE(1, 0, bfr0, {},                        {}, {})

  // epilogue: row = lq*4+reg -> m; col = l16 -> o. (B,C,N) store, 4 consecutive n.
#pragma unroll
  for (int f = 0; f < 8; ++f) {
    const int gmb = (f < 4) ? (wm * 64 + f * 16) : (128 + wm * 64 + (f - 4) * 16);
    const int mg = m0 + gmb + lq * 4;
    const int b  = mg / 80;
    const int n0 = mg - b * 80;
#pragma unroll
    for (int gi = 0; gi < 4; ++gi) {
      const int gnb = (gi < 2) ? (wn * 32 + gi * 16) : (128 + wn * 32 + (gi - 2) * 16);
      const int og = o0 + gnb + l16;
      const size_t off = (size_t)b * CN + (size_t)og * N_ + n0;
      if (out_bf) {
        ushort4 u;
        u.x = f2bf(acc[f][gi][0]); u.y = f2bf(acc[f][gi][1]);
        u.z = f2bf(acc[f][gi][2]); u.w = f2bf(acc[f][gi][3]);
        *(ushort4*)((ushort*)outp + off) = u;
      } else {
        *(f32x4*)((float*)outp + off) = acc[f][gi];
      }
    }
  }
#undef STA
#undef STB
#undef STA_H
#undef STB_H
#undef RDA
#undef RDB
#undef MFMAS
#undef PHASE
}

// ---------------------------------------------------------------------------
// K2b: dadj MFMA GEMM. A: x2t bf16 (M=20480, K=1024). Bw: Wco2t bf16 (80,1024).
// dadj[b,o,n] = go[b,o] + bco[o] + sum_k A[m=(b,n)][k]*Bw[o][k].
// ---------------------------------------------------------------------------
__global__ __launch_bounds__(256) void k_dadj_mfma(const ushort* __restrict__ A,
                                                   const ushort* __restrict__ Bw,
                                                   const float* __restrict__ go,
                                                   const float* __restrict__ bco,
                                                   float* __restrict__ dadj) {
  __shared__ ushort smA[128 * 32];
  __shared__ ushort smB[80 * 32];
  const int t = threadIdx.x;
  const int lane = t & 63, wid = t >> 6;
  const int m0 = blockIdx.x * 128;
  const int rto = t >> 2, ch = t & 3;
  const size_t gA0 = (size_t)(m0 + rto) * C_ + (size_t)ch * 8;
  ushort* ldsA = smA + wid * 512;
  const int l16 = lane & 15, lq = lane >> 4;
  const int wrow = wid * 32;
  f32x4 zero = {0.f, 0.f, 0.f, 0.f};
  f32x4 acc[2][5];
#pragma unroll
  for (int i = 0; i < 2; ++i)
#pragma unroll
    for (int j = 0; j < 5; ++j) acc[i][j] = zero;
  for (int k0 = 0; k0 < C_; k0 += 32) {
    load_lds16(A + gA0 + k0,            ldsA);
    load_lds16(A + gA0 + 64 * C_ + k0,  ldsA + 2048);
    {
      const int idx = t;                               // 320 chunks of 16B
      uint4 v = *(const uint4*)&Bw[(size_t)(idx >> 2) * C_ + k0 + (idx & 3) * 8];
      *(uint4*)&smB[idx * 8] = v;
      if (t < 64) {
        const int idx2 = 256 + t;
        uint4 v2 = *(const uint4*)&Bw[(size_t)(idx2 >> 2) * C_ + k0 + (idx2 & 3) * 8];
        *(uint4*)&smB[idx2 * 8] = v2;
      }
    }
    __syncthreads();
    bf16x8 af[2], bfr[5];
#pragma unroll
    for (int i = 0; i < 2; ++i) af[i]  = *(const bf16x8*)&smA[(wrow + i * 16 + l16) * 32 + lq * 8];
#pragma unroll
    for (int j = 0; j < 5; ++j) bfr[j] = *(const bf16x8*)&smB[(j * 16 + l16) * 32 + lq * 8];
#pragma unroll
    for (int i = 0; i < 2; ++i)
#pragma unroll
      for (int j = 0; j < 5; ++j)
        acc[i][j] = __builtin_amdgcn_mfma_f32_16x16x32_bf16(af[i], bfr[j], acc[i][j], 0, 0, 0);
    __syncthreads();
  }
#pragma unroll
  for (int i = 0; i < 2; ++i) {
    const int mg = m0 + wrow + i * 16 + lq * 4;
    const int b  = mg / 80;
    const int n0 = mg - b * 80;
    const float* gob = go + b * N_;
#pragma unroll
    for (int j = 0; j < 5; ++j) {
      const int o = j * 16 + l16;
      const float g = gob[o] + bco[o];
      f32x4 v = acc[i][j];
      v[0] += g; v[1] += g; v[2] += g; v[3] += g;
      *(f32x4*)&dadj[(size_t)b * NN + (size_t)o * N_ + n0] = v;
    }
  }
}

// ---------------------------------------------------------------------------
// K2c: glb1 MFMA GEMM. A: glb0_bf (256 x 1024). Bw: Wg_bf (1024 x 1024, K-contig).
// ---------------------------------------------------------------------------
__global__ __launch_bounds__(256) void k_glb_mfma(const ushort* __restrict__ A,
                                                  const ushort* __restrict__ Bw,
                                                  const float* __restrict__ bias,
                                                  float* __restrict__ outp) {
  __shared__ ushort smA[2][64 * 32];
  __shared__ ushort smB[2][64 * 32];
  const int t = threadIdx.x;
  const int lane = t & 63, wid = t >> 6;
  const int o0 = blockIdx.x * 64, m0 = blockIdx.y * 64;
  const int rto = t >> 2, ch = t & 3;
  const size_t gA0 = (size_t)(m0 + rto) * C_ + (size_t)ch * 8;
  const size_t gB0 = (size_t)(o0 + rto) * C_ + (size_t)ch * 8;
  const int l16 = lane & 15, lq = lane >> 4;
  const int wm = wid & 1, wn = wid >> 1;
  f32x4 zero = {0.f, 0.f, 0.f, 0.f};
  f32x4 acc[2][2];
#pragma unroll
  for (int i = 0; i < 2; ++i)
#pragma unroll
    for (int j = 0; j < 2; ++j) acc[i][j] = zero;
  for (int k0 = 0; k0 < C_; k0 += 64) {
    load_lds16(A  + gA0 + k0,       smA[0] + wid * 512);
    load_lds16(A  + gA0 + k0 + 32,  smA[1] + wid * 512);
    load_lds16(Bw + gB0 + k0,       smB[0] + wid * 512);
    load_lds16(Bw + gB0 + k0 + 32,  smB[1] + wid * 512);
    __syncthreads();
#pragma unroll
    for (int h = 0; h < 2; ++h) {
      bf16x8 af[2], bfr[2];
#pragma unroll
      for (int i = 0; i < 2; ++i) af[i]  = *(const bf16x8*)&smA[h][(wm * 32 + i * 16 + l16) * 32 + lq * 8];
#pragma unroll
      for (int j = 0; j < 2; ++j) bfr[j] = *(const bf16x8*)&smB[h][(wn * 32 + j * 16 + l16) * 32 + lq * 8];
#pragma unroll
      for (int i = 0; i < 2; ++i)
#pragma unroll
        for (int j = 0; j < 2; ++j)
          acc[i][j] = __builtin_amdgcn_mfma_f32_16x16x32_bf16(af[i], bfr[j], acc[i][j], 0, 0, 0);
    }
    __syncthreads();
  }
#pragma unroll
  for (int i = 0; i < 2; ++i) {
    const int mg = m0 + wm * 32 + i * 16 + lq * 4;
#pragma unroll
    for (int j = 0; j < 2; ++j) {
      const int og = o0 + wn * 32 + j * 16 + l16;
      const float bs = bias[og];
      f32x4 v = acc[i][j];
#pragma unroll
      for (int r = 0; r < 4; ++r) outp[(size_t)(mg + r) * C_ + og] = v[r] + bs;
    }
  }
}

// ---------------------------------------------------------------------------
// K2d: go MFMA GEMM, split-K x8.  A: glbf_bf (256 x 1024). Bw: Wco1t (80 x 1024).
// ---------------------------------------------------------------------------
__global__ __launch_bounds__(256) void k_go_mfma(const ushort* __restrict__ A,
                                                 const ushort* __restrict__ Bw,
                                                 float* __restrict__ go) {
  __shared__ ushort smA[128 * 32];
  __shared__ ushort smB[80 * 32];
  const int t = threadIdx.x;
  const int lane = t & 63, wid = t >> 6;
  const int kbase = blockIdx.x * 128;
  const int m0 = blockIdx.y * 128;
  const int rto = t >> 2, ch = t & 3;
  const size_t gA0 = (size_t)(m0 + rto) * C_ + (size_t)ch * 8;
  ushort* ldsA = smA + wid * 512;
  const int l16 = lane & 15, lq = lane >> 4;
  const int wrow = wid * 32;
  f32x4 zero = {0.f, 0.f, 0.f, 0.f};
  f32x4 acc[2][5];
#pragma unroll
  for (int i = 0; i < 2; ++i)
#pragma unroll
    for (int j = 0; j < 5; ++j) acc[i][j] = zero;
  for (int kk0 = 0; kk0 < 128; kk0 += 32) {
    const int k0 = kbase + kk0;
    load_lds16(A + gA0 + k0,            ldsA);
    load_lds16(A + gA0 + 64 * C_ + k0,  ldsA + 2048);
    {
      const int idx = t;
      uint4 v = *(const uint4*)&Bw[(size_t)(idx >> 2) * C_ + k0 + (idx & 3) * 8];
      *(uint4*)&smB[idx * 8] = v;
      if (t < 64) {
        const int idx2 = 256 + t;
        uint4 v2 = *(const uint4*)&Bw[(size_t)(idx2 >> 2) * C_ + k0 + (idx2 & 3) * 8];
        *(uint4*)&smB[idx2 * 8] = v2;
      }
    }
    __syncthreads();
    bf16x8 af[2], bfr[5];
#pragma unroll
    for (int i = 0; i < 2; ++i) af[i]  = *(const bf16x8*)&smA[(wrow + i * 16 + l16) * 32 + lq * 8];
#pragma unroll
    for (int j = 0; j < 5; ++j) bfr[j] = *(const bf16x8*)&smB[(j * 16 + l16) * 32 + lq * 8];
#pragma unroll
    for (int i = 0; i < 2; ++i)
#pragma unroll
      for (int j = 0; j < 5; ++j)
        acc[i][j] = __builtin_amdgcn_mfma_f32_16x16x32_bf16(af[i], bfr[j], acc[i][j], 0, 0, 0);
    __syncthreads();
  }
#pragma unroll
  for (int i = 0; i < 2; ++i) {
    const int mg = m0 + wrow + i * 16 + lq * 4;
#pragma unroll
    for (int j = 0; j < 5; ++j) {
      const int o = j * 16 + l16;
#pragma unroll
      for (int r = 0; r < 4; ++r)
        atomicAdd(&go[(size_t)(mg + r) * N_ + o], acc[i][j][r]);
    }
  }
}

// ---------------------------------------------------------------------------
// K3: BN stats per channel over (b,n) — fp32 (B,C,N) input, float4 loads.
// ---------------------------------------------------------------------------
__global__ void k_bn_stats(const float* __restrict__ X, float* __restrict__ mu, float* __restrict__ rstd) {
  const int c = blockIdx.x, t = threadIdx.x;
  const float* base = X + (long)c * N_;
  float s = 0.f, sq = 0.f;
  for (int i4 = t; i4 < BNr / 4; i4 += TPB) {
    const int b = i4 / 20, n0 = (i4 % 20) * 4;
    float4 v = *(const float4*)&base[(long)b * CN + n0];
    s += v.x + v.y + v.z + v.w;
    sq += v.x * v.x + v.y * v.y + v.z * v.z + v.w * v.w;
  }
  __shared__ float rs[TPB], rq[TPB];
  rs[t] = s; rq[t] = sq; __syncthreads();
  for (int o = 128; o > 0; o >>= 1) { if (t < o) { rs[t] += rs[t + o]; rq[t] += rq[t + o]; } __syncthreads(); }
  if (t == 0) {
    const float m = rs[0] / BNr;
    const float var = rq[0] / BNr - m * m;
    mu[c] = m;
    rstd[c] = rsqrtf(var + EPSf);
  }
}

// K3b: same, bf16 (B,C,N) input.
__global__ void k_bn_stats_bf(const ushort* __restrict__ X, float* __restrict__ mu, float* __restrict__ rstd) {
  const int c = blockIdx.x, t = threadIdx.x;
  const ushort* base = X + (long)c * N_;
  float s = 0.f, sq = 0.f;
  for (int i4 = t; i4 < BNr / 4; i4 += TPB) {
    const int b = i4 / 20, n0 = (i4 % 20) * 4;
    ushort4 v = *(const ushort4*)&base[(long)b * CN + n0];
    const float f0 = b2f(v.x), f1 = b2f(v.y), f2 = b2f(v.z), f3 = b2f(v.w);
    s += f0 + f1 + f2 + f3;
    sq += f0 * f0 + f1 * f1 + f2 * f2 + f3 * f3;
  }
  __shared__ float rs[TPB], rq[TPB];
  rs[t] = s; rq[t] = sq; __syncthreads();
  for (int o = 128; o > 0; o >>= 1) { if (t < o) { rs[t] += rs[t + o]; rq[t] += rq[t + o]; } __syncthreads(); }
  if (t == 0) {
    const float m = rs[0] / BNr;
    const float var = rq[0] / BNr - m * m;
    mu[c] = m;
    rstd[c] = rsqrtf(var + EPSf);
  }
}

// ---------------------------------------------------------------------------
// K4f: fused x2 = x + leaky(bn(hT)) ; x2t transpose (bf16, B,N,C) ; glb0 mean.
// One block = one b, 64 c-rows, all 80 n.
// ---------------------------------------------------------------------------
__global__ __launch_bounds__(256) void k_x2_fused(
    const float* __restrict__ x, const ushort* __restrict__ hT,
    const float* __restrict__ g, const float* __restrict__ be,
    const float* __restrict__ mu, const float* __restrict__ rstd,
    float* __restrict__ out, ushort* __restrict__ x2t, ushort* __restrict__ glb0b) {
  __shared__ float s[64][84];
  __shared__ float pg[64], pm[64], pb[64];
  const int t = threadIdx.x;
  const long row0 = (long)blockIdx.x * 64;     // row = b*C + c
  const int b = (int)(row0 >> 10), c0 = (int)(row0 & 1023);
  if (t < 64) {
    const int c = c0 + t;
    pg[t] = g[c] * rstd[c]; pm[t] = mu[c]; pb[t] = be[c];
  }
  __syncthreads();
  const float*  xb = x   + row0 * N_;
  const ushort* hb = hT  + row0 * N_;
  float*        ob = out + row0 * N_;
  for (int i4 = t; i4 < (64 * N_) / 4; i4 += TPB) {
    const int e = i4 * 4, r = e / N_, n = e % N_;
    float4 xv = *(const float4*)&xb[e];
    ushort4 hu = *(const ushort4*)&hb[e];
    const float gm = pg[r], m = pm[r], bb = pb[r];
    float4 o;
    o.x = xv.x + leakyf(gm * (b2f(hu.x) - m) + bb);
    o.y = xv.y + leakyf(gm * (b2f(hu.y) - m) + bb);
    o.z = xv.z + leakyf(gm * (b2f(hu.z) - m) + bb);
    o.w = xv.w + leakyf(gm * (b2f(hu.w) - m) + bb);
    *(float4*)&ob[e] = o;
    *(float4*)&s[r][n] = o;
  }
  __syncthreads();
  // transpose to (B,N,C) bf16
  const int tx = t % 16, ty = t / 16;
  ushort* tb = x2t + (size_t)b * CN + c0 + tx * 4;
#pragma unroll
  for (int u = 0; u < 5; ++u) {
    const int n = ty + 16 * u;
    ushort4 v;
    v.x = f2bf(s[tx * 4 + 0][n]); v.y = f2bf(s[tx * 4 + 1][n]);
    v.z = f2bf(s[tx * 4 + 2][n]); v.w = f2bf(s[tx * 4 + 3][n]);
    *(ushort4*)&tb[(size_t)n * C_] = v;
  }
  // glb0 mean over n — 4 threads per c-row, shfl-reduce the quad
  {
    const int r = t >> 2, q = t & 3;           // r in 0..63
    float sacc = 0.f;
    for (int n = q; n < N_; n += 4) sacc += s[r][n];
    sacc += __shfl_down(sacc, 1);
    sacc += __shfl_down(sacc, 2);
    if (q == 0) glb0b[(size_t)b * C_ + c0 + r] = f2bf(sacc * (1.0f / N_));
  }
}

// ---------------------------------------------------------------------------
// K7: BN over batch (256 rows) per channel + leaky -> bf16 out.
// ---------------------------------------------------------------------------
__global__ void k_bng(const float* __restrict__ glb1, const float* __restrict__ gg,
                      const float* __restrict__ gb, ushort* __restrict__ glbf) {
  const int c = blockIdx.x, t = threadIdx.x;
  const float v = glb1[(long)t * C_ + c];
  __shared__ float rs[TPB], rq[TPB];
  rs[t] = v; rq[t] = v * v; __syncthreads();
  for (int o = 128; o > 0; o >>= 1) { if (t < o) { rs[t] += rs[t + o]; rq[t] += rq[t + o]; } __syncthreads(); }
  __shared__ float sm, sr;
  if (t == 0) { const float m = rs[0] / B_; const float var = rq[0] / B_ - m * m; sm = m; sr = rsqrtf(var + EPSf); }
  __syncthreads();
  glbf[(long)t * C_ + c] = f2bf(leakyf(gg[c] * (v - sm) * sr + gb[c]));
}

// ---------------------------------------------------------------------------
// K9/K10: global minmax of dadj (2-pass). Normalization folded into consumers.
// ---------------------------------------------------------------------------
__global__ void k_minmax1(const float* __restrict__ d, float* __restrict__ bmin, float* __restrict__ bmax) {
  const int t = threadIdx.x;
  float lo = 3.4e38f, hi = -3.4e38f;
  for (long i = (long)blockIdx.x * TPB + t; i < BNN; i += (long)512 * TPB) {
    const float v = d[i]; lo = fminf(lo, v); hi = fmaxf(hi, v);
  }
  __shared__ float rl[TPB], rh[TPB];
  rl[t] = lo; rh[t] = hi; __syncthreads();
  for (int o = 128; o > 0; o >>= 1) { if (t < o) { rl[t] = fminf(rl[t], rl[t + o]); rh[t] = fmaxf(rh[t], rh[t + o]); } __syncthreads(); }
  if (t == 0) { bmin[blockIdx.x] = rl[0]; bmax[blockIdx.x] = rh[0]; }
}

__global__ void k_minmax2(const float* __restrict__ bmin, const float* __restrict__ bmax, float* __restrict__ dmm) {
  const int t = threadIdx.x;
  float lo = fminf(bmin[t], bmin[t + 256]);
  float hi = fmaxf(bmax[t], bmax[t + 256]);
  __shared__ float rl[TPB], rh[TPB];
  rl[t] = lo; rh[t] = hi; __syncthreads();
  for (int o = 128; o > 0; o >>= 1) { if (t < o) { rl[t] = fminf(rl[t], rl[t + o]); rh[t] = fmaxf(rh[t], rh[t + o]); } __syncthreads(); }
  if (t == 0) { dmm[0] = rl[0]; dmm[1] = 1.0f / (rh[0] - rl[0]); }
}

// ---------------------------------------------------------------------------
// K12: loss per batch; dadj read RAW, normalized inline via dmm.
// ---------------------------------------------------------------------------
__global__ void k_loss(const float* __restrict__ dadj, const float* __restrict__ sadj,
                       const float* __restrict__ out1, float* __restrict__ lossa,
                       const float* __restrict__ dmm) {
  const int b = blockIdx.x, t = threadIdx.x;
  const float* db = dadj + (long)b * NN;
  const float* o1 = out1 + b * N_;
  const float lo = dmm[0], inv = dmm[1];
  float p2 = 0.f;
  for (int i = t; i < NN; i += TPB) { const float d = (db[i] - lo) * inv - sadj[i]; p2 += d * d; }
  float p1 = 0.f;
  if (t < N_) {
    float acc = 0.f;
    for (int n = 0; n < N_; ++n) acc += o1[n] * ((db[n * N_ + t] - lo) * inv);
    const float d = o1[t] - acc * (1.0f / N_);
    p1 = d * d;
  }
  __shared__ float red[TPB];
  __shared__ float s2;
  red[t] = p2; __syncthreads();
  for (int o = 128; o > 0; o >>= 1) { if (t < o) red[t] += red[t + o]; __syncthreads(); }
  if (t == 0) s2 = red[0];
  __syncthreads();
  red[t] = p1; __syncthreads();
  for (int o = 128; o > 0; o >>= 1) { if (t < o) red[t] += red[t + o]; __syncthreads(); }
  if (t == 0) atomicAdd(lossa, sqrtf(s2) + sqrtf(red[0]));
}

// ---------------------------------------------------------------------------
// K14: final BN + leaky in place on d_out (B,C,N); writes loss scalar.
// ---------------------------------------------------------------------------
__global__ void k_final(float* __restrict__ outp, const float* __restrict__ g, const float* __restrict__ be,
                        const float* __restrict__ mu, const float* __restrict__ rstd,
                        const float* __restrict__ lossa) {
  const long i = ((long)blockIdx.x * TPB + threadIdx.x) * 4;
  const int c = (int)((i / N_) % C_);
  float4 v = *(const float4*)&outp[i];
  const float gm = g[c] * rstd[c], m = mu[c], bb = be[c];
  v.x = leakyf(gm * (v.x - m) + bb);
  v.y = leakyf(gm * (v.y - m) + bb);
  v.z = leakyf(gm * (v.z - m) + bb);
  v.w = leakyf(gm * (v.w - m) + bb);
  *(float4*)&outp[i] = v;
  if (blockIdx.x == 0 && threadIdx.x == 0) outp[BCN] = *lossa;
}

// ---------------------------------------------------------------------------
extern "C" void kernel_launch(void* const* d_in, const int* in_sizes, int n_in,
                              void* d_out, int out_size, void* d_ws, size_t ws_size,
                              hipStream_t stream) {
  const float* x    = (const float*)d_in[0];
  const float* out1 = (const float*)d_in[1];
  const float* ap   = (const float*)d_in[2];
  const float* Ws   = (const float*)d_in[3];
  const float* Wd   = (const float*)d_in[4];
  const float* Wg   = (const float*)d_in[5];
  const float* bg   = (const float*)d_in[6];
  const float* Wco  = (const float*)d_in[7];
  const float* bco  = (const float*)d_in[8];
  const float* bn_g  = (const float*)d_in[9];
  const float* bn_b  = (const float*)d_in[10];
  const float* bng_g = (const float*)d_in[11];
  const float* bng_b = (const float*)d_in[12];
  float* out = (float*)d_out;

  float* w = (float*)d_ws;
  float* sadj  = w;                    // 6400
  float* dadj  = sadj + NN;            // 1638400
  float* glb0  = dadj + BNN;           // 262144 (used as bf16 ushorts)
  float* glb1  = glb0 + B_ * C_;       // 262144
  float* glbf  = glb1 + B_ * C_;       // 262144 (used as bf16 ushorts)
  float* go    = glbf + B_ * C_;       // 20480
  float* mu1   = go + BNr;             // 1024
  float* rstd1 = mu1 + C_;             // 1024
  float* mu2   = rstd1 + C_;           // 1024
  float* rstd2 = mu2 + C_;             // 1024
  float* bmin  = rstd2 + C_;           // 512
  float* bmax  = bmin + 512;           // 512
  float* dmm   = bmax + 512;           // 2
  float* lossa = dmm + 2;              // 1
  ushort* ub   = (ushort*)(((uintptr_t)(lossa + 1) + 255) & ~(uintptr_t)255);
  ushort* xa_bf  = ub;                    // BCN bf16 (B,N,C): fold out / x2t / fold2 out
  ushort* hT_bf  = xa_bf + BCN;           // BCN bf16 (B,C,N)
  ushort* Wts    = hT_bf + BCN;           // 1M bf16 (O,C)
  ushort* Wtd    = Wts + (size_t)C_ * C_; // 1M bf16 (O,C)
  ushort* Wco2t  = Wtd + (size_t)C_ * C_; // 80K bf16 (80,1024)
  ushort* adj_bf = Wco2t + (size_t)N_ * C_; // 80x96 bf16 prepadded
  // bf16 aliases in regions dead at time of use:
  ushort* Wg_bf   = (ushort*)dadj;                      // 1M ushorts; dadj written later
  ushort* Wco1t   = (ushort*)dadj + (size_t)C_ * C_;    // 80K ushorts, same region
  ushort* glb0_bf = (ushort*)glb0;
  ushort* glbf_bf = (ushort*)glbf;
  ushort* x2t_bf  = xa_bf;                              // xa dead after GEMM#1; x2t dead before fold#2

  // ---- prep ----
  k_prep_adj<<<1, TPB, 0, stream>>>(ap, sadj, adj_bf, lossa);
  k_w_bf_t<<<dim3(32, 32), TPB, 0, stream>>>(Ws, Wts);
  k_w_bf_t<<<dim3(32, 32), TPB, 0, stream>>>(Wd, Wtd);
  k_wco_bf<<<(N_ * 2 * C_) / (4 * TPB), TPB, 0, stream>>>(Wco, Wco1t, Wco2t);
  k_cvt_bf<<<(C_ * C_) / (4 * TPB), TPB, 0, stream>>>(Wg, Wg_bf);
  k_zero_go<<<BNr / (4 * TPB), TPB, 0, stream>>>(go);

  // ---- static GCN ----
  k_fold_mfma<<<B_ * 8, TPB, 0, stream>>>(x, adj_bf, xa_bf, 0, dmm);
  k_gemm_256<<<320, 512, 0, stream>>>(xa_bf, Wts, hT_bf, 1);
  k_bn_stats_bf<<<C_, TPB, 0, stream>>>(hT_bf, mu1, rstd1);
  k_x2_fused<<<(B_ * C_) / 64, TPB, 0, stream>>>(x, hT_bf, bn_g, bn_b, mu1, rstd1,
                                                 out, x2t_bf, glb0_bf);

  // ---- dynamic graph construction ----
  k_glb_mfma<<<dim3(C_ / 64, B_ / 64), TPB, 0, stream>>>(glb0_bf, Wg_bf, bg, glb1);
  k_bng<<<C_, TPB, 0, stream>>>(glb1, bng_g, bng_b, glbf_bf);
  k_go_mfma<<<dim3(8, B_ / 128), TPB, 0, stream>>>(glbf_bf, Wco1t, go);
  k_dadj_mfma<<<BNr / 128, TPB, 0, stream>>>(x2t_bf, Wco2t, go, bco, dadj);
  k_minmax1<<<512, TPB, 0, stream>>>(dadj, bmin, bmax);
  k_minmax2<<<1, TPB, 0, stream>>>(bmin, bmax, dmm);

  // ---- adjacency loss (reads raw dadj + dmm) ----
  k_loss<<<B_, TPB, 0, stream>>>(dadj, sadj, out1, lossa, dmm);

  // ---- dynamic GCN (fold normalizes dadj inline via dmm) ----
  k_fold_mfma<<<B_ * 8, TPB, 0, stream>>>(out, dadj, xa_bf, 1, dmm);
  k_gemm_256<<<320, 512, 0, stream>>>(xa_bf, Wtd, out, 0);
  k_bn_stats<<<C_, TPB, 0, stream>>>(out, mu2, rstd2);
  k_final<<<(int)(BCN / (4 * TPB)), TPB, 0, stream>>>(out, bn_g, bn_b, mu2, rstd2, lossa);
}

// Round 5
// 534.503 us; speedup vs baseline: 1.3035x; 1.0642x over previous
//
#include <hip/hip_runtime.h>
#include <hip/hip_bf16.h>
#include <math.h>

#define TPB 256

constexpr int   B_  = 256;
constexpr int   C_  = 1024;
constexpr int   N_  = 80;
constexpr int   BNr = B_ * N_;                 // 20480 rows for BN / GEMM M
constexpr int   CN  = C_ * N_;                 // 81920
constexpr long  BCN = (long)B_ * C_ * N_;      // 20971520
constexpr int   NN  = N_ * N_;                 // 6400
constexpr int   BNN = B_ * NN;                 // 1638400
constexpr float EPSf = 1e-5f;

typedef __bf16 bf16x8 __attribute__((ext_vector_type(8)));
typedef float  f32x4  __attribute__((ext_vector_type(4)));

__device__ __forceinline__ float leakyf(float v) { return v >= 0.0f ? v : 0.2f * v; }

__device__ __forceinline__ ushort f2bf(float f) {
  __hip_bfloat16 h = __float2bfloat16(f);
  ushort u; __builtin_memcpy(&u, &h, 2); return u;
}
__device__ __forceinline__ float b2f(ushort u) {
  __hip_bfloat16 h; __builtin_memcpy(&h, &u, 2);
  return __bfloat162float(h);
}

#define GLOBAL_AS __attribute__((address_space(1)))
#define LDS_AS    __attribute__((address_space(3)))
__device__ __forceinline__ void load_lds16(const void* g, void* l) {
  __builtin_amdgcn_global_load_lds((const GLOBAL_AS void*)g, (LDS_AS void*)l, 16, 0, 0);
}

// ---------------------------------------------------------------------------
// K0: sadj = minmax(adj_param); D = rsqrt(rowsum);
// adj_bf[n*96+m] = bf16(D[n]*sadj[m,n]*D[m]) for m<80, 0 for m in [80,96).
// ---------------------------------------------------------------------------
__global__ void k_prep_adj(const float* __restrict__ ap, float* __restrict__ sadj,
                           ushort* __restrict__ adj_bf, float* __restrict__ lossa) {
  __shared__ float s[NN];
  __shared__ float red[TPB];
  __shared__ float s_lo, s_hi;
  __shared__ float sD[N_];
  const int t = threadIdx.x;
  float lo = 3.4e38f, hi = -3.4e38f;
  for (int i = t; i < NN; i += TPB) { float v = ap[i]; s[i] = v; lo = fminf(lo, v); hi = fmaxf(hi, v); }
  red[t] = lo; __syncthreads();
  for (int o = 128; o > 0; o >>= 1) { if (t < o) red[t] = fminf(red[t], red[t + o]); __syncthreads(); }
  if (t == 0) s_lo = red[0];
  __syncthreads();
  red[t] = hi; __syncthreads();
  for (int o = 128; o > 0; o >>= 1) { if (t < o) red[t] = fmaxf(red[t], red[t + o]); __syncthreads(); }
  if (t == 0) s_hi = red[0];
  __syncthreads();
  const float inv = 1.0f / (s_hi - s_lo);
  for (int i = t; i < NN; i += TPB) { float v = (s[i] - s_lo) * inv; s[i] = v; sadj[i] = v; }
  __syncthreads();
  if (t < N_) { float sum = 0.f; for (int m = 0; m < N_; ++m) sum += s[t * N_ + m]; sD[t] = rsqrtf(sum); }
  if (t == 0) *lossa = 0.0f;
  __syncthreads();
  for (int i = t; i < N_ * 96; i += TPB) {
    const int n = i / 96, m = i % 96;
    adj_bf[i] = f2bf((m < N_) ? sD[n] * s[m * N_ + n] * sD[m] : 0.0f);
  }
}

// ---------------------------------------------------------------------------
// KW: Wt[o][c] = bf16(W[c][o]) — transpose + convert, 32x32 LDS tiles.
// ---------------------------------------------------------------------------
__global__ void k_w_bf_t(const float* __restrict__ W, ushort* __restrict__ Wt) {
  __shared__ float s[32][33];
  const int t = threadIdx.x;
  const int tx = t % 32, ty = t / 32;            // 8 rows per pass
  const int r0 = blockIdx.y * 32, c0 = blockIdx.x * 32;
#pragma unroll
  for (int k = 0; k < 4; ++k) s[ty + 8 * k][tx] = W[(size_t)(r0 + ty + 8 * k) * C_ + c0 + tx];
  __syncthreads();
#pragma unroll
  for (int k = 0; k < 4; ++k) Wt[(size_t)(c0 + ty + 8 * k) * C_ + r0 + tx] = f2bf(s[tx][ty + 8 * k]);
}

// ---------------------------------------------------------------------------
// KW2: split Wco (80 x 2048) into two bf16 (80 x 1024) K-major buffers.
// ---------------------------------------------------------------------------
__global__ void k_wco_bf(const float* __restrict__ Wco, ushort* __restrict__ Wco1t,
                         ushort* __restrict__ Wco2t) {
  const int i4 = (blockIdx.x * TPB + threadIdx.x) * 4;   // 80*2048 elems
  const int o = i4 >> 11, k = i4 & 2047;
  float4 v = *(const float4*)&Wco[(size_t)o * 2048 + k];
  ushort4 u;
  u.x = f2bf(v.x); u.y = f2bf(v.y); u.z = f2bf(v.z); u.w = f2bf(v.w);
  if (k < C_) *(ushort4*)&Wco1t[(size_t)o * C_ + k] = u;
  else        *(ushort4*)&Wco2t[(size_t)o * C_ + (k - C_)] = u;
}

// ---------------------------------------------------------------------------
// KW3: plain fp32 -> bf16 elementwise convert (for Wg, already o-major/K-contig).
// ---------------------------------------------------------------------------
__global__ void k_cvt_bf(const float* __restrict__ W, ushort* __restrict__ Wb) {
  const long i4 = ((long)blockIdx.x * TPB + threadIdx.x) * 4;
  float4 v = *(const float4*)&W[i4];
  ushort4 u;
  u.x = f2bf(v.x); u.y = f2bf(v.y); u.z = f2bf(v.z); u.w = f2bf(v.w);
  *(ushort4*)&Wb[i4] = u;
}

// K-zero: go accumulator (20480 floats).
__global__ void k_zero_go(float* __restrict__ go) {
  const int i = (blockIdx.x * TPB + threadIdx.x) * 4;
  float4 z = make_float4(0.f, 0.f, 0.f, 0.f);
  *(float4*)&go[i] = z;
}

// ---------------------------------------------------------------------------
// K1v3: MFMA fold.  out[(b*80+n)*1024 + c] (bf16, B,N,C) =
//   sum_m adj[n,m] * X[b, c, m]
// mode 0: adjsrc = adj_bf global (80x96 bf16, prepadded); X from Xf32 (B,C,N).
// mode 1: adjsrc = dadj RAW fp32 (B,80,80), normalized by dmm, tadj in LDS;
//         X from Xbf (bf16, B,C,N) — no convert, half the read traffic.
// ---------------------------------------------------------------------------
__global__ __launch_bounds__(256) void k_fold_mfma(const float* __restrict__ Xf32,
                                                   const ushort* __restrict__ Xbf,
                                                   const void* __restrict__ adjsrc,
                                                   ushort* __restrict__ outp, int mode,
                                                   const float* __restrict__ dmm) {
  __shared__ __align__(16) ushort sX[128][104];     // rows c, cols m (pad->104, b128 2-way free)
  __shared__ __align__(16) ushort sAdj[80][104];    // rows n, cols m
  __shared__ float sD[N_];
  const int t = threadIdx.x;
  const int b  = blockIdx.x >> 3;
  const int c0 = (blockIdx.x & 7) * 128;

  // ---- adjacency -> sAdj (bf16, m 80..95 zero) ----
  if (mode == 0) {
    const ushort* ab = (const ushort*)adjsrc;
    for (int i = t; i < (N_ * 96) / 4; i += TPB) {
      ushort4 v = *(const ushort4*)&ab[i * 4];
      *(ushort4*)&sAdj[(i * 4) / 96][(i * 4) % 96] = v;
    }
    __syncthreads();
  } else {
    float* sF = (float*)&sX[0][0];                  // 80*80 fp32 = 25.6KB <= sX
    const float* db = (const float*)adjsrc + (size_t)b * NN;
    const float lo = dmm[0], inv = dmm[1];
    for (int i = t; i < NN / 4; i += TPB) {
      float4 v = *(const float4*)&db[i * 4];
      v.x = (v.x - lo) * inv; v.y = (v.y - lo) * inv;
      v.z = (v.z - lo) * inv; v.w = (v.w - lo) * inv;
      *(float4*)&sF[i * 4] = v;
    }
    __syncthreads();
    if (t < N_) { float s = 0.f; for (int m = 0; m < N_; ++m) s += sF[t * N_ + m]; sD[t] = rsqrtf(s); }
    __syncthreads();
    for (int i = t; i < N_ * 96; i += TPB) {
      const int n = i / 96, m = i % 96;
      sAdj[n][m] = f2bf((m < N_) ? sF[m * N_ + n] * sD[n] * sD[m] : 0.0f);
    }
    __syncthreads();                                 // before sX overwrite
  }

  // ---- stage X (128 rows x 80 m); zero pad m 80..95 ----
  if (mode == 0) {
    const float* Xb = Xf32 + ((size_t)b * C_ + c0) * N_;
    for (int i = t; i < (128 * N_) / 4; i += TPB) {
      float4 v = *(const float4*)&Xb[i * 4];
      const int r = (i * 4) / N_, m = (i * 4) % N_;
      ushort4 u; u.x = f2bf(v.x); u.y = f2bf(v.y); u.z = f2bf(v.z); u.w = f2bf(v.w);
      *(ushort4*)&sX[r][m] = u;
    }
  } else {
    const ushort* Xb = Xbf + ((size_t)b * C_ + c0) * N_;
    for (int i = t; i < (128 * N_) / 8; i += TPB) {  // 1280 chunks of 16B
      const int r = i / 10, m = (i % 10) * 8;
      uint4 v = *(const uint4*)&Xb[(size_t)r * N_ + m];
      *(uint4*)&sX[r][m] = v;
    }
  }
  for (int i = t; i < (128 * 16) / 4; i += TPB) {
    const int r = i / 4, m = 80 + (i % 4) * 4;
    ushort4 z; z.x = 0; z.y = 0; z.z = 0; z.w = 0;
    *(ushort4*)&sX[r][m] = z;
  }
  __syncthreads();

  const int lane = t & 63, wid = t >> 6;
  const int l16 = lane & 15, lq = lane >> 4;
  f32x4 acc[2][5];
#pragma unroll
  for (int i = 0; i < 2; ++i)
#pragma unroll
    for (int j = 0; j < 5; ++j) { f32x4 z = {0.f, 0.f, 0.f, 0.f}; acc[i][j] = z; }
  bf16x8 af[2][3], bfr[5][3];
#pragma unroll
  for (int i = 0; i < 2; ++i)
#pragma unroll
    for (int kk = 0; kk < 3; ++kk)
      af[i][kk] = *(const bf16x8*)&sX[wid * 32 + i * 16 + l16][kk * 32 + lq * 8];
#pragma unroll
  for (int j = 0; j < 5; ++j)
#pragma unroll
    for (int kk = 0; kk < 3; ++kk)
      bfr[j][kk] = *(const bf16x8*)&sAdj[j * 16 + l16][kk * 32 + lq * 8];
#pragma unroll
  for (int i = 0; i < 2; ++i)
#pragma unroll
    for (int j = 0; j < 5; ++j)
#pragma unroll
      for (int kk = 0; kk < 3; ++kk)
        acc[i][j] = __builtin_amdgcn_mfma_f32_16x16x32_bf16(af[i][kk], bfr[j][kk], acc[i][j], 0, 0, 0);

  // ---- epilogue: D[row=c_local (lq*4+reg)][col=n (l16)] -> (B,N,C) ushort4 ----
  ushort* ob = outp + (size_t)b * CN;
#pragma unroll
  for (int i = 0; i < 2; ++i) {
    const int c = c0 + wid * 32 + i * 16 + lq * 4;
#pragma unroll
    for (int j = 0; j < 5; ++j) {
      const int n = j * 16 + l16;
      ushort4 u;
      u.x = f2bf(acc[i][j][0]); u.y = f2bf(acc[i][j][1]);
      u.z = f2bf(acc[i][j][2]); u.w = f2bf(acc[i][j][3]);
      *(ushort4*)&ob[(size_t)n * C_ + c] = u;
    }
  }
}

// ---------------------------------------------------------------------------
// K2: 256x256x64 8-phase counted-vmcnt MFMA GEMM (T2+T3+T4+T5)
// + gray-code operand carry (48 ds_read_b128 / 8 phases). Verified r4.
// ---------------------------------------------------------------------------
__global__ __launch_bounds__(512, 2) void k_gemm_256(const ushort* __restrict__ A,
                                                     const ushort* __restrict__ Bt,
                                                     void* __restrict__ outp, int out_bf) {
  __shared__ ushort sA[2][256 * 64];   // 64 KB
  __shared__ ushort sB[2][256 * 64];   // 64 KB
  const int t = threadIdx.x;
  const int lane = t & 63, wid = t >> 6;       // 8 waves
  const int wm = wid >> 2, wn = wid & 3;       // 2 x 4
  const int l16 = lane & 15, lq = lane >> 4;

  // XCD-chunked swizzle: 320 blocks; each XCD: tm in [xcd*10, xcd*10+10), tn 0..3.
  const int lin = blockIdx.x;
  const int xcd = lin & 7, bi = lin >> 3;      // bi in 0..39
  const int tm = xcd * 10 + (bi >> 2);
  const int tn = bi & 3;
  const int m0 = tm * 256, o0 = tn * 256;

  const int srow = t >> 3;
  const int sswz = ((t & 7) ^ ((t >> 3) & 7)) * 8;   // elems

  f32x4 acc[8][4];
#pragma unroll
  for (int i = 0; i < 8; ++i)
#pragma unroll
    for (int j = 0; j < 4; ++j) { f32x4 z = {0.f, 0.f, 0.f, 0.f}; acc[i][j] = z; }

  bf16x8 afr[4][2], bfr0[2][2], bfr1[2][2];    // carried fragments

#define STA(PAR, ROWB, KT) load_lds16(A  + (size_t)(m0 + (ROWB) + srow) * C_ + (KT) * 64 + sswz, \
                                      &sA[PAR][((ROWB) + (wid << 3)) * 64])
#define STB(PAR, ROWB, KT) load_lds16(Bt + (size_t)(o0 + (ROWB) + srow) * C_ + (KT) * 64 + sswz, \
                                      &sB[PAR][((ROWB) + (wid << 3)) * 64])
#define STA_H(PAR, H, KT) { STA(PAR, (H)*128, KT); STA(PAR, (H)*128 + 64, KT); }
#define STB_H(PAR, H, KT) { STB(PAR, (H)*128, KT); STB(PAR, (H)*128 + 64, KT); }

#define RDA(PAR, MH)                                                                      \
  _Pragma("unroll") for (int fi = 0; fi < 4; ++fi) {                                      \
    const int row = ((MH) ? 128 : 0) + wm * 64 + fi * 16 + l16;                           \
    _Pragma("unroll") for (int kk = 0; kk < 2; ++kk)                                      \
      afr[fi][kk] = *(const bf16x8*)&sA[PAR][row * 64 + ((kk * 4 + lq) ^ (l16 & 7)) * 8]; \
  }
#define RDB(PAR, NH, DST)                                                                 \
  _Pragma("unroll") for (int gi = 0; gi < 2; ++gi) {                                      \
    const int row = ((NH) ? 128 : 0) + wn * 32 + gi * 16 + l16;                           \
    _Pragma("unroll") for (int kk = 0; kk < 2; ++kk)                                      \
      DST[gi][kk] = *(const bf16x8*)&sB[PAR][row * 64 + ((kk * 4 + lq) ^ (l16 & 7)) * 8]; \
  }

#define MFMAS(MH, NH, BF)                                                          \
  _Pragma("unroll") for (int kk = 0; kk < 2; ++kk)                                 \
  _Pragma("unroll") for (int fi = 0; fi < 4; ++fi)                                 \
  _Pragma("unroll") for (int gi = 0; gi < 2; ++gi)                                 \
    acc[(MH) * 4 + fi][(NH) * 2 + gi] = __builtin_amdgcn_mfma_f32_16x16x32_bf16(   \
        afr[fi][kk], BF[gi][kk], acc[(MH) * 4 + fi][(NH) * 2 + gi], 0, 0, 0);

#define PHASE(MH, NH, BF, RD, STAGES, VMW)                                         \
  {                                                                                \
    RD                                                                             \
    STAGES                                                                         \
    asm volatile("s_barrier" ::: "memory");                                        \
    asm volatile("s_waitcnt lgkmcnt(0)" ::: "memory");                             \
    __builtin_amdgcn_s_setprio(1);                                                 \
    MFMAS(MH, NH, BF)                                                              \
    __builtin_amdgcn_s_setprio(0);                                                 \
    VMW                                                                            \
    asm volatile("s_barrier" ::: "memory");                                        \
  }

  // prologue: T0 fully (8 calls) + T1's A-half0, B-half1 (4 calls)
  STA_H(0, 0, 0); STA_H(0, 1, 0); STB_H(0, 0, 0); STB_H(0, 1, 0);
  STA_H(1, 0, 1); STB_H(1, 1, 1);
  asm volatile("s_waitcnt vmcnt(4)" ::: "memory");
  asm volatile("s_barrier" ::: "memory");

  for (int i = 0; i < 7; ++i) {
    const int t1 = 2 * i + 1, t2 = 2 * i + 2, t3 = 2 * i + 3;
    PHASE(0, 0, bfr0, RDA(0, 0) RDB(0, 0, bfr0), { STA_H(1, 1, t1); }, {})
    PHASE(0, 1, bfr1, RDB(0, 1, bfr1),           { STB_H(1, 0, t1); }, {})
    PHASE(1, 1, bfr1, RDA(0, 1),                 { STA_H(0, 0, t2); }, {})
    PHASE(1, 0, bfr0, {},                        { STB_H(0, 1, t2); }, { asm volatile("s_waitcnt vmcnt(4)" ::: "memory"); })
    PHASE(0, 0, bfr0, RDA(1, 0) RDB(1, 0, bfr0), { STA_H(0, 1, t2); }, {})
    PHASE(0, 1, bfr1, RDB(1, 1, bfr1),           { STB_H(0, 0, t2); }, {})
    PHASE(1, 1, bfr1, RDA(1, 1),                 { STA_H(1, 0, t3); }, {})
    PHASE(1, 0, bfr0, {},                        { STB_H(1, 1, t3); }, { asm volatile("s_waitcnt vmcnt(4)" ::: "memory"); })
  }
  // peeled last iter: tiles 14 (par0), 15 (par1); only T15's A1/B0 remain to stage.
  PHASE(0, 0, bfr0, RDA(0, 0) RDB(0, 0, bfr0), { STA_H(1, 1, 15); }, {})
  PHASE(0, 1, bfr1, RDB(0, 1, bfr1),           { STB_H(1, 0, 15); }, {})
  PHASE(1, 1, bfr1, RDA(0, 1),                 {}, {})
  PHASE(1, 0, bfr0, {},                        {}, { asm volatile("s_waitcnt vmcnt(0)" ::: "memory"); })
  PHASE(0, 0, bfr0, RDA(1, 0) RDB(1, 0, bfr0), {}, {})
  PHASE(0, 1, bfr1, RDB(1, 1, bfr1),           {}, {})
  PHASE(1, 1, bfr1, RDA(1, 1),                 {}, {})
  PHASE(1, 0, bfr0, {},                        {}, {})

  // epilogue: row = lq*4+reg -> m; col = l16 -> o. (B,C,N) store, 4 consecutive n.
#pragma unroll
  for (int f = 0; f < 8; ++f) {
    const int gmb = (f < 4) ? (wm * 64 + f * 16) : (128 + wm * 64 + (f - 4) * 16);
    const int mg = m0 + gmb + lq * 4;
    const int b  = mg / 80;
    const int n0 = mg - b * 80;
#pragma unroll
    for (int gi = 0; gi < 4; ++gi) {
      const int gnb = (gi < 2) ? (wn * 32 + gi * 16) : (128 + wn * 32 + (gi - 2) * 16);
      const int og = o0 + gnb + l16;
      const size_t off = (size_t)b * CN + (size_t)og * N_ + n0;
      if (out_bf) {
        ushort4 u;
        u.x = f2bf(acc[f][gi][0]); u.y = f2bf(acc[f][gi][1]);
        u.z = f2bf(acc[f][gi][2]); u.w = f2bf(acc[f][gi][3]);
        *(ushort4*)((ushort*)outp + off) = u;
      } else {
        *(f32x4*)((float*)outp + off) = acc[f][gi];
      }
    }
  }
#undef STA
#undef STB
#undef STA_H
#undef STB_H
#undef RDA
#undef RDB
#undef MFMAS
#undef PHASE
}

// ---------------------------------------------------------------------------
// K2b: dadj MFMA GEMM. A: x2t bf16 (M=20480, K=1024). Bw: Wco2t bf16 (80,1024).
// dadj[b,o,n] = go[b,o] + bco[o] + sum_k A[m=(b,n)][k]*Bw[o][k].
// Fused per-block min/max -> bmin/bmax[160] (replaces k_minmax1 pass).
// ---------------------------------------------------------------------------
__global__ __launch_bounds__(256) void k_dadj_mfma(const ushort* __restrict__ A,
                                                   const ushort* __restrict__ Bw,
                                                   const float* __restrict__ go,
                                                   const float* __restrict__ bco,
                                                   float* __restrict__ dadj,
                                                   float* __restrict__ bmin,
                                                   float* __restrict__ bmax) {
  __shared__ ushort smA[128 * 32];
  __shared__ ushort smB[80 * 32];
  const int t = threadIdx.x;
  const int lane = t & 63, wid = t >> 6;
  const int m0 = blockIdx.x * 128;
  const int rto = t >> 2, ch = t & 3;
  const size_t gA0 = (size_t)(m0 + rto) * C_ + (size_t)ch * 8;
  ushort* ldsA = smA + wid * 512;
  const int l16 = lane & 15, lq = lane >> 4;
  const int wrow = wid * 32;
  f32x4 zero = {0.f, 0.f, 0.f, 0.f};
  f32x4 acc[2][5];
#pragma unroll
  for (int i = 0; i < 2; ++i)
#pragma unroll
    for (int j = 0; j < 5; ++j) acc[i][j] = zero;
  for (int k0 = 0; k0 < C_; k0 += 32) {
    load_lds16(A + gA0 + k0,            ldsA);
    load_lds16(A + gA0 + 64 * C_ + k0,  ldsA + 2048);
    {
      const int idx = t;                               // 320 chunks of 16B
      uint4 v = *(const uint4*)&Bw[(size_t)(idx >> 2) * C_ + k0 + (idx & 3) * 8];
      *(uint4*)&smB[idx * 8] = v;
      if (t < 64) {
        const int idx2 = 256 + t;
        uint4 v2 = *(const uint4*)&Bw[(size_t)(idx2 >> 2) * C_ + k0 + (idx2 & 3) * 8];
        *(uint4*)&smB[idx2 * 8] = v2;
      }
    }
    __syncthreads();
    bf16x8 af[2], bfr[5];
#pragma unroll
    for (int i = 0; i < 2; ++i) af[i]  = *(const bf16x8*)&smA[(wrow + i * 16 + l16) * 32 + lq * 8];
#pragma unroll
    for (int j = 0; j < 5; ++j) bfr[j] = *(const bf16x8*)&smB[(j * 16 + l16) * 32 + lq * 8];
#pragma unroll
    for (int i = 0; i < 2; ++i)
#pragma unroll
      for (int j = 0; j < 5; ++j)
        acc[i][j] = __builtin_amdgcn_mfma_f32_16x16x32_bf16(af[i], bfr[j], acc[i][j], 0, 0, 0);
    __syncthreads();
  }
  float vlo = 3.4e38f, vhi = -3.4e38f;
#pragma unroll
  for (int i = 0; i < 2; ++i) {
    const int mg = m0 + wrow + i * 16 + lq * 4;
    const int b  = mg / 80;
    const int n0 = mg - b * 80;
    const float* gob = go + b * N_;
#pragma unroll
    for (int j = 0; j < 5; ++j) {
      const int o = j * 16 + l16;
      const float g = gob[o] + bco[o];
      f32x4 v = acc[i][j];
      v[0] += g; v[1] += g; v[2] += g; v[3] += g;
      vlo = fminf(vlo, fminf(fminf(v[0], v[1]), fminf(v[2], v[3])));
      vhi = fmaxf(vhi, fmaxf(fmaxf(v[0], v[1]), fmaxf(v[2], v[3])));
      *(f32x4*)&dadj[(size_t)b * NN + (size_t)o * N_ + n0] = v;
    }
  }
  // block min/max reduce (reuse smA as float scratch; all LDS reads done)
  float* red = (float*)smA;
  red[t] = vlo; red[TPB + t] = vhi;
  __syncthreads();
  for (int o = 128; o > 0; o >>= 1) {
    if (t < o) {
      red[t] = fminf(red[t], red[t + o]);
      red[TPB + t] = fmaxf(red[TPB + t], red[TPB + t + o]);
    }
    __syncthreads();
  }
  if (t == 0) { bmin[blockIdx.x] = red[0]; bmax[blockIdx.x] = red[TPB]; }
}

// ---------------------------------------------------------------------------
// K2c: glb1 MFMA GEMM. A: glb0_bf (256 x 1024). Bw: Wg_bf (1024 x 1024, K-contig).
// ---------------------------------------------------------------------------
__global__ __launch_bounds__(256) void k_glb_mfma(const ushort* __restrict__ A,
                                                  const ushort* __restrict__ Bw,
                                                  const float* __restrict__ bias,
                                                  float* __restrict__ outp) {
  __shared__ ushort smA[2][64 * 32];
  __shared__ ushort smB[2][64 * 32];
  const int t = threadIdx.x;
  const int lane = t & 63, wid = t >> 6;
  const int o0 = blockIdx.x * 64, m0 = blockIdx.y * 64;
  const int rto = t >> 2, ch = t & 3;
  const size_t gA0 = (size_t)(m0 + rto) * C_ + (size_t)ch * 8;
  const size_t gB0 = (size_t)(o0 + rto) * C_ + (size_t)ch * 8;
  const int l16 = lane & 15, lq = lane >> 4;
  const int wm = wid & 1, wn = wid >> 1;
  f32x4 zero = {0.f, 0.f, 0.f, 0.f};
  f32x4 acc[2][2];
#pragma unroll
  for (int i = 0; i < 2; ++i)
#pragma unroll
    for (int j = 0; j < 2; ++j) acc[i][j] = zero;
  for (int k0 = 0; k0 < C_; k0 += 64) {
    load_lds16(A  + gA0 + k0,       smA[0] + wid * 512);
    load_lds16(A  + gA0 + k0 + 32,  smA[1] + wid * 512);
    load_lds16(Bw + gB0 + k0,       smB[0] + wid * 512);
    load_lds16(Bw + gB0 + k0 + 32,  smB[1] + wid * 512);
    __syncthreads();
#pragma unroll
    for (int h = 0; h < 2; ++h) {
      bf16x8 af[2], bfr[2];
#pragma unroll
      for (int i = 0; i < 2; ++i) af[i]  = *(const bf16x8*)&smA[h][(wm * 32 + i * 16 + l16) * 32 + lq * 8];
#pragma unroll
      for (int j = 0; j < 2; ++j) bfr[j] = *(const bf16x8*)&smB[h][(wn * 32 + j * 16 + l16) * 32 + lq * 8];
#pragma unroll
      for (int i = 0; i < 2; ++i)
#pragma unroll
        for (int j = 0; j < 2; ++j)
          acc[i][j] = __builtin_amdgcn_mfma_f32_16x16x32_bf16(af[i], bfr[j], acc[i][j], 0, 0, 0);
    }
    __syncthreads();
  }
#pragma unroll
  for (int i = 0; i < 2; ++i) {
    const int mg = m0 + wm * 32 + i * 16 + lq * 4;
#pragma unroll
    for (int j = 0; j < 2; ++j) {
      const int og = o0 + wn * 32 + j * 16 + l16;
      const float bs = bias[og];
      f32x4 v = acc[i][j];
#pragma unroll
      for (int r = 0; r < 4; ++r) outp[(size_t)(mg + r) * C_ + og] = v[r] + bs;
    }
  }
}

// ---------------------------------------------------------------------------
// K2d: go MFMA GEMM, split-K x8.  A: glbf_bf (256 x 1024). Bw: Wco1t (80 x 1024).
// ---------------------------------------------------------------------------
__global__ __launch_bounds__(256) void k_go_mfma(const ushort* __restrict__ A,
                                                 const ushort* __restrict__ Bw,
                                                 float* __restrict__ go) {
  __shared__ ushort smA[128 * 32];
  __shared__ ushort smB[80 * 32];
  const int t = threadIdx.x;
  const int lane = t & 63, wid = t >> 6;
  const int kbase = blockIdx.x * 128;
  const int m0 = blockIdx.y * 128;
  const int rto = t >> 2, ch = t & 3;
  const size_t gA0 = (size_t)(m0 + rto) * C_ + (size_t)ch * 8;
  ushort* ldsA = smA + wid * 512;
  const int l16 = lane & 15, lq = lane >> 4;
  const int wrow = wid * 32;
  f32x4 zero = {0.f, 0.f, 0.f, 0.f};
  f32x4 acc[2][5];
#pragma unroll
  for (int i = 0; i < 2; ++i)
#pragma unroll
    for (int j = 0; j < 5; ++j) acc[i][j] = zero;
  for (int kk0 = 0; kk0 < 128; kk0 += 32) {
    const int k0 = kbase + kk0;
    load_lds16(A + gA0 + k0,            ldsA);
    load_lds16(A + gA0 + 64 * C_ + k0,  ldsA + 2048);
    {
      const int idx = t;
      uint4 v = *(const uint4*)&Bw[(size_t)(idx >> 2) * C_ + k0 + (idx & 3) * 8];
      *(uint4*)&smB[idx * 8] = v;
      if (t < 64) {
        const int idx2 = 256 + t;
        uint4 v2 = *(const uint4*)&Bw[(size_t)(idx2 >> 2) * C_ + k0 + (idx2 & 3) * 8];
        *(uint4*)&smB[idx2 * 8] = v2;
      }
    }
    __syncthreads();
    bf16x8 af[2], bfr[5];
#pragma unroll
    for (int i = 0; i < 2; ++i) af[i]  = *(const bf16x8*)&smA[(wrow + i * 16 + l16) * 32 + lq * 8];
#pragma unroll
    for (int j = 0; j < 5; ++j) bfr[j] = *(const bf16x8*)&smB[(j * 16 + l16) * 32 + lq * 8];
#pragma unroll
    for (int i = 0; i < 2; ++i)
#pragma unroll
      for (int j = 0; j < 5; ++j)
        acc[i][j] = __builtin_amdgcn_mfma_f32_16x16x32_bf16(af[i], bfr[j], acc[i][j], 0, 0, 0);
    __syncthreads();
  }
#pragma unroll
  for (int i = 0; i < 2; ++i) {
    const int mg = m0 + wrow + i * 16 + lq * 4;
#pragma unroll
    for (int j = 0; j < 5; ++j) {
      const int o = j * 16 + l16;
#pragma unroll
      for (int r = 0; r < 4; ++r)
        atomicAdd(&go[(size_t)(mg + r) * N_ + o], acc[i][j][r]);
    }
  }
}

// ---------------------------------------------------------------------------
// K3b: BN stats per channel over (b,n), bf16 (B,C,N) input.
// ---------------------------------------------------------------------------
__global__ void k_bn_stats_bf(const ushort* __restrict__ X, float* __restrict__ mu, float* __restrict__ rstd) {
  const int c = blockIdx.x, t = threadIdx.x;
  const ushort* base = X + (long)c * N_;
  float s = 0.f, sq = 0.f;
  for (int i4 = t; i4 < BNr / 4; i4 += TPB) {
    const int b = i4 / 20, n0 = (i4 % 20) * 4;
    ushort4 v = *(const ushort4*)&base[(long)b * CN + n0];
    const float f0 = b2f(v.x), f1 = b2f(v.y), f2 = b2f(v.z), f3 = b2f(v.w);
    s += f0 + f1 + f2 + f3;
    sq += f0 * f0 + f1 * f1 + f2 * f2 + f3 * f3;
  }
  __shared__ float rs[TPB], rq[TPB];
  rs[t] = s; rq[t] = sq; __syncthreads();
  for (int o = 128; o > 0; o >>= 1) { if (t < o) { rs[t] += rs[t + o]; rq[t] += rq[t + o]; } __syncthreads(); }
  if (t == 0) {
    const float m = rs[0] / BNr;
    const float var = rq[0] / BNr - m * m;
    mu[c] = m;
    rstd[c] = rsqrtf(var + EPSf);
  }
}

// ---------------------------------------------------------------------------
// K4f: fused x2 = x + leaky(bn(hT)) ; bf16 x2 written IN PLACE over hT ;
// x2t transpose (bf16, B,N,C) ; glb0 mean. One block = one b, 64 c-rows.
// ---------------------------------------------------------------------------
__global__ __launch_bounds__(256) void k_x2_fused(
    const float* __restrict__ x, ushort* __restrict__ hx,
    const float* __restrict__ g, const float* __restrict__ be,
    const float* __restrict__ mu, const float* __restrict__ rstd,
    ushort* __restrict__ x2t, ushort* __restrict__ glb0b) {
  __shared__ float s[64][84];
  __shared__ float pg[64], pm[64], pb[64];
  const int t = threadIdx.x;
  const long row0 = (long)blockIdx.x * 64;     // row = b*C + c
  const int b = (int)(row0 >> 10), c0 = (int)(row0 & 1023);
  if (t < 64) {
    const int c = c0 + t;
    pg[t] = g[c] * rstd[c]; pm[t] = mu[c]; pb[t] = be[c];
  }
  __syncthreads();
  const float* xb = x  + row0 * N_;
  ushort*      hb = hx + row0 * N_;
  for (int i4 = t; i4 < (64 * N_) / 4; i4 += TPB) {
    const int e = i4 * 4, r = e / N_, n = e % N_;
    float4 xv = *(const float4*)&xb[e];
    ushort4 hu = *(const ushort4*)&hb[e];
    const float gm = pg[r], m = pm[r], bb = pb[r];
    float4 o;
    o.x = xv.x + leakyf(gm * (b2f(hu.x) - m) + bb);
    o.y = xv.y + leakyf(gm * (b2f(hu.y) - m) + bb);
    o.z = xv.z + leakyf(gm * (b2f(hu.z) - m) + bb);
    o.w = xv.w + leakyf(gm * (b2f(hu.w) - m) + bb);
    *(float4*)&s[r][n] = o;
    ushort4 ou;
    ou.x = f2bf(o.x); ou.y = f2bf(o.y); ou.z = f2bf(o.z); ou.w = f2bf(o.w);
    *(ushort4*)&hb[e] = ou;                     // in-place bf16 x2 (hT dead)
  }
  __syncthreads();
  // transpose to (B,N,C) bf16
  const int tx = t % 16, ty = t / 16;
  ushort* tb = x2t + (size_t)b * CN + c0 + tx * 4;
#pragma unroll
  for (int u = 0; u < 5; ++u) {
    const int n = ty + 16 * u;
    ushort4 v;
    v.x = f2bf(s[tx * 4 + 0][n]); v.y = f2bf(s[tx * 4 + 1][n]);
    v.z = f2bf(s[tx * 4 + 2][n]); v.w = f2bf(s[tx * 4 + 3][n]);
    *(ushort4*)&tb[(size_t)n * C_] = v;
  }
  // glb0 mean over n — 4 threads per c-row, shfl-reduce the quad
  {
    const int r = t >> 2, q = t & 3;           // r in 0..63
    float sacc = 0.f;
    for (int n = q; n < N_; n += 4) sacc += s[r][n];
    sacc += __shfl_down(sacc, 1);
    sacc += __shfl_down(sacc, 2);
    if (q == 0) glb0b[(size_t)b * C_ + c0 + r] = f2bf(sacc * (1.0f / N_));
  }
}

// ---------------------------------------------------------------------------
// K7: BN over batch (256 rows) per channel + leaky -> bf16 out.
// ---------------------------------------------------------------------------
__global__ void k_bng(const float* __restrict__ glb1, const float* __restrict__ gg,
                      const float* __restrict__ gb, ushort* __restrict__ glbf) {
  const int c = blockIdx.x, t = threadIdx.x;
  const float v = glb1[(long)t * C_ + c];
  __shared__ float rs[TPB], rq[TPB];
  rs[t] = v; rq[t] = v * v; __syncthreads();
  for (int o = 128; o > 0; o >>= 1) { if (t < o) { rs[t] += rs[t + o]; rq[t] += rq[t + o]; } __syncthreads(); }
  __shared__ float sm, sr;
  if (t == 0) { const float m = rs[0] / B_; const float var = rq[0] / B_ - m * m; sm = m; sr = rsqrtf(var + EPSf); }
  __syncthreads();
  glbf[(long)t * C_ + c] = f2bf(leakyf(gg[c] * (v - sm) * sr + gb[c]));
}

// ---------------------------------------------------------------------------
// K10: reduce 160 per-block min/max -> dmm.
// ---------------------------------------------------------------------------
__global__ void k_minmax2(const float* __restrict__ bmin, const float* __restrict__ bmax, float* __restrict__ dmm) {
  const int t = threadIdx.x;
  float lo = (t < 160) ? bmin[t] : 3.4e38f;
  float hi = (t < 160) ? bmax[t] : -3.4e38f;
  __shared__ float rl[TPB], rh[TPB];
  rl[t] = lo; rh[t] = hi; __syncthreads();
  for (int o = 128; o > 0; o >>= 1) { if (t < o) { rl[t] = fminf(rl[t], rl[t + o]); rh[t] = fmaxf(rh[t], rh[t + o]); } __syncthreads(); }
  if (t == 0) { dmm[0] = rl[0]; dmm[1] = 1.0f / (rh[0] - rl[0]); }
}

// ---------------------------------------------------------------------------
// K12: loss per batch; dadj read RAW, normalized inline via dmm.
// ---------------------------------------------------------------------------
__global__ void k_loss(const float* __restrict__ dadj, const float* __restrict__ sadj,
                       const float* __restrict__ out1, float* __restrict__ lossa,
                       const float* __restrict__ dmm) {
  const int b = blockIdx.x, t = threadIdx.x;
  const float* db = dadj + (long)b * NN;
  const float* o1 = out1 + b * N_;
  const float lo = dmm[0], inv = dmm[1];
  float p2 = 0.f;
  for (int i = t; i < NN; i += TPB) { const float d = (db[i] - lo) * inv - sadj[i]; p2 += d * d; }
  float p1 = 0.f;
  if (t < N_) {
    float acc = 0.f;
    for (int n = 0; n < N_; ++n) acc += o1[n] * ((db[n * N_ + t] - lo) * inv);
    const float d = o1[t] - acc * (1.0f / N_);
    p1 = d * d;
  }
  __shared__ float red[TPB];
  __shared__ float s2;
  red[t] = p2; __syncthreads();
  for (int o = 128; o > 0; o >>= 1) { if (t < o) red[t] += red[t + o]; __syncthreads(); }
  if (t == 0) s2 = red[0];
  __syncthreads();
  red[t] = p1; __syncthreads();
  for (int o = 128; o > 0; o >>= 1) { if (t < o) red[t] += red[t + o]; __syncthreads(); }
  if (t == 0) atomicAdd(lossa, sqrtf(s2) + sqrtf(red[0]));
}

// ---------------------------------------------------------------------------
// K14: final BN + leaky: reads h2 bf16 (B,C,N), writes fp32 out + loss scalar.
// ---------------------------------------------------------------------------
__global__ void k_final(const ushort* __restrict__ h2, float* __restrict__ outp,
                        const float* __restrict__ g, const float* __restrict__ be,
                        const float* __restrict__ mu, const float* __restrict__ rstd,
                        const float* __restrict__ lossa) {
  const long i = ((long)blockIdx.x * TPB + threadIdx.x) * 4;
  const int c = (int)((i / N_) % C_);
  ushort4 hu = *(const ushort4*)&h2[i];
  const float gm = g[c] * rstd[c], m = mu[c], bb = be[c];
  float4 v;
  v.x = leakyf(gm * (b2f(hu.x) - m) + bb);
  v.y = leakyf(gm * (b2f(hu.y) - m) + bb);
  v.z = leakyf(gm * (b2f(hu.z) - m) + bb);
  v.w = leakyf(gm * (b2f(hu.w) - m) + bb);
  *(float4*)&outp[i] = v;
  if (blockIdx.x == 0 && threadIdx.x == 0) outp[BCN] = *lossa;
}

// ---------------------------------------------------------------------------
extern "C" void kernel_launch(void* const* d_in, const int* in_sizes, int n_in,
                              void* d_out, int out_size, void* d_ws, size_t ws_size,
                              hipStream_t stream) {
  const float* x    = (const float*)d_in[0];
  const float* out1 = (const float*)d_in[1];
  const float* ap   = (const float*)d_in[2];
  const float* Ws   = (const float*)d_in[3];
  const float* Wd   = (const float*)d_in[4];
  const float* Wg   = (const float*)d_in[5];
  const float* bg   = (const float*)d_in[6];
  const float* Wco  = (const float*)d_in[7];
  const float* bco  = (const float*)d_in[8];
  const float* bn_g  = (const float*)d_in[9];
  const float* bn_b  = (const float*)d_in[10];
  const float* bng_g = (const float*)d_in[11];
  const float* bng_b = (const float*)d_in[12];
  float* out = (float*)d_out;

  float* w = (float*)d_ws;
  float* sadj  = w;                    // 6400
  float* dadj  = sadj + NN;            // 1638400
  float* glb0  = dadj + BNN;           // 262144 (used as bf16 ushorts)
  float* glb1  = glb0 + B_ * C_;       // 262144
  float* glbf  = glb1 + B_ * C_;       // 262144 (used as bf16 ushorts)
  float* go    = glbf + B_ * C_;       // 20480
  float* mu1   = go + BNr;             // 1024
  float* rstd1 = mu1 + C_;             // 1024
  float* mu2   = rstd1 + C_;           // 1024
  float* rstd2 = mu2 + C_;             // 1024
  float* bmin  = rstd2 + C_;           // 512 (160 used)
  float* bmax  = bmin + 512;           // 512 (160 used)
  float* dmm   = bmax + 512;           // 2
  float* lossa = dmm + 2;              // 1
  ushort* ub   = (ushort*)(((uintptr_t)(lossa + 1) + 255) & ~(uintptr_t)255);
  ushort* xa_bf  = ub;                    // BCN bf16 (B,N,C): fold out / x2t / fold2 out
  ushort* hT_bf  = xa_bf + BCN;           // BCN bf16 (B,C,N): h -> x2bf (in-place) -> h2
  ushort* Wts    = hT_bf + BCN;           // 1M bf16 (O,C)
  ushort* Wtd    = Wts + (size_t)C_ * C_; // 1M bf16 (O,C)
  ushort* Wco2t  = Wtd + (size_t)C_ * C_; // 80K bf16 (80,1024)
  ushort* adj_bf = Wco2t + (size_t)N_ * C_; // 80x96 bf16 prepadded
  // bf16 aliases in regions dead at time of use:
  ushort* Wg_bf   = (ushort*)dadj;                      // 1M ushorts; dadj written later
  ushort* Wco1t   = (ushort*)dadj + (size_t)C_ * C_;    // 80K ushorts, same region
  ushort* glb0_bf = (ushort*)glb0;
  ushort* glbf_bf = (ushort*)glbf;
  ushort* x2t_bf  = xa_bf;                              // xa dead after GEMM#1; x2t dead before fold#2

  // ---- prep ----
  k_prep_adj<<<1, TPB, 0, stream>>>(ap, sadj, adj_bf, lossa);
  k_w_bf_t<<<dim3(32, 32), TPB, 0, stream>>>(Ws, Wts);
  k_w_bf_t<<<dim3(32, 32), TPB, 0, stream>>>(Wd, Wtd);
  k_wco_bf<<<(N_ * 2 * C_) / (4 * TPB), TPB, 0, stream>>>(Wco, Wco1t, Wco2t);
  k_cvt_bf<<<(C_ * C_) / (4 * TPB), TPB, 0, stream>>>(Wg, Wg_bf);
  k_zero_go<<<BNr / (4 * TPB), TPB, 0, stream>>>(go);

  // ---- static GCN ----
  k_fold_mfma<<<B_ * 8, TPB, 0, stream>>>(x, hT_bf, adj_bf, xa_bf, 0, dmm);
  k_gemm_256<<<320, 512, 0, stream>>>(xa_bf, Wts, hT_bf, 1);
  k_bn_stats_bf<<<C_, TPB, 0, stream>>>(hT_bf, mu1, rstd1);
  k_x2_fused<<<(B_ * C_) / 64, TPB, 0, stream>>>(x, hT_bf, bn_g, bn_b, mu1, rstd1,
                                                 x2t_bf, glb0_bf);

  // ---- dynamic graph construction ----
  k_glb_mfma<<<dim3(C_ / 64, B_ / 64), TPB, 0, stream>>>(glb0_bf, Wg_bf, bg, glb1);
  k_bng<<<C_, TPB, 0, stream>>>(glb1, bng_g, bng_b, glbf_bf);
  k_go_mfma<<<dim3(8, B_ / 128), TPB, 0, stream>>>(glbf_bf, Wco1t, go);
  k_dadj_mfma<<<BNr / 128, TPB, 0, stream>>>(x2t_bf, Wco2t, go, bco, dadj, bmin, bmax);
  k_minmax2<<<1, TPB, 0, stream>>>(bmin, bmax, dmm);

  // ---- adjacency loss (reads raw dadj + dmm) ----
  k_loss<<<B_, TPB, 0, stream>>>(dadj, sadj, out1, lossa, dmm);

  // ---- dynamic GCN (fold reads x2 bf16 from hT region; normalizes dadj inline) ----
  k_fold_mfma<<<B_ * 8, TPB, 0, stream>>>(x, hT_bf, dadj, xa_bf, 1, dmm);
  k_gemm_256<<<320, 512, 0, stream>>>(xa_bf, Wtd, hT_bf, 1);
  k_bn_stats_bf<<<C_, TPB, 0, stream>>>(hT_bf, mu2, rstd2);
  k_final<<<(int)(BCN / (4 * TPB)), TPB, 0, stream>>>(hT_bf, out, bn_g, bn_b, mu2, rstd2, lossa);
}

// Round 7
// 503.424 us; speedup vs baseline: 1.3840x; 1.0617x over previous
//
#include <hip/hip_runtime.h>
#include <hip/hip_bf16.h>
#include <math.h>

#define TPB 256

constexpr int   B_  = 256;
constexpr int   C_  = 1024;
constexpr int   N_  = 80;
constexpr int   BNr = B_ * N_;                 // 20480 rows for BN / GEMM M
constexpr int   CN  = C_ * N_;                 // 81920
constexpr long  BCN = (long)B_ * C_ * N_;      // 20971520
constexpr int   NN  = N_ * N_;                 // 6400
constexpr int   BNN = B_ * NN;                 // 1638400
constexpr float EPSf = 1e-5f;

typedef __bf16 bf16x8 __attribute__((ext_vector_type(8)));
typedef float  f32x4  __attribute__((ext_vector_type(4)));

__device__ __forceinline__ float leakyf(float v) { return v >= 0.0f ? v : 0.2f * v; }

__device__ __forceinline__ ushort f2bf(float f) {
  __hip_bfloat16 h = __float2bfloat16(f);
  ushort u; __builtin_memcpy(&u, &h, 2); return u;
}
__device__ __forceinline__ float b2f(ushort u) {
  __hip_bfloat16 h; __builtin_memcpy(&h, &u, 2);
  return __bfloat162float(h);
}

#define GLOBAL_AS __attribute__((address_space(1)))
#define LDS_AS    __attribute__((address_space(3)))
__device__ __forceinline__ void load_lds16(const void* g, void* l) {
  __builtin_amdgcn_global_load_lds((const GLOBAL_AS void*)g, (LDS_AS void*)l, 16, 0, 0);
}

// ---------------------------------------------------------------------------
// K-PREP (merged): blockIdx ranges ->
//   [0,1024)    : Wts[o][c] = bf16(Ws[c][o])   (32x32 tile transpose)
//   [1024,2048) : Wtd[o][c] = bf16(Wd[c][o])
//   [2048,2208) : split Wco (80x2048) -> Wco1t / Wco2t bf16
//   [2208,3232) : Wg -> Wg_bf elementwise
//   [3232,3256) : zero go(20480) + ssum1/ssq1/ssum2/ssq2 (4096 floats)
//   [3256]      : prep_adj (sadj, adj_bf, lossa=0)
// ---------------------------------------------------------------------------
__global__ __launch_bounds__(256) void k_prep_all(
    const float* __restrict__ Ws, const float* __restrict__ Wd,
    const float* __restrict__ Wco, const float* __restrict__ Wg,
    ushort* __restrict__ Wts, ushort* __restrict__ Wtd,
    ushort* __restrict__ Wco1t, ushort* __restrict__ Wco2t, ushort* __restrict__ Wg_bf,
    float* __restrict__ zbase,
    const float* __restrict__ ap, float* __restrict__ sadj,
    ushort* __restrict__ adj_bf, float* __restrict__ lossa) {
  __shared__ float sh[NN];          // 25.6 KB; doubles as 32x33 transpose tile
  __shared__ float red[TPB];
  __shared__ float sD[N_];
  __shared__ float s_lo, s_hi;
  const int t = threadIdx.x;
  const int blk = blockIdx.x;
  if (blk < 2048) {
    const float* W = (blk < 1024) ? Ws : Wd;
    ushort* Wt = (blk < 1024) ? Wts : Wtd;
    const int bb = blk & 1023;
    const int bx = bb & 31, by = bb >> 5;
    const int tx = t % 32, ty = t / 32;
    const int r0 = by * 32, c0 = bx * 32;
#pragma unroll
    for (int k = 0; k < 4; ++k) sh[(ty + 8 * k) * 33 + tx] = W[(size_t)(r0 + ty + 8 * k) * C_ + c0 + tx];
    __syncthreads();
#pragma unroll
    for (int k = 0; k < 4; ++k) Wt[(size_t)(c0 + ty + 8 * k) * C_ + r0 + tx] = f2bf(sh[tx * 33 + ty + 8 * k]);
  } else if (blk < 2208) {
    const int i4 = ((blk - 2048) * TPB + t) * 4;   // 80*2048 elems
    const int o = i4 >> 11, k = i4 & 2047;
    float4 v = *(const float4*)&Wco[(size_t)o * 2048 + k];
    ushort4 u;
    u.x = f2bf(v.x); u.y = f2bf(v.y); u.z = f2bf(v.z); u.w = f2bf(v.w);
    if (k < C_) *(ushort4*)&Wco1t[(size_t)o * C_ + k] = u;
    else        *(ushort4*)&Wco2t[(size_t)o * C_ + (k - C_)] = u;
  } else if (blk < 3232) {
    const long i4 = ((long)(blk - 2208) * TPB + t) * 4;
    float4 v = *(const float4*)&Wg[i4];
    ushort4 u;
    u.x = f2bf(v.x); u.y = f2bf(v.y); u.z = f2bf(v.z); u.w = f2bf(v.w);
    *(ushort4*)&Wg_bf[i4] = u;
  } else if (blk < 3256) {
    const int i = ((blk - 3232) * TPB + t) * 4;    // 24576 floats
    float4 z = make_float4(0.f, 0.f, 0.f, 0.f);
    *(float4*)&zbase[i] = z;
  } else {
    // ---- prep_adj (single block) ----
    float lo = 3.4e38f, hi = -3.4e38f;
    for (int i = t; i < NN; i += TPB) { float v = ap[i]; sh[i] = v; lo = fminf(lo, v); hi = fmaxf(hi, v); }
    red[t] = lo; __syncthreads();
    for (int o = 128; o > 0; o >>= 1) { if (t < o) red[t] = fminf(red[t], red[t + o]); __syncthreads(); }
    if (t == 0) s_lo = red[0];
    __syncthreads();
    red[t] = hi; __syncthreads();
    for (int o = 128; o > 0; o >>= 1) { if (t < o) red[t] = fmaxf(red[t], red[t + o]); __syncthreads(); }
    if (t == 0) s_hi = red[0];
    __syncthreads();
    const float inv = 1.0f / (s_hi - s_lo);
    for (int i = t; i < NN; i += TPB) { float v = (sh[i] - s_lo) * inv; sh[i] = v; sadj[i] = v; }
    __syncthreads();
    if (t < N_) { float sum = 0.f; for (int m = 0; m < N_; ++m) sum += sh[t * N_ + m]; sD[t] = rsqrtf(sum); }
    if (t == 0) *lossa = 0.0f;
    __syncthreads();
    for (int i = t; i < N_ * 96; i += TPB) {
      const int n = i / 96, m = i % 96;
      adj_bf[i] = f2bf((m < N_) ? sD[n] * sh[m * N_ + n] * sD[m] : 0.0f);
    }
  }
}

// ---------------------------------------------------------------------------
// K1v3: MFMA fold.  out[(b*80+n)*1024 + c] (bf16, B,N,C) =
//   sum_m adj[n,m] * X[b, c, m]
// mode 0: adjsrc = adj_bf global (80x96 bf16, prepadded); X from Xf32 (B,C,N).
// mode 1: adjsrc = dadj RAW fp32 (B,80,80), normalized by dmm, tadj in LDS;
//         X from Xbf (bf16, B,C,N).
// ---------------------------------------------------------------------------
__global__ __launch_bounds__(256) void k_fold_mfma(const float* __restrict__ Xf32,
                                                   const ushort* __restrict__ Xbf,
                                                   const void* __restrict__ adjsrc,
                                                   ushort* __restrict__ outp, int mode,
                                                   const float* __restrict__ dmm) {
  __shared__ __align__(16) ushort sX[128][104];     // rows c, cols m (pad->104, b128 2-way free)
  __shared__ __align__(16) ushort sAdj[80][104];    // rows n, cols m
  __shared__ float sD[N_];
  const int t = threadIdx.x;
  const int b  = blockIdx.x >> 3;
  const int c0 = (blockIdx.x & 7) * 128;

  // ---- adjacency -> sAdj (bf16, m 80..95 zero) ----
  if (mode == 0) {
    const ushort* ab = (const ushort*)adjsrc;
    for (int i = t; i < (N_ * 96) / 4; i += TPB) {
      ushort4 v = *(const ushort4*)&ab[i * 4];
      *(ushort4*)&sAdj[(i * 4) / 96][(i * 4) % 96] = v;
    }
    __syncthreads();
  } else {
    float* sF = (float*)&sX[0][0];                  // 80*80 fp32 = 25.6KB <= sX
    const float* db = (const float*)adjsrc + (size_t)b * NN;
    const float lo = dmm[0], inv = dmm[1];
    for (int i = t; i < NN / 4; i += TPB) {
      float4 v = *(const float4*)&db[i * 4];
      v.x = (v.x - lo) * inv; v.y = (v.y - lo) * inv;
      v.z = (v.z - lo) * inv; v.w = (v.w - lo) * inv;
      *(float4*)&sF[i * 4] = v;
    }
    __syncthreads();
    if (t < N_) { float s = 0.f; for (int m = 0; m < N_; ++m) s += sF[t * N_ + m]; sD[t] = rsqrtf(s); }
    __syncthreads();
    for (int i = t; i < N_ * 96; i += TPB) {
      const int n = i / 96, m = i % 96;
      sAdj[n][m] = f2bf((m < N_) ? sF[m * N_ + n] * sD[n] * sD[m] : 0.0f);
    }
    __syncthreads();                                 // before sX overwrite
  }

  // ---- stage X (128 rows x 80 m); zero pad m 80..95 ----
  if (mode == 0) {
    const float* Xb = Xf32 + ((size_t)b * C_ + c0) * N_;
    for (int i = t; i < (128 * N_) / 4; i += TPB) {
      float4 v = *(const float4*)&Xb[i * 4];
      const int r = (i * 4) / N_, m = (i * 4) % N_;
      ushort4 u; u.x = f2bf(v.x); u.y = f2bf(v.y); u.z = f2bf(v.z); u.w = f2bf(v.w);
      *(ushort4*)&sX[r][m] = u;
    }
  } else {
    const ushort* Xb = Xbf + ((size_t)b * C_ + c0) * N_;
    for (int i = t; i < (128 * N_) / 8; i += TPB) {  // 1280 chunks of 16B
      const int r = i / 10, m = (i % 10) * 8;
      uint4 v = *(const uint4*)&Xb[(size_t)r * N_ + m];
      *(uint4*)&sX[r][m] = v;
    }
  }
  for (int i = t; i < (128 * 16) / 4; i += TPB) {
    const int r = i / 4, m = 80 + (i % 4) * 4;
    ushort4 z; z.x = 0; z.y = 0; z.z = 0; z.w = 0;
    *(ushort4*)&sX[r][m] = z;
  }
  __syncthreads();

  const int lane = t & 63, wid = t >> 6;
  const int l16 = lane & 15, lq = lane >> 4;
  f32x4 acc[2][5];
#pragma unroll
  for (int i = 0; i < 2; ++i)
#pragma unroll
    for (int j = 0; j < 5; ++j) { f32x4 z = {0.f, 0.f, 0.f, 0.f}; acc[i][j] = z; }
  bf16x8 af[2][3], bfr[5][3];
#pragma unroll
  for (int i = 0; i < 2; ++i)
#pragma unroll
    for (int kk = 0; kk < 3; ++kk)
      af[i][kk] = *(const bf16x8*)&sX[wid * 32 + i * 16 + l16][kk * 32 + lq * 8];
#pragma unroll
  for (int j = 0; j < 5; ++j)
#pragma unroll
    for (int kk = 0; kk < 3; ++kk)
      bfr[j][kk] = *(const bf16x8*)&sAdj[j * 16 + l16][kk * 32 + lq * 8];
#pragma unroll
  for (int i = 0; i < 2; ++i)
#pragma unroll
    for (int j = 0; j < 5; ++j)
#pragma unroll
      for (int kk = 0; kk < 3; ++kk)
        acc[i][j] = __builtin_amdgcn_mfma_f32_16x16x32_bf16(af[i][kk], bfr[j][kk], acc[i][j], 0, 0, 0);

  // ---- epilogue: D[row=c_local (lq*4+reg)][col=n (l16)] -> (B,N,C) ushort4 ----
  ushort* ob = outp + (size_t)b * CN;
#pragma unroll
  for (int i = 0; i < 2; ++i) {
    const int c = c0 + wid * 32 + i * 16 + lq * 4;
#pragma unroll
    for (int j = 0; j < 5; ++j) {
      const int n = j * 16 + l16;
      ushort4 u;
      u.x = f2bf(acc[i][j][0]); u.y = f2bf(acc[i][j][1]);
      u.z = f2bf(acc[i][j][2]); u.w = f2bf(acc[i][j][3]);
      *(ushort4*)&ob[(size_t)n * C_ + c] = u;
    }
  }
}

// ---------------------------------------------------------------------------
// K2: 256x256x64 8-phase counted-vmcnt MFMA GEMM (T2+T3+T4+T5)
// + gray-code operand carry (48 ds_read_b128 / 8 phases). Verified r4/r5.
// + fused per-channel BN partial stats: sum/sumsq over this block's 256 rows,
//   reduced via deterministic LDS slots [256ch][8], one atomicAdd pair/channel.
// ---------------------------------------------------------------------------
__global__ __launch_bounds__(512, 2) void k_gemm_256(const ushort* __restrict__ A,
                                                     const ushort* __restrict__ Bt,
                                                     void* __restrict__ outp, int out_bf,
                                                     float* __restrict__ bnsum,
                                                     float* __restrict__ bnsq) {
  __shared__ ushort sA[2][256 * 64];   // 64 KB
  __shared__ ushort sB[2][256 * 64];   // 64 KB
  const int t = threadIdx.x;
  const int lane = t & 63, wid = t >> 6;       // 8 waves
  const int wm = wid >> 2, wn = wid & 3;       // 2 x 4
  const int l16 = lane & 15, lq = lane >> 4;

  // XCD-chunked swizzle: 320 blocks; each XCD: tm in [xcd*10, xcd*10+10), tn 0..3.
  const int lin = blockIdx.x;
  const int xcd = lin & 7, bi = lin >> 3;      // bi in 0..39
  const int tm = xcd * 10 + (bi >> 2);
  const int tn = bi & 3;
  const int m0 = tm * 256, o0 = tn * 256;

  const int srow = t >> 3;
  const int sswz = ((t & 7) ^ ((t >> 3) & 7)) * 8;   // elems

  f32x4 acc[8][4];
#pragma unroll
  for (int i = 0; i < 8; ++i)
#pragma unroll
    for (int j = 0; j < 4; ++j) { f32x4 z = {0.f, 0.f, 0.f, 0.f}; acc[i][j] = z; }

  bf16x8 afr[4][2], bfr0[2][2], bfr1[2][2];    // carried fragments

#define STA(PAR, ROWB, KT) load_lds16(A  + (size_t)(m0 + (ROWB) + srow) * C_ + (KT) * 64 + sswz, \
                                      &sA[PAR][((ROWB) + (wid << 3)) * 64])
#define STB(PAR, ROWB, KT) load_lds16(Bt + (size_t)(o0 + (ROWB) + srow) * C_ + (KT) * 64 + sswz, \
                                      &sB[PAR][((ROWB) + (wid << 3)) * 64])
#define STA_H(PAR, H, KT) { STA(PAR, (H)*128, KT); STA(PAR, (H)*128 + 64, KT); }
#define STB_H(PAR, H, KT) { STB(PAR, (H)*128, KT); STB(PAR, (H)*128 + 64, KT); }

#define RDA(PAR, MH)                                                                      \
  _Pragma("unroll") for (int fi = 0; fi < 4; ++fi) {                                      \
    const int row = ((MH) ? 128 : 0) + wm * 64 + fi * 16 + l16;                           \
    _Pragma("unroll") for (int kk = 0; kk < 2; ++kk)                                      \
      afr[fi][kk] = *(const bf16x8*)&sA[PAR][row * 64 + ((kk * 4 + lq) ^ (l16 & 7)) * 8]; \
  }
#define RDB(PAR, NH, DST)                                                                 \
  _Pragma("unroll") for (int gi = 0; gi < 2; ++gi) {                                      \
    const int row = ((NH) ? 128 : 0) + wn * 32 + gi * 16 + l16;                           \
    _Pragma("unroll") for (int kk = 0; kk < 2; ++kk)                                      \
      DST[gi][kk] = *(const bf16x8*)&sB[PAR][row * 64 + ((kk * 4 + lq) ^ (l16 & 7)) * 8]; \
  }

#define MFMAS(MH, NH, BF)                                                          \
  _Pragma("unroll") for (int kk = 0; kk < 2; ++kk)                                 \
  _Pragma("unroll") for (int fi = 0; fi < 4; ++fi)                                 \
  _Pragma("unroll") for (int gi = 0; gi < 2; ++gi)                                 \
    acc[(MH) * 4 + fi][(NH) * 2 + gi] = __builtin_amdgcn_mfma_f32_16x16x32_bf16(   \
        afr[fi][kk], BF[gi][kk], acc[(MH) * 4 + fi][(NH) * 2 + gi], 0, 0, 0);

#define PHASE(MH, NH, BF, RD, STAGES, VMW)                                         \
  {                                                                                \
    RD                                                                             \
    STAGES                                                                         \
    asm volatile("s_barrier" ::: "memory");                                        \
    asm volatile("s_waitcnt lgkmcnt(0)" ::: "memory");                             \
    __builtin_amdgcn_s_setprio(1);                                                 \
    MFMAS(MH, NH, BF)                                                              \
    __builtin_amdgcn_s_setprio(0);                                                 \
    VMW                                                                            \
    asm volatile("s_barrier" ::: "memory");                                        \
  }

  // prologue: T0 fully (8 calls) + T1's A-half0, B-half1 (4 calls)
  STA_H(0, 0, 0); STA_H(0, 1, 0); STB_H(0, 0, 0); STB_H(0, 1, 0);
  STA_H(1, 0, 1); STB_H(1, 1, 1);
  asm volatile("s_waitcnt vmcnt(4)" ::: "memory");
  asm volatile("s_barrier" ::: "memory");

  for (int i = 0; i < 7; ++i) {
    const int t1 = 2 * i + 1, t2 = 2 * i + 2, t3 = 2 * i + 3;
    PHASE(0, 0, bfr0, RDA(0, 0) RDB(0, 0, bfr0), { STA_H(1, 1, t1); }, {})
    PHASE(0, 1, bfr1, RDB(0, 1, bfr1),           { STB_H(1, 0, t1); }, {})
    PHASE(1, 1, bfr1, RDA(0, 1),                 { STA_H(0, 0, t2); }, {})
    PHASE(1, 0, bfr0, {},                        { STB_H(0, 1, t2); }, { asm volatile("s_waitcnt vmcnt(4)" ::: "memory"); })
    PHASE(0, 0, bfr0, RDA(1, 0) RDB(1, 0, bfr0), { STA_H(0, 1, t2); }, {})
    PHASE(0, 1, bfr1, RDB(1, 1, bfr1),           { STB_H(0, 0, t2); }, {})
    PHASE(1, 1, bfr1, RDA(1, 1),                 { STA_H(1, 0, t3); }, {})
    PHASE(1, 0, bfr0, {},                        { STB_H(1, 1, t3); }, { asm volatile("s_waitcnt vmcnt(4)" ::: "memory"); })
  }
  // peeled last iter: tiles 14 (par0), 15 (par1); only T15's A1/B0 remain to stage.
  PHASE(0, 0, bfr0, RDA(0, 0) RDB(0, 0, bfr0), { STA_H(1, 1, 15); }, {})
  PHASE(0, 1, bfr1, RDB(0, 1, bfr1),           { STB_H(1, 0, 15); }, {})
  PHASE(1, 1, bfr1, RDA(0, 1),                 {}, {})
  PHASE(1, 0, bfr0, {},                        {}, { asm volatile("s_waitcnt vmcnt(0)" ::: "memory"); })
  PHASE(0, 0, bfr0, RDA(1, 0) RDB(1, 0, bfr0), {}, {})
  PHASE(0, 1, bfr1, RDB(1, 1, bfr1),           {}, {})
  PHASE(1, 1, bfr1, RDA(1, 1),                 {}, {})
  PHASE(1, 0, bfr0, {},                        {}, {})

  // epilogue: row = lq*4+reg -> m; col = l16 -> o. (B,C,N) store, 4 consecutive n.
#pragma unroll
  for (int f = 0; f < 8; ++f) {
    const int gmb = (f < 4) ? (wm * 64 + f * 16) : (128 + wm * 64 + (f - 4) * 16);
    const int mg = m0 + gmb + lq * 4;
    const int b  = mg / 80;
    const int n0 = mg - b * 80;
#pragma unroll
    for (int gi = 0; gi < 4; ++gi) {
      const int gnb = (gi < 2) ? (wn * 32 + gi * 16) : (128 + wn * 32 + (gi - 2) * 16);
      const int og = o0 + gnb + l16;
      const size_t off = (size_t)b * CN + (size_t)og * N_ + n0;
      if (out_bf) {
        ushort4 u;
        u.x = f2bf(acc[f][gi][0]); u.y = f2bf(acc[f][gi][1]);
        u.z = f2bf(acc[f][gi][2]); u.w = f2bf(acc[f][gi][3]);
        *(ushort4*)((ushort*)outp + off) = u;
      } else {
        *(f32x4*)((float*)outp + off) = acc[f][gi];
      }
    }
  }

  // ---- fused BN partial stats (sA free after last phase barrier) ----
  {
    float* redS = (float*)&sA[0][0];           // [256][8]
    float* redQ = redS + 2048;                 // [256][8]
    const int slot = wm * 4 + lq;
#pragma unroll
    for (int gi = 0; gi < 4; ++gi) {
      float s = 0.f, q = 0.f;
#pragma unroll
      for (int f = 0; f < 8; ++f)
#pragma unroll
        for (int r = 0; r < 4; ++r) { const float v = acc[f][gi][r]; s += v; q += v * v; }
      const int gnb = (gi < 2) ? (wn * 32 + gi * 16) : (128 + wn * 32 + (gi - 2) * 16);
      const int ol = gnb + l16;                // 0..255, unique per (wn,gi,l16)
      redS[ol * 8 + slot] = s;
      redQ[ol * 8 + slot] = q;
    }
    __syncthreads();
    if (t < 256) {
      float s = 0.f, q = 0.f;
#pragma unroll
      for (int k = 0; k < 8; ++k) { s += redS[t * 8 + k]; q += redQ[t * 8 + k]; }
      atomicAdd(&bnsum[o0 + t], s);
      atomicAdd(&bnsq[o0 + t], q);
    }
  }
#undef STA
#undef STB
#undef STA_H
#undef STB_H
#undef RDA
#undef RDB
#undef MFMAS
#undef PHASE
}

// ---------------------------------------------------------------------------
// K2b: dadj MFMA GEMM. A: x2t bf16 (M=20480, K=1024). Bw: Wco2t bf16 (80,1024).
// dadj[b,o,n] = go[b,o] + bco[o] + sum_k A[m=(b,n)][k]*Bw[o][k].
// Fused per-block min/max -> bmin/bmax[160].
// ---------------------------------------------------------------------------
__global__ __launch_bounds__(256) void k_dadj_mfma(const ushort* __restrict__ A,
                                                   const ushort* __restrict__ Bw,
                                                   const float* __restrict__ go,
                                                   const float* __restrict__ bco,
                                                   float* __restrict__ dadj,
                                                   float* __restrict__ bmin,
                                                   float* __restrict__ bmax) {
  __shared__ ushort smA[128 * 32];
  __shared__ ushort smB[80 * 32];
  const int t = threadIdx.x;
  const int lane = t & 63, wid = t >> 6;
  const int m0 = blockIdx.x * 128;
  const int rto = t >> 2, ch = t & 3;
  const size_t gA0 = (size_t)(m0 + rto) * C_ + (size_t)ch * 8;
  ushort* ldsA = smA + wid * 512;
  const int l16 = lane & 15, lq = lane >> 4;
  const int wrow = wid * 32;
  f32x4 zero = {0.f, 0.f, 0.f, 0.f};
  f32x4 acc[2][5];
#pragma unroll
  for (int i = 0; i < 2; ++i)
#pragma unroll
    for (int j = 0; j < 5; ++j) acc[i][j] = zero;
  for (int k0 = 0; k0 < C_; k0 += 32) {
    load_lds16(A + gA0 + k0,            ldsA);
    load_lds16(A + gA0 + 64 * C_ + k0,  ldsA + 2048);
    {
      const int idx = t;                               // 320 chunks of 16B
      uint4 v = *(const uint4*)&Bw[(size_t)(idx >> 2) * C_ + k0 + (idx & 3) * 8];
      *(uint4*)&smB[idx * 8] = v;
      if (t < 64) {
        const int idx2 = 256 + t;
        uint4 v2 = *(const uint4*)&Bw[(size_t)(idx2 >> 2) * C_ + k0 + (idx2 & 3) * 8];
        *(uint4*)&smB[idx2 * 8] = v2;
      }
    }
    __syncthreads();
    bf16x8 af[2], bfr[5];
#pragma unroll
    for (int i = 0; i < 2; ++i) af[i]  = *(const bf16x8*)&smA[(wrow + i * 16 + l16) * 32 + lq * 8];
#pragma unroll
    for (int j = 0; j < 5; ++j) bfr[j] = *(const bf16x8*)&smB[(j * 16 + l16) * 32 + lq * 8];
#pragma unroll
    for (int i = 0; i < 2; ++i)
#pragma unroll
      for (int j = 0; j < 5; ++j)
        acc[i][j] = __builtin_amdgcn_mfma_f32_16x16x32_bf16(af[i], bfr[j], acc[i][j], 0, 0, 0);
    __syncthreads();
  }
  float vlo = 3.4e38f, vhi = -3.4e38f;
#pragma unroll
  for (int i = 0; i < 2; ++i) {
    const int mg = m0 + wrow + i * 16 + lq * 4;
    const int b  = mg / 80;
    const int n0 = mg - b * 80;
    const float* gob = go + b * N_;
#pragma unroll
    for (int j = 0; j < 5; ++j) {
      const int o = j * 16 + l16;
      const float g = gob[o] + bco[o];
      f32x4 v = acc[i][j];
      v[0] += g; v[1] += g; v[2] += g; v[3] += g;
      vlo = fminf(vlo, fminf(fminf(v[0], v[1]), fminf(v[2], v[3])));
      vhi = fmaxf(vhi, fmaxf(fmaxf(v[0], v[1]), fmaxf(v[2], v[3])));
      *(f32x4*)&dadj[(size_t)b * NN + (size_t)o * N_ + n0] = v;
    }
  }
  // block min/max reduce (reuse smA as float scratch; all LDS reads done)
  float* red = (float*)smA;
  red[t] = vlo; red[TPB + t] = vhi;
  __syncthreads();
  for (int o = 128; o > 0; o >>= 1) {
    if (t < o) {
      red[t] = fminf(red[t], red[t + o]);
      red[TPB + t] = fmaxf(red[TPB + t], red[TPB + t + o]);
    }
    __syncthreads();
  }
  if (t == 0) { bmin[blockIdx.x] = red[0]; bmax[blockIdx.x] = red[TPB]; }
}

// ---------------------------------------------------------------------------
// K2c: glb1 MFMA GEMM. A: glb0_bf (256 x 1024). Bw: Wg_bf (1024 x 1024, K-contig).
// ---------------------------------------------------------------------------
__global__ __launch_bounds__(256) void k_glb_mfma(const ushort* __restrict__ A,
                                                  const ushort* __restrict__ Bw,
                                                  const float* __restrict__ bias,
                                                  float* __restrict__ outp) {
  __shared__ ushort smA[2][64 * 32];
  __shared__ ushort smB[2][64 * 32];
  const int t = threadIdx.x;
  const int lane = t & 63, wid = t >> 6;
  const int o0 = blockIdx.x * 64, m0 = blockIdx.y * 64;
  const int rto = t >> 2, ch = t & 3;
  const size_t gA0 = (size_t)(m0 + rto) * C_ + (size_t)ch * 8;
  const size_t gB0 = (size_t)(o0 + rto) * C_ + (size_t)ch * 8;
  const int l16 = lane & 15, lq = lane >> 4;
  const int wm = wid & 1, wn = wid >> 1;
  f32x4 zero = {0.f, 0.f, 0.f, 0.f};
  f32x4 acc[2][2];
#pragma unroll
  for (int i = 0; i < 2; ++i)
#pragma unroll
    for (int j = 0; j < 2; ++j) acc[i][j] = zero;
  for (int k0 = 0; k0 < C_; k0 += 64) {
    load_lds16(A  + gA0 + k0,       smA[0] + wid * 512);
    load_lds16(A  + gA0 + k0 + 32,  smA[1] + wid * 512);
    load_lds16(Bw + gB0 + k0,       smB[0] + wid * 512);
    load_lds16(Bw + gB0 + k0 + 32,  smB[1] + wid * 512);
    __syncthreads();
#pragma unroll
    for (int h = 0; h < 2; ++h) {
      bf16x8 af[2], bfr[2];
#pragma unroll
      for (int i = 0; i < 2; ++i) af[i]  = *(const bf16x8*)&smA[h][(wm * 32 + i * 16 + l16) * 32 + lq * 8];
#pragma unroll
      for (int j = 0; j < 2; ++j) bfr[j] = *(const bf16x8*)&smB[h][(wn * 32 + j * 16 + l16) * 32 + lq * 8];
#pragma unroll
      for (int i = 0; i < 2; ++i)
#pragma unroll
        for (int j = 0; j < 2; ++j)
          acc[i][j] = __builtin_amdgcn_mfma_f32_16x16x32_bf16(af[i], bfr[j], acc[i][j], 0, 0, 0);
    }
    __syncthreads();
  }
#pragma unroll
  for (int i = 0; i < 2; ++i) {
    const int mg = m0 + wm * 32 + i * 16 + lq * 4;
#pragma unroll
    for (int j = 0; j < 2; ++j) {
      const int og = o0 + wn * 32 + j * 16 + l16;
      const float bs = bias[og];
      f32x4 v = acc[i][j];
#pragma unroll
      for (int r = 0; r < 4; ++r) outp[(size_t)(mg + r) * C_ + og] = v[r] + bs;
    }
  }
}

// ---------------------------------------------------------------------------
// K2d: go MFMA GEMM, split-K x8.  A: glbf_bf (256 x 1024). Bw: Wco1t (80 x 1024).
// ---------------------------------------------------------------------------
__global__ __launch_bounds__(256) void k_go_mfma(const ushort* __restrict__ A,
                                                 const ushort* __restrict__ Bw,
                                                 float* __restrict__ go) {
  __shared__ ushort smA[128 * 32];
  __shared__ ushort smB[80 * 32];
  const int t = threadIdx.x;
  const int lane = t & 63, wid = t >> 6;
  const int kbase = blockIdx.x * 128;
  const int m0 = blockIdx.y * 128;
  const int rto = t >> 2, ch = t & 3;
  const size_t gA0 = (size_t)(m0 + rto) * C_ + (size_t)ch * 8;
  ushort* ldsA = smA + wid * 512;
  const int l16 = lane & 15, lq = lane >> 4;
  const int wrow = wid * 32;
  f32x4 zero = {0.f, 0.f, 0.f, 0.f};
  f32x4 acc[2][5];
#pragma unroll
  for (int i = 0; i < 2; ++i)
#pragma unroll
    for (int j = 0; j < 5; ++j) acc[i][j] = zero;
  for (int kk0 = 0; kk0 < 128; kk0 += 32) {
    const int k0 = kbase + kk0;
    load_lds16(A + gA0 + k0,            ldsA);
    load_lds16(A + gA0 + 64 * C_ + k0,  ldsA + 2048);
    {
      const int idx = t;
      uint4 v = *(const uint4*)&Bw[(size_t)(idx >> 2) * C_ + k0 + (idx & 3) * 8];
      *(uint4*)&smB[idx * 8] = v;
      if (t < 64) {
        const int idx2 = 256 + t;
        uint4 v2 = *(const uint4*)&Bw[(size_t)(idx2 >> 2) * C_ + k0 + (idx2 & 3) * 8];
        *(uint4*)&smB[idx2 * 8] = v2;
      }
    }
    __syncthreads();
    bf16x8 af[2], bfr[5];
#pragma unroll
    for (int i = 0; i < 2; ++i) af[i]  = *(const bf16x8*)&smA[(wrow + i * 16 + l16) * 32 + lq * 8];
#pragma unroll
    for (int j = 0; j < 5; ++j) bfr[j] = *(const bf16x8*)&smB[(j * 16 + l16) * 32 + lq * 8];
#pragma unroll
    for (int i = 0; i < 2; ++i)
#pragma unroll
      for (int j = 0; j < 5; ++j)
        acc[i][j] = __builtin_amdgcn_mfma_f32_16x16x32_bf16(af[i], bfr[j], acc[i][j], 0, 0, 0);
    __syncthreads();
  }
#pragma unroll
  for (int i = 0; i < 2; ++i) {
    const int mg = m0 + wrow + i * 16 + lq * 4;
#pragma unroll
    for (int j = 0; j < 5; ++j) {
      const int o = j * 16 + l16;
#pragma unroll
      for (int r = 0; r < 4; ++r)
        atomicAdd(&go[(size_t)(mg + r) * N_ + o], acc[i][j][r]);
    }
  }
}

// ---------------------------------------------------------------------------
// K4f: fused x2 = x + leaky(bn(hT)) ; bf16 x2 written IN PLACE over hT ;
// x2t transpose (bf16, B,N,C) ; glb0 mean. BN stats from fused gemm sums.
// ---------------------------------------------------------------------------
__global__ __launch_bounds__(256) void k_x2_fused(
    const float* __restrict__ x, ushort* __restrict__ hx,
    const float* __restrict__ g, const float* __restrict__ be,
    const float* __restrict__ ssum, const float* __restrict__ ssq,
    ushort* __restrict__ x2t, ushort* __restrict__ glb0b) {
  __shared__ float s[64][84];
  __shared__ float pg[64], pm[64], pb[64];
  const int t = threadIdx.x;
  const long row0 = (long)blockIdx.x * 64;     // row = b*C + c
  const int b = (int)(row0 >> 10), c0 = (int)(row0 & 1023);
  if (t < 64) {
    const int c = c0 + t;
    const float mu = ssum[c] * (1.0f / BNr);
    const float var = ssq[c] * (1.0f / BNr) - mu * mu;
    const float rstd = rsqrtf(var + EPSf);
    pg[t] = g[c] * rstd; pm[t] = mu; pb[t] = be[c];
  }
  __syncthreads();
  const float* xb = x  + row0 * N_;
  ushort*      hb = hx + row0 * N_;
  for (int i4 = t; i4 < (64 * N_) / 4; i4 += TPB) {
    const int e = i4 * 4, r = e / N_, n = e % N_;
    float4 xv = *(const float4*)&xb[e];
    ushort4 hu = *(const ushort4*)&hb[e];
    const float gm = pg[r], m = pm[r], bb = pb[r];
    float4 o;
    o.x = xv.x + leakyf(gm * (b2f(hu.x) - m) + bb);
    o.y = xv.y + leakyf(gm * (b2f(hu.y) - m) + bb);
    o.z = xv.z + leakyf(gm * (b2f(hu.z) - m) + bb);
    o.w = xv.w + leakyf(gm * (b2f(hu.w) - m) + bb);
    *(float4*)&s[r][n] = o;
    ushort4 ou;
    ou.x = f2bf(o.x); ou.y = f2bf(o.y); ou.z = f2bf(o.z); ou.w = f2bf(o.w);
    *(ushort4*)&hb[e] = ou;                     // in-place bf16 x2 (hT dead)
  }
  __syncthreads();
  // transpose to (B,N,C) bf16
  const int tx = t % 16, ty = t / 16;
  ushort* tb = x2t + (size_t)b * CN + c0 + tx * 4;
#pragma unroll
  for (int u = 0; u < 5; ++u) {
    const int n = ty + 16 * u;
    ushort4 v;
    v.x = f2bf(s[tx * 4 + 0][n]); v.y = f2bf(s[tx * 4 + 1][n]);
    v.z = f2bf(s[tx * 4 + 2][n]); v.w = f2bf(s[tx * 4 + 3][n]);
    *(ushort4*)&tb[(size_t)n * C_] = v;
  }
  // glb0 mean over n — 4 threads per c-row, shfl-reduce the quad
  {
    const int r = t >> 2, q = t & 3;           // r in 0..63
    float sacc = 0.f;
    for (int n = q; n < N_; n += 4) sacc += s[r][n];
    sacc += __shfl_down(sacc, 1);
    sacc += __shfl_down(sacc, 2);
    if (q == 0) glb0b[(size_t)b * C_ + c0 + r] = f2bf(sacc * (1.0f / N_));
  }
}

// ---------------------------------------------------------------------------
// K7: BN over batch (256 rows) per channel + leaky -> bf16 out.
// ---------------------------------------------------------------------------
__global__ void k_bng(const float* __restrict__ glb1, const float* __restrict__ gg,
                      const float* __restrict__ gb, ushort* __restrict__ glbf) {
  const int c = blockIdx.x, t = threadIdx.x;
  const float v = glb1[(long)t * C_ + c];
  __shared__ float rs[TPB], rq[TPB];
  rs[t] = v; rq[t] = v * v; __syncthreads();
  for (int o = 128; o > 0; o >>= 1) { if (t < o) { rs[t] += rs[t + o]; rq[t] += rq[t + o]; } __syncthreads(); }
  __shared__ float sm, sr;
  if (t == 0) { const float m = rs[0] / B_; const float var = rq[0] / B_ - m * m; sm = m; sr = rsqrtf(var + EPSf); }
  __syncthreads();
  glbf[(long)t * C_ + c] = f2bf(leakyf(gg[c] * (v - sm) * sr + gb[c]));
}

// ---------------------------------------------------------------------------
// K10: reduce 160 per-block min/max -> dmm.
// ---------------------------------------------------------------------------
__global__ void k_minmax2(const float* __restrict__ bmin, const float* __restrict__ bmax, float* __restrict__ dmm) {
  const int t = threadIdx.x;
  float lo = (t < 160) ? bmin[t] : 3.4e38f;
  float hi = (t < 160) ? bmax[t] : -3.4e38f;
  __shared__ float rl[TPB], rh[TPB];
  rl[t] = lo; rh[t] = hi; __syncthreads();
  for (int o = 128; o > 0; o >>= 1) { if (t < o) { rl[t] = fminf(rl[t], rl[t + o]); rh[t] = fmaxf(rh[t], rh[t + o]); } __syncthreads(); }
  if (t == 0) { dmm[0] = rl[0]; dmm[1] = 1.0f / (rh[0] - rl[0]); }
}

// ---------------------------------------------------------------------------
// K12: loss per batch; dadj read RAW, normalized inline via dmm.
// ---------------------------------------------------------------------------
__global__ void k_loss(const float* __restrict__ dadj, const float* __restrict__ sadj,
                       const float* __restrict__ out1, float* __restrict__ lossa,
                       const float* __restrict__ dmm) {
  const int b = blockIdx.x, t = threadIdx.x;
  const float* db = dadj + (long)b * NN;
  const float* o1 = out1 + b * N_;
  const float lo = dmm[0], inv = dmm[1];
  float p2 = 0.f;
  for (int i = t; i < NN; i += TPB) { const float d = (db[i] - lo) * inv - sadj[i]; p2 += d * d; }
  float p1 = 0.f;
  if (t < N_) {
    float acc = 0.f;
    for (int n = 0; n < N_; ++n) acc += o1[n] * ((db[n * N_ + t] - lo) * inv);
    const float d = o1[t] - acc * (1.0f / N_);
    p1 = d * d;
  }
  __shared__ float red[TPB];
  __shared__ float s2;
  red[t] = p2; __syncthreads();
  for (int o = 128; o > 0; o >>= 1) { if (t < o) red[t] += red[t + o]; __syncthreads(); }
  if (t == 0) s2 = red[0];
  __syncthreads();
  red[t] = p1; __syncthreads();
  for (int o = 128; o > 0; o >>= 1) { if (t < o) red[t] += red[t + o]; __syncthreads(); }
  if (t == 0) atomicAdd(lossa, sqrtf(s2) + sqrtf(red[0]));
}

// ---------------------------------------------------------------------------
// K14: final BN + leaky: reads h2 bf16 (B,C,N) + fused gemm sums,
// writes fp32 out + loss scalar.
// ---------------------------------------------------------------------------
__global__ void k_final(const ushort* __restrict__ h2, float* __restrict__ outp,
                        const float* __restrict__ g, const float* __restrict__ be,
                        const float* __restrict__ ssum, const float* __restrict__ ssq,
                        const float* __restrict__ lossa) {
  const long i = ((long)blockIdx.x * TPB + threadIdx.x) * 4;
  const int c = (int)((i / N_) % C_);
  ushort4 hu = *(const ushort4*)&h2[i];
  const float mu = ssum[c] * (1.0f / BNr);
  const float rstd = rsqrtf(ssq[c] * (1.0f / BNr) - mu * mu + EPSf);
  const float gm = g[c] * rstd, bb = be[c];
  float4 v;
  v.x = leakyf(gm * (b2f(hu.x) - mu) + bb);
  v.y = leakyf(gm * (b2f(hu.y) - mu) + bb);
  v.z = leakyf(gm * (b2f(hu.z) - mu) + bb);
  v.w = leakyf(gm * (b2f(hu.w) - mu) + bb);
  *(float4*)&outp[i] = v;
  if (blockIdx.x == 0 && threadIdx.x == 0) outp[BCN] = *lossa;
}

// ---------------------------------------------------------------------------
extern "C" void kernel_launch(void* const* d_in, const int* in_sizes, int n_in,
                              void* d_out, int out_size, void* d_ws, size_t ws_size,
                              hipStream_t stream) {
  const float* x    = (const float*)d_in[0];
  const float* out1 = (const float*)d_in[1];
  const float* ap   = (const float*)d_in[2];
  const float* Ws   = (const float*)d_in[3];
  const float* Wd   = (const float*)d_in[4];
  const float* Wg   = (const float*)d_in[5];
  const float* bg   = (const float*)d_in[6];
  const float* Wco  = (const float*)d_in[7];
  const float* bco  = (const float*)d_in[8];
  const float* bn_g  = (const float*)d_in[9];
  const float* bn_b  = (const float*)d_in[10];
  const float* bng_g = (const float*)d_in[11];
  const float* bng_b = (const float*)d_in[12];
  float* out = (float*)d_out;

  float* w = (float*)d_ws;
  float* sadj  = w;                    // 6400
  float* dadj  = sadj + NN;            // 1638400
  float* glb0  = dadj + BNN;           // 262144 (used as bf16 ushorts)
  float* glb1  = glb0 + B_ * C_;       // 262144
  float* glbf  = glb1 + B_ * C_;       // 262144 (used as bf16 ushorts)
  float* go    = glbf + B_ * C_;       // 20480 -- start of contiguous zero region
  float* ssum1 = go + BNr;             // 1024
  float* ssq1  = ssum1 + C_;           // 1024
  float* ssum2 = ssq1 + C_;            // 1024
  float* ssq2  = ssum2 + C_;           // 1024 -- end of zero region (24576 floats)
  float* bmin  = ssq2 + C_;            // 512 (160 used)
  float* bmax  = bmin + 512;           // 512 (160 used)
  float* dmm   = bmax + 512;           // 2
  float* lossa = dmm + 2;              // 1
  ushort* ub   = (ushort*)(((uintptr_t)(lossa + 1) + 255) & ~(uintptr_t)255);
  ushort* xa_bf  = ub;                    // BCN bf16 (B,N,C): fold out / x2t / fold2 out
  ushort* hT_bf  = xa_bf + BCN;           // BCN bf16 (B,C,N): h -> x2bf (in-place) -> h2
  ushort* Wts    = hT_bf + BCN;           // 1M bf16 (O,C)
  ushort* Wtd    = Wts + (size_t)C_ * C_; // 1M bf16 (O,C)
  ushort* Wco2t  = Wtd + (size_t)C_ * C_; // 80K bf16 (80,1024)
  ushort* adj_bf = Wco2t + (size_t)N_ * C_; // 80x96 bf16 prepadded
  // bf16 aliases in regions dead at time of use:
  ushort* Wg_bf   = (ushort*)dadj;                      // 1M ushorts; dadj written later
  ushort* Wco1t   = (ushort*)dadj + (size_t)C_ * C_;    // 80K ushorts, same region
  ushort* glb0_bf = (ushort*)glb0;
  ushort* glbf_bf = (ushort*)glbf;
  ushort* x2t_bf  = xa_bf;                              // xa dead after GEMM#1; x2t dead before fold#2

  // ---- prep (single merged launch: transposes, converts, zeroes, prep_adj) ----
  k_prep_all<<<3257, TPB, 0, stream>>>(Ws, Wd, Wco, Wg, Wts, Wtd, Wco1t, Wco2t, Wg_bf,
                                       go, ap, sadj, adj_bf, lossa);

  // ---- static GCN ----
  k_fold_mfma<<<B_ * 8, TPB, 0, stream>>>(x, hT_bf, adj_bf, xa_bf, 0, dmm);
  k_gemm_256<<<320, 512, 0, stream>>>(xa_bf, Wts, hT_bf, 1, ssum1, ssq1);
  k_x2_fused<<<(B_ * C_) / 64, TPB, 0, stream>>>(x, hT_bf, bn_g, bn_b, ssum1, ssq1,
                                                 x2t_bf, glb0_bf);

  // ---- dynamic graph construction ----
  k_glb_mfma<<<dim3(C_ / 64, B_ / 64), TPB, 0, stream>>>(glb0_bf, Wg_bf, bg, glb1);
  k_bng<<<C_, TPB, 0, stream>>>(glb1, bng_g, bng_b, glbf_bf);
  k_go_mfma<<<dim3(8, B_ / 128), TPB, 0, stream>>>(glbf_bf, Wco1t, go);
  k_dadj_mfma<<<BNr / 128, TPB, 0, stream>>>(x2t_bf, Wco2t, go, bco, dadj, bmin, bmax);
  k_minmax2<<<1, TPB, 0, stream>>>(bmin, bmax, dmm);

  // ---- adjacency loss (reads raw dadj + dmm) ----
  k_loss<<<B_, TPB, 0, stream>>>(dadj, sadj, out1, lossa, dmm);

  // ---- dynamic GCN (fold reads x2 bf16 from hT region; normalizes dadj inline) ----
  k_fold_mfma<<<B_ * 8, TPB, 0, stream>>>(x, hT_bf, dadj, xa_bf, 1, dmm);
  k_gemm_256<<<320, 512, 0, stream>>>(xa_bf, Wtd, hT_bf, 1, ssum2, ssq2);
  k_final<<<(int)(BCN / (4 * TPB)), TPB, 0, stream>>>(hT_bf, out, bn_g, bn_b, ssum2, ssq2, lossa);
}

// Round 8
// 501.201 us; speedup vs baseline: 1.3901x; 1.0044x over previous
//
#include <hip/hip_runtime.h>
#include <hip/hip_bf16.h>
#include <math.h>

#define TPB 256

constexpr int   B_  = 256;
constexpr int   C_  = 1024;
constexpr int   N_  = 80;
constexpr int   BNr = B_ * N_;                 // 20480 rows for BN / GEMM M
constexpr int   CN  = C_ * N_;                 // 81920
constexpr long  BCN = (long)B_ * C_ * N_;      // 20971520
constexpr int   NN  = N_ * N_;                 // 6400
constexpr int   BNN = B_ * NN;                 // 1638400
constexpr float EPSf = 1e-5f;

typedef __bf16 bf16x8 __attribute__((ext_vector_type(8)));
typedef float  f32x4  __attribute__((ext_vector_type(4)));

__device__ __forceinline__ float leakyf(float v) { return v >= 0.0f ? v : 0.2f * v; }

__device__ __forceinline__ ushort f2bf(float f) {
  __hip_bfloat16 h = __float2bfloat16(f);
  ushort u; __builtin_memcpy(&u, &h, 2); return u;
}
__device__ __forceinline__ float b2f(ushort u) {
  __hip_bfloat16 h; __builtin_memcpy(&h, &u, 2);
  return __bfloat162float(h);
}

#define GLOBAL_AS __attribute__((address_space(1)))
#define LDS_AS    __attribute__((address_space(3)))
__device__ __forceinline__ void load_lds16(const void* g, void* l) {
  __builtin_amdgcn_global_load_lds((const GLOBAL_AS void*)g, (LDS_AS void*)l, 16, 0, 0);
}

// ---------------------------------------------------------------------------
// K-PREP (merged): blockIdx ranges ->
//   [0,1024)    : Wts[o][c] = bf16(Ws[c][o])   (32x32 tile transpose)
//   [1024,2048) : Wtd[o][c] = bf16(Wd[c][o])
//   [2048,2208) : split Wco (80x2048) -> Wco1t / Wco2t bf16
//   [2208,3232) : Wg -> Wg_bf elementwise
//   [3232,3258) : zero go(20480) + ssum1/ssq1/ssum2/ssq2/gsum/gsq (6144 floats)
//   [3258]      : prep_adj (sadj, adj_bf, lossa=0)
// ---------------------------------------------------------------------------
__global__ __launch_bounds__(256) void k_prep_all(
    const float* __restrict__ Ws, const float* __restrict__ Wd,
    const float* __restrict__ Wco, const float* __restrict__ Wg,
    ushort* __restrict__ Wts, ushort* __restrict__ Wtd,
    ushort* __restrict__ Wco1t, ushort* __restrict__ Wco2t, ushort* __restrict__ Wg_bf,
    float* __restrict__ zbase,
    const float* __restrict__ ap, float* __restrict__ sadj,
    ushort* __restrict__ adj_bf, float* __restrict__ lossa) {
  __shared__ float sh[NN];          // 25.6 KB; doubles as 32x33 transpose tile
  __shared__ float red[TPB];
  __shared__ float sD[N_];
  __shared__ float s_lo, s_hi;
  const int t = threadIdx.x;
  const int blk = blockIdx.x;
  if (blk < 2048) {
    const float* W = (blk < 1024) ? Ws : Wd;
    ushort* Wt = (blk < 1024) ? Wts : Wtd;
    const int bb = blk & 1023;
    const int bx = bb & 31, by = bb >> 5;
    const int tx = t % 32, ty = t / 32;
    const int r0 = by * 32, c0 = bx * 32;
#pragma unroll
    for (int k = 0; k < 4; ++k) sh[(ty + 8 * k) * 33 + tx] = W[(size_t)(r0 + ty + 8 * k) * C_ + c0 + tx];
    __syncthreads();
#pragma unroll
    for (int k = 0; k < 4; ++k) Wt[(size_t)(c0 + ty + 8 * k) * C_ + r0 + tx] = f2bf(sh[tx * 33 + ty + 8 * k]);
  } else if (blk < 2208) {
    const int i4 = ((blk - 2048) * TPB + t) * 4;   // 80*2048 elems
    const int o = i4 >> 11, k = i4 & 2047;
    float4 v = *(const float4*)&Wco[(size_t)o * 2048 + k];
    ushort4 u;
    u.x = f2bf(v.x); u.y = f2bf(v.y); u.z = f2bf(v.z); u.w = f2bf(v.w);
    if (k < C_) *(ushort4*)&Wco1t[(size_t)o * C_ + k] = u;
    else        *(ushort4*)&Wco2t[(size_t)o * C_ + (k - C_)] = u;
  } else if (blk < 3232) {
    const long i4 = ((long)(blk - 2208) * TPB + t) * 4;
    float4 v = *(const float4*)&Wg[i4];
    ushort4 u;
    u.x = f2bf(v.x); u.y = f2bf(v.y); u.z = f2bf(v.z); u.w = f2bf(v.w);
    *(ushort4*)&Wg_bf[i4] = u;
  } else if (blk < 3258) {
    const int i = ((blk - 3232) * TPB + t) * 4;    // 26624 floats
    float4 z = make_float4(0.f, 0.f, 0.f, 0.f);
    *(float4*)&zbase[i] = z;
  } else {
    // ---- prep_adj (single block) ----
    float lo = 3.4e38f, hi = -3.4e38f;
    for (int i = t; i < NN; i += TPB) { float v = ap[i]; sh[i] = v; lo = fminf(lo, v); hi = fmaxf(hi, v); }
    red[t] = lo; __syncthreads();
    for (int o = 128; o > 0; o >>= 1) { if (t < o) red[t] = fminf(red[t], red[t + o]); __syncthreads(); }
    if (t == 0) s_lo = red[0];
    __syncthreads();
    red[t] = hi; __syncthreads();
    for (int o = 128; o > 0; o >>= 1) { if (t < o) red[t] = fmaxf(red[t], red[t + o]); __syncthreads(); }
    if (t == 0) s_hi = red[0];
    __syncthreads();
    const float inv = 1.0f / (s_hi - s_lo);
    for (int i = t; i < NN; i += TPB) { float v = (sh[i] - s_lo) * inv; sh[i] = v; sadj[i] = v; }
    __syncthreads();
    if (t < N_) { float sum = 0.f; for (int m = 0; m < N_; ++m) sum += sh[t * N_ + m]; sD[t] = rsqrtf(sum); }
    if (t == 0) *lossa = 0.0f;
    __syncthreads();
    for (int i = t; i < N_ * 96; i += TPB) {
      const int n = i / 96, m = i % 96;
      adj_bf[i] = f2bf((m < N_) ? sD[n] * sh[m * N_ + n] * sD[m] : 0.0f);
    }
  }
}

// ---------------------------------------------------------------------------
// K1v3: MFMA fold.  out[(b*80+n)*1024 + c] (bf16, B,N,C) =
//   sum_m adj[n,m] * X[b, c, m]
// mode 0: adjsrc = adj_bf global (80x96 bf16, prepadded); X from Xf32 (B,C,N).
// mode 1: adjsrc = dadj RAW fp32 (B,80,80), min/max from bmin/bmax[160]
//         reduced inline; tadj in LDS; X from Xbf (bf16, B,C,N).
// ---------------------------------------------------------------------------
__global__ __launch_bounds__(256) void k_fold_mfma(const float* __restrict__ Xf32,
                                                   const ushort* __restrict__ Xbf,
                                                   const void* __restrict__ adjsrc,
                                                   ushort* __restrict__ outp, int mode,
                                                   const float* __restrict__ bmin,
                                                   const float* __restrict__ bmax) {
  __shared__ __align__(16) ushort sX[128][104];     // rows c, cols m (pad->104, b128 2-way free)
  __shared__ __align__(16) ushort sAdj[80][104];    // rows n, cols m
  __shared__ float sD[N_];
  __shared__ float rl[TPB], rh[TPB];
  __shared__ float s_lo, s_inv;
  const int t = threadIdx.x;
  const int b  = blockIdx.x >> 3;
  const int c0 = (blockIdx.x & 7) * 128;

  // ---- adjacency -> sAdj (bf16, m 80..95 zero) ----
  if (mode == 0) {
    const ushort* ab = (const ushort*)adjsrc;
    for (int i = t; i < (N_ * 96) / 4; i += TPB) {
      ushort4 v = *(const ushort4*)&ab[i * 4];
      *(ushort4*)&sAdj[(i * 4) / 96][(i * 4) % 96] = v;
    }
    __syncthreads();
  } else {
    // inline dmm reduce from 160 per-block partials
    rl[t] = (t < 160) ? bmin[t] : 3.4e38f;
    rh[t] = (t < 160) ? bmax[t] : -3.4e38f;
    __syncthreads();
    for (int o = 128; o > 0; o >>= 1) {
      if (t < o) { rl[t] = fminf(rl[t], rl[t + o]); rh[t] = fmaxf(rh[t], rh[t + o]); }
      __syncthreads();
    }
    if (t == 0) { s_lo = rl[0]; s_inv = 1.0f / (rh[0] - rl[0]); }
    __syncthreads();
    const float lo = s_lo, inv = s_inv;
    float* sF = (float*)&sX[0][0];                  // 80*80 fp32 = 25.6KB <= sX
    const float* db = (const float*)adjsrc + (size_t)b * NN;
    for (int i = t; i < NN / 4; i += TPB) {
      float4 v = *(const float4*)&db[i * 4];
      v.x = (v.x - lo) * inv; v.y = (v.y - lo) * inv;
      v.z = (v.z - lo) * inv; v.w = (v.w - lo) * inv;
      *(float4*)&sF[i * 4] = v;
    }
    __syncthreads();
    if (t < N_) { float s = 0.f; for (int m = 0; m < N_; ++m) s += sF[t * N_ + m]; sD[t] = rsqrtf(s); }
    __syncthreads();
    for (int i = t; i < N_ * 96; i += TPB) {
      const int n = i / 96, m = i % 96;
      sAdj[n][m] = f2bf((m < N_) ? sF[m * N_ + n] * sD[n] * sD[m] : 0.0f);
    }
    __syncthreads();                                 // before sX overwrite
  }

  // ---- stage X (128 rows x 80 m); zero pad m 80..95 ----
  if (mode == 0) {
    const float* Xb = Xf32 + ((size_t)b * C_ + c0) * N_;
    for (int i = t; i < (128 * N_) / 4; i += TPB) {
      float4 v = *(const float4*)&Xb[i * 4];
      const int r = (i * 4) / N_, m = (i * 4) % N_;
      ushort4 u; u.x = f2bf(v.x); u.y = f2bf(v.y); u.z = f2bf(v.z); u.w = f2bf(v.w);
      *(ushort4*)&sX[r][m] = u;
    }
  } else {
    const ushort* Xb = Xbf + ((size_t)b * C_ + c0) * N_;
    for (int i = t; i < (128 * N_) / 8; i += TPB) {  // 1280 chunks of 16B
      const int r = i / 10, m = (i % 10) * 8;
      uint4 v = *(const uint4*)&Xb[(size_t)r * N_ + m];
      *(uint4*)&sX[r][m] = v;
    }
  }
  for (int i = t; i < (128 * 16) / 4; i += TPB) {
    const int r = i / 4, m = 80 + (i % 4) * 4;
    ushort4 z; z.x = 0; z.y = 0; z.z = 0; z.w = 0;
    *(ushort4*)&sX[r][m] = z;
  }
  __syncthreads();

  const int lane = t & 63, wid = t >> 6;
  const int l16 = lane & 15, lq = lane >> 4;
  f32x4 acc[2][5];
#pragma unroll
  for (int i = 0; i < 2; ++i)
#pragma unroll
    for (int j = 0; j < 5; ++j) { f32x4 z = {0.f, 0.f, 0.f, 0.f}; acc[i][j] = z; }
  bf16x8 af[2][3], bfr[5][3];
#pragma unroll
  for (int i = 0; i < 2; ++i)
#pragma unroll
    for (int kk = 0; kk < 3; ++kk)
      af[i][kk] = *(const bf16x8*)&sX[wid * 32 + i * 16 + l16][kk * 32 + lq * 8];
#pragma unroll
  for (int j = 0; j < 5; ++j)
#pragma unroll
    for (int kk = 0; kk < 3; ++kk)
      bfr[j][kk] = *(const bf16x8*)&sAdj[j * 16 + l16][kk * 32 + lq * 8];
#pragma unroll
  for (int i = 0; i < 2; ++i)
#pragma unroll
    for (int j = 0; j < 5; ++j)
#pragma unroll
      for (int kk = 0; kk < 3; ++kk)
        acc[i][j] = __builtin_amdgcn_mfma_f32_16x16x32_bf16(af[i][kk], bfr[j][kk], acc[i][j], 0, 0, 0);

  // ---- epilogue: D[row=c_local (lq*4+reg)][col=n (l16)] -> (B,N,C) ushort4 ----
  ushort* ob = outp + (size_t)b * CN;
#pragma unroll
  for (int i = 0; i < 2; ++i) {
    const int c = c0 + wid * 32 + i * 16 + lq * 4;
#pragma unroll
    for (int j = 0; j < 5; ++j) {
      const int n = j * 16 + l16;
      ushort4 u;
      u.x = f2bf(acc[i][j][0]); u.y = f2bf(acc[i][j][1]);
      u.z = f2bf(acc[i][j][2]); u.w = f2bf(acc[i][j][3]);
      *(ushort4*)&ob[(size_t)n * C_ + c] = u;
    }
  }
}

// ---------------------------------------------------------------------------
// K2: 256x256x64 8-phase counted-vmcnt MFMA GEMM (T2+T3+T4+T5)
// + gray-code operand carry (48 ds_read_b128 / 8 phases). Verified r4/r5.
// + fused per-channel BN partial stats (verified r7).
// ---------------------------------------------------------------------------
__global__ __launch_bounds__(512, 2) void k_gemm_256(const ushort* __restrict__ A,
                                                     const ushort* __restrict__ Bt,
                                                     void* __restrict__ outp, int out_bf,
                                                     float* __restrict__ bnsum,
                                                     float* __restrict__ bnsq) {
  __shared__ ushort sA[2][256 * 64];   // 64 KB
  __shared__ ushort sB[2][256 * 64];   // 64 KB
  const int t = threadIdx.x;
  const int lane = t & 63, wid = t >> 6;       // 8 waves
  const int wm = wid >> 2, wn = wid & 3;       // 2 x 4
  const int l16 = lane & 15, lq = lane >> 4;

  // XCD-chunked swizzle: 320 blocks; each XCD: tm in [xcd*10, xcd*10+10), tn 0..3.
  const int lin = blockIdx.x;
  const int xcd = lin & 7, bi = lin >> 3;      // bi in 0..39
  const int tm = xcd * 10 + (bi >> 2);
  const int tn = bi & 3;
  const int m0 = tm * 256, o0 = tn * 256;

  const int srow = t >> 3;
  const int sswz = ((t & 7) ^ ((t >> 3) & 7)) * 8;   // elems

  f32x4 acc[8][4];
#pragma unroll
  for (int i = 0; i < 8; ++i)
#pragma unroll
    for (int j = 0; j < 4; ++j) { f32x4 z = {0.f, 0.f, 0.f, 0.f}; acc[i][j] = z; }

  bf16x8 afr[4][2], bfr0[2][2], bfr1[2][2];    // carried fragments

#define STA(PAR, ROWB, KT) load_lds16(A  + (size_t)(m0 + (ROWB) + srow) * C_ + (KT) * 64 + sswz, \
                                      &sA[PAR][((ROWB) + (wid << 3)) * 64])
#define STB(PAR, ROWB, KT) load_lds16(Bt + (size_t)(o0 + (ROWB) + srow) * C_ + (KT) * 64 + sswz, \
                                      &sB[PAR][((ROWB) + (wid << 3)) * 64])
#define STA_H(PAR, H, KT) { STA(PAR, (H)*128, KT); STA(PAR, (H)*128 + 64, KT); }
#define STB_H(PAR, H, KT) { STB(PAR, (H)*128, KT); STB(PAR, (H)*128 + 64, KT); }

#define RDA(PAR, MH)                                                                      \
  _Pragma("unroll") for (int fi = 0; fi < 4; ++fi) {                                      \
    const int row = ((MH) ? 128 : 0) + wm * 64 + fi * 16 + l16;                           \
    _Pragma("unroll") for (int kk = 0; kk < 2; ++kk)                                      \
      afr[fi][kk] = *(const bf16x8*)&sA[PAR][row * 64 + ((kk * 4 + lq) ^ (l16 & 7)) * 8]; \
  }
#define RDB(PAR, NH, DST)                                                                 \
  _Pragma("unroll") for (int gi = 0; gi < 2; ++gi) {                                      \
    const int row = ((NH) ? 128 : 0) + wn * 32 + gi * 16 + l16;                           \
    _Pragma("unroll") for (int kk = 0; kk < 2; ++kk)                                      \
      DST[gi][kk] = *(const bf16x8*)&sB[PAR][row * 64 + ((kk * 4 + lq) ^ (l16 & 7)) * 8]; \
  }

#define MFMAS(MH, NH, BF)                                                          \
  _Pragma("unroll") for (int kk = 0; kk < 2; ++kk)                                 \
  _Pragma("unroll") for (int fi = 0; fi < 4; ++fi)                                 \
  _Pragma("unroll") for (int gi = 0; gi < 2; ++gi)                                 \
    acc[(MH) * 4 + fi][(NH) * 2 + gi] = __builtin_amdgcn_mfma_f32_16x16x32_bf16(   \
        afr[fi][kk], BF[gi][kk], acc[(MH) * 4 + fi][(NH) * 2 + gi], 0, 0, 0);

#define PHASE(MH, NH, BF, RD, STAGES, VMW)                                         \
  {                                                                                \
    RD                                                                             \
    STAGES                                                                         \
    asm volatile("s_barrier" ::: "memory");                                        \
    asm volatile("s_waitcnt lgkmcnt(0)" ::: "memory");                             \
    __builtin_amdgcn_s_setprio(1);                                                 \
    MFMAS(MH, NH, BF)                                                              \
    __builtin_amdgcn_s_setprio(0);                                                 \
    VMW                                                                            \
    asm volatile("s_barrier" ::: "memory");                                        \
  }

  // prologue: T0 fully (8 calls) + T1's A-half0, B-half1 (4 calls)
  STA_H(0, 0, 0); STA_H(0, 1, 0); STB_H(0, 0, 0); STB_H(0, 1, 0);
  STA_H(1, 0, 1); STB_H(1, 1, 1);
  asm volatile("s_waitcnt vmcnt(4)" ::: "memory");
  asm volatile("s_barrier" ::: "memory");

  for (int i = 0; i < 7; ++i) {
    const int t1 = 2 * i + 1, t2 = 2 * i + 2, t3 = 2 * i + 3;
    PHASE(0, 0, bfr0, RDA(0, 0) RDB(0, 0, bfr0), { STA_H(1, 1, t1); }, {})
    PHASE(0, 1, bfr1, RDB(0, 1, bfr1),           { STB_H(1, 0, t1); }, {})
    PHASE(1, 1, bfr1, RDA(0, 1),                 { STA_H(0, 0, t2); }, {})
    PHASE(1, 0, bfr0, {},                        { STB_H(0, 1, t2); }, { asm volatile("s_waitcnt vmcnt(4)" ::: "memory"); })
    PHASE(0, 0, bfr0, RDA(1, 0) RDB(1, 0, bfr0), { STA_H(0, 1, t2); }, {})
    PHASE(0, 1, bfr1, RDB(1, 1, bfr1),           { STB_H(0, 0, t2); }, {})
    PHASE(1, 1, bfr1, RDA(1, 1),                 { STA_H(1, 0, t3); }, {})
    PHASE(1, 0, bfr0, {},                        { STB_H(1, 1, t3); }, { asm volatile("s_waitcnt vmcnt(4)" ::: "memory"); })
  }
  // peeled last iter: tiles 14 (par0), 15 (par1); only T15's A1/B0 remain to stage.
  PHASE(0, 0, bfr0, RDA(0, 0) RDB(0, 0, bfr0), { STA_H(1, 1, 15); }, {})
  PHASE(0, 1, bfr1, RDB(0, 1, bfr1),           { STB_H(1, 0, 15); }, {})
  PHASE(1, 1, bfr1, RDA(0, 1),                 {}, {})
  PHASE(1, 0, bfr0, {},                        {}, { asm volatile("s_waitcnt vmcnt(0)" ::: "memory"); })
  PHASE(0, 0, bfr0, RDA(1, 0) RDB(1, 0, bfr0), {}, {})
  PHASE(0, 1, bfr1, RDB(1, 1, bfr1),           {}, {})
  PHASE(1, 1, bfr1, RDA(1, 1),                 {}, {})
  PHASE(1, 0, bfr0, {},                        {}, {})

  // epilogue: row = lq*4+reg -> m; col = l16 -> o. (B,C,N) store, 4 consecutive n.
#pragma unroll
  for (int f = 0; f < 8; ++f) {
    const int gmb = (f < 4) ? (wm * 64 + f * 16) : (128 + wm * 64 + (f - 4) * 16);
    const int mg = m0 + gmb + lq * 4;
    const int b  = mg / 80;
    const int n0 = mg - b * 80;
#pragma unroll
    for (int gi = 0; gi < 4; ++gi) {
      const int gnb = (gi < 2) ? (wn * 32 + gi * 16) : (128 + wn * 32 + (gi - 2) * 16);
      const int og = o0 + gnb + l16;
      const size_t off = (size_t)b * CN + (size_t)og * N_ + n0;
      if (out_bf) {
        ushort4 u;
        u.x = f2bf(acc[f][gi][0]); u.y = f2bf(acc[f][gi][1]);
        u.z = f2bf(acc[f][gi][2]); u.w = f2bf(acc[f][gi][3]);
        *(ushort4*)((ushort*)outp + off) = u;
      } else {
        *(f32x4*)((float*)outp + off) = acc[f][gi];
      }
    }
  }

  // ---- fused BN partial stats (sA free after last phase barrier) ----
  {
    float* redS = (float*)&sA[0][0];           // [256][8]
    float* redQ = redS + 2048;                 // [256][8]
    const int slot = wm * 4 + lq;
#pragma unroll
    for (int gi = 0; gi < 4; ++gi) {
      float s = 0.f, q = 0.f;
#pragma unroll
      for (int f = 0; f < 8; ++f)
#pragma unroll
        for (int r = 0; r < 4; ++r) { const float v = acc[f][gi][r]; s += v; q += v * v; }
      const int gnb = (gi < 2) ? (wn * 32 + gi * 16) : (128 + wn * 32 + (gi - 2) * 16);
      const int ol = gnb + l16;                // 0..255, unique per (wn,gi,l16)
      redS[ol * 8 + slot] = s;
      redQ[ol * 8 + slot] = q;
    }
    __syncthreads();
    if (t < 256) {
      float s = 0.f, q = 0.f;
#pragma unroll
      for (int k = 0; k < 8; ++k) { s += redS[t * 8 + k]; q += redQ[t * 8 + k]; }
      atomicAdd(&bnsum[o0 + t], s);
      atomicAdd(&bnsq[o0 + t], q);
    }
  }
#undef STA
#undef STB
#undef STA_H
#undef STB_H
#undef RDA
#undef RDB
#undef MFMAS
#undef PHASE
}

// ---------------------------------------------------------------------------
// K2b: dadj MFMA GEMM. A: x2t bf16 (M=20480, K=1024). Bw: Wco2t bf16 (80,1024).
// dadj[b,o,n] = go[b,o] + bco[o] + sum_k A[m=(b,n)][k]*Bw[o][k].
// Fused per-block min/max -> bmin/bmax[160].
// ---------------------------------------------------------------------------
__global__ __launch_bounds__(256) void k_dadj_mfma(const ushort* __restrict__ A,
                                                   const ushort* __restrict__ Bw,
                                                   const float* __restrict__ go,
                                                   const float* __restrict__ bco,
                                                   float* __restrict__ dadj,
                                                   float* __restrict__ bmin,
                                                   float* __restrict__ bmax) {
  __shared__ ushort smA[128 * 32];
  __shared__ ushort smB[80 * 32];
  const int t = threadIdx.x;
  const int lane = t & 63, wid = t >> 6;
  const int m0 = blockIdx.x * 128;
  const int rto = t >> 2, ch = t & 3;
  const size_t gA0 = (size_t)(m0 + rto) * C_ + (size_t)ch * 8;
  ushort* ldsA = smA + wid * 512;
  const int l16 = lane & 15, lq = lane >> 4;
  const int wrow = wid * 32;
  f32x4 zero = {0.f, 0.f, 0.f, 0.f};
  f32x4 acc[2][5];
#pragma unroll
  for (int i = 0; i < 2; ++i)
#pragma unroll
    for (int j = 0; j < 5; ++j) acc[i][j] = zero;
  for (int k0 = 0; k0 < C_; k0 += 32) {
    load_lds16(A + gA0 + k0,            ldsA);
    load_lds16(A + gA0 + 64 * C_ + k0,  ldsA + 2048);
    {
      const int idx = t;                               // 320 chunks of 16B
      uint4 v = *(const uint4*)&Bw[(size_t)(idx >> 2) * C_ + k0 + (idx & 3) * 8];
      *(uint4*)&smB[idx * 8] = v;
      if (t < 64) {
        const int idx2 = 256 + t;
        uint4 v2 = *(const uint4*)&Bw[(size_t)(idx2 >> 2) * C_ + k0 + (idx2 & 3) * 8];
        *(uint4*)&smB[idx2 * 8] = v2;
      }
    }
    __syncthreads();
    bf16x8 af[2], bfr[5];
#pragma unroll
    for (int i = 0; i < 2; ++i) af[i]  = *(const bf16x8*)&smA[(wrow + i * 16 + l16) * 32 + lq * 8];
#pragma unroll
    for (int j = 0; j < 5; ++j) bfr[j] = *(const bf16x8*)&smB[(j * 16 + l16) * 32 + lq * 8];
#pragma unroll
    for (int i = 0; i < 2; ++i)
#pragma unroll
      for (int j = 0; j < 5; ++j)
        acc[i][j] = __builtin_amdgcn_mfma_f32_16x16x32_bf16(af[i], bfr[j], acc[i][j], 0, 0, 0);
    __syncthreads();
  }
  float vlo = 3.4e38f, vhi = -3.4e38f;
#pragma unroll
  for (int i = 0; i < 2; ++i) {
    const int mg = m0 + wrow + i * 16 + lq * 4;
    const int b  = mg / 80;
    const int n0 = mg - b * 80;
    const float* gob = go + b * N_;
#pragma unroll
    for (int j = 0; j < 5; ++j) {
      const int o = j * 16 + l16;
      const float g = gob[o] + bco[o];
      f32x4 v = acc[i][j];
      v[0] += g; v[1] += g; v[2] += g; v[3] += g;
      vlo = fminf(vlo, fminf(fminf(v[0], v[1]), fminf(v[2], v[3])));
      vhi = fmaxf(vhi, fmaxf(fmaxf(v[0], v[1]), fmaxf(v[2], v[3])));
      *(f32x4*)&dadj[(size_t)b * NN + (size_t)o * N_ + n0] = v;
    }
  }
  // block min/max reduce (reuse smA as float scratch; all LDS reads done)
  float* red = (float*)smA;
  red[t] = vlo; red[TPB + t] = vhi;
  __syncthreads();
  for (int o = 128; o > 0; o >>= 1) {
    if (t < o) {
      red[t] = fminf(red[t], red[t + o]);
      red[TPB + t] = fmaxf(red[TPB + t], red[TPB + t + o]);
    }
    __syncthreads();
  }
  if (t == 0) { bmin[blockIdx.x] = red[0]; bmax[blockIdx.x] = red[TPB]; }
}

// ---------------------------------------------------------------------------
// K2c: glb1 MFMA GEMM. A: glb0_bf (256 x 1024). Bw: Wg_bf (1024 x 1024, K-contig).
// + fused per-channel stats (sum/sumsq of glb1 incl. bias) -> gsum/gsq atomics.
// ---------------------------------------------------------------------------
__global__ __launch_bounds__(256) void k_glb_mfma(const ushort* __restrict__ A,
                                                  const ushort* __restrict__ Bw,
                                                  const float* __restrict__ bias,
                                                  float* __restrict__ outp,
                                                  float* __restrict__ gsum,
                                                  float* __restrict__ gsq) {
  __shared__ ushort smA[2][64 * 32];
  __shared__ ushort smB[2][64 * 32];
  const int t = threadIdx.x;
  const int lane = t & 63, wid = t >> 6;
  const int o0 = blockIdx.x * 64, m0 = blockIdx.y * 64;
  const int rto = t >> 2, ch = t & 3;
  const size_t gA0 = (size_t)(m0 + rto) * C_ + (size_t)ch * 8;
  const size_t gB0 = (size_t)(o0 + rto) * C_ + (size_t)ch * 8;
  const int l16 = lane & 15, lq = lane >> 4;
  const int wm = wid & 1, wn = wid >> 1;
  f32x4 zero = {0.f, 0.f, 0.f, 0.f};
  f32x4 acc[2][2];
#pragma unroll
  for (int i = 0; i < 2; ++i)
#pragma unroll
    for (int j = 0; j < 2; ++j) acc[i][j] = zero;
  for (int k0 = 0; k0 < C_; k0 += 64) {
    load_lds16(A  + gA0 + k0,       smA[0] + wid * 512);
    load_lds16(A  + gA0 + k0 + 32,  smA[1] + wid * 512);
    load_lds16(Bw + gB0 + k0,       smB[0] + wid * 512);
    load_lds16(Bw + gB0 + k0 + 32,  smB[1] + wid * 512);
    __syncthreads();
#pragma unroll
    for (int h = 0; h < 2; ++h) {
      bf16x8 af[2], bfr[2];
#pragma unroll
      for (int i = 0; i < 2; ++i) af[i]  = *(const bf16x8*)&smA[h][(wm * 32 + i * 16 + l16) * 32 + lq * 8];
#pragma unroll
      for (int j = 0; j < 2; ++j) bfr[j] = *(const bf16x8*)&smB[h][(wn * 32 + j * 16 + l16) * 32 + lq * 8];
#pragma unroll
      for (int i = 0; i < 2; ++i)
#pragma unroll
        for (int j = 0; j < 2; ++j)
          acc[i][j] = __builtin_amdgcn_mfma_f32_16x16x32_bf16(af[i], bfr[j], acc[i][j], 0, 0, 0);
    }
    __syncthreads();
  }
  float ssv[2] = {0.f, 0.f}, sqv[2] = {0.f, 0.f};
#pragma unroll
  for (int i = 0; i < 2; ++i) {
    const int mg = m0 + wm * 32 + i * 16 + lq * 4;
#pragma unroll
    for (int j = 0; j < 2; ++j) {
      const int og = o0 + wn * 32 + j * 16 + l16;
      const float bs = bias[og];
      f32x4 v = acc[i][j];
#pragma unroll
      for (int r = 0; r < 4; ++r) {
        const float val = v[r] + bs;
        outp[(size_t)(mg + r) * C_ + og] = val;
        ssv[j] += val; sqv[j] += val * val;
      }
    }
  }
  // stats reduce: [64 og_local][8 slots] in smA (free after last sync)
  {
    float* redS = (float*)&smA[0][0];
    float* redQ = redS + 512;
    const int slot = wm * 4 + lq;
#pragma unroll
    for (int j = 0; j < 2; ++j) {
      const int ol = wn * 32 + j * 16 + l16;   // 0..63
      redS[ol * 8 + slot] = ssv[j];
      redQ[ol * 8 + slot] = sqv[j];
    }
    __syncthreads();
    if (t < 64) {
      float s = 0.f, q = 0.f;
#pragma unroll
      for (int k = 0; k < 8; ++k) { s += redS[t * 8 + k]; q += redQ[t * 8 + k]; }
      atomicAdd(&gsum[o0 + t], s);
      atomicAdd(&gsq[o0 + t], q);
    }
  }
}

// ---------------------------------------------------------------------------
// K2d: go MFMA GEMM, split-K x8, BN+leaky applied inline from gsum/gsq while
// reg-staging A from fp32 glb1 (replaces k_bng + glbf buffer).
// ---------------------------------------------------------------------------
__global__ __launch_bounds__(256) void k_go_mfma(const float* __restrict__ glb1,
                                                 const ushort* __restrict__ Bw,
                                                 const float* __restrict__ gsum,
                                                 const float* __restrict__ gsq,
                                                 const float* __restrict__ gg,
                                                 const float* __restrict__ gb,
                                                 float* __restrict__ go) {
  __shared__ ushort smA[128 * 32];
  __shared__ ushort smB[80 * 32];
  __shared__ float pgm[C_], pmu[C_], pgb[C_];
  const int t = threadIdx.x;
  const int lane = t & 63, wid = t >> 6;
  const int kbase = blockIdx.x * 128;
  const int m0 = blockIdx.y * 128;
  const int rto = t >> 2, ch = t & 3;
  const int l16 = lane & 15, lq = lane >> 4;
  const int wrow = wid * 32;
  for (int c = t; c < C_; c += TPB) {
    const float mu = gsum[c] * (1.0f / B_);
    const float var = gsq[c] * (1.0f / B_) - mu * mu;
    pgm[c] = gg[c] * rsqrtf(var + EPSf); pmu[c] = mu; pgb[c] = gb[c];
  }
  __syncthreads();
  f32x4 zero = {0.f, 0.f, 0.f, 0.f};
  f32x4 acc[2][5];
#pragma unroll
  for (int i = 0; i < 2; ++i)
#pragma unroll
    for (int j = 0; j < 5; ++j) acc[i][j] = zero;
  for (int kk0 = 0; kk0 < 128; kk0 += 32) {
    const int k0 = kbase + kk0;
    // A: rows m0+h*64+rto, cols k0+ch*8..+8; BN+leaky+bf16 in registers
#pragma unroll
    for (int h = 0; h < 2; ++h) {
      const float* src = &glb1[(size_t)(m0 + h * 64 + rto) * C_ + k0 + ch * 8];
      float4 a0 = *(const float4*)src;
      float4 a1 = *(const float4*)(src + 4);
      float av[8] = {a0.x, a0.y, a0.z, a0.w, a1.x, a1.y, a1.z, a1.w};
      ushort4 u0, u1;
      const int cb = k0 + ch * 8;
      u0.x = f2bf(leakyf(pgm[cb+0]*(av[0]-pmu[cb+0])+pgb[cb+0]));
      u0.y = f2bf(leakyf(pgm[cb+1]*(av[1]-pmu[cb+1])+pgb[cb+1]));
      u0.z = f2bf(leakyf(pgm[cb+2]*(av[2]-pmu[cb+2])+pgb[cb+2]));
      u0.w = f2bf(leakyf(pgm[cb+3]*(av[3]-pmu[cb+3])+pgb[cb+3]));
      u1.x = f2bf(leakyf(pgm[cb+4]*(av[4]-pmu[cb+4])+pgb[cb+4]));
      u1.y = f2bf(leakyf(pgm[cb+5]*(av[5]-pmu[cb+5])+pgb[cb+5]));
      u1.z = f2bf(leakyf(pgm[cb+6]*(av[6]-pmu[cb+6])+pgb[cb+6]));
      u1.w = f2bf(leakyf(pgm[cb+7]*(av[7]-pmu[cb+7])+pgb[cb+7]));
      *(ushort4*)&smA[h * 2048 + t * 8]     = u0;
      *(ushort4*)&smA[h * 2048 + t * 8 + 4] = u1;
    }
    {
      const int idx = t;
      uint4 v = *(const uint4*)&Bw[(size_t)(idx >> 2) * C_ + k0 + (idx & 3) * 8];
      *(uint4*)&smB[idx * 8] = v;
      if (t < 64) {
        const int idx2 = 256 + t;
        uint4 v2 = *(const uint4*)&Bw[(size_t)(idx2 >> 2) * C_ + k0 + (idx2 & 3) * 8];
        *(uint4*)&smB[idx2 * 8] = v2;
      }
    }
    __syncthreads();
    bf16x8 af[2], bfr[5];
#pragma unroll
    for (int i = 0; i < 2; ++i) af[i]  = *(const bf16x8*)&smA[(wrow + i * 16 + l16) * 32 + lq * 8];
#pragma unroll
    for (int j = 0; j < 5; ++j) bfr[j] = *(const bf16x8*)&smB[(j * 16 + l16) * 32 + lq * 8];
#pragma unroll
    for (int i = 0; i < 2; ++i)
#pragma unroll
      for (int j = 0; j < 5; ++j)
        acc[i][j] = __builtin_amdgcn_mfma_f32_16x16x32_bf16(af[i], bfr[j], acc[i][j], 0, 0, 0);
    __syncthreads();
  }
#pragma unroll
  for (int i = 0; i < 2; ++i) {
    const int mg = m0 + wrow + i * 16 + lq * 4;
#pragma unroll
    for (int j = 0; j < 5; ++j) {
      const int o = j * 16 + l16;
#pragma unroll
      for (int r = 0; r < 4; ++r)
        atomicAdd(&go[(size_t)(mg + r) * N_ + o], acc[i][j][r]);
    }
  }
}

// ---------------------------------------------------------------------------
// K4f: fused x2 = x + leaky(bn(hT)) ; bf16 x2 written IN PLACE over hT ;
// x2t transpose (bf16, B,N,C) ; glb0 mean. BN stats from fused gemm sums.
// LDS pad 85 (84 was 8-way bank-conflicted on the transpose column reads).
// ---------------------------------------------------------------------------
__global__ __launch_bounds__(256) void k_x2_fused(
    const float* __restrict__ x, ushort* __restrict__ hx,
    const float* __restrict__ g, const float* __restrict__ be,
    const float* __restrict__ ssum, const float* __restrict__ ssq,
    ushort* __restrict__ x2t, ushort* __restrict__ glb0b) {
  __shared__ float s[64][85];
  __shared__ float pg[64], pm[64], pb[64];
  const int t = threadIdx.x;
  const long row0 = (long)blockIdx.x * 64;     // row = b*C + c
  const int b = (int)(row0 >> 10), c0 = (int)(row0 & 1023);
  if (t < 64) {
    const int c = c0 + t;
    const float mu = ssum[c] * (1.0f / BNr);
    const float var = ssq[c] * (1.0f / BNr) - mu * mu;
    const float rstd = rsqrtf(var + EPSf);
    pg[t] = g[c] * rstd; pm[t] = mu; pb[t] = be[c];
  }
  __syncthreads();
  const float* xb = x  + row0 * N_;
  ushort*      hb = hx + row0 * N_;
  for (int i4 = t; i4 < (64 * N_) / 4; i4 += TPB) {
    const int e = i4 * 4, r = e / N_, n = e % N_;
    float4 xv = *(const float4*)&xb[e];
    ushort4 hu = *(const ushort4*)&hb[e];
    const float gm = pg[r], m = pm[r], bb = pb[r];
    float4 o;
    o.x = xv.x + leakyf(gm * (b2f(hu.x) - m) + bb);
    o.y = xv.y + leakyf(gm * (b2f(hu.y) - m) + bb);
    o.z = xv.z + leakyf(gm * (b2f(hu.z) - m) + bb);
    o.w = xv.w + leakyf(gm * (b2f(hu.w) - m) + bb);
    *(float4*)&s[r][n] = o;
    ushort4 ou;
    ou.x = f2bf(o.x); ou.y = f2bf(o.y); ou.z = f2bf(o.z); ou.w = f2bf(o.w);
    *(ushort4*)&hb[e] = ou;                     // in-place bf16 x2 (hT dead)
  }
  __syncthreads();
  // transpose to (B,N,C) bf16
  const int tx = t % 16, ty = t / 16;
  ushort* tb = x2t + (size_t)b * CN + c0 + tx * 4;
#pragma unroll
  for (int u = 0; u < 5; ++u) {
    const int n = ty + 16 * u;
    ushort4 v;
    v.x = f2bf(s[tx * 4 + 0][n]); v.y = f2bf(s[tx * 4 + 1][n]);
    v.z = f2bf(s[tx * 4 + 2][n]); v.w = f2bf(s[tx * 4 + 3][n]);
    *(ushort4*)&tb[(size_t)n * C_] = v;
  }
  // glb0 mean over n — 4 threads per c-row, shfl-reduce the quad
  {
    const int r = t >> 2, q = t & 3;           // r in 0..63
    float sacc = 0.f;
    for (int n = q; n < N_; n += 4) sacc += s[r][n];
    sacc += __shfl_down(sacc, 1);
    sacc += __shfl_down(sacc, 2);
    if (q == 0) glb0b[(size_t)b * C_ + c0 + r] = f2bf(sacc * (1.0f / N_));
  }
}

// ---------------------------------------------------------------------------
// K12: loss per batch; dadj read RAW; min/max reduced inline from bmin/bmax.
// ---------------------------------------------------------------------------
__global__ void k_loss(const float* __restrict__ dadj, const float* __restrict__ sadj,
                       const float* __restrict__ out1, float* __restrict__ lossa,
                       const float* __restrict__ bmin, const float* __restrict__ bmax) {
  const int b = blockIdx.x, t = threadIdx.x;
  __shared__ float red[TPB], red2[TPB];
  __shared__ float slo, sinv, s2;
  red[t]  = (t < 160) ? bmin[t] : 3.4e38f;
  red2[t] = (t < 160) ? bmax[t] : -3.4e38f;
  __syncthreads();
  for (int o = 128; o > 0; o >>= 1) {
    if (t < o) { red[t] = fminf(red[t], red[t + o]); red2[t] = fmaxf(red2[t], red2[t + o]); }
    __syncthreads();
  }
  if (t == 0) { slo = red[0]; sinv = 1.0f / (red2[0] - red[0]); }
  __syncthreads();
  const float lo = slo, inv = sinv;
  const float* db = dadj + (long)b * NN;
  const float* o1 = out1 + b * N_;
  float p2 = 0.f;
  for (int i = t; i < NN; i += TPB) { const float d = (db[i] - lo) * inv - sadj[i]; p2 += d * d; }
  float p1 = 0.f;
  if (t < N_) {
    float acc = 0.f;
    for (int n = 0; n < N_; ++n) acc += o1[n] * ((db[n * N_ + t] - lo) * inv);
    const float d = o1[t] - acc * (1.0f / N_);
    p1 = d * d;
  }
  red[t] = p2; __syncthreads();
  for (int o = 128; o > 0; o >>= 1) { if (t < o) red[t] += red[t + o]; __syncthreads(); }
  if (t == 0) s2 = red[0];
  __syncthreads();
  red[t] = p1; __syncthreads();
  for (int o = 128; o > 0; o >>= 1) { if (t < o) red[t] += red[t + o]; __syncthreads(); }
  if (t == 0) atomicAdd(lossa, sqrtf(s2) + sqrtf(red[0]));
}

// ---------------------------------------------------------------------------
// K14: final BN + leaky: reads h2 bf16 (B,C,N) + fused gemm sums,
// writes fp32 out + loss scalar.
// ---------------------------------------------------------------------------
__global__ void k_final(const ushort* __restrict__ h2, float* __restrict__ outp,
                        const float* __restrict__ g, const float* __restrict__ be,
                        const float* __restrict__ ssum, const float* __restrict__ ssq,
                        const float* __restrict__ lossa) {
  const long i = ((long)blockIdx.x * TPB + threadIdx.x) * 4;
  const int c = (int)((i / N_) % C_);
  ushort4 hu = *(const ushort4*)&h2[i];
  const float mu = ssum[c] * (1.0f / BNr);
  const float rstd = rsqrtf(ssq[c] * (1.0f / BNr) - mu * mu + EPSf);
  const float gm = g[c] * rstd, bb = be[c];
  float4 v;
  v.x = leakyf(gm * (b2f(hu.x) - mu) + bb);
  v.y = leakyf(gm * (b2f(hu.y) - mu) + bb);
  v.z = leakyf(gm * (b2f(hu.z) - mu) + bb);
  v.w = leakyf(gm * (b2f(hu.w) - mu) + bb);
  *(float4*)&outp[i] = v;
  if (blockIdx.x == 0 && threadIdx.x == 0) outp[BCN] = *lossa;
}

// ---------------------------------------------------------------------------
extern "C" void kernel_launch(void* const* d_in, const int* in_sizes, int n_in,
                              void* d_out, int out_size, void* d_ws, size_t ws_size,
                              hipStream_t stream) {
  const float* x    = (const float*)d_in[0];
  const float* out1 = (const float*)d_in[1];
  const float* ap   = (const float*)d_in[2];
  const float* Ws   = (const float*)d_in[3];
  const float* Wd   = (const float*)d_in[4];
  const float* Wg   = (const float*)d_in[5];
  const float* bg   = (const float*)d_in[6];
  const float* Wco  = (const float*)d_in[7];
  const float* bco  = (const float*)d_in[8];
  const float* bn_g  = (const float*)d_in[9];
  const float* bn_b  = (const float*)d_in[10];
  const float* bng_g = (const float*)d_in[11];
  const float* bng_b = (const float*)d_in[12];
  float* out = (float*)d_out;

  float* w = (float*)d_ws;
  float* sadj  = w;                    // 6400
  float* dadj  = sadj + NN;            // 1638400
  float* glb0  = dadj + BNN;           // 262144 (used as bf16 ushorts)
  float* glb1  = glb0 + B_ * C_;       // 262144
  float* go    = glb1 + B_ * C_;       // 20480 -- start of contiguous zero region
  float* ssum1 = go + BNr;             // 1024
  float* ssq1  = ssum1 + C_;           // 1024
  float* ssum2 = ssq1 + C_;            // 1024
  float* ssq2  = ssum2 + C_;           // 1024
  float* gsum  = ssq2 + C_;            // 1024
  float* gsq   = gsum + C_;            // 1024 -- end of zero region (26624 floats)
  float* bmin  = gsq + C_;             // 512 (160 used)
  float* bmax  = bmin + 512;           // 512 (160 used)
  float* lossa = bmax + 512;           // 1
  ushort* ub   = (ushort*)(((uintptr_t)(lossa + 1) + 255) & ~(uintptr_t)255);
  ushort* xa_bf  = ub;                    // BCN bf16 (B,N,C): fold out / x2t / fold2 out
  ushort* hT_bf  = xa_bf + BCN;           // BCN bf16 (B,C,N): h -> x2bf (in-place) -> h2
  ushort* Wts    = hT_bf + BCN;           // 1M bf16 (O,C)
  ushort* Wtd    = Wts + (size_t)C_ * C_; // 1M bf16 (O,C)
  ushort* Wco2t  = Wtd + (size_t)C_ * C_; // 80K bf16 (80,1024)
  ushort* adj_bf = Wco2t + (size_t)N_ * C_; // 80x96 bf16 prepadded
  // bf16 aliases in regions dead at time of use:
  ushort* Wg_bf   = (ushort*)dadj;                      // 1M ushorts; dadj written later
  ushort* Wco1t   = (ushort*)dadj + (size_t)C_ * C_;    // 80K ushorts, same region
  ushort* glb0_bf = (ushort*)glb0;
  ushort* x2t_bf  = xa_bf;                              // xa dead after GEMM#1; x2t dead before fold#2

  // ---- prep (single merged launch: transposes, converts, zeroes, prep_adj) ----
  k_prep_all<<<3259, TPB, 0, stream>>>(Ws, Wd, Wco, Wg, Wts, Wtd, Wco1t, Wco2t, Wg_bf,
                                       go, ap, sadj, adj_bf, lossa);

  // ---- static GCN ----
  k_fold_mfma<<<B_ * 8, TPB, 0, stream>>>(x, hT_bf, adj_bf, xa_bf, 0, bmin, bmax);
  k_gemm_256<<<320, 512, 0, stream>>>(xa_bf, Wts, hT_bf, 1, ssum1, ssq1);
  k_x2_fused<<<(B_ * C_) / 64, TPB, 0, stream>>>(x, hT_bf, bn_g, bn_b, ssum1, ssq1,
                                                 x2t_bf, glb0_bf);

  // ---- dynamic graph construction ----
  k_glb_mfma<<<dim3(C_ / 64, B_ / 64), TPB, 0, stream>>>(glb0_bf, Wg_bf, bg, glb1, gsum, gsq);
  k_go_mfma<<<dim3(8, B_ / 128), TPB, 0, stream>>>(glb1, Wco1t, gsum, gsq, bng_g, bng_b, go);
  k_dadj_mfma<<<BNr / 128, TPB, 0, stream>>>(x2t_bf, Wco2t, go, bco, dadj, bmin, bmax);

  // ---- adjacency loss (reads raw dadj; minmax reduced inline) ----
  k_loss<<<B_, TPB, 0, stream>>>(dadj, sadj, out1, lossa, bmin, bmax);

  // ---- dynamic GCN (fold reads x2 bf16 from hT region; normalizes dadj inline) ----
  k_fold_mfma<<<B_ * 8, TPB, 0, stream>>>(x, hT_bf, dadj, xa_bf, 1, bmin, bmax);
  k_gemm_256<<<320, 512, 0, stream>>>(xa_bf, Wtd, hT_bf, 1, ssum2, ssq2);
  k_final<<<(int)(BCN / (4 * TPB)), TPB, 0, stream>>>(hT_bf, out, bn_g, bn_b, ssum2, ssq2, lossa);
}

// Round 9
// 491.403 us; speedup vs baseline: 1.4178x; 1.0199x over previous
//
#include <hip/hip_runtime.h>
#include <hip/hip_bf16.h>
#include <math.h>

#define TPB 256

constexpr int   B_  = 256;
constexpr int   C_  = 1024;
constexpr int   N_  = 80;
constexpr int   BNr = B_ * N_;                 // 20480 rows for BN / GEMM M
constexpr int   CN  = C_ * N_;                 // 81920
constexpr long  BCN = (long)B_ * C_ * N_;      // 20971520
constexpr int   NN  = N_ * N_;                 // 6400
constexpr int   BNN = B_ * NN;                 // 1638400
constexpr float EPSf = 1e-5f;

typedef __bf16 bf16x8 __attribute__((ext_vector_type(8)));
typedef float  f32x4  __attribute__((ext_vector_type(4)));

__device__ __forceinline__ float leakyf(float v) { return v >= 0.0f ? v : 0.2f * v; }

__device__ __forceinline__ ushort f2bf(float f) {
  __hip_bfloat16 h = __float2bfloat16(f);
  ushort u; __builtin_memcpy(&u, &h, 2); return u;
}
__device__ __forceinline__ float b2f(ushort u) {
  __hip_bfloat16 h; __builtin_memcpy(&h, &u, 2);
  return __bfloat162float(h);
}

#define GLOBAL_AS __attribute__((address_space(1)))
#define LDS_AS    __attribute__((address_space(3)))
__device__ __forceinline__ void load_lds16(const void* g, void* l) {
  __builtin_amdgcn_global_load_lds((const GLOBAL_AS void*)g, (LDS_AS void*)l, 16, 0, 0);
}

// ---------------------------------------------------------------------------
// K-PREP (merged): blockIdx ranges ->
//   [0,1024)    : Wts[o][c] = bf16(Ws[c][o])   (32x32 tile transpose)
//   [1024,2048) : Wtd[o][c] = bf16(Wd[c][o])
//   [2048,2208) : split Wco (80x2048) -> Wco1t / Wco2t bf16
//   [2208,3232) : Wg -> Wg_bf elementwise
//   [3232,3258) : zero go(20480) + ssum1/ssq1/ssum2/ssq2/gsum/gsq (6144 floats)
//   [3258]      : prep_adj (sadj, adj_bf, lossa=0)
// ---------------------------------------------------------------------------
__global__ __launch_bounds__(256) void k_prep_all(
    const float* __restrict__ Ws, const float* __restrict__ Wd,
    const float* __restrict__ Wco, const float* __restrict__ Wg,
    ushort* __restrict__ Wts, ushort* __restrict__ Wtd,
    ushort* __restrict__ Wco1t, ushort* __restrict__ Wco2t, ushort* __restrict__ Wg_bf,
    float* __restrict__ zbase,
    const float* __restrict__ ap, float* __restrict__ sadj,
    ushort* __restrict__ adj_bf, float* __restrict__ lossa) {
  __shared__ float sh[NN];          // 25.6 KB; doubles as 32x33 transpose tile
  __shared__ float red[TPB];
  __shared__ float sD[N_];
  __shared__ float s_lo, s_hi;
  const int t = threadIdx.x;
  const int blk = blockIdx.x;
  if (blk < 2048) {
    const float* W = (blk < 1024) ? Ws : Wd;
    ushort* Wt = (blk < 1024) ? Wts : Wtd;
    const int bb = blk & 1023;
    const int bx = bb & 31, by = bb >> 5;
    const int tx = t % 32, ty = t / 32;
    const int r0 = by * 32, c0 = bx * 32;
#pragma unroll
    for (int k = 0; k < 4; ++k) sh[(ty + 8 * k) * 33 + tx] = W[(size_t)(r0 + ty + 8 * k) * C_ + c0 + tx];
    __syncthreads();
#pragma unroll
    for (int k = 0; k < 4; ++k) Wt[(size_t)(c0 + ty + 8 * k) * C_ + r0 + tx] = f2bf(sh[tx * 33 + ty + 8 * k]);
  } else if (blk < 2208) {
    const int i4 = ((blk - 2048) * TPB + t) * 4;   // 80*2048 elems
    const int o = i4 >> 11, k = i4 & 2047;
    float4 v = *(const float4*)&Wco[(size_t)o * 2048 + k];
    ushort4 u;
    u.x = f2bf(v.x); u.y = f2bf(v.y); u.z = f2bf(v.z); u.w = f2bf(v.w);
    if (k < C_) *(ushort4*)&Wco1t[(size_t)o * C_ + k] = u;
    else        *(ushort4*)&Wco2t[(size_t)o * C_ + (k - C_)] = u;
  } else if (blk < 3232) {
    const long i4 = ((long)(blk - 2208) * TPB + t) * 4;
    float4 v = *(const float4*)&Wg[i4];
    ushort4 u;
    u.x = f2bf(v.x); u.y = f2bf(v.y); u.z = f2bf(v.z); u.w = f2bf(v.w);
    *(ushort4*)&Wg_bf[i4] = u;
  } else if (blk < 3258) {
    const int i = ((blk - 3232) * TPB + t) * 4;    // 26624 floats
    float4 z = make_float4(0.f, 0.f, 0.f, 0.f);
    *(float4*)&zbase[i] = z;
  } else {
    // ---- prep_adj (single block) ----
    float lo = 3.4e38f, hi = -3.4e38f;
    for (int i = t; i < NN; i += TPB) { float v = ap[i]; sh[i] = v; lo = fminf(lo, v); hi = fmaxf(hi, v); }
    red[t] = lo; __syncthreads();
    for (int o = 128; o > 0; o >>= 1) { if (t < o) red[t] = fminf(red[t], red[t + o]); __syncthreads(); }
    if (t == 0) s_lo = red[0];
    __syncthreads();
    red[t] = hi; __syncthreads();
    for (int o = 128; o > 0; o >>= 1) { if (t < o) red[t] = fmaxf(red[t], red[t + o]); __syncthreads(); }
    if (t == 0) s_hi = red[0];
    __syncthreads();
    const float inv = 1.0f / (s_hi - s_lo);
    for (int i = t; i < NN; i += TPB) { float v = (sh[i] - s_lo) * inv; sh[i] = v; sadj[i] = v; }
    __syncthreads();
    if (t < N_) { float sum = 0.f; for (int m = 0; m < N_; ++m) sum += sh[t * N_ + m]; sD[t] = rsqrtf(sum); }
    if (t == 0) *lossa = 0.0f;
    __syncthreads();
    for (int i = t; i < N_ * 96; i += TPB) {
      const int n = i / 96, m = i % 96;
      adj_bf[i] = f2bf((m < N_) ? sD[n] * sh[m * N_ + n] * sD[m] : 0.0f);
    }
  }
}

// ---------------------------------------------------------------------------
// K1v3: MFMA fold.  out[(b*80+n)*1024 + c] (bf16, B,N,C) =
//   sum_m adj[n,m] * X[b, c, m]
// mode 0: adjsrc = adj_bf global (80x96 bf16, prepadded); X from Xf32 (B,C,N).
// mode 1: adjsrc = dadj RAW fp32 (B,80,80), min/max from bmin/bmax[160]
//         reduced inline; tadj in LDS; X from Xbf (bf16, B,C,N).
// ---------------------------------------------------------------------------
__global__ __launch_bounds__(256) void k_fold_mfma(const float* __restrict__ Xf32,
                                                   const ushort* __restrict__ Xbf,
                                                   const void* __restrict__ adjsrc,
                                                   ushort* __restrict__ outp, int mode,
                                                   const float* __restrict__ bmin,
                                                   const float* __restrict__ bmax) {
  __shared__ __align__(16) ushort sX[128][104];     // rows c, cols m (pad->104, b128 2-way free)
  __shared__ __align__(16) ushort sAdj[80][104];    // rows n, cols m
  __shared__ float sD[N_];
  __shared__ float rl[TPB], rh[TPB];
  __shared__ float s_lo, s_inv;
  const int t = threadIdx.x;
  const int b  = blockIdx.x >> 3;
  const int c0 = (blockIdx.x & 7) * 128;

  // ---- adjacency -> sAdj (bf16, m 80..95 zero) ----
  if (mode == 0) {
    const ushort* ab = (const ushort*)adjsrc;
    for (int i = t; i < (N_ * 96) / 4; i += TPB) {
      ushort4 v = *(const ushort4*)&ab[i * 4];
      *(ushort4*)&sAdj[(i * 4) / 96][(i * 4) % 96] = v;
    }
    __syncthreads();
  } else {
    // inline dmm reduce from 160 per-block partials
    rl[t] = (t < 160) ? bmin[t] : 3.4e38f;
    rh[t] = (t < 160) ? bmax[t] : -3.4e38f;
    __syncthreads();
    for (int o = 128; o > 0; o >>= 1) {
      if (t < o) { rl[t] = fminf(rl[t], rl[t + o]); rh[t] = fmaxf(rh[t], rh[t + o]); }
      __syncthreads();
    }
    if (t == 0) { s_lo = rl[0]; s_inv = 1.0f / (rh[0] - rl[0]); }
    __syncthreads();
    const float lo = s_lo, inv = s_inv;
    float* sF = (float*)&sX[0][0];                  // 80*80 fp32 = 25.6KB <= sX
    const float* db = (const float*)adjsrc + (size_t)b * NN;
    for (int i = t; i < NN / 4; i += TPB) {
      float4 v = *(const float4*)&db[i * 4];
      v.x = (v.x - lo) * inv; v.y = (v.y - lo) * inv;
      v.z = (v.z - lo) * inv; v.w = (v.w - lo) * inv;
      *(float4*)&sF[i * 4] = v;
    }
    __syncthreads();
    if (t < N_) { float s = 0.f; for (int m = 0; m < N_; ++m) s += sF[t * N_ + m]; sD[t] = rsqrtf(s); }
    __syncthreads();
    for (int i = t; i < N_ * 96; i += TPB) {
      const int n = i / 96, m = i % 96;
      sAdj[n][m] = f2bf((m < N_) ? sF[m * N_ + n] * sD[n] * sD[m] : 0.0f);
    }
    __syncthreads();                                 // before sX overwrite
  }

  // ---- stage X (128 rows x 80 m); zero pad m 80..95 ----
  if (mode == 0) {
    const float* Xb = Xf32 + ((size_t)b * C_ + c0) * N_;
    for (int i = t; i < (128 * N_) / 4; i += TPB) {
      float4 v = *(const float4*)&Xb[i * 4];
      const int r = (i * 4) / N_, m = (i * 4) % N_;
      ushort4 u; u.x = f2bf(v.x); u.y = f2bf(v.y); u.z = f2bf(v.z); u.w = f2bf(v.w);
      *(ushort4*)&sX[r][m] = u;
    }
  } else {
    const ushort* Xb = Xbf + ((size_t)b * C_ + c0) * N_;
    for (int i = t; i < (128 * N_) / 8; i += TPB) {  // 1280 chunks of 16B
      const int r = i / 10, m = (i % 10) * 8;
      uint4 v = *(const uint4*)&Xb[(size_t)r * N_ + m];
      *(uint4*)&sX[r][m] = v;
    }
  }
  for (int i = t; i < (128 * 16) / 4; i += TPB) {
    const int r = i / 4, m = 80 + (i % 4) * 4;
    ushort4 z; z.x = 0; z.y = 0; z.z = 0; z.w = 0;
    *(ushort4*)&sX[r][m] = z;
  }
  __syncthreads();

  const int lane = t & 63, wid = t >> 6;
  const int l16 = lane & 15, lq = lane >> 4;
  f32x4 acc[2][5];
#pragma unroll
  for (int i = 0; i < 2; ++i)
#pragma unroll
    for (int j = 0; j < 5; ++j) { f32x4 z = {0.f, 0.f, 0.f, 0.f}; acc[i][j] = z; }
  bf16x8 af[2][3], bfr[5][3];
#pragma unroll
  for (int i = 0; i < 2; ++i)
#pragma unroll
    for (int kk = 0; kk < 3; ++kk)
      af[i][kk] = *(const bf16x8*)&sX[wid * 32 + i * 16 + l16][kk * 32 + lq * 8];
#pragma unroll
  for (int j = 0; j < 5; ++j)
#pragma unroll
    for (int kk = 0; kk < 3; ++kk)
      bfr[j][kk] = *(const bf16x8*)&sAdj[j * 16 + l16][kk * 32 + lq * 8];
#pragma unroll
  for (int i = 0; i < 2; ++i)
#pragma unroll
    for (int j = 0; j < 5; ++j)
#pragma unroll
      for (int kk = 0; kk < 3; ++kk)
        acc[i][j] = __builtin_amdgcn_mfma_f32_16x16x32_bf16(af[i][kk], bfr[j][kk], acc[i][j], 0, 0, 0);

  // ---- epilogue: D[row=c_local (lq*4+reg)][col=n (l16)] -> (B,N,C) ushort4 ----
  ushort* ob = outp + (size_t)b * CN;
#pragma unroll
  for (int i = 0; i < 2; ++i) {
    const int c = c0 + wid * 32 + i * 16 + lq * 4;
#pragma unroll
    for (int j = 0; j < 5; ++j) {
      const int n = j * 16 + l16;
      ushort4 u;
      u.x = f2bf(acc[i][j][0]); u.y = f2bf(acc[i][j][1]);
      u.z = f2bf(acc[i][j][2]); u.w = f2bf(acc[i][j][3]);
      *(ushort4*)&ob[(size_t)n * C_ + c] = u;
    }
  }
}

// ---------------------------------------------------------------------------
// K2: 320x128x64 2-phase dbuf MFMA GEMM (T2 swizzle + counted in-flight).
// 64 M-tiles x 8 N-tiles = 512 blocks = exactly 2 full CU rounds (was 320
// blocks -> 62.5% packing).  8 waves as 4M x 2N; per-wave 80x64, acc 5x4.
// Per tile: ph1 {stage next tile (7 calls) into freed buffer; read kk0 frags;
// bar; lgkm; 20 MFMA; bar}  ph2 {read kk1; bar; lgkm; 20 MFMA; vmcnt(0); bar}.
// Staging invariant: next tile's buffer's last reads ended before the barrier
// preceding ph1.  + fused per-channel BN stats ([128ch][16slot] LDS).
// ---------------------------------------------------------------------------
__global__ __launch_bounds__(512, 2) void k_gemm_320(const ushort* __restrict__ A,
                                                     const ushort* __restrict__ Bt,
                                                     void* __restrict__ outp, int out_bf,
                                                     float* __restrict__ bnsum,
                                                     float* __restrict__ bnsq) {
  __shared__ ushort sA[2][320 * 64];   // 80 KB
  __shared__ ushort sB[2][128 * 64];   // 32 KB
  const int t = threadIdx.x;
  const int lane = t & 63, wid = t >> 6;       // 8 waves
  const int wm = wid >> 1, wn = wid & 1;       // 4M x 2N
  const int l16 = lane & 15, lq = lane >> 4;

  // XCD-chunked swizzle: 512 blocks; each XCD: tm in [xcd*8, xcd*8+8), tn 0..7.
  const int lin = blockIdx.x;
  const int xcd = lin & 7, bi = lin >> 3;      // bi in 0..63
  const int tm = xcd * 8 + (bi >> 3);
  const int tn = bi & 7;
  const int m0 = tm * 320, o0 = tn * 128;

  const int srow = t >> 3;                           // 0..63
  const int sswz = ((t & 7) ^ ((t >> 3) & 7)) * 8;   // pre-swizzled source slot

  f32x4 acc[5][4];
#pragma unroll
  for (int i = 0; i < 5; ++i)
#pragma unroll
    for (int j = 0; j < 4; ++j) { f32x4 z = {0.f, 0.f, 0.f, 0.f}; acc[i][j] = z; }

#define STA(PAR, ROWB, KT) load_lds16(A  + (size_t)(m0 + (ROWB) + srow) * C_ + (KT) * 64 + sswz, \
                                      &sA[PAR][((ROWB) + (wid << 3)) * 64])
#define STB(PAR, ROWB, KT) load_lds16(Bt + (size_t)(o0 + (ROWB) + srow) * C_ + (KT) * 64 + sswz, \
                                      &sB[PAR][((ROWB) + (wid << 3)) * 64])
#define STAGE_T(PAR, KT) { STA(PAR, 0, KT); STA(PAR, 64, KT); STA(PAR, 128, KT); \
                           STA(PAR, 192, KT); STA(PAR, 256, KT); \
                           STB(PAR, 0, KT); STB(PAR, 64, KT); }

#define PH(PAR, KK, STAGES, VMW)                                                          \
  {                                                                                       \
    STAGES                                                                                \
    bf16x8 afr[5], bfr[4];                                                                \
    _Pragma("unroll") for (int fi = 0; fi < 5; ++fi)                                      \
      afr[fi] = *(const bf16x8*)&sA[PAR][(wm * 80 + fi * 16 + l16) * 64 +                 \
                                         (((KK) * 4 + lq) ^ (l16 & 7)) * 8];              \
    _Pragma("unroll") for (int gi = 0; gi < 4; ++gi)                                      \
      bfr[gi] = *(const bf16x8*)&sB[PAR][(wn * 64 + gi * 16 + l16) * 64 +                 \
                                         (((KK) * 4 + lq) ^ (l16 & 7)) * 8];              \
    asm volatile("s_barrier" ::: "memory");                                               \
    asm volatile("s_waitcnt lgkmcnt(0)" ::: "memory");                                    \
    __builtin_amdgcn_s_setprio(1);                                                        \
    _Pragma("unroll") for (int fi = 0; fi < 5; ++fi)                                      \
      _Pragma("unroll") for (int gi = 0; gi < 4; ++gi)                                    \
        acc[fi][gi] = __builtin_amdgcn_mfma_f32_16x16x32_bf16(afr[fi], bfr[gi],           \
                                                              acc[fi][gi], 0, 0, 0);      \
    __builtin_amdgcn_s_setprio(0);                                                        \
    VMW                                                                                   \
    asm volatile("s_barrier" ::: "memory");                                               \
  }

  // prologue: stage T0 into par0, drain, sync.
  STAGE_T(0, 0);
  asm volatile("s_waitcnt vmcnt(0)" ::: "memory");
  asm volatile("s_barrier" ::: "memory");

  for (int i = 0; i < 8; ++i) {
    const int t1 = 2 * i + 1, t2 = 2 * i + 2;
    // tile 2i in par0; stage T(2i+1) -> par1 (par1's last reads ended at prior barrier)
    PH(0, 0, { STAGE_T(1, t1); }, {})
    PH(0, 1, {}, { asm volatile("s_waitcnt vmcnt(0)" ::: "memory"); })
    // tile 2i+1 in par1; stage T(2i+2) -> par0
    PH(1, 0, { if (i < 7) STAGE_T(0, t2); }, {})
    PH(1, 1, {}, { if (i < 7) { asm volatile("s_waitcnt vmcnt(0)" ::: "memory"); } })
  }

  // epilogue: row = lq*4+reg -> m; col = l16 -> o. (B,C,N) store, 4 consecutive n.
#pragma unroll
  for (int fi = 0; fi < 5; ++fi) {
    const int mg = m0 + wm * 80 + fi * 16 + lq * 4;
    const int b  = mg / 80;
    const int n0 = mg - b * 80;
#pragma unroll
    for (int gi = 0; gi < 4; ++gi) {
      const int og = o0 + wn * 64 + gi * 16 + l16;
      const size_t off = (size_t)b * CN + (size_t)og * N_ + n0;
      if (out_bf) {
        ushort4 u;
        u.x = f2bf(acc[fi][gi][0]); u.y = f2bf(acc[fi][gi][1]);
        u.z = f2bf(acc[fi][gi][2]); u.w = f2bf(acc[fi][gi][3]);
        *(ushort4*)((ushort*)outp + off) = u;
      } else {
        *(f32x4*)((float*)outp + off) = acc[fi][gi];
      }
    }
  }

  // ---- fused BN partial stats (sA free after last phase barrier) ----
  {
    float* redS = (float*)&sA[0][0];           // [128][16]
    float* redQ = redS + 2048;                 // [128][16]
    const int slot = wm * 4 + lq;              // 0..15
#pragma unroll
    for (int gi = 0; gi < 4; ++gi) {
      float s = 0.f, q = 0.f;
#pragma unroll
      for (int fi = 0; fi < 5; ++fi)
#pragma unroll
        for (int r = 0; r < 4; ++r) { const float v = acc[fi][gi][r]; s += v; q += v * v; }
      const int ol = wn * 64 + gi * 16 + l16;  // 0..127, unique per (wn,gi,l16)
      redS[ol * 16 + slot] = s;
      redQ[ol * 16 + slot] = q;
    }
    __syncthreads();
    if (t < 128) {
      float s = 0.f, q = 0.f;
#pragma unroll
      for (int k = 0; k < 16; ++k) { s += redS[t * 16 + k]; q += redQ[t * 16 + k]; }
      atomicAdd(&bnsum[o0 + t], s);
      atomicAdd(&bnsq[o0 + t], q);
    }
  }
#undef STA
#undef STB
#undef STAGE_T
#undef PH
}

// ---------------------------------------------------------------------------
// K2b: dadj MFMA GEMM. A: x2t bf16 (M=20480, K=1024). Bw: Wco2t bf16 (80,1024).
// dadj[b,o,n] = go[b,o] + bco[o] + sum_k A[m=(b,n)][k]*Bw[o][k].
// Fused per-block min/max -> bmin/bmax[160].
// ---------------------------------------------------------------------------
__global__ __launch_bounds__(256) void k_dadj_mfma(const ushort* __restrict__ A,
                                                   const ushort* __restrict__ Bw,
                                                   const float* __restrict__ go,
                                                   const float* __restrict__ bco,
                                                   float* __restrict__ dadj,
                                                   float* __restrict__ bmin,
                                                   float* __restrict__ bmax) {
  __shared__ ushort smA[128 * 32];
  __shared__ ushort smB[80 * 32];
  const int t = threadIdx.x;
  const int lane = t & 63, wid = t >> 6;
  const int m0 = blockIdx.x * 128;
  const int rto = t >> 2, ch = t & 3;
  const size_t gA0 = (size_t)(m0 + rto) * C_ + (size_t)ch * 8;
  ushort* ldsA = smA + wid * 512;
  const int l16 = lane & 15, lq = lane >> 4;
  const int wrow = wid * 32;
  f32x4 zero = {0.f, 0.f, 0.f, 0.f};
  f32x4 acc[2][5];
#pragma unroll
  for (int i = 0; i < 2; ++i)
#pragma unroll
    for (int j = 0; j < 5; ++j) acc[i][j] = zero;
  for (int k0 = 0; k0 < C_; k0 += 32) {
    load_lds16(A + gA0 + k0,            ldsA);
    load_lds16(A + gA0 + 64 * C_ + k0,  ldsA + 2048);
    {
      const int idx = t;                               // 320 chunks of 16B
      uint4 v = *(const uint4*)&Bw[(size_t)(idx >> 2) * C_ + k0 + (idx & 3) * 8];
      *(uint4*)&smB[idx * 8] = v;
      if (t < 64) {
        const int idx2 = 256 + t;
        uint4 v2 = *(const uint4*)&Bw[(size_t)(idx2 >> 2) * C_ + k0 + (idx2 & 3) * 8];
        *(uint4*)&smB[idx2 * 8] = v2;
      }
    }
    __syncthreads();
    bf16x8 af[2], bfr[5];
#pragma unroll
    for (int i = 0; i < 2; ++i) af[i]  = *(const bf16x8*)&smA[(wrow + i * 16 + l16) * 32 + lq * 8];
#pragma unroll
    for (int j = 0; j < 5; ++j) bfr[j] = *(const bf16x8*)&smB[(j * 16 + l16) * 32 + lq * 8];
#pragma unroll
    for (int i = 0; i < 2; ++i)
#pragma unroll
      for (int j = 0; j < 5; ++j)
        acc[i][j] = __builtin_amdgcn_mfma_f32_16x16x32_bf16(af[i], bfr[j], acc[i][j], 0, 0, 0);
    __syncthreads();
  }
  float vlo = 3.4e38f, vhi = -3.4e38f;
#pragma unroll
  for (int i = 0; i < 2; ++i) {
    const int mg = m0 + wrow + i * 16 + lq * 4;
    const int b  = mg / 80;
    const int n0 = mg - b * 80;
    const float* gob = go + b * N_;
#pragma unroll
    for (int j = 0; j < 5; ++j) {
      const int o = j * 16 + l16;
      const float g = gob[o] + bco[o];
      f32x4 v = acc[i][j];
      v[0] += g; v[1] += g; v[2] += g; v[3] += g;
      vlo = fminf(vlo, fminf(fminf(v[0], v[1]), fminf(v[2], v[3])));
      vhi = fmaxf(vhi, fmaxf(fmaxf(v[0], v[1]), fmaxf(v[2], v[3])));
      *(f32x4*)&dadj[(size_t)b * NN + (size_t)o * N_ + n0] = v;
    }
  }
  // block min/max reduce (reuse smA as float scratch; all LDS reads done)
  float* red = (float*)smA;
  red[t] = vlo; red[TPB + t] = vhi;
  __syncthreads();
  for (int o = 128; o > 0; o >>= 1) {
    if (t < o) {
      red[t] = fminf(red[t], red[t + o]);
      red[TPB + t] = fmaxf(red[TPB + t], red[TPB + t + o]);
    }
    __syncthreads();
  }
  if (t == 0) { bmin[blockIdx.x] = red[0]; bmax[blockIdx.x] = red[TPB]; }
}

// ---------------------------------------------------------------------------
// K2c: glb1 MFMA GEMM. A: glb0_bf (256 x 1024). Bw: Wg_bf (1024 x 1024, K-contig).
// + fused per-channel stats (sum/sumsq of glb1 incl. bias) -> gsum/gsq atomics.
// ---------------------------------------------------------------------------
__global__ __launch_bounds__(256) void k_glb_mfma(const ushort* __restrict__ A,
                                                  const ushort* __restrict__ Bw,
                                                  const float* __restrict__ bias,
                                                  float* __restrict__ outp,
                                                  float* __restrict__ gsum,
                                                  float* __restrict__ gsq) {
  __shared__ ushort smA[2][64 * 32];
  __shared__ ushort smB[2][64 * 32];
  const int t = threadIdx.x;
  const int lane = t & 63, wid = t >> 6;
  const int o0 = blockIdx.x * 64, m0 = blockIdx.y * 64;
  const int rto = t >> 2, ch = t & 3;
  const size_t gA0 = (size_t)(m0 + rto) * C_ + (size_t)ch * 8;
  const size_t gB0 = (size_t)(o0 + rto) * C_ + (size_t)ch * 8;
  const int l16 = lane & 15, lq = lane >> 4;
  const int wm = wid & 1, wn = wid >> 1;
  f32x4 zero = {0.f, 0.f, 0.f, 0.f};
  f32x4 acc[2][2];
#pragma unroll
  for (int i = 0; i < 2; ++i)
#pragma unroll
    for (int j = 0; j < 2; ++j) acc[i][j] = zero;
  for (int k0 = 0; k0 < C_; k0 += 64) {
    load_lds16(A  + gA0 + k0,       smA[0] + wid * 512);
    load_lds16(A  + gA0 + k0 + 32,  smA[1] + wid * 512);
    load_lds16(Bw + gB0 + k0,       smB[0] + wid * 512);
    load_lds16(Bw + gB0 + k0 + 32,  smB[1] + wid * 512);
    __syncthreads();
#pragma unroll
    for (int h = 0; h < 2; ++h) {
      bf16x8 af[2], bfr[2];
#pragma unroll
      for (int i = 0; i < 2; ++i) af[i]  = *(const bf16x8*)&smA[h][(wm * 32 + i * 16 + l16) * 32 + lq * 8];
#pragma unroll
      for (int j = 0; j < 2; ++j) bfr[j] = *(const bf16x8*)&smB[h][(wn * 32 + j * 16 + l16) * 32 + lq * 8];
#pragma unroll
      for (int i = 0; i < 2; ++i)
#pragma unroll
        for (int j = 0; j < 2; ++j)
          acc[i][j] = __builtin_amdgcn_mfma_f32_16x16x32_bf16(af[i], bfr[j], acc[i][j], 0, 0, 0);
    }
    __syncthreads();
  }
  float ssv[2] = {0.f, 0.f}, sqv[2] = {0.f, 0.f};
#pragma unroll
  for (int i = 0; i < 2; ++i) {
    const int mg = m0 + wm * 32 + i * 16 + lq * 4;
#pragma unroll
    for (int j = 0; j < 2; ++j) {
      const int og = o0 + wn * 32 + j * 16 + l16;
      const float bs = bias[og];
      f32x4 v = acc[i][j];
#pragma unroll
      for (int r = 0; r < 4; ++r) {
        const float val = v[r] + bs;
        outp[(size_t)(mg + r) * C_ + og] = val;
        ssv[j] += val; sqv[j] += val * val;
      }
    }
  }
  // stats reduce: [64 og_local][8 slots] in smA (free after last sync)
  {
    float* redS = (float*)&smA[0][0];
    float* redQ = redS + 512;
    const int slot = wm * 4 + lq;
#pragma unroll
    for (int j = 0; j < 2; ++j) {
      const int ol = wn * 32 + j * 16 + l16;   // 0..63
      redS[ol * 8 + slot] = ssv[j];
      redQ[ol * 8 + slot] = sqv[j];
    }
    __syncthreads();
    if (t < 64) {
      float s = 0.f, q = 0.f;
#pragma unroll
      for (int k = 0; k < 8; ++k) { s += redS[t * 8 + k]; q += redQ[t * 8 + k]; }
      atomicAdd(&gsum[o0 + t], s);
      atomicAdd(&gsq[o0 + t], q);
    }
  }
}

// ---------------------------------------------------------------------------
// K2d: go MFMA GEMM, split-K x8, BN+leaky applied inline from gsum/gsq while
// reg-staging A from fp32 glb1 (replaces k_bng + glbf buffer).
// ---------------------------------------------------------------------------
__global__ __launch_bounds__(256) void k_go_mfma(const float* __restrict__ glb1,
                                                 const ushort* __restrict__ Bw,
                                                 const float* __restrict__ gsum,
                                                 const float* __restrict__ gsq,
                                                 const float* __restrict__ gg,
                                                 const float* __restrict__ gb,
                                                 float* __restrict__ go) {
  __shared__ ushort smA[128 * 32];
  __shared__ ushort smB[80 * 32];
  __shared__ float pgm[C_], pmu[C_], pgb[C_];
  const int t = threadIdx.x;
  const int lane = t & 63, wid = t >> 6;
  const int kbase = blockIdx.x * 128;
  const int m0 = blockIdx.y * 128;
  const int rto = t >> 2, ch = t & 3;
  const int l16 = lane & 15, lq = lane >> 4;
  const int wrow = wid * 32;
  for (int c = t; c < C_; c += TPB) {
    const float mu = gsum[c] * (1.0f / B_);
    const float var = gsq[c] * (1.0f / B_) - mu * mu;
    pgm[c] = gg[c] * rsqrtf(var + EPSf); pmu[c] = mu; pgb[c] = gb[c];
  }
  __syncthreads();
  f32x4 zero = {0.f, 0.f, 0.f, 0.f};
  f32x4 acc[2][5];
#pragma unroll
  for (int i = 0; i < 2; ++i)
#pragma unroll
    for (int j = 0; j < 5; ++j) acc[i][j] = zero;
  for (int kk0 = 0; kk0 < 128; kk0 += 32) {
    const int k0 = kbase + kk0;
    // A: rows m0+h*64+rto, cols k0+ch*8..+8; BN+leaky+bf16 in registers
#pragma unroll
    for (int h = 0; h < 2; ++h) {
      const float* src = &glb1[(size_t)(m0 + h * 64 + rto) * C_ + k0 + ch * 8];
      float4 a0 = *(const float4*)src;
      float4 a1 = *(const float4*)(src + 4);
      float av[8] = {a0.x, a0.y, a0.z, a0.w, a1.x, a1.y, a1.z, a1.w};
      ushort4 u0, u1;
      const int cb = k0 + ch * 8;
      u0.x = f2bf(leakyf(pgm[cb+0]*(av[0]-pmu[cb+0])+pgb[cb+0]));
      u0.y = f2bf(leakyf(pgm[cb+1]*(av[1]-pmu[cb+1])+pgb[cb+1]));
      u0.z = f2bf(leakyf(pgm[cb+2]*(av[2]-pmu[cb+2])+pgb[cb+2]));
      u0.w = f2bf(leakyf(pgm[cb+3]*(av[3]-pmu[cb+3])+pgb[cb+3]));
      u1.x = f2bf(leakyf(pgm[cb+4]*(av[4]-pmu[cb+4])+pgb[cb+4]));
      u1.y = f2bf(leakyf(pgm[cb+5]*(av[5]-pmu[cb+5])+pgb[cb+5]));
      u1.z = f2bf(leakyf(pgm[cb+6]*(av[6]-pmu[cb+6])+pgb[cb+6]));
      u1.w = f2bf(leakyf(pgm[cb+7]*(av[7]-pmu[cb+7])+pgb[cb+7]));
      *(ushort4*)&smA[h * 2048 + t * 8]     = u0;
      *(ushort4*)&smA[h * 2048 + t * 8 + 4] = u1;
    }
    {
      const int idx = t;
      uint4 v = *(const uint4*)&Bw[(size_t)(idx >> 2) * C_ + k0 + (idx & 3) * 8];
      *(uint4*)&smB[idx * 8] = v;
      if (t < 64) {
        const int idx2 = 256 + t;
        uint4 v2 = *(const uint4*)&Bw[(size_t)(idx2 >> 2) * C_ + k0 + (idx2 & 3) * 8];
        *(uint4*)&smB[idx2 * 8] = v2;
      }
    }
    __syncthreads();
    bf16x8 af[2], bfr[5];
#pragma unroll
    for (int i = 0; i < 2; ++i) af[i]  = *(const bf16x8*)&smA[(wrow + i * 16 + l16) * 32 + lq * 8];
#pragma unroll
    for (int j = 0; j < 5; ++j) bfr[j] = *(const bf16x8*)&smB[(j * 16 + l16) * 32 + lq * 8];
#pragma unroll
    for (int i = 0; i < 2; ++i)
#pragma unroll
      for (int j = 0; j < 5; ++j)
        acc[i][j] = __builtin_amdgcn_mfma_f32_16x16x32_bf16(af[i], bfr[j], acc[i][j], 0, 0, 0);
    __syncthreads();
  }
#pragma unroll
  for (int i = 0; i < 2; ++i) {
    const int mg = m0 + wrow + i * 16 + lq * 4;
#pragma unroll
    for (int j = 0; j < 5; ++j) {
      const int o = j * 16 + l16;
#pragma unroll
      for (int r = 0; r < 4; ++r)
        atomicAdd(&go[(size_t)(mg + r) * N_ + o], acc[i][j][r]);
    }
  }
}

// ---------------------------------------------------------------------------
// K4f: fused x2 = x + leaky(bn(hT)) ; bf16 x2 written IN PLACE over hT ;
// x2t transpose (bf16, B,N,C) ; glb0 mean. BN stats from fused gemm sums.
// ---------------------------------------------------------------------------
__global__ __launch_bounds__(256) void k_x2_fused(
    const float* __restrict__ x, ushort* __restrict__ hx,
    const float* __restrict__ g, const float* __restrict__ be,
    const float* __restrict__ ssum, const float* __restrict__ ssq,
    ushort* __restrict__ x2t, ushort* __restrict__ glb0b) {
  __shared__ float s[64][85];
  __shared__ float pg[64], pm[64], pb[64];
  const int t = threadIdx.x;
  const long row0 = (long)blockIdx.x * 64;     // row = b*C + c
  const int b = (int)(row0 >> 10), c0 = (int)(row0 & 1023);
  if (t < 64) {
    const int c = c0 + t;
    const float mu = ssum[c] * (1.0f / BNr);
    const float var = ssq[c] * (1.0f / BNr) - mu * mu;
    const float rstd = rsqrtf(var + EPSf);
    pg[t] = g[c] * rstd; pm[t] = mu; pb[t] = be[c];
  }
  __syncthreads();
  const float* xb = x  + row0 * N_;
  ushort*      hb = hx + row0 * N_;
  for (int i4 = t; i4 < (64 * N_) / 4; i4 += TPB) {
    const int e = i4 * 4, r = e / N_, n = e % N_;
    float4 xv = *(const float4*)&xb[e];
    ushort4 hu = *(const ushort4*)&hb[e];
    const float gm = pg[r], m = pm[r], bb = pb[r];
    float4 o;
    o.x = xv.x + leakyf(gm * (b2f(hu.x) - m) + bb);
    o.y = xv.y + leakyf(gm * (b2f(hu.y) - m) + bb);
    o.z = xv.z + leakyf(gm * (b2f(hu.z) - m) + bb);
    o.w = xv.w + leakyf(gm * (b2f(hu.w) - m) + bb);
    *(float4*)&s[r][n] = o;
    ushort4 ou;
    ou.x = f2bf(o.x); ou.y = f2bf(o.y); ou.z = f2bf(o.z); ou.w = f2bf(o.w);
    *(ushort4*)&hb[e] = ou;                     // in-place bf16 x2 (hT dead)
  }
  __syncthreads();
  // transpose to (B,N,C) bf16
  const int tx = t % 16, ty = t / 16;
  ushort* tb = x2t + (size_t)b * CN + c0 + tx * 4;
#pragma unroll
  for (int u = 0; u < 5; ++u) {
    const int n = ty + 16 * u;
    ushort4 v;
    v.x = f2bf(s[tx * 4 + 0][n]); v.y = f2bf(s[tx * 4 + 1][n]);
    v.z = f2bf(s[tx * 4 + 2][n]); v.w = f2bf(s[tx * 4 + 3][n]);
    *(ushort4*)&tb[(size_t)n * C_] = v;
  }
  // glb0 mean over n — 4 threads per c-row, shfl-reduce the quad
  {
    const int r = t >> 2, q = t & 3;           // r in 0..63
    float sacc = 0.f;
    for (int n = q; n < N_; n += 4) sacc += s[r][n];
    sacc += __shfl_down(sacc, 1);
    sacc += __shfl_down(sacc, 2);
    if (q == 0) glb0b[(size_t)b * C_ + c0 + r] = f2bf(sacc * (1.0f / N_));
  }
}

// ---------------------------------------------------------------------------
// K12: loss per batch; dadj read RAW; min/max reduced inline from bmin/bmax.
// ---------------------------------------------------------------------------
__global__ void k_loss(const float* __restrict__ dadj, const float* __restrict__ sadj,
                       const float* __restrict__ out1, float* __restrict__ lossa,
                       const float* __restrict__ bmin, const float* __restrict__ bmax) {
  const int b = blockIdx.x, t = threadIdx.x;
  __shared__ float red[TPB], red2[TPB];
  __shared__ float slo, sinv, s2;
  red[t]  = (t < 160) ? bmin[t] : 3.4e38f;
  red2[t] = (t < 160) ? bmax[t] : -3.4e38f;
  __syncthreads();
  for (int o = 128; o > 0; o >>= 1) {
    if (t < o) { red[t] = fminf(red[t], red[t + o]); red2[t] = fmaxf(red2[t], red2[t + o]); }
    __syncthreads();
  }
  if (t == 0) { slo = red[0]; sinv = 1.0f / (red2[0] - red[0]); }
  __syncthreads();
  const float lo = slo, inv = sinv;
  const float* db = dadj + (long)b * NN;
  const float* o1 = out1 + b * N_;
  float p2 = 0.f;
  for (int i = t; i < NN; i += TPB) { const float d = (db[i] - lo) * inv - sadj[i]; p2 += d * d; }
  float p1 = 0.f;
  if (t < N_) {
    float acc = 0.f;
    for (int n = 0; n < N_; ++n) acc += o1[n] * ((db[n * N_ + t] - lo) * inv);
    const float d = o1[t] - acc * (1.0f / N_);
    p1 = d * d;
  }
  red[t] = p2; __syncthreads();
  for (int o = 128; o > 0; o >>= 1) { if (t < o) red[t] += red[t + o]; __syncthreads(); }
  if (t == 0) s2 = red[0];
  __syncthreads();
  red[t] = p1; __syncthreads();
  for (int o = 128; o > 0; o >>= 1) { if (t < o) red[t] += red[t + o]; __syncthreads(); }
  if (t == 0) atomicAdd(lossa, sqrtf(s2) + sqrtf(red[0]));
}

// ---------------------------------------------------------------------------
// K14: final BN + leaky: reads h2 bf16 (B,C,N) + fused gemm sums,
// writes fp32 out + loss scalar.
// ---------------------------------------------------------------------------
__global__ void k_final(const ushort* __restrict__ h2, float* __restrict__ outp,
                        const float* __restrict__ g, const float* __restrict__ be,
                        const float* __restrict__ ssum, const float* __restrict__ ssq,
                        const float* __restrict__ lossa) {
  const long i = ((long)blockIdx.x * TPB + threadIdx.x) * 4;
  const int c = (int)((i / N_) % C_);
  ushort4 hu = *(const ushort4*)&h2[i];
  const float mu = ssum[c] * (1.0f / BNr);
  const float rstd = rsqrtf(ssq[c] * (1.0f / BNr) - mu * mu + EPSf);
  const float gm = g[c] * rstd, bb = be[c];
  float4 v;
  v.x = leakyf(gm * (b2f(hu.x) - mu) + bb);
  v.y = leakyf(gm * (b2f(hu.y) - mu) + bb);
  v.z = leakyf(gm * (b2f(hu.z) - mu) + bb);
  v.w = leakyf(gm * (b2f(hu.w) - mu) + bb);
  *(float4*)&outp[i] = v;
  if (blockIdx.x == 0 && threadIdx.x == 0) outp[BCN] = *lossa;
}

// ---------------------------------------------------------------------------
extern "C" void kernel_launch(void* const* d_in, const int* in_sizes, int n_in,
                              void* d_out, int out_size, void* d_ws, size_t ws_size,
                              hipStream_t stream) {
  const float* x    = (const float*)d_in[0];
  const float* out1 = (const float*)d_in[1];
  const float* ap   = (const float*)d_in[2];
  const float* Ws   = (const float*)d_in[3];
  const float* Wd   = (const float*)d_in[4];
  const float* Wg   = (const float*)d_in[5];
  const float* bg   = (const float*)d_in[6];
  const float* Wco  = (const float*)d_in[7];
  const float* bco  = (const float*)d_in[8];
  const float* bn_g  = (const float*)d_in[9];
  const float* bn_b  = (const float*)d_in[10];
  const float* bng_g = (const float*)d_in[11];
  const float* bng_b = (const float*)d_in[12];
  float* out = (float*)d_out;

  float* w = (float*)d_ws;
  float* sadj  = w;                    // 6400
  float* dadj  = sadj + NN;            // 1638400
  float* glb0  = dadj + BNN;           // 262144 (used as bf16 ushorts)
  float* glb1  = glb0 + B_ * C_;       // 262144
  float* go    = glb1 + B_ * C_;       // 20480 -- start of contiguous zero region
  float* ssum1 = go + BNr;             // 1024
  float* ssq1  = ssum1 + C_;           // 1024
  float* ssum2 = ssq1 + C_;            // 1024
  float* ssq2  = ssum2 + C_;           // 1024
  float* gsum  = ssq2 + C_;            // 1024
  float* gsq   = gsum + C_;            // 1024 -- end of zero region (26624 floats)
  float* bmin  = gsq + C_;             // 512 (160 used)
  float* bmax  = bmin + 512;           // 512 (160 used)
  float* lossa = bmax + 512;           // 1
  ushort* ub   = (ushort*)(((uintptr_t)(lossa + 1) + 255) & ~(uintptr_t)255);
  ushort* xa_bf  = ub;                    // BCN bf16 (B,N,C): fold out / x2t / fold2 out
  ushort* hT_bf  = xa_bf + BCN;           // BCN bf16 (B,C,N): h -> x2bf (in-place) -> h2
  ushort* Wts    = hT_bf + BCN;           // 1M bf16 (O,C)
  ushort* Wtd    = Wts + (size_t)C_ * C_; // 1M bf16 (O,C)
  ushort* Wco2t  = Wtd + (size_t)C_ * C_; // 80K bf16 (80,1024)
  ushort* adj_bf = Wco2t + (size_t)N_ * C_; // 80x96 bf16 prepadded
  // bf16 aliases in regions dead at time of use:
  ushort* Wg_bf   = (ushort*)dadj;                      // 1M ushorts; dadj written later
  ushort* Wco1t   = (ushort*)dadj + (size_t)C_ * C_;    // 80K ushorts, same region
  ushort* glb0_bf = (ushort*)glb0;
  ushort* x2t_bf  = xa_bf;                              // xa dead after GEMM#1; x2t dead before fold#2

  // ---- prep (single merged launch: transposes, converts, zeroes, prep_adj) ----
  k_prep_all<<<3259, TPB, 0, stream>>>(Ws, Wd, Wco, Wg, Wts, Wtd, Wco1t, Wco2t, Wg_bf,
                                       go, ap, sadj, adj_bf, lossa);

  // ---- static GCN ----
  k_fold_mfma<<<B_ * 8, TPB, 0, stream>>>(x, hT_bf, adj_bf, xa_bf, 0, bmin, bmax);
  k_gemm_320<<<512, 512, 0, stream>>>(xa_bf, Wts, hT_bf, 1, ssum1, ssq1);
  k_x2_fused<<<(B_ * C_) / 64, TPB, 0, stream>>>(x, hT_bf, bn_g, bn_b, ssum1, ssq1,
                                                 x2t_bf, glb0_bf);

  // ---- dynamic graph construction ----
  k_glb_mfma<<<dim3(C_ / 64, B_ / 64), TPB, 0, stream>>>(glb0_bf, Wg_bf, bg, glb1, gsum, gsq);
  k_go_mfma<<<dim3(8, B_ / 128), TPB, 0, stream>>>(glb1, Wco1t, gsum, gsq, bng_g, bng_b, go);
  k_dadj_mfma<<<BNr / 128, TPB, 0, stream>>>(x2t_bf, Wco2t, go, bco, dadj, bmin, bmax);

  // ---- adjacency loss (reads raw dadj; minmax reduced inline) ----
  k_loss<<<B_, TPB, 0, stream>>>(dadj, sadj, out1, lossa, bmin, bmax);

  // ---- dynamic GCN (fold reads x2 bf16 from hT region; normalizes dadj inline) ----
  k_fold_mfma<<<B_ * 8, TPB, 0, stream>>>(x, hT_bf, dadj, xa_bf, 1, bmin, bmax);
  k_gemm_320<<<512, 512, 0, stream>>>(xa_bf, Wtd, hT_bf, 1, ssum2, ssq2);
  k_final<<<(int)(BCN / (4 * TPB)), TPB, 0, stream>>>(hT_bf, out, bn_g, bn_b, ssum2, ssq2, lossa);
}

// Round 10
// 467.236 us; speedup vs baseline: 1.4911x; 1.0517x over previous
//
#include <hip/hip_runtime.h>
#include <hip/hip_bf16.h>
#include <math.h>

#define TPB 256

constexpr int   B_  = 256;
constexpr int   C_  = 1024;
constexpr int   N_  = 80;
constexpr int   BNr = B_ * N_;                 // 20480 rows for BN / GEMM M
constexpr int   CN  = C_ * N_;                 // 81920
constexpr long  BCN = (long)B_ * C_ * N_;      // 20971520
constexpr int   NN  = N_ * N_;                 // 6400
constexpr int   BNN = B_ * NN;                 // 1638400
constexpr float EPSf = 1e-5f;

typedef __bf16 bf16x8 __attribute__((ext_vector_type(8)));
typedef float  f32x4  __attribute__((ext_vector_type(4)));

__device__ __forceinline__ float leakyf(float v) { return v >= 0.0f ? v : 0.2f * v; }

__device__ __forceinline__ ushort f2bf(float f) {
  __hip_bfloat16 h = __float2bfloat16(f);
  ushort u; __builtin_memcpy(&u, &h, 2); return u;
}
__device__ __forceinline__ float b2f(ushort u) {
  __hip_bfloat16 h; __builtin_memcpy(&h, &u, 2);
  return __bfloat162float(h);
}

#define GLOBAL_AS __attribute__((address_space(1)))
#define LDS_AS    __attribute__((address_space(3)))
__device__ __forceinline__ void load_lds16(const void* g, void* l) {
  __builtin_amdgcn_global_load_lds((const GLOBAL_AS void*)g, (LDS_AS void*)l, 16, 0, 0);
}

// ---------------------------------------------------------------------------
// K-PREP (merged): blockIdx ranges ->
//   [0,1024)    : Wts[o][c] = bf16(Ws[c][o])   (32x32 tile transpose)
//   [1024,2048) : Wtd[o][c] = bf16(Wd[c][o])
//   [2048,2208) : split Wco (80x2048) -> Wco1t / Wco2t bf16
//   [2208,3232) : Wg -> Wg_bf elementwise
//   [3232,3258) : zero go(20480) + ssum1/ssq1/ssum2/ssq2/gsum/gsq (6144 floats)
//   [3258]      : prep_adj (sadj, adj_bf, lossa=0)
// ---------------------------------------------------------------------------
__global__ __launch_bounds__(256) void k_prep_all(
    const float* __restrict__ Ws, const float* __restrict__ Wd,
    const float* __restrict__ Wco, const float* __restrict__ Wg,
    ushort* __restrict__ Wts, ushort* __restrict__ Wtd,
    ushort* __restrict__ Wco1t, ushort* __restrict__ Wco2t, ushort* __restrict__ Wg_bf,
    float* __restrict__ zbase,
    const float* __restrict__ ap, float* __restrict__ sadj,
    ushort* __restrict__ adj_bf, float* __restrict__ lossa) {
  __shared__ float sh[NN];          // 25.6 KB; doubles as 32x33 transpose tile
  __shared__ float red[TPB];
  __shared__ float sD[N_];
  __shared__ float s_lo, s_hi;
  const int t = threadIdx.x;
  const int blk = blockIdx.x;
  if (blk < 2048) {
    const float* W = (blk < 1024) ? Ws : Wd;
    ushort* Wt = (blk < 1024) ? Wts : Wtd;
    const int bb = blk & 1023;
    const int bx = bb & 31, by = bb >> 5;
    const int tx = t % 32, ty = t / 32;
    const int r0 = by * 32, c0 = bx * 32;
#pragma unroll
    for (int k = 0; k < 4; ++k) sh[(ty + 8 * k) * 33 + tx] = W[(size_t)(r0 + ty + 8 * k) * C_ + c0 + tx];
    __syncthreads();
#pragma unroll
    for (int k = 0; k < 4; ++k) Wt[(size_t)(c0 + ty + 8 * k) * C_ + r0 + tx] = f2bf(sh[tx * 33 + ty + 8 * k]);
  } else if (blk < 2208) {
    const int i4 = ((blk - 2048) * TPB + t) * 4;   // 80*2048 elems
    const int o = i4 >> 11, k = i4 & 2047;
    float4 v = *(const float4*)&Wco[(size_t)o * 2048 + k];
    ushort4 u;
    u.x = f2bf(v.x); u.y = f2bf(v.y); u.z = f2bf(v.z); u.w = f2bf(v.w);
    if (k < C_) *(ushort4*)&Wco1t[(size_t)o * C_ + k] = u;
    else        *(ushort4*)&Wco2t[(size_t)o * C_ + (k - C_)] = u;
  } else if (blk < 3232) {
    const long i4 = ((long)(blk - 2208) * TPB + t) * 4;
    float4 v = *(const float4*)&Wg[i4];
    ushort4 u;
    u.x = f2bf(v.x); u.y = f2bf(v.y); u.z = f2bf(v.z); u.w = f2bf(v.w);
    *(ushort4*)&Wg_bf[i4] = u;
  } else if (blk < 3258) {
    const int i = ((blk - 3232) * TPB + t) * 4;    // 26624 floats
    float4 z = make_float4(0.f, 0.f, 0.f, 0.f);
    *(float4*)&zbase[i] = z;
  } else {
    // ---- prep_adj (single block) ----
    float lo = 3.4e38f, hi = -3.4e38f;
    for (int i = t; i < NN; i += TPB) { float v = ap[i]; sh[i] = v; lo = fminf(lo, v); hi = fmaxf(hi, v); }
    red[t] = lo; __syncthreads();
    for (int o = 128; o > 0; o >>= 1) { if (t < o) red[t] = fminf(red[t], red[t + o]); __syncthreads(); }
    if (t == 0) s_lo = red[0];
    __syncthreads();
    red[t] = hi; __syncthreads();
    for (int o = 128; o > 0; o >>= 1) { if (t < o) red[t] = fmaxf(red[t], red[t + o]); __syncthreads(); }
    if (t == 0) s_hi = red[0];
    __syncthreads();
    const float inv = 1.0f / (s_hi - s_lo);
    for (int i = t; i < NN; i += TPB) { float v = (sh[i] - s_lo) * inv; sh[i] = v; sadj[i] = v; }
    __syncthreads();
    if (t < N_) { float sum = 0.f; for (int m = 0; m < N_; ++m) sum += sh[t * N_ + m]; sD[t] = rsqrtf(sum); }
    if (t == 0) *lossa = 0.0f;
    __syncthreads();
    for (int i = t; i < N_ * 96; i += TPB) {
      const int n = i / 96, m = i % 96;
      adj_bf[i] = f2bf((m < N_) ? sD[n] * sh[m * N_ + n] * sD[m] : 0.0f);
    }
  }
}

// ---------------------------------------------------------------------------
// K1v3: MFMA fold.  out[(b*80+n)*1024 + c] (bf16, B,N,C) =
//   sum_m adj[n,m] * X[b, c, m]
// mode 0: adjsrc = adj_bf global (80x96 bf16, prepadded); X from Xf32 (B,C,N).
// mode 1: adjsrc = dadj RAW fp32 (B,80,80), min/max from bmin/bmax[160]
//         reduced inline; tadj in LDS; X from Xbf (bf16, B,C,N).
//         Chunk-0 blocks additionally compute the adjacency loss from the
//         normalized dadj already sitting in LDS (replaces k_loss).
// ---------------------------------------------------------------------------
__global__ __launch_bounds__(256) void k_fold_mfma(const float* __restrict__ Xf32,
                                                   const ushort* __restrict__ Xbf,
                                                   const void* __restrict__ adjsrc,
                                                   ushort* __restrict__ outp, int mode,
                                                   const float* __restrict__ bmin,
                                                   const float* __restrict__ bmax,
                                                   const float* __restrict__ sadj,
                                                   const float* __restrict__ out1,
                                                   float* __restrict__ lossa) {
  __shared__ __align__(16) ushort sX[128][104];     // rows c, cols m (pad->104, b128 2-way free)
  __shared__ __align__(16) ushort sAdj[80][104];    // rows n, cols m
  __shared__ float sD[N_];
  __shared__ float rl[TPB], rh[TPB];
  __shared__ float s_lo, s_inv;
  const int t = threadIdx.x;
  const int b  = blockIdx.x >> 3;
  const int c0 = (blockIdx.x & 7) * 128;

  // ---- adjacency -> sAdj (bf16, m 80..95 zero) ----
  if (mode == 0) {
    const ushort* ab = (const ushort*)adjsrc;
    for (int i = t; i < (N_ * 96) / 4; i += TPB) {
      ushort4 v = *(const ushort4*)&ab[i * 4];
      *(ushort4*)&sAdj[(i * 4) / 96][(i * 4) % 96] = v;
    }
    __syncthreads();
  } else {
    // inline dmm reduce from 160 per-block partials
    rl[t] = (t < 160) ? bmin[t] : 3.4e38f;
    rh[t] = (t < 160) ? bmax[t] : -3.4e38f;
    __syncthreads();
    for (int o = 128; o > 0; o >>= 1) {
      if (t < o) { rl[t] = fminf(rl[t], rl[t + o]); rh[t] = fmaxf(rh[t], rh[t + o]); }
      __syncthreads();
    }
    if (t == 0) { s_lo = rl[0]; s_inv = 1.0f / (rh[0] - rl[0]); }
    __syncthreads();
    const float lo = s_lo, inv = s_inv;
    float* sF = (float*)&sX[0][0];                  // 80*80 fp32 = 25.6KB <= sX
    const float* db = (const float*)adjsrc + (size_t)b * NN;
    for (int i = t; i < NN / 4; i += TPB) {
      float4 v = *(const float4*)&db[i * 4];
      v.x = (v.x - lo) * inv; v.y = (v.y - lo) * inv;
      v.z = (v.z - lo) * inv; v.w = (v.w - lo) * inv;
      *(float4*)&sF[i * 4] = v;
    }
    __syncthreads();
    if (t < N_) { float s = 0.f; for (int m = 0; m < N_; ++m) s += sF[t * N_ + m]; sD[t] = rsqrtf(s); }
    __syncthreads();
    for (int i = t; i < N_ * 96; i += TPB) {
      const int n = i / 96, m = i % 96;
      sAdj[n][m] = f2bf((m < N_) ? sF[m * N_ + n] * sD[n] * sD[m] : 0.0f);
    }
    __syncthreads();                                 // before sX overwrite / loss reads
    // ---- fused adjacency loss: one block per b (chunk 0) ----
    if ((blockIdx.x & 7) == 0) {
      const float* o1 = out1 + b * N_;
      float p2 = 0.f;
      for (int i = t; i < NN; i += TPB) { const float d = sF[i] - sadj[i]; p2 += d * d; }
      float p1 = 0.f;
      if (t < N_) {
        float a = 0.f;
        for (int n = 0; n < N_; ++n) a += o1[n] * sF[n * N_ + t];
        const float d = o1[t] - a * (1.0f / N_);
        p1 = d * d;
      }
      rl[t] = p2; rh[t] = p1;
      __syncthreads();
      for (int o = 128; o > 0; o >>= 1) {
        if (t < o) { rl[t] += rl[t + o]; rh[t] += rh[t + o]; }
        __syncthreads();
      }
      if (t == 0) atomicAdd(lossa, sqrtf(rl[0]) + sqrtf(rh[0]));
      __syncthreads();                               // loss reads done before sX staging
    }
  }

  // ---- stage X (128 rows x 80 m); zero pad m 80..95 ----
  if (mode == 0) {
    const float* Xb = Xf32 + ((size_t)b * C_ + c0) * N_;
    for (int i = t; i < (128 * N_) / 4; i += TPB) {
      float4 v = *(const float4*)&Xb[i * 4];
      const int r = (i * 4) / N_, m = (i * 4) % N_;
      ushort4 u; u.x = f2bf(v.x); u.y = f2bf(v.y); u.z = f2bf(v.z); u.w = f2bf(v.w);
      *(ushort4*)&sX[r][m] = u;
    }
  } else {
    const ushort* Xb = Xbf + ((size_t)b * C_ + c0) * N_;
    for (int i = t; i < (128 * N_) / 8; i += TPB) {  // 1280 chunks of 16B
      const int r = i / 10, m = (i % 10) * 8;
      uint4 v = *(const uint4*)&Xb[(size_t)r * N_ + m];
      *(uint4*)&sX[r][m] = v;
    }
  }
  for (int i = t; i < (128 * 16) / 4; i += TPB) {
    const int r = i / 4, m = 80 + (i % 4) * 4;
    ushort4 z; z.x = 0; z.y = 0; z.z = 0; z.w = 0;
    *(ushort4*)&sX[r][m] = z;
  }
  __syncthreads();

  const int lane = t & 63, wid = t >> 6;
  const int l16 = lane & 15, lq = lane >> 4;
  f32x4 acc[2][5];
#pragma unroll
  for (int i = 0; i < 2; ++i)
#pragma unroll
    for (int j = 0; j < 5; ++j) { f32x4 z = {0.f, 0.f, 0.f, 0.f}; acc[i][j] = z; }
  bf16x8 af[2][3], bfr[5][3];
#pragma unroll
  for (int i = 0; i < 2; ++i)
#pragma unroll
    for (int kk = 0; kk < 3; ++kk)
      af[i][kk] = *(const bf16x8*)&sX[wid * 32 + i * 16 + l16][kk * 32 + lq * 8];
#pragma unroll
  for (int j = 0; j < 5; ++j)
#pragma unroll
    for (int kk = 0; kk < 3; ++kk)
      bfr[j][kk] = *(const bf16x8*)&sAdj[j * 16 + l16][kk * 32 + lq * 8];
#pragma unroll
  for (int i = 0; i < 2; ++i)
#pragma unroll
    for (int j = 0; j < 5; ++j)
#pragma unroll
      for (int kk = 0; kk < 3; ++kk)
        acc[i][j] = __builtin_amdgcn_mfma_f32_16x16x32_bf16(af[i][kk], bfr[j][kk], acc[i][j], 0, 0, 0);

  // ---- epilogue: D[row=c_local (lq*4+reg)][col=n (l16)] -> (B,N,C) ushort4 ----
  ushort* ob = outp + (size_t)b * CN;
#pragma unroll
  for (int i = 0; i < 2; ++i) {
    const int c = c0 + wid * 32 + i * 16 + lq * 4;
#pragma unroll
    for (int j = 0; j < 5; ++j) {
      const int n = j * 16 + l16;
      ushort4 u;
      u.x = f2bf(acc[i][j][0]); u.y = f2bf(acc[i][j][1]);
      u.z = f2bf(acc[i][j][2]); u.w = f2bf(acc[i][j][3]);
      *(ushort4*)&ob[(size_t)n * C_ + c] = u;
    }
  }
}

// ---------------------------------------------------------------------------
// K2: 160x128x64 2-phase dbuf MFMA GEMM, 2 blocks/CU for cross-block overlap
// (m97 mechanism: one block's MFMA hides the other's stage+barrier drain).
// 128 M-tiles x 8 N-tiles = 1024 blocks = 4 exact CU rounds at 2-deep.
// 4 waves as 2M x 2N; per-wave 80x64, acc 5x4.  T2 swizzle as before.
// LDS 72 KB (sA 2x20K + sB 2x16K) -> 2 blocks/CU, 8 waves/CU.
// + fused per-channel BN stats ([128ch][8slot] LDS).
// ---------------------------------------------------------------------------
__global__ __launch_bounds__(256, 2) void k_gemm_160(const ushort* __restrict__ A,
                                                     const ushort* __restrict__ Bt,
                                                     void* __restrict__ outp, int out_bf,
                                                     float* __restrict__ bnsum,
                                                     float* __restrict__ bnsq) {
  __shared__ ushort sA[2][160 * 64];   // 2 x 20 KB
  __shared__ ushort sB[2][128 * 64];   // 2 x 16 KB
  const int t = threadIdx.x;
  const int lane = t & 63, wid = t >> 6;       // 4 waves
  const int wm = wid >> 1, wn = wid & 1;       // 2M x 2N
  const int l16 = lane & 15, lq = lane >> 4;

  // XCD-chunked swizzle: 1024 blocks; each XCD: tm in [xcd*16, xcd*16+16), tn 0..7.
  const int lin = blockIdx.x;
  const int xcd = lin & 7, bi = lin >> 3;      // bi in 0..127
  const int tm = xcd * 16 + (bi >> 3);
  const int tn = bi & 7;
  const int m0 = tm * 160, o0 = tn * 128;

  const int srow = t >> 3;                           // 0..31 (32 rows per call)
  const int sswz = ((t & 7) ^ ((t >> 3) & 7)) * 8;   // pre-swizzled source slot

  f32x4 acc[5][4];
#pragma unroll
  for (int i = 0; i < 5; ++i)
#pragma unroll
    for (int j = 0; j < 4; ++j) { f32x4 z = {0.f, 0.f, 0.f, 0.f}; acc[i][j] = z; }

#define STA(PAR, ROWB, KT) load_lds16(A  + (size_t)(m0 + (ROWB) + srow) * C_ + (KT) * 64 + sswz, \
                                      &sA[PAR][((ROWB) + (wid << 3)) * 64])
#define STB(PAR, ROWB, KT) load_lds16(Bt + (size_t)(o0 + (ROWB) + srow) * C_ + (KT) * 64 + sswz, \
                                      &sB[PAR][((ROWB) + (wid << 3)) * 64])
#define STAGE_T(PAR, KT) { STA(PAR, 0, KT); STA(PAR, 32, KT); STA(PAR, 64, KT); \
                           STA(PAR, 96, KT); STA(PAR, 128, KT); \
                           STB(PAR, 0, KT); STB(PAR, 32, KT); STB(PAR, 64, KT); STB(PAR, 96, KT); }

#define PH(PAR, KK, STAGES, VMW)                                                          \
  {                                                                                       \
    STAGES                                                                                \
    bf16x8 afr[5], bfr[4];                                                                \
    _Pragma("unroll") for (int fi = 0; fi < 5; ++fi)                                      \
      afr[fi] = *(const bf16x8*)&sA[PAR][(wm * 80 + fi * 16 + l16) * 64 +                 \
                                         (((KK) * 4 + lq) ^ (l16 & 7)) * 8];              \
    _Pragma("unroll") for (int gi = 0; gi < 4; ++gi)                                      \
      bfr[gi] = *(const bf16x8*)&sB[PAR][(wn * 64 + gi * 16 + l16) * 64 +                 \
                                         (((KK) * 4 + lq) ^ (l16 & 7)) * 8];              \
    asm volatile("s_barrier" ::: "memory");                                               \
    asm volatile("s_waitcnt lgkmcnt(0)" ::: "memory");                                    \
    __builtin_amdgcn_s_setprio(1);                                                        \
    _Pragma("unroll") for (int fi = 0; fi < 5; ++fi)                                      \
      _Pragma("unroll") for (int gi = 0; gi < 4; ++gi)                                    \
        acc[fi][gi] = __builtin_amdgcn_mfma_f32_16x16x32_bf16(afr[fi], bfr[gi],           \
                                                              acc[fi][gi], 0, 0, 0);      \
    __builtin_amdgcn_s_setprio(0);                                                        \
    VMW                                                                                   \
    asm volatile("s_barrier" ::: "memory");                                               \
  }

  // prologue: stage T0 into par0, drain, sync.
  STAGE_T(0, 0);
  asm volatile("s_waitcnt vmcnt(0)" ::: "memory");
  asm volatile("s_barrier" ::: "memory");

  for (int i = 0; i < 8; ++i) {
    const int t1 = 2 * i + 1, t2 = 2 * i + 2;
    // tile 2i in par0; stage T(2i+1) -> par1 (par1's last reads ended at prior barrier)
    PH(0, 0, { STAGE_T(1, t1); }, {})
    PH(0, 1, {}, { asm volatile("s_waitcnt vmcnt(0)" ::: "memory"); })
    // tile 2i+1 in par1; stage T(2i+2) -> par0
    PH(1, 0, { if (i < 7) STAGE_T(0, t2); }, {})
    PH(1, 1, {}, { if (i < 7) { asm volatile("s_waitcnt vmcnt(0)" ::: "memory"); } })
  }

  // epilogue: row = lq*4+reg -> m; col = l16 -> o. (B,C,N) store, 4 consecutive n.
#pragma unroll
  for (int fi = 0; fi < 5; ++fi) {
    const int mg = m0 + wm * 80 + fi * 16 + lq * 4;
    const int b  = mg / 80;
    const int n0 = mg - b * 80;
#pragma unroll
    for (int gi = 0; gi < 4; ++gi) {
      const int og = o0 + wn * 64 + gi * 16 + l16;
      const size_t off = (size_t)b * CN + (size_t)og * N_ + n0;
      if (out_bf) {
        ushort4 u;
        u.x = f2bf(acc[fi][gi][0]); u.y = f2bf(acc[fi][gi][1]);
        u.z = f2bf(acc[fi][gi][2]); u.w = f2bf(acc[fi][gi][3]);
        *(ushort4*)((ushort*)outp + off) = u;
      } else {
        *(f32x4*)((float*)outp + off) = acc[fi][gi];
      }
    }
  }

  // ---- fused BN partial stats (sA free after last phase barrier) ----
  {
    float* redS = (float*)&sA[0][0];           // [128][8]
    float* redQ = redS + 1024;                 // [128][8]
    const int slot = wm * 4 + lq;              // 0..7
#pragma unroll
    for (int gi = 0; gi < 4; ++gi) {
      float s = 0.f, q = 0.f;
#pragma unroll
      for (int fi = 0; fi < 5; ++fi)
#pragma unroll
        for (int r = 0; r < 4; ++r) { const float v = acc[fi][gi][r]; s += v; q += v * v; }
      const int ol = wn * 64 + gi * 16 + l16;  // 0..127, unique per (wn,gi,l16)
      redS[ol * 8 + slot] = s;
      redQ[ol * 8 + slot] = q;
    }
    __syncthreads();
    if (t < 128) {
      float s = 0.f, q = 0.f;
#pragma unroll
      for (int k = 0; k < 8; ++k) { s += redS[t * 8 + k]; q += redQ[t * 8 + k]; }
      atomicAdd(&bnsum[o0 + t], s);
      atomicAdd(&bnsq[o0 + t], q);
    }
  }
#undef STA
#undef STB
#undef STAGE_T
#undef PH
}

// ---------------------------------------------------------------------------
// K2b: dadj MFMA GEMM. A: x2t bf16 (M=20480, K=1024). Bw: Wco2t bf16 (80,1024).
// dadj[b,o,n] = go[b,o] + bco[o] + sum_k A[m=(b,n)][k]*Bw[o][k].
// Fused per-block min/max -> bmin/bmax[160].
// ---------------------------------------------------------------------------
__global__ __launch_bounds__(256) void k_dadj_mfma(const ushort* __restrict__ A,
                                                   const ushort* __restrict__ Bw,
                                                   const float* __restrict__ go,
                                                   const float* __restrict__ bco,
                                                   float* __restrict__ dadj,
                                                   float* __restrict__ bmin,
                                                   float* __restrict__ bmax) {
  __shared__ ushort smA[128 * 32];
  __shared__ ushort smB[80 * 32];
  const int t = threadIdx.x;
  const int lane = t & 63, wid = t >> 6;
  const int m0 = blockIdx.x * 128;
  const int rto = t >> 2, ch = t & 3;
  const size_t gA0 = (size_t)(m0 + rto) * C_ + (size_t)ch * 8;
  ushort* ldsA = smA + wid * 512;
  const int l16 = lane & 15, lq = lane >> 4;
  const int wrow = wid * 32;
  f32x4 zero = {0.f, 0.f, 0.f, 0.f};
  f32x4 acc[2][5];
#pragma unroll
  for (int i = 0; i < 2; ++i)
#pragma unroll
    for (int j = 0; j < 5; ++j) acc[i][j] = zero;
  for (int k0 = 0; k0 < C_; k0 += 32) {
    load_lds16(A + gA0 + k0,            ldsA);
    load_lds16(A + gA0 + 64 * C_ + k0,  ldsA + 2048);
    {
      const int idx = t;                               // 320 chunks of 16B
      uint4 v = *(const uint4*)&Bw[(size_t)(idx >> 2) * C_ + k0 + (idx & 3) * 8];
      *(uint4*)&smB[idx * 8] = v;
      if (t < 64) {
        const int idx2 = 256 + t;
        uint4 v2 = *(const uint4*)&Bw[(size_t)(idx2 >> 2) * C_ + k0 + (idx2 & 3) * 8];
        *(uint4*)&smB[idx2 * 8] = v2;
      }
    }
    __syncthreads();
    bf16x8 af[2], bfr[5];
#pragma unroll
    for (int i = 0; i < 2; ++i) af[i]  = *(const bf16x8*)&smA[(wrow + i * 16 + l16) * 32 + lq * 8];
#pragma unroll
    for (int j = 0; j < 5; ++j) bfr[j] = *(const bf16x8*)&smB[(j * 16 + l16) * 32 + lq * 8];
#pragma unroll
    for (int i = 0; i < 2; ++i)
#pragma unroll
      for (int j = 0; j < 5; ++j)
        acc[i][j] = __builtin_amdgcn_mfma_f32_16x16x32_bf16(af[i], bfr[j], acc[i][j], 0, 0, 0);
    __syncthreads();
  }
  float vlo = 3.4e38f, vhi = -3.4e38f;
#pragma unroll
  for (int i = 0; i < 2; ++i) {
    const int mg = m0 + wrow + i * 16 + lq * 4;
    const int b  = mg / 80;
    const int n0 = mg - b * 80;
    const float* gob = go + b * N_;
#pragma unroll
    for (int j = 0; j < 5; ++j) {
      const int o = j * 16 + l16;
      const float g = gob[o] + bco[o];
      f32x4 v = acc[i][j];
      v[0] += g; v[1] += g; v[2] += g; v[3] += g;
      vlo = fminf(vlo, fminf(fminf(v[0], v[1]), fminf(v[2], v[3])));
      vhi = fmaxf(vhi, fmaxf(fmaxf(v[0], v[1]), fmaxf(v[2], v[3])));
      *(f32x4*)&dadj[(size_t)b * NN + (size_t)o * N_ + n0] = v;
    }
  }
  // block min/max reduce (reuse smA as float scratch; all LDS reads done)
  float* red = (float*)smA;
  red[t] = vlo; red[TPB + t] = vhi;
  __syncthreads();
  for (int o = 128; o > 0; o >>= 1) {
    if (t < o) {
      red[t] = fminf(red[t], red[t + o]);
      red[TPB + t] = fmaxf(red[TPB + t], red[TPB + t + o]);
    }
    __syncthreads();
  }
  if (t == 0) { bmin[blockIdx.x] = red[0]; bmax[blockIdx.x] = red[TPB]; }
}

// ---------------------------------------------------------------------------
// K2c: glb1 MFMA GEMM. A: glb0_bf (256 x 1024). Bw: Wg_bf (1024 x 1024, K-contig).
// + fused per-channel stats (sum/sumsq of glb1 incl. bias) -> gsum/gsq atomics.
// ---------------------------------------------------------------------------
__global__ __launch_bounds__(256) void k_glb_mfma(const ushort* __restrict__ A,
                                                  const ushort* __restrict__ Bw,
                                                  const float* __restrict__ bias,
                                                  float* __restrict__ outp,
                                                  float* __restrict__ gsum,
                                                  float* __restrict__ gsq) {
  __shared__ ushort smA[2][64 * 32];
  __shared__ ushort smB[2][64 * 32];
  const int t = threadIdx.x;
  const int lane = t & 63, wid = t >> 6;
  const int o0 = blockIdx.x * 64, m0 = blockIdx.y * 64;
  const int rto = t >> 2, ch = t & 3;
  const size_t gA0 = (size_t)(m0 + rto) * C_ + (size_t)ch * 8;
  const size_t gB0 = (size_t)(o0 + rto) * C_ + (size_t)ch * 8;
  const int l16 = lane & 15, lq = lane >> 4;
  const int wm = wid & 1, wn = wid >> 1;
  f32x4 zero = {0.f, 0.f, 0.f, 0.f};
  f32x4 acc[2][2];
#pragma unroll
  for (int i = 0; i < 2; ++i)
#pragma unroll
    for (int j = 0; j < 2; ++j) acc[i][j] = zero;
  for (int k0 = 0; k0 < C_; k0 += 64) {
    load_lds16(A  + gA0 + k0,       smA[0] + wid * 512);
    load_lds16(A  + gA0 + k0 + 32,  smA[1] + wid * 512);
    load_lds16(Bw + gB0 + k0,       smB[0] + wid * 512);
    load_lds16(Bw + gB0 + k0 + 32,  smB[1] + wid * 512);
    __syncthreads();
#pragma unroll
    for (int h = 0; h < 2; ++h) {
      bf16x8 af[2], bfr[2];
#pragma unroll
      for (int i = 0; i < 2; ++i) af[i]  = *(const bf16x8*)&smA[h][(wm * 32 + i * 16 + l16) * 32 + lq * 8];
#pragma unroll
      for (int j = 0; j < 2; ++j) bfr[j] = *(const bf16x8*)&smB[h][(wn * 32 + j * 16 + l16) * 32 + lq * 8];
#pragma unroll
      for (int i = 0; i < 2; ++i)
#pragma unroll
        for (int j = 0; j < 2; ++j)
          acc[i][j] = __builtin_amdgcn_mfma_f32_16x16x32_bf16(af[i], bfr[j], acc[i][j], 0, 0, 0);
    }
    __syncthreads();
  }
  float ssv[2] = {0.f, 0.f}, sqv[2] = {0.f, 0.f};
#pragma unroll
  for (int i = 0; i < 2; ++i) {
    const int mg = m0 + wm * 32 + i * 16 + lq * 4;
#pragma unroll
    for (int j = 0; j < 2; ++j) {
      const int og = o0 + wn * 32 + j * 16 + l16;
      const float bs = bias[og];
      f32x4 v = acc[i][j];
#pragma unroll
      for (int r = 0; r < 4; ++r) {
        const float val = v[r] + bs;
        outp[(size_t)(mg + r) * C_ + og] = val;
        ssv[j] += val; sqv[j] += val * val;
      }
    }
  }
  // stats reduce: [64 og_local][8 slots] in smA (free after last sync)
  {
    float* redS = (float*)&smA[0][0];
    float* redQ = redS + 512;
    const int slot = wm * 4 + lq;
#pragma unroll
    for (int j = 0; j < 2; ++j) {
      const int ol = wn * 32 + j * 16 + l16;   // 0..63
      redS[ol * 8 + slot] = ssv[j];
      redQ[ol * 8 + slot] = sqv[j];
    }
    __syncthreads();
    if (t < 64) {
      float s = 0.f, q = 0.f;
#pragma unroll
      for (int k = 0; k < 8; ++k) { s += redS[t * 8 + k]; q += redQ[t * 8 + k]; }
      atomicAdd(&gsum[o0 + t], s);
      atomicAdd(&gsq[o0 + t], q);
    }
  }
}

// ---------------------------------------------------------------------------
// K2d: go MFMA GEMM, split-K x8, BN+leaky applied inline from gsum/gsq while
// reg-staging A from fp32 glb1 (replaces k_bng + glbf buffer).
// ---------------------------------------------------------------------------
__global__ __launch_bounds__(256) void k_go_mfma(const float* __restrict__ glb1,
                                                 const ushort* __restrict__ Bw,
                                                 const float* __restrict__ gsum,
                                                 const float* __restrict__ gsq,
                                                 const float* __restrict__ gg,
                                                 const float* __restrict__ gb,
                                                 float* __restrict__ go) {
  __shared__ ushort smA[128 * 32];
  __shared__ ushort smB[80 * 32];
  __shared__ float pgm[C_], pmu[C_], pgb[C_];
  const int t = threadIdx.x;
  const int lane = t & 63, wid = t >> 6;
  const int kbase = blockIdx.x * 128;
  const int m0 = blockIdx.y * 128;
  const int rto = t >> 2, ch = t & 3;
  const int l16 = lane & 15, lq = lane >> 4;
  const int wrow = wid * 32;
  for (int c = t; c < C_; c += TPB) {
    const float mu = gsum[c] * (1.0f / B_);
    const float var = gsq[c] * (1.0f / B_) - mu * mu;
    pgm[c] = gg[c] * rsqrtf(var + EPSf); pmu[c] = mu; pgb[c] = gb[c];
  }
  __syncthreads();
  f32x4 zero = {0.f, 0.f, 0.f, 0.f};
  f32x4 acc[2][5];
#pragma unroll
  for (int i = 0; i < 2; ++i)
#pragma unroll
    for (int j = 0; j < 5; ++j) acc[i][j] = zero;
  for (int kk0 = 0; kk0 < 128; kk0 += 32) {
    const int k0 = kbase + kk0;
    // A: rows m0+h*64+rto, cols k0+ch*8..+8; BN+leaky+bf16 in registers
#pragma unroll
    for (int h = 0; h < 2; ++h) {
      const float* src = &glb1[(size_t)(m0 + h * 64 + rto) * C_ + k0 + ch * 8];
      float4 a0 = *(const float4*)src;
      float4 a1 = *(const float4*)(src + 4);
      float av[8] = {a0.x, a0.y, a0.z, a0.w, a1.x, a1.y, a1.z, a1.w};
      ushort4 u0, u1;
      const int cb = k0 + ch * 8;
      u0.x = f2bf(leakyf(pgm[cb+0]*(av[0]-pmu[cb+0])+pgb[cb+0]));
      u0.y = f2bf(leakyf(pgm[cb+1]*(av[1]-pmu[cb+1])+pgb[cb+1]));
      u0.z = f2bf(leakyf(pgm[cb+2]*(av[2]-pmu[cb+2])+pgb[cb+2]));
      u0.w = f2bf(leakyf(pgm[cb+3]*(av[3]-pmu[cb+3])+pgb[cb+3]));
      u1.x = f2bf(leakyf(pgm[cb+4]*(av[4]-pmu[cb+4])+pgb[cb+4]));
      u1.y = f2bf(leakyf(pgm[cb+5]*(av[5]-pmu[cb+5])+pgb[cb+5]));
      u1.z = f2bf(leakyf(pgm[cb+6]*(av[6]-pmu[cb+6])+pgb[cb+6]));
      u1.w = f2bf(leakyf(pgm[cb+7]*(av[7]-pmu[cb+7])+pgb[cb+7]));
      *(ushort4*)&smA[h * 2048 + t * 8]     = u0;
      *(ushort4*)&smA[h * 2048 + t * 8 + 4] = u1;
    }
    {
      const int idx = t;
      uint4 v = *(const uint4*)&Bw[(size_t)(idx >> 2) * C_ + k0 + (idx & 3) * 8];
      *(uint4*)&smB[idx * 8] = v;
      if (t < 64) {
        const int idx2 = 256 + t;
        uint4 v2 = *(const uint4*)&Bw[(size_t)(idx2 >> 2) * C_ + k0 + (idx2 & 3) * 8];
        *(uint4*)&smB[idx2 * 8] = v2;
      }
    }
    __syncthreads();
    bf16x8 af[2], bfr[5];
#pragma unroll
    for (int i = 0; i < 2; ++i) af[i]  = *(const bf16x8*)&smA[(wrow + i * 16 + l16) * 32 + lq * 8];
#pragma unroll
    for (int j = 0; j < 5; ++j) bfr[j] = *(const bf16x8*)&smB[(j * 16 + l16) * 32 + lq * 8];
#pragma unroll
    for (int i = 0; i < 2; ++i)
#pragma unroll
      for (int j = 0; j < 5; ++j)
        acc[i][j] = __builtin_amdgcn_mfma_f32_16x16x32_bf16(af[i], bfr[j], acc[i][j], 0, 0, 0);
    __syncthreads();
  }
#pragma unroll
  for (int i = 0; i < 2; ++i) {
    const int mg = m0 + wrow + i * 16 + lq * 4;
#pragma unroll
    for (int j = 0; j < 5; ++j) {
      const int o = j * 16 + l16;
#pragma unroll
      for (int r = 0; r < 4; ++r)
        atomicAdd(&go[(size_t)(mg + r) * N_ + o], acc[i][j][r]);
    }
  }
}

// ---------------------------------------------------------------------------
// K4f: fused x2 = x + leaky(bn(hT)) ; bf16 x2 written IN PLACE over hT ;
// x2t transpose (bf16, B,N,C) ; glb0 mean. BN stats from fused gemm sums.
// ---------------------------------------------------------------------------
__global__ __launch_bounds__(256) void k_x2_fused(
    const float* __restrict__ x, ushort* __restrict__ hx,
    const float* __restrict__ g, const float* __restrict__ be,
    const float* __restrict__ ssum, const float* __restrict__ ssq,
    ushort* __restrict__ x2t, ushort* __restrict__ glb0b) {
  __shared__ float s[64][85];
  __shared__ float pg[64], pm[64], pb[64];
  const int t = threadIdx.x;
  const long row0 = (long)blockIdx.x * 64;     // row = b*C + c
  const int b = (int)(row0 >> 10), c0 = (int)(row0 & 1023);
  if (t < 64) {
    const int c = c0 + t;
    const float mu = ssum[c] * (1.0f / BNr);
    const float var = ssq[c] * (1.0f / BNr) - mu * mu;
    const float rstd = rsqrtf(var + EPSf);
    pg[t] = g[c] * rstd; pm[t] = mu; pb[t] = be[c];
  }
  __syncthreads();
  const float* xb = x  + row0 * N_;
  ushort*      hb = hx + row0 * N_;
  for (int i4 = t; i4 < (64 * N_) / 4; i4 += TPB) {
    const int e = i4 * 4, r = e / N_, n = e % N_;
    float4 xv = *(const float4*)&xb[e];
    ushort4 hu = *(const ushort4*)&hb[e];
    const float gm = pg[r], m = pm[r], bb = pb[r];
    float4 o;
    o.x = xv.x + leakyf(gm * (b2f(hu.x) - m) + bb);
    o.y = xv.y + leakyf(gm * (b2f(hu.y) - m) + bb);
    o.z = xv.z + leakyf(gm * (b2f(hu.z) - m) + bb);
    o.w = xv.w + leakyf(gm * (b2f(hu.w) - m) + bb);
    *(float4*)&s[r][n] = o;
    ushort4 ou;
    ou.x = f2bf(o.x); ou.y = f2bf(o.y); ou.z = f2bf(o.z); ou.w = f2bf(o.w);
    *(ushort4*)&hb[e] = ou;                     // in-place bf16 x2 (hT dead)
  }
  __syncthreads();
  // transpose to (B,N,C) bf16
  const int tx = t % 16, ty = t / 16;
  ushort* tb = x2t + (size_t)b * CN + c0 + tx * 4;
#pragma unroll
  for (int u = 0; u < 5; ++u) {
    const int n = ty + 16 * u;
    ushort4 v;
    v.x = f2bf(s[tx * 4 + 0][n]); v.y = f2bf(s[tx * 4 + 1][n]);
    v.z = f2bf(s[tx * 4 + 2][n]); v.w = f2bf(s[tx * 4 + 3][n]);
    *(ushort4*)&tb[(size_t)n * C_] = v;
  }
  // glb0 mean over n — 4 threads per c-row, shfl-reduce the quad
  {
    const int r = t >> 2, q = t & 3;           // r in 0..63
    float sacc = 0.f;
    for (int n = q; n < N_; n += 4) sacc += s[r][n];
    sacc += __shfl_down(sacc, 1);
    sacc += __shfl_down(sacc, 2);
    if (q == 0) glb0b[(size_t)b * C_ + c0 + r] = f2bf(sacc * (1.0f / N_));
  }
}

// ---------------------------------------------------------------------------
// K14: final BN + leaky: reads h2 bf16 (B,C,N) + fused gemm sums,
// writes fp32 out + loss scalar.
// ---------------------------------------------------------------------------
__global__ void k_final(const ushort* __restrict__ h2, float* __restrict__ outp,
                        const float* __restrict__ g, const float* __restrict__ be,
                        const float* __restrict__ ssum, const float* __restrict__ ssq,
                        const float* __restrict__ lossa) {
  const long i = ((long)blockIdx.x * TPB + threadIdx.x) * 4;
  const int c = (int)((i / N_) % C_);
  ushort4 hu = *(const ushort4*)&h2[i];
  const float mu = ssum[c] * (1.0f / BNr);
  const float rstd = rsqrtf(ssq[c] * (1.0f / BNr) - mu * mu + EPSf);
  const float gm = g[c] * rstd, bb = be[c];
  float4 v;
  v.x = leakyf(gm * (b2f(hu.x) - mu) + bb);
  v.y = leakyf(gm * (b2f(hu.y) - mu) + bb);
  v.z = leakyf(gm * (b2f(hu.z) - mu) + bb);
  v.w = leakyf(gm * (b2f(hu.w) - mu) + bb);
  *(float4*)&outp[i] = v;
  if (blockIdx.x == 0 && threadIdx.x == 0) outp[BCN] = *lossa;
}

// ---------------------------------------------------------------------------
extern "C" void kernel_launch(void* const* d_in, const int* in_sizes, int n_in,
                              void* d_out, int out_size, void* d_ws, size_t ws_size,
                              hipStream_t stream) {
  const float* x    = (const float*)d_in[0];
  const float* out1 = (const float*)d_in[1];
  const float* ap   = (const float*)d_in[2];
  const float* Ws   = (const float*)d_in[3];
  const float* Wd   = (const float*)d_in[4];
  const float* Wg   = (const float*)d_in[5];
  const float* bg   = (const float*)d_in[6];
  const float* Wco  = (const float*)d_in[7];
  const float* bco  = (const float*)d_in[8];
  const float* bn_g  = (const float*)d_in[9];
  const float* bn_b  = (const float*)d_in[10];
  const float* bng_g = (const float*)d_in[11];
  const float* bng_b = (const float*)d_in[12];
  float* out = (float*)d_out;

  float* w = (float*)d_ws;
  float* sadj  = w;                    // 6400
  float* dadj  = sadj + NN;            // 1638400
  float* glb0  = dadj + BNN;           // 262144 (used as bf16 ushorts)
  float* glb1  = glb0 + B_ * C_;       // 262144
  float* go    = glb1 + B_ * C_;       // 20480 -- start of contiguous zero region
  float* ssum1 = go + BNr;             // 1024
  float* ssq1  = ssum1 + C_;           // 1024
  float* ssum2 = ssq1 + C_;            // 1024
  float* ssq2  = ssum2 + C_;           // 1024
  float* gsum  = ssq2 + C_;            // 1024
  float* gsq   = gsum + C_;            // 1024 -- end of zero region (26624 floats)
  float* bmin  = gsq + C_;             // 512 (160 used)
  float* bmax  = bmin + 512;           // 512 (160 used)
  float* lossa = bmax + 512;           // 1
  ushort* ub   = (ushort*)(((uintptr_t)(lossa + 1) + 255) & ~(uintptr_t)255);
  ushort* xa_bf  = ub;                    // BCN bf16 (B,N,C): fold out / x2t / fold2 out
  ushort* hT_bf  = xa_bf + BCN;           // BCN bf16 (B,C,N): h -> x2bf (in-place) -> h2
  ushort* Wts    = hT_bf + BCN;           // 1M bf16 (O,C)
  ushort* Wtd    = Wts + (size_t)C_ * C_; // 1M bf16 (O,C)
  ushort* Wco2t  = Wtd + (size_t)C_ * C_; // 80K bf16 (80,1024)
  ushort* adj_bf = Wco2t + (size_t)N_ * C_; // 80x96 bf16 prepadded
  // bf16 aliases in regions dead at time of use:
  ushort* Wg_bf   = (ushort*)dadj;                      // 1M ushorts; dadj written later
  ushort* Wco1t   = (ushort*)dadj + (size_t)C_ * C_;    // 80K ushorts, same region
  ushort* glb0_bf = (ushort*)glb0;
  ushort* x2t_bf  = xa_bf;                              // xa dead after GEMM#1; x2t dead before fold#2

  // ---- prep (single merged launch: transposes, converts, zeroes, prep_adj) ----
  k_prep_all<<<3259, TPB, 0, stream>>>(Ws, Wd, Wco, Wg, Wts, Wtd, Wco1t, Wco2t, Wg_bf,
                                       go, ap, sadj, adj_bf, lossa);

  // ---- static GCN ----
  k_fold_mfma<<<B_ * 8, TPB, 0, stream>>>(x, hT_bf, adj_bf, xa_bf, 0, bmin, bmax,
                                          sadj, out1, lossa);
  k_gemm_160<<<1024, TPB, 0, stream>>>(xa_bf, Wts, hT_bf, 1, ssum1, ssq1);
  k_x2_fused<<<(B_ * C_) / 64, TPB, 0, stream>>>(x, hT_bf, bn_g, bn_b, ssum1, ssq1,
                                                 x2t_bf, glb0_bf);

  // ---- dynamic graph construction ----
  k_glb_mfma<<<dim3(C_ / 64, B_ / 64), TPB, 0, stream>>>(glb0_bf, Wg_bf, bg, glb1, gsum, gsq);
  k_go_mfma<<<dim3(8, B_ / 128), TPB, 0, stream>>>(glb1, Wco1t, gsum, gsq, bng_g, bng_b, go);
  k_dadj_mfma<<<BNr / 128, TPB, 0, stream>>>(x2t_bf, Wco2t, go, bco, dadj, bmin, bmax);

  // ---- dynamic GCN (fold normalizes dadj inline + fused adjacency loss) ----
  k_fold_mfma<<<B_ * 8, TPB, 0, stream>>>(x, hT_bf, dadj, xa_bf, 1, bmin, bmax,
                                          sadj, out1, lossa);
  k_gemm_160<<<1024, TPB, 0, stream>>>(xa_bf, Wtd, hT_bf, 1, ssum2, ssq2);
  k_final<<<(int)(BCN / (4 * TPB)), TPB, 0, stream>>>(hT_bf, out, bn_g, bn_b, ssum2, ssq2, lossa);
}

// Round 11
// 443.871 us; speedup vs baseline: 1.5696x; 1.0526x over previous
//
#include <hip/hip_runtime.h>
#include <hip/hip_bf16.h>
#include <math.h>

#define TPB 256

constexpr int   B_  = 256;
constexpr int   C_  = 1024;
constexpr int   N_  = 80;
constexpr int   BNr = B_ * N_;                 // 20480 rows for BN / GEMM M
constexpr int   CN  = C_ * N_;                 // 81920
constexpr long  BCN = (long)B_ * C_ * N_;      // 20971520
constexpr int   NN  = N_ * N_;                 // 6400
constexpr int   BNN = B_ * NN;                 // 1638400
constexpr int   ADJP = N_ * 96;                // 7680 padded adj elems
constexpr float EPSf = 1e-5f;

typedef __bf16 bf16x8 __attribute__((ext_vector_type(8)));
typedef float  f32x4  __attribute__((ext_vector_type(4)));

__device__ __forceinline__ float leakyf(float v) { return v >= 0.0f ? v : 0.2f * v; }

__device__ __forceinline__ ushort f2bf(float f) {
  __hip_bfloat16 h = __float2bfloat16(f);
  ushort u; __builtin_memcpy(&u, &h, 2); return u;
}
__device__ __forceinline__ float b2f(ushort u) {
  __hip_bfloat16 h; __builtin_memcpy(&h, &u, 2);
  return __bfloat162float(h);
}

#define GLOBAL_AS __attribute__((address_space(1)))
#define LDS_AS    __attribute__((address_space(3)))
__device__ __forceinline__ void load_lds16(const void* g, void* l) {
  __builtin_amdgcn_global_load_lds((const GLOBAL_AS void*)g, (LDS_AS void*)l, 16, 0, 0);
}

// ---------------------------------------------------------------------------
// K-PREP (merged): blockIdx ranges ->
//   [0,1024)    : Wts[o][c] = bf16(Ws[c][o])   (32x32 tile transpose)
//   [1024,2048) : Wtd[o][c] = bf16(Wd[c][o])
//   [2048,2208) : split Wco (80x2048) -> Wco1t / Wco2t bf16
//   [2208,3232) : Wg -> Wg_bf elementwise
//   [3232,3258) : zero go(20480) + ssum1/ssq1/ssum2/ssq2/gsum/gsq (6144 floats)
//   [3258]      : prep_adj (sadj, adj_bf, lossa=0)
// ---------------------------------------------------------------------------
__global__ __launch_bounds__(256) void k_prep_all(
    const float* __restrict__ Ws, const float* __restrict__ Wd,
    const float* __restrict__ Wco, const float* __restrict__ Wg,
    ushort* __restrict__ Wts, ushort* __restrict__ Wtd,
    ushort* __restrict__ Wco1t, ushort* __restrict__ Wco2t, ushort* __restrict__ Wg_bf,
    float* __restrict__ zbase,
    const float* __restrict__ ap, float* __restrict__ sadj,
    ushort* __restrict__ adj_bf, float* __restrict__ lossa) {
  __shared__ float sh[NN];          // 25.6 KB; doubles as 32x33 transpose tile
  __shared__ float red[TPB];
  __shared__ float sD[N_];
  __shared__ float s_lo, s_hi;
  const int t = threadIdx.x;
  const int blk = blockIdx.x;
  if (blk < 2048) {
    const float* W = (blk < 1024) ? Ws : Wd;
    ushort* Wt = (blk < 1024) ? Wts : Wtd;
    const int bb = blk & 1023;
    const int bx = bb & 31, by = bb >> 5;
    const int tx = t % 32, ty = t / 32;
    const int r0 = by * 32, c0 = bx * 32;
#pragma unroll
    for (int k = 0; k < 4; ++k) sh[(ty + 8 * k) * 33 + tx] = W[(size_t)(r0 + ty + 8 * k) * C_ + c0 + tx];
    __syncthreads();
#pragma unroll
    for (int k = 0; k < 4; ++k) Wt[(size_t)(c0 + ty + 8 * k) * C_ + r0 + tx] = f2bf(sh[tx * 33 + ty + 8 * k]);
  } else if (blk < 2208) {
    const int i4 = ((blk - 2048) * TPB + t) * 4;   // 80*2048 elems
    const int o = i4 >> 11, k = i4 & 2047;
    float4 v = *(const float4*)&Wco[(size_t)o * 2048 + k];
    ushort4 u;
    u.x = f2bf(v.x); u.y = f2bf(v.y); u.z = f2bf(v.z); u.w = f2bf(v.w);
    if (k < C_) *(ushort4*)&Wco1t[(size_t)o * C_ + k] = u;
    else        *(ushort4*)&Wco2t[(size_t)o * C_ + (k - C_)] = u;
  } else if (blk < 3232) {
    const long i4 = ((long)(blk - 2208) * TPB + t) * 4;
    float4 v = *(const float4*)&Wg[i4];
    ushort4 u;
    u.x = f2bf(v.x); u.y = f2bf(v.y); u.z = f2bf(v.z); u.w = f2bf(v.w);
    *(ushort4*)&Wg_bf[i4] = u;
  } else if (blk < 3258) {
    const int i = ((blk - 3232) * TPB + t) * 4;    // 26624 floats
    float4 z = make_float4(0.f, 0.f, 0.f, 0.f);
    *(float4*)&zbase[i] = z;
  } else {
    // ---- prep_adj (single block) ----
    float lo = 3.4e38f, hi = -3.4e38f;
    for (int i = t; i < NN; i += TPB) { float v = ap[i]; sh[i] = v; lo = fminf(lo, v); hi = fmaxf(hi, v); }
    red[t] = lo; __syncthreads();
    for (int o = 128; o > 0; o >>= 1) { if (t < o) red[t] = fminf(red[t], red[t + o]); __syncthreads(); }
    if (t == 0) s_lo = red[0];
    __syncthreads();
    red[t] = hi; __syncthreads();
    for (int o = 128; o > 0; o >>= 1) { if (t < o) red[t] = fmaxf(red[t], red[t + o]); __syncthreads(); }
    if (t == 0) s_hi = red[0];
    __syncthreads();
    const float inv = 1.0f / (s_hi - s_lo);
    for (int i = t; i < NN; i += TPB) { float v = (sh[i] - s_lo) * inv; sh[i] = v; sadj[i] = v; }
    __syncthreads();
    if (t < N_) { float sum = 0.f; for (int m = 0; m < N_; ++m) sum += sh[t * N_ + m]; sD[t] = rsqrtf(sum); }
    if (t == 0) *lossa = 0.0f;
    __syncthreads();
    for (int i = t; i < ADJP; i += TPB) {
      const int n = i / 96, m = i % 96;
      adj_bf[i] = f2bf((m < N_) ? sD[n] * sh[m * N_ + n] * sD[m] : 0.0f);
    }
  }
}

// ---------------------------------------------------------------------------
// K-TADJ: per-b tadj build (replaces fold mode-1 per-block redundancy) +
// fused adjacency loss.  One block per b.
//   dmm reduced inline from bmin/bmax[160]; dadj[b] normalized in LDS;
//   tadj_bf[b][n][96] = bf16(D[n]*dnorm[m][n]*D[m]) (m 80..95 zero);
//   loss += ||dnorm - sadj||_F + ||out1 - out1*dnorm/N||.
// ---------------------------------------------------------------------------
__global__ __launch_bounds__(256) void k_tadj(const float* __restrict__ dadj,
                                              const float* __restrict__ bmin,
                                              const float* __restrict__ bmax,
                                              const float* __restrict__ sadj,
                                              const float* __restrict__ out1,
                                              ushort* __restrict__ tadj,
                                              float* __restrict__ lossa) {
  __shared__ float sF[NN];
  __shared__ float sD[N_];
  __shared__ float rl[TPB], rh[TPB];
  __shared__ float s_lo, s_inv;
  const int t = threadIdx.x;
  const int b = blockIdx.x;
  rl[t] = (t < 160) ? bmin[t] : 3.4e38f;
  rh[t] = (t < 160) ? bmax[t] : -3.4e38f;
  __syncthreads();
  for (int o = 128; o > 0; o >>= 1) {
    if (t < o) { rl[t] = fminf(rl[t], rl[t + o]); rh[t] = fmaxf(rh[t], rh[t + o]); }
    __syncthreads();
  }
  if (t == 0) { s_lo = rl[0]; s_inv = 1.0f / (rh[0] - rl[0]); }
  __syncthreads();
  const float lo = s_lo, inv = s_inv;
  const float* db = dadj + (size_t)b * NN;
  for (int i = t; i < NN / 4; i += TPB) {
    float4 v = *(const float4*)&db[i * 4];
    v.x = (v.x - lo) * inv; v.y = (v.y - lo) * inv;
    v.z = (v.z - lo) * inv; v.w = (v.w - lo) * inv;
    *(float4*)&sF[i * 4] = v;
  }
  __syncthreads();
  if (t < N_) { float s = 0.f; for (int m = 0; m < N_; ++m) s += sF[t * N_ + m]; sD[t] = rsqrtf(s); }
  __syncthreads();
  ushort* tb = tadj + (size_t)b * ADJP;
  for (int i = t; i < ADJP; i += TPB) {
    const int n = i / 96, m = i % 96;
    tb[i] = f2bf((m < N_) ? sF[m * N_ + n] * sD[n] * sD[m] : 0.0f);
  }
  // ---- fused loss ----
  const float* o1 = out1 + b * N_;
  float p2 = 0.f;
  for (int i = t; i < NN; i += TPB) { const float d = sF[i] - sadj[i]; p2 += d * d; }
  float p1 = 0.f;
  if (t < N_) {
    float a = 0.f;
    for (int n = 0; n < N_; ++n) a += o1[n] * sF[n * N_ + t];
    const float d = o1[t] - a * (1.0f / N_);
    p1 = d * d;
  }
  rl[t] = p2; rh[t] = p1;
  __syncthreads();
  for (int o = 128; o > 0; o >>= 1) {
    if (t < o) { rl[t] += rl[t + o]; rh[t] += rh[t + o]; }
    __syncthreads();
  }
  if (t == 0) atomicAdd(lossa, sqrtf(rl[0]) + sqrtf(rh[0]));
}

// ---------------------------------------------------------------------------
// K-FOLD (barrier-free, zero-LDS streaming):
//   out[(b*80+n)*1024 + c] (bf16, B,N,C) = sum_m adj[n,m] * X[b,c,m]
// A-frags read DIRECTLY from global (fp32 x + cvt in mode 0, bf16 x2 in
// mode 1); B-frags read directly from the prepadded 80x96 bf16 adjacency
// (adj_bf in mode 0, tadj_bf[b] in mode 1; both L2-resident).
// No __syncthreads, no LDS, no bank conflicts: pure latency-tolerant stream.
// ---------------------------------------------------------------------------
__global__ __launch_bounds__(256) void k_fold(const float* __restrict__ Xf32,
                                              const ushort* __restrict__ Xbf,
                                              const ushort* __restrict__ adjb,
                                              ushort* __restrict__ outp, int mode) {
  const int t = threadIdx.x;
  const int b  = blockIdx.x >> 3;
  const int c0 = (blockIdx.x & 7) * 128;
  const int lane = t & 63, wid = t >> 6;
  const int l16 = lane & 15, lq = lane >> 4;
  const ushort* ab = adjb + (mode ? (size_t)b * ADJP : 0);

  f32x4 acc[2][5];
#pragma unroll
  for (int i = 0; i < 2; ++i)
#pragma unroll
    for (int j = 0; j < 5; ++j) { f32x4 z = {0.f, 0.f, 0.f, 0.f}; acc[i][j] = z; }

#pragma unroll
  for (int kk = 0; kk < 3; ++kk) {
    const int mf = kk * 32 + lq * 8;
    bf16x8 b5[5], a2[2];
#pragma unroll
    for (int j = 0; j < 5; ++j)
      b5[j] = *(const bf16x8*)&ab[(j * 16 + l16) * 96 + mf];
#pragma unroll
    for (int i = 0; i < 2; ++i) {
      const int row = wid * 32 + i * 16 + l16;
      if (mf >= N_) {
        union { bf16x8 v; uint4 u; } z; z.u = make_uint4(0, 0, 0, 0);
        a2[i] = z.v;
      } else if (mode == 0) {
        const float* src = Xf32 + ((size_t)b * C_ + c0 + row) * N_ + mf;
        float4 v0 = *(const float4*)src;
        float4 v1 = *(const float4*)(src + 4);
        union { bf16x8 v; ushort u[8]; } tmp;
        tmp.u[0] = f2bf(v0.x); tmp.u[1] = f2bf(v0.y); tmp.u[2] = f2bf(v0.z); tmp.u[3] = f2bf(v0.w);
        tmp.u[4] = f2bf(v1.x); tmp.u[5] = f2bf(v1.y); tmp.u[6] = f2bf(v1.z); tmp.u[7] = f2bf(v1.w);
        a2[i] = tmp.v;
      } else {
        a2[i] = *(const bf16x8*)&Xbf[((size_t)b * C_ + c0 + row) * N_ + mf];
      }
    }
#pragma unroll
    for (int i = 0; i < 2; ++i)
#pragma unroll
      for (int j = 0; j < 5; ++j)
        acc[i][j] = __builtin_amdgcn_mfma_f32_16x16x32_bf16(a2[i], b5[j], acc[i][j], 0, 0, 0);
  }

  // ---- epilogue: D[row=c_local (lq*4+reg)][col=n (l16)] -> (B,N,C) ushort4 ----
  ushort* ob = outp + (size_t)b * CN;
#pragma unroll
  for (int i = 0; i < 2; ++i) {
    const int c = c0 + wid * 32 + i * 16 + lq * 4;
#pragma unroll
    for (int j = 0; j < 5; ++j) {
      const int n = j * 16 + l16;
      ushort4 u;
      u.x = f2bf(acc[i][j][0]); u.y = f2bf(acc[i][j][1]);
      u.z = f2bf(acc[i][j][2]); u.w = f2bf(acc[i][j][3]);
      *(ushort4*)&ob[(size_t)n * C_ + c] = u;
    }
  }
}

// ---------------------------------------------------------------------------
// K2: 160x128x64 2-phase dbuf MFMA GEMM, 2 blocks/CU (verified r10).
// + fused per-channel BN stats ([128ch][8slot] LDS).
// ---------------------------------------------------------------------------
__global__ __launch_bounds__(256, 2) void k_gemm_160(const ushort* __restrict__ A,
                                                     const ushort* __restrict__ Bt,
                                                     void* __restrict__ outp, int out_bf,
                                                     float* __restrict__ bnsum,
                                                     float* __restrict__ bnsq) {
  __shared__ ushort sA[2][160 * 64];   // 2 x 20 KB
  __shared__ ushort sB[2][128 * 64];   // 2 x 16 KB
  const int t = threadIdx.x;
  const int lane = t & 63, wid = t >> 6;       // 4 waves
  const int wm = wid >> 1, wn = wid & 1;       // 2M x 2N
  const int l16 = lane & 15, lq = lane >> 4;

  // XCD-chunked swizzle: 1024 blocks; each XCD: tm in [xcd*16, xcd*16+16), tn 0..7.
  const int lin = blockIdx.x;
  const int xcd = lin & 7, bi = lin >> 3;      // bi in 0..127
  const int tm = xcd * 16 + (bi >> 3);
  const int tn = bi & 7;
  const int m0 = tm * 160, o0 = tn * 128;

  const int srow = t >> 3;                           // 0..31 (32 rows per call)
  const int sswz = ((t & 7) ^ ((t >> 3) & 7)) * 8;   // pre-swizzled source slot

  f32x4 acc[5][4];
#pragma unroll
  for (int i = 0; i < 5; ++i)
#pragma unroll
    for (int j = 0; j < 4; ++j) { f32x4 z = {0.f, 0.f, 0.f, 0.f}; acc[i][j] = z; }

#define STA(PAR, ROWB, KT) load_lds16(A  + (size_t)(m0 + (ROWB) + srow) * C_ + (KT) * 64 + sswz, \
                                      &sA[PAR][((ROWB) + (wid << 3)) * 64])
#define STB(PAR, ROWB, KT) load_lds16(Bt + (size_t)(o0 + (ROWB) + srow) * C_ + (KT) * 64 + sswz, \
                                      &sB[PAR][((ROWB) + (wid << 3)) * 64])
#define STAGE_T(PAR, KT) { STA(PAR, 0, KT); STA(PAR, 32, KT); STA(PAR, 64, KT); \
                           STA(PAR, 96, KT); STA(PAR, 128, KT); \
                           STB(PAR, 0, KT); STB(PAR, 32, KT); STB(PAR, 64, KT); STB(PAR, 96, KT); }

#define PH(PAR, KK, STAGES, VMW)                                                          \
  {                                                                                       \
    STAGES                                                                                \
    bf16x8 afr[5], bfr[4];                                                                \
    _Pragma("unroll") for (int fi = 0; fi < 5; ++fi)                                      \
      afr[fi] = *(const bf16x8*)&sA[PAR][(wm * 80 + fi * 16 + l16) * 64 +                 \
                                         (((KK) * 4 + lq) ^ (l16 & 7)) * 8];              \
    _Pragma("unroll") for (int gi = 0; gi < 4; ++gi)                                      \
      bfr[gi] = *(const bf16x8*)&sB[PAR][(wn * 64 + gi * 16 + l16) * 64 +                 \
                                         (((KK) * 4 + lq) ^ (l16 & 7)) * 8];              \
    asm volatile("s_barrier" ::: "memory");                                               \
    asm volatile("s_waitcnt lgkmcnt(0)" ::: "memory");                                    \
    __builtin_amdgcn_s_setprio(1);                                                        \
    _Pragma("unroll") for (int fi = 0; fi < 5; ++fi)                                      \
      _Pragma("unroll") for (int gi = 0; gi < 4; ++gi)                                    \
        acc[fi][gi] = __builtin_amdgcn_mfma_f32_16x16x32_bf16(afr[fi], bfr[gi],           \
                                                              acc[fi][gi], 0, 0, 0);      \
    __builtin_amdgcn_s_setprio(0);                                                        \
    VMW                                                                                   \
    asm volatile("s_barrier" ::: "memory");                                               \
  }

  // prologue: stage T0 into par0, drain, sync.
  STAGE_T(0, 0);
  asm volatile("s_waitcnt vmcnt(0)" ::: "memory");
  asm volatile("s_barrier" ::: "memory");

  for (int i = 0; i < 8; ++i) {
    const int t1 = 2 * i + 1, t2 = 2 * i + 2;
    // tile 2i in par0; stage T(2i+1) -> par1 (par1's last reads ended at prior barrier)
    PH(0, 0, { STAGE_T(1, t1); }, {})
    PH(0, 1, {}, { asm volatile("s_waitcnt vmcnt(0)" ::: "memory"); })
    // tile 2i+1 in par1; stage T(2i+2) -> par0
    PH(1, 0, { if (i < 7) STAGE_T(0, t2); }, {})
    PH(1, 1, {}, { if (i < 7) { asm volatile("s_waitcnt vmcnt(0)" ::: "memory"); } })
  }

  // epilogue: row = lq*4+reg -> m; col = l16 -> o. (B,C,N) store, 4 consecutive n.
#pragma unroll
  for (int fi = 0; fi < 5; ++fi) {
    const int mg = m0 + wm * 80 + fi * 16 + lq * 4;
    const int b  = mg / 80;
    const int n0 = mg - b * 80;
#pragma unroll
    for (int gi = 0; gi < 4; ++gi) {
      const int og = o0 + wn * 64 + gi * 16 + l16;
      const size_t off = (size_t)b * CN + (size_t)og * N_ + n0;
      if (out_bf) {
        ushort4 u;
        u.x = f2bf(acc[fi][gi][0]); u.y = f2bf(acc[fi][gi][1]);
        u.z = f2bf(acc[fi][gi][2]); u.w = f2bf(acc[fi][gi][3]);
        *(ushort4*)((ushort*)outp + off) = u;
      } else {
        *(f32x4*)((float*)outp + off) = acc[fi][gi];
      }
    }
  }

  // ---- fused BN partial stats (sA free after last phase barrier) ----
  {
    float* redS = (float*)&sA[0][0];           // [128][8]
    float* redQ = redS + 1024;                 // [128][8]
    const int slot = wm * 4 + lq;              // 0..7
#pragma unroll
    for (int gi = 0; gi < 4; ++gi) {
      float s = 0.f, q = 0.f;
#pragma unroll
      for (int fi = 0; fi < 5; ++fi)
#pragma unroll
        for (int r = 0; r < 4; ++r) { const float v = acc[fi][gi][r]; s += v; q += v * v; }
      const int ol = wn * 64 + gi * 16 + l16;  // 0..127, unique per (wn,gi,l16)
      redS[ol * 8 + slot] = s;
      redQ[ol * 8 + slot] = q;
    }
    __syncthreads();
    if (t < 128) {
      float s = 0.f, q = 0.f;
#pragma unroll
      for (int k = 0; k < 8; ++k) { s += redS[t * 8 + k]; q += redQ[t * 8 + k]; }
      atomicAdd(&bnsum[o0 + t], s);
      atomicAdd(&bnsq[o0 + t], q);
    }
  }
#undef STA
#undef STB
#undef STAGE_T
#undef PH
}

// ---------------------------------------------------------------------------
// K2b: dadj MFMA GEMM. A: x2t bf16 (M=20480, K=1024). Bw: Wco2t bf16 (80,1024).
// dadj[b,o,n] = go[b,o] + bco[o] + sum_k A[m=(b,n)][k]*Bw[o][k].
// Fused per-block min/max -> bmin/bmax[160].
// ---------------------------------------------------------------------------
__global__ __launch_bounds__(256) void k_dadj_mfma(const ushort* __restrict__ A,
                                                   const ushort* __restrict__ Bw,
                                                   const float* __restrict__ go,
                                                   const float* __restrict__ bco,
                                                   float* __restrict__ dadj,
                                                   float* __restrict__ bmin,
                                                   float* __restrict__ bmax) {
  __shared__ ushort smA[128 * 32];
  __shared__ ushort smB[80 * 32];
  const int t = threadIdx.x;
  const int lane = t & 63, wid = t >> 6;
  const int m0 = blockIdx.x * 128;
  const int rto = t >> 2, ch = t & 3;
  const size_t gA0 = (size_t)(m0 + rto) * C_ + (size_t)ch * 8;
  ushort* ldsA = smA + wid * 512;
  const int l16 = lane & 15, lq = lane >> 4;
  const int wrow = wid * 32;
  f32x4 zero = {0.f, 0.f, 0.f, 0.f};
  f32x4 acc[2][5];
#pragma unroll
  for (int i = 0; i < 2; ++i)
#pragma unroll
    for (int j = 0; j < 5; ++j) acc[i][j] = zero;
  for (int k0 = 0; k0 < C_; k0 += 32) {
    load_lds16(A + gA0 + k0,            ldsA);
    load_lds16(A + gA0 + 64 * C_ + k0,  ldsA + 2048);
    {
      const int idx = t;                               // 320 chunks of 16B
      uint4 v = *(const uint4*)&Bw[(size_t)(idx >> 2) * C_ + k0 + (idx & 3) * 8];
      *(uint4*)&smB[idx * 8] = v;
      if (t < 64) {
        const int idx2 = 256 + t;
        uint4 v2 = *(const uint4*)&Bw[(size_t)(idx2 >> 2) * C_ + k0 + (idx2 & 3) * 8];
        *(uint4*)&smB[idx2 * 8] = v2;
      }
    }
    __syncthreads();
    bf16x8 af[2], bfr[5];
#pragma unroll
    for (int i = 0; i < 2; ++i) af[i]  = *(const bf16x8*)&smA[(wrow + i * 16 + l16) * 32 + lq * 8];
#pragma unroll
    for (int j = 0; j < 5; ++j) bfr[j] = *(const bf16x8*)&smB[(j * 16 + l16) * 32 + lq * 8];
#pragma unroll
    for (int i = 0; i < 2; ++i)
#pragma unroll
      for (int j = 0; j < 5; ++j)
        acc[i][j] = __builtin_amdgcn_mfma_f32_16x16x32_bf16(af[i], bfr[j], acc[i][j], 0, 0, 0);
    __syncthreads();
  }
  float vlo = 3.4e38f, vhi = -3.4e38f;
#pragma unroll
  for (int i = 0; i < 2; ++i) {
    const int mg = m0 + wrow + i * 16 + lq * 4;
    const int b  = mg / 80;
    const int n0 = mg - b * 80;
    const float* gob = go + b * N_;
#pragma unroll
    for (int j = 0; j < 5; ++j) {
      const int o = j * 16 + l16;
      const float g = gob[o] + bco[o];
      f32x4 v = acc[i][j];
      v[0] += g; v[1] += g; v[2] += g; v[3] += g;
      vlo = fminf(vlo, fminf(fminf(v[0], v[1]), fminf(v[2], v[3])));
      vhi = fmaxf(vhi, fmaxf(fmaxf(v[0], v[1]), fmaxf(v[2], v[3])));
      *(f32x4*)&dadj[(size_t)b * NN + (size_t)o * N_ + n0] = v;
    }
  }
  // block min/max reduce (reuse smA as float scratch; all LDS reads done)
  float* red = (float*)smA;
  red[t] = vlo; red[TPB + t] = vhi;
  __syncthreads();
  for (int o = 128; o > 0; o >>= 1) {
    if (t < o) {
      red[t] = fminf(red[t], red[t + o]);
      red[TPB + t] = fmaxf(red[TPB + t], red[TPB + t + o]);
    }
    __syncthreads();
  }
  if (t == 0) { bmin[blockIdx.x] = red[0]; bmax[blockIdx.x] = red[TPB]; }
}

// ---------------------------------------------------------------------------
// K2c: glb1 MFMA GEMM. A: glb0_bf (256 x 1024). Bw: Wg_bf (1024 x 1024, K-contig).
// + fused per-channel stats (sum/sumsq of glb1 incl. bias) -> gsum/gsq atomics.
// ---------------------------------------------------------------------------
__global__ __launch_bounds__(256) void k_glb_mfma(const ushort* __restrict__ A,
                                                  const ushort* __restrict__ Bw,
                                                  const float* __restrict__ bias,
                                                  float* __restrict__ outp,
                                                  float* __restrict__ gsum,
                                                  float* __restrict__ gsq) {
  __shared__ ushort smA[2][64 * 32];
  __shared__ ushort smB[2][64 * 32];
  const int t = threadIdx.x;
  const int lane = t & 63, wid = t >> 6;
  const int o0 = blockIdx.x * 64, m0 = blockIdx.y * 64;
  const int rto = t >> 2, ch = t & 3;
  const size_t gA0 = (size_t)(m0 + rto) * C_ + (size_t)ch * 8;
  const size_t gB0 = (size_t)(o0 + rto) * C_ + (size_t)ch * 8;
  const int l16 = lane & 15, lq = lane >> 4;
  const int wm = wid & 1, wn = wid >> 1;
  f32x4 zero = {0.f, 0.f, 0.f, 0.f};
  f32x4 acc[2][2];
#pragma unroll
  for (int i = 0; i < 2; ++i)
#pragma unroll
    for (int j = 0; j < 2; ++j) acc[i][j] = zero;
  for (int k0 = 0; k0 < C_; k0 += 64) {
    load_lds16(A  + gA0 + k0,       smA[0] + wid * 512);
    load_lds16(A  + gA0 + k0 + 32,  smA[1] + wid * 512);
    load_lds16(Bw + gB0 + k0,       smB[0] + wid * 512);
    load_lds16(Bw + gB0 + k0 + 32,  smB[1] + wid * 512);
    __syncthreads();
#pragma unroll
    for (int h = 0; h < 2; ++h) {
      bf16x8 af[2], bfr[2];
#pragma unroll
      for (int i = 0; i < 2; ++i) af[i]  = *(const bf16x8*)&smA[h][(wm * 32 + i * 16 + l16) * 32 + lq * 8];
#pragma unroll
      for (int j = 0; j < 2; ++j) bfr[j] = *(const bf16x8*)&smB[h][(wn * 32 + j * 16 + l16) * 32 + lq * 8];
#pragma unroll
      for (int i = 0; i < 2; ++i)
#pragma unroll
        for (int j = 0; j < 2; ++j)
          acc[i][j] = __builtin_amdgcn_mfma_f32_16x16x32_bf16(af[i], bfr[j], acc[i][j], 0, 0, 0);
    }
    __syncthreads();
  }
  float ssv[2] = {0.f, 0.f}, sqv[2] = {0.f, 0.f};
#pragma unroll
  for (int i = 0; i < 2; ++i) {
    const int mg = m0 + wm * 32 + i * 16 + lq * 4;
#pragma unroll
    for (int j = 0; j < 2; ++j) {
      const int og = o0 + wn * 32 + j * 16 + l16;
      const float bs = bias[og];
      f32x4 v = acc[i][j];
#pragma unroll
      for (int r = 0; r < 4; ++r) {
        const float val = v[r] + bs;
        outp[(size_t)(mg + r) * C_ + og] = val;
        ssv[j] += val; sqv[j] += val * val;
      }
    }
  }
  // stats reduce: [64 og_local][8 slots] in smA (free after last sync)
  {
    float* redS = (float*)&smA[0][0];
    float* redQ = redS + 512;
    const int slot = wm * 4 + lq;
#pragma unroll
    for (int j = 0; j < 2; ++j) {
      const int ol = wn * 32 + j * 16 + l16;   // 0..63
      redS[ol * 8 + slot] = ssv[j];
      redQ[ol * 8 + slot] = sqv[j];
    }
    __syncthreads();
    if (t < 64) {
      float s = 0.f, q = 0.f;
#pragma unroll
      for (int k = 0; k < 8; ++k) { s += redS[t * 8 + k]; q += redQ[t * 8 + k]; }
      atomicAdd(&gsum[o0 + t], s);
      atomicAdd(&gsq[o0 + t], q);
    }
  }
}

// ---------------------------------------------------------------------------
// K2d: go MFMA GEMM, split-K x8, BN+leaky applied inline from gsum/gsq while
// reg-staging A from fp32 glb1 (replaces k_bng + glbf buffer).
// ---------------------------------------------------------------------------
__global__ __launch_bounds__(256) void k_go_mfma(const float* __restrict__ glb1,
                                                 const ushort* __restrict__ Bw,
                                                 const float* __restrict__ gsum,
                                                 const float* __restrict__ gsq,
                                                 const float* __restrict__ gg,
                                                 const float* __restrict__ gb,
                                                 float* __restrict__ go) {
  __shared__ ushort smA[128 * 32];
  __shared__ ushort smB[80 * 32];
  __shared__ float pgm[C_], pmu[C_], pgb[C_];
  const int t = threadIdx.x;
  const int lane = t & 63, wid = t >> 6;
  const int kbase = blockIdx.x * 128;
  const int m0 = blockIdx.y * 128;
  const int rto = t >> 2, ch = t & 3;
  const int l16 = lane & 15, lq = lane >> 4;
  const int wrow = wid * 32;
  for (int c = t; c < C_; c += TPB) {
    const float mu = gsum[c] * (1.0f / B_);
    const float var = gsq[c] * (1.0f / B_) - mu * mu;
    pgm[c] = gg[c] * rsqrtf(var + EPSf); pmu[c] = mu; pgb[c] = gb[c];
  }
  __syncthreads();
  f32x4 zero = {0.f, 0.f, 0.f, 0.f};
  f32x4 acc[2][5];
#pragma unroll
  for (int i = 0; i < 2; ++i)
#pragma unroll
    for (int j = 0; j < 5; ++j) acc[i][j] = zero;
  for (int kk0 = 0; kk0 < 128; kk0 += 32) {
    const int k0 = kbase + kk0;
    // A: rows m0+h*64+rto, cols k0+ch*8..+8; BN+leaky+bf16 in registers
#pragma unroll
    for (int h = 0; h < 2; ++h) {
      const float* src = &glb1[(size_t)(m0 + h * 64 + rto) * C_ + k0 + ch * 8];
      float4 a0 = *(const float4*)src;
      float4 a1 = *(const float4*)(src + 4);
      float av[8] = {a0.x, a0.y, a0.z, a0.w, a1.x, a1.y, a1.z, a1.w};
      ushort4 u0, u1;
      const int cb = k0 + ch * 8;
      u0.x = f2bf(leakyf(pgm[cb+0]*(av[0]-pmu[cb+0])+pgb[cb+0]));
      u0.y = f2bf(leakyf(pgm[cb+1]*(av[1]-pmu[cb+1])+pgb[cb+1]));
      u0.z = f2bf(leakyf(pgm[cb+2]*(av[2]-pmu[cb+2])+pgb[cb+2]));
      u0.w = f2bf(leakyf(pgm[cb+3]*(av[3]-pmu[cb+3])+pgb[cb+3]));
      u1.x = f2bf(leakyf(pgm[cb+4]*(av[4]-pmu[cb+4])+pgb[cb+4]));
      u1.y = f2bf(leakyf(pgm[cb+5]*(av[5]-pmu[cb+5])+pgb[cb+5]));
      u1.z = f2bf(leakyf(pgm[cb+6]*(av[6]-pmu[cb+6])+pgb[cb+6]));
      u1.w = f2bf(leakyf(pgm[cb+7]*(av[7]-pmu[cb+7])+pgb[cb+7]));
      *(ushort4*)&smA[h * 2048 + t * 8]     = u0;
      *(ushort4*)&smA[h * 2048 + t * 8 + 4] = u1;
    }
    {
      const int idx = t;
      uint4 v = *(const uint4*)&Bw[(size_t)(idx >> 2) * C_ + k0 + (idx & 3) * 8];
      *(uint4*)&smB[idx * 8] = v;
      if (t < 64) {
        const int idx2 = 256 + t;
        uint4 v2 = *(const uint4*)&Bw[(size_t)(idx2 >> 2) * C_ + k0 + (idx2 & 3) * 8];
        *(uint4*)&smB[idx2 * 8] = v2;
      }
    }
    __syncthreads();
    bf16x8 af[2], bfr[5];
#pragma unroll
    for (int i = 0; i < 2; ++i) af[i]  = *(const bf16x8*)&smA[(wrow + i * 16 + l16) * 32 + lq * 8];
#pragma unroll
    for (int j = 0; j < 5; ++j) bfr[j] = *(const bf16x8*)&smB[(j * 16 + l16) * 32 + lq * 8];
#pragma unroll
    for (int i = 0; i < 2; ++i)
#pragma unroll
      for (int j = 0; j < 5; ++j)
        acc[i][j] = __builtin_amdgcn_mfma_f32_16x16x32_bf16(af[i], bfr[j], acc[i][j], 0, 0, 0);
    __syncthreads();
  }
#pragma unroll
  for (int i = 0; i < 2; ++i) {
    const int mg = m0 + wrow + i * 16 + lq * 4;
#pragma unroll
    for (int j = 0; j < 5; ++j) {
      const int o = j * 16 + l16;
#pragma unroll
      for (int r = 0; r < 4; ++r)
        atomicAdd(&go[(size_t)(mg + r) * N_ + o], acc[i][j][r]);
    }
  }
}

// ---------------------------------------------------------------------------
// K4f: fused x2 = x + leaky(bn(hT)) ; bf16 x2 written IN PLACE over hT ;
// x2t transpose (bf16, B,N,C) ; glb0 mean. BN stats from fused gemm sums.
// ---------------------------------------------------------------------------
__global__ __launch_bounds__(256) void k_x2_fused(
    const float* __restrict__ x, ushort* __restrict__ hx,
    const float* __restrict__ g, const float* __restrict__ be,
    const float* __restrict__ ssum, const float* __restrict__ ssq,
    ushort* __restrict__ x2t, ushort* __restrict__ glb0b) {
  __shared__ float s[64][85];
  __shared__ float pg[64], pm[64], pb[64];
  const int t = threadIdx.x;
  const long row0 = (long)blockIdx.x * 64;     // row = b*C + c
  const int b = (int)(row0 >> 10), c0 = (int)(row0 & 1023);
  if (t < 64) {
    const int c = c0 + t;
    const float mu = ssum[c] * (1.0f / BNr);
    const float var = ssq[c] * (1.0f / BNr) - mu * mu;
    const float rstd = rsqrtf(var + EPSf);
    pg[t] = g[c] * rstd; pm[t] = mu; pb[t] = be[c];
  }
  __syncthreads();
  const float* xb = x  + row0 * N_;
  ushort*      hb = hx + row0 * N_;
  for (int i4 = t; i4 < (64 * N_) / 4; i4 += TPB) {
    const int e = i4 * 4, r = e / N_, n = e % N_;
    float4 xv = *(const float4*)&xb[e];
    ushort4 hu = *(const ushort4*)&hb[e];
    const float gm = pg[r], m = pm[r], bb = pb[r];
    float4 o;
    o.x = xv.x + leakyf(gm * (b2f(hu.x) - m) + bb);
    o.y = xv.y + leakyf(gm * (b2f(hu.y) - m) + bb);
    o.z = xv.z + leakyf(gm * (b2f(hu.z) - m) + bb);
    o.w = xv.w + leakyf(gm * (b2f(hu.w) - m) + bb);
    *(float4*)&s[r][n] = o;
    ushort4 ou;
    ou.x = f2bf(o.x); ou.y = f2bf(o.y); ou.z = f2bf(o.z); ou.w = f2bf(o.w);
    *(ushort4*)&hb[e] = ou;                     // in-place bf16 x2 (hT dead)
  }
  __syncthreads();
  // transpose to (B,N,C) bf16
  const int tx = t % 16, ty = t / 16;
  ushort* tb = x2t + (size_t)b * CN + c0 + tx * 4;
#pragma unroll
  for (int u = 0; u < 5; ++u) {
    const int n = ty + 16 * u;
    ushort4 v;
    v.x = f2bf(s[tx * 4 + 0][n]); v.y = f2bf(s[tx * 4 + 1][n]);
    v.z = f2bf(s[tx * 4 + 2][n]); v.w = f2bf(s[tx * 4 + 3][n]);
    *(ushort4*)&tb[(size_t)n * C_] = v;
  }
  // glb0 mean over n — 4 threads per c-row, shfl-reduce the quad
  {
    const int r = t >> 2, q = t & 3;           // r in 0..63
    float sacc = 0.f;
    for (int n = q; n < N_; n += 4) sacc += s[r][n];
    sacc += __shfl_down(sacc, 1);
    sacc += __shfl_down(sacc, 2);
    if (q == 0) glb0b[(size_t)b * C_ + c0 + r] = f2bf(sacc * (1.0f / N_));
  }
}

// ---------------------------------------------------------------------------
// K14: final BN + leaky: reads h2 bf16 (B,C,N) + fused gemm sums,
// writes fp32 out + loss scalar.
// ---------------------------------------------------------------------------
__global__ void k_final(const ushort* __restrict__ h2, float* __restrict__ outp,
                        const float* __restrict__ g, const float* __restrict__ be,
                        const float* __restrict__ ssum, const float* __restrict__ ssq,
                        const float* __restrict__ lossa) {
  const long i = ((long)blockIdx.x * TPB + threadIdx.x) * 4;
  const int c = (int)((i / N_) % C_);
  ushort4 hu = *(const ushort4*)&h2[i];
  const float mu = ssum[c] * (1.0f / BNr);
  const float rstd = rsqrtf(ssq[c] * (1.0f / BNr) - mu * mu + EPSf);
  const float gm = g[c] * rstd, bb = be[c];
  float4 v;
  v.x = leakyf(gm * (b2f(hu.x) - mu) + bb);
  v.y = leakyf(gm * (b2f(hu.y) - mu) + bb);
  v.z = leakyf(gm * (b2f(hu.z) - mu) + bb);
  v.w = leakyf(gm * (b2f(hu.w) - mu) + bb);
  *(float4*)&outp[i] = v;
  if (blockIdx.x == 0 && threadIdx.x == 0) outp[BCN] = *lossa;
}

// ---------------------------------------------------------------------------
extern "C" void kernel_launch(void* const* d_in, const int* in_sizes, int n_in,
                              void* d_out, int out_size, void* d_ws, size_t ws_size,
                              hipStream_t stream) {
  const float* x    = (const float*)d_in[0];
  const float* out1 = (const float*)d_in[1];
  const float* ap   = (const float*)d_in[2];
  const float* Ws   = (const float*)d_in[3];
  const float* Wd   = (const float*)d_in[4];
  const float* Wg   = (const float*)d_in[5];
  const float* bg   = (const float*)d_in[6];
  const float* Wco  = (const float*)d_in[7];
  const float* bco  = (const float*)d_in[8];
  const float* bn_g  = (const float*)d_in[9];
  const float* bn_b  = (const float*)d_in[10];
  const float* bng_g = (const float*)d_in[11];
  const float* bng_b = (const float*)d_in[12];
  float* out = (float*)d_out;

  float* w = (float*)d_ws;
  float* sadj  = w;                    // 6400
  float* dadj  = sadj + NN;            // 1638400
  float* glb0  = dadj + BNN;           // 262144 (used as bf16 ushorts)
  float* glb1  = glb0 + B_ * C_;       // 262144
  float* go    = glb1 + B_ * C_;       // 20480 -- start of contiguous zero region
  float* ssum1 = go + BNr;             // 1024
  float* ssq1  = ssum1 + C_;           // 1024
  float* ssum2 = ssq1 + C_;            // 1024
  float* ssq2  = ssum2 + C_;           // 1024
  float* gsum  = ssq2 + C_;            // 1024
  float* gsq   = gsum + C_;            // 1024 -- end of zero region (26624 floats)
  float* bmin  = gsq + C_;             // 512 (160 used)
  float* bmax  = bmin + 512;           // 512 (160 used)
  float* lossa = bmax + 512;           // 1
  ushort* ub   = (ushort*)(((uintptr_t)(lossa + 1) + 255) & ~(uintptr_t)255);
  ushort* xa_bf  = ub;                    // BCN bf16 (B,N,C): fold out / x2t / fold2 out
  ushort* hT_bf  = xa_bf + BCN;           // BCN bf16 (B,C,N): h -> x2bf (in-place) -> h2
  ushort* Wts    = hT_bf + BCN;           // 1M bf16 (O,C)
  ushort* Wtd    = Wts + (size_t)C_ * C_; // 1M bf16 (O,C)
  ushort* Wco2t  = Wtd + (size_t)C_ * C_; // 80K bf16 (80,1024)
  ushort* adj_bf = Wco2t + (size_t)N_ * C_; // 80x96 bf16 prepadded
  ushort* tadj_bf = adj_bf + ADJP;        // B x 80x96 bf16 (3.93 MB)
  // bf16 aliases in regions dead at time of use:
  ushort* Wg_bf   = (ushort*)dadj;                      // 1M ushorts; dadj written later
  ushort* Wco1t   = (ushort*)dadj + (size_t)C_ * C_;    // 80K ushorts, same region
  ushort* glb0_bf = (ushort*)glb0;
  ushort* x2t_bf  = xa_bf;                              // xa dead after GEMM#1; x2t dead before fold#2

  // ---- prep (single merged launch: transposes, converts, zeroes, prep_adj) ----
  k_prep_all<<<3259, TPB, 0, stream>>>(Ws, Wd, Wco, Wg, Wts, Wtd, Wco1t, Wco2t, Wg_bf,
                                       go, ap, sadj, adj_bf, lossa);

  // ---- static GCN ----
  k_fold<<<B_ * 8, TPB, 0, stream>>>(x, hT_bf, adj_bf, xa_bf, 0);
  k_gemm_160<<<1024, TPB, 0, stream>>>(xa_bf, Wts, hT_bf, 1, ssum1, ssq1);
  k_x2_fused<<<(B_ * C_) / 64, TPB, 0, stream>>>(x, hT_bf, bn_g, bn_b, ssum1, ssq1,
                                                 x2t_bf, glb0_bf);

  // ---- dynamic graph construction ----
  k_glb_mfma<<<dim3(C_ / 64, B_ / 64), TPB, 0, stream>>>(glb0_bf, Wg_bf, bg, glb1, gsum, gsq);
  k_go_mfma<<<dim3(8, B_ / 128), TPB, 0, stream>>>(glb1, Wco1t, gsum, gsq, bng_g, bng_b, go);
  k_dadj_mfma<<<BNr / 128, TPB, 0, stream>>>(x2t_bf, Wco2t, go, bco, dadj, bmin, bmax);

  // ---- tadj build (per-b normalize + rowsum) + fused adjacency loss ----
  k_tadj<<<B_, TPB, 0, stream>>>(dadj, bmin, bmax, sadj, out1, tadj_bf, lossa);

  // ---- dynamic GCN ----
  k_fold<<<B_ * 8, TPB, 0, stream>>>(x, hT_bf, tadj_bf, xa_bf, 1);
  k_gemm_160<<<1024, TPB, 0, stream>>>(xa_bf, Wtd, hT_bf, 1, ssum2, ssq2);
  k_final<<<(int)(BCN / (4 * TPB)), TPB, 0, stream>>>(hT_bf, out, bn_g, bn_b, ssum2, ssq2, lossa);
}

// Round 12
// 431.143 us; speedup vs baseline: 1.6160x; 1.0295x over previous
//
#include <hip/hip_runtime.h>
#include <hip/hip_bf16.h>
#include <math.h>

#define TPB 256

constexpr int   B_  = 256;
constexpr int   C_  = 1024;
constexpr int   N_  = 80;
constexpr int   BNr = B_ * N_;                 // 20480 rows for BN / GEMM M
constexpr int   CN  = C_ * N_;                 // 81920
constexpr long  BCN = (long)B_ * C_ * N_;      // 20971520
constexpr int   NN  = N_ * N_;                 // 6400
constexpr int   BNN = B_ * NN;                 // 1638400
constexpr int   ADJP = N_ * 96;                // 7680 padded adj elems
constexpr float EPSf = 1e-5f;

typedef __bf16 bf16x8 __attribute__((ext_vector_type(8)));
typedef float  f32x4  __attribute__((ext_vector_type(4)));

__device__ __forceinline__ float leakyf(float v) { return v >= 0.0f ? v : 0.2f * v; }

__device__ __forceinline__ ushort f2bf(float f) {
  __hip_bfloat16 h = __float2bfloat16(f);
  ushort u; __builtin_memcpy(&u, &h, 2); return u;
}
__device__ __forceinline__ float b2f(ushort u) {
  __hip_bfloat16 h; __builtin_memcpy(&h, &u, 2);
  return __bfloat162float(h);
}

#define GLOBAL_AS __attribute__((address_space(1)))
#define LDS_AS    __attribute__((address_space(3)))
__device__ __forceinline__ void load_lds16(const void* g, void* l) {
  __builtin_amdgcn_global_load_lds((const GLOBAL_AS void*)g, (LDS_AS void*)l, 16, 0, 0);
}

// ---------------------------------------------------------------------------
// K-PREP (merged): blockIdx ranges ->
//   [0,1024)    : Wts[o][c] = bf16(Ws[c][o])   (32x32 tile transpose)
//   [1024,2048) : Wtd[o][c] = bf16(Wd[c][o])
//   [2048,2208) : split Wco (80x2048) -> Wco1t / Wco2t bf16
//   [2208,3232) : Wg -> Wg_bf elementwise
//   [3232,3258) : zero go(20480) + ssum1/ssq1/ssum2/ssq2/gsum/gsq (6144 floats)
//   [3258]      : prep_adj (sadj, adj_bf, lossa=0)
// ---------------------------------------------------------------------------
__global__ __launch_bounds__(256) void k_prep_all(
    const float* __restrict__ Ws, const float* __restrict__ Wd,
    const float* __restrict__ Wco, const float* __restrict__ Wg,
    ushort* __restrict__ Wts, ushort* __restrict__ Wtd,
    ushort* __restrict__ Wco1t, ushort* __restrict__ Wco2t, ushort* __restrict__ Wg_bf,
    float* __restrict__ zbase,
    const float* __restrict__ ap, float* __restrict__ sadj,
    ushort* __restrict__ adj_bf, float* __restrict__ lossa) {
  __shared__ float sh[NN];          // 25.6 KB; doubles as 32x33 transpose tile
  __shared__ float red[TPB];
  __shared__ float sD[N_];
  __shared__ float s_lo, s_hi;
  const int t = threadIdx.x;
  const int blk = blockIdx.x;
  if (blk < 2048) {
    const float* W = (blk < 1024) ? Ws : Wd;
    ushort* Wt = (blk < 1024) ? Wts : Wtd;
    const int bb = blk & 1023;
    const int bx = bb & 31, by = bb >> 5;
    const int tx = t % 32, ty = t / 32;
    const int r0 = by * 32, c0 = bx * 32;
#pragma unroll
    for (int k = 0; k < 4; ++k) sh[(ty + 8 * k) * 33 + tx] = W[(size_t)(r0 + ty + 8 * k) * C_ + c0 + tx];
    __syncthreads();
#pragma unroll
    for (int k = 0; k < 4; ++k) Wt[(size_t)(c0 + ty + 8 * k) * C_ + r0 + tx] = f2bf(sh[tx * 33 + ty + 8 * k]);
  } else if (blk < 2208) {
    const int i4 = ((blk - 2048) * TPB + t) * 4;   // 80*2048 elems
    const int o = i4 >> 11, k = i4 & 2047;
    float4 v = *(const float4*)&Wco[(size_t)o * 2048 + k];
    ushort4 u;
    u.x = f2bf(v.x); u.y = f2bf(v.y); u.z = f2bf(v.z); u.w = f2bf(v.w);
    if (k < C_) *(ushort4*)&Wco1t[(size_t)o * C_ + k] = u;
    else        *(ushort4*)&Wco2t[(size_t)o * C_ + (k - C_)] = u;
  } else if (blk < 3232) {
    const long i4 = ((long)(blk - 2208) * TPB + t) * 4;
    float4 v = *(const float4*)&Wg[i4];
    ushort4 u;
    u.x = f2bf(v.x); u.y = f2bf(v.y); u.z = f2bf(v.z); u.w = f2bf(v.w);
    *(ushort4*)&Wg_bf[i4] = u;
  } else if (blk < 3258) {
    const int i = ((blk - 3232) * TPB + t) * 4;    // 26624 floats
    float4 z = make_float4(0.f, 0.f, 0.f, 0.f);
    *(float4*)&zbase[i] = z;
  } else {
    // ---- prep_adj (single block) ----
    float lo = 3.4e38f, hi = -3.4e38f;
    for (int i = t; i < NN; i += TPB) { float v = ap[i]; sh[i] = v; lo = fminf(lo, v); hi = fmaxf(hi, v); }
    red[t] = lo; __syncthreads();
    for (int o = 128; o > 0; o >>= 1) { if (t < o) red[t] = fminf(red[t], red[t + o]); __syncthreads(); }
    if (t == 0) s_lo = red[0];
    __syncthreads();
    red[t] = hi; __syncthreads();
    for (int o = 128; o > 0; o >>= 1) { if (t < o) red[t] = fmaxf(red[t], red[t + o]); __syncthreads(); }
    if (t == 0) s_hi = red[0];
    __syncthreads();
    const float inv = 1.0f / (s_hi - s_lo);
    for (int i = t; i < NN; i += TPB) { float v = (sh[i] - s_lo) * inv; sh[i] = v; sadj[i] = v; }
    __syncthreads();
    if (t < N_) { float sum = 0.f; for (int m = 0; m < N_; ++m) sum += sh[t * N_ + m]; sD[t] = rsqrtf(sum); }
    if (t == 0) *lossa = 0.0f;
    __syncthreads();
    for (int i = t; i < ADJP; i += TPB) {
      const int n = i / 96, m = i % 96;
      adj_bf[i] = f2bf((m < N_) ? sD[n] * sh[m * N_ + n] * sD[m] : 0.0f);
    }
  }
}

// ---------------------------------------------------------------------------
// K-TADJ: per-b tadj build + fused adjacency loss.  One block per b.
// ---------------------------------------------------------------------------
__global__ __launch_bounds__(256) void k_tadj(const float* __restrict__ dadj,
                                              const float* __restrict__ bmin,
                                              const float* __restrict__ bmax,
                                              const float* __restrict__ sadj,
                                              const float* __restrict__ out1,
                                              ushort* __restrict__ tadj,
                                              float* __restrict__ lossa) {
  __shared__ float sF[NN];
  __shared__ float sD[N_];
  __shared__ float rl[TPB], rh[TPB];
  __shared__ float s_lo, s_inv;
  const int t = threadIdx.x;
  const int b = blockIdx.x;
  rl[t] = (t < 160) ? bmin[t] : 3.4e38f;
  rh[t] = (t < 160) ? bmax[t] : -3.4e38f;
  __syncthreads();
  for (int o = 128; o > 0; o >>= 1) {
    if (t < o) { rl[t] = fminf(rl[t], rl[t + o]); rh[t] = fmaxf(rh[t], rh[t + o]); }
    __syncthreads();
  }
  if (t == 0) { s_lo = rl[0]; s_inv = 1.0f / (rh[0] - rl[0]); }
  __syncthreads();
  const float lo = s_lo, inv = s_inv;
  const float* db = dadj + (size_t)b * NN;
  for (int i = t; i < NN / 4; i += TPB) {
    float4 v = *(const float4*)&db[i * 4];
    v.x = (v.x - lo) * inv; v.y = (v.y - lo) * inv;
    v.z = (v.z - lo) * inv; v.w = (v.w - lo) * inv;
    *(float4*)&sF[i * 4] = v;
  }
  __syncthreads();
  if (t < N_) { float s = 0.f; for (int m = 0; m < N_; ++m) s += sF[t * N_ + m]; sD[t] = rsqrtf(s); }
  __syncthreads();
  ushort* tb = tadj + (size_t)b * ADJP;
  for (int i = t; i < ADJP; i += TPB) {
    const int n = i / 96, m = i % 96;
    tb[i] = f2bf((m < N_) ? sF[m * N_ + n] * sD[n] * sD[m] : 0.0f);
  }
  // ---- fused loss ----
  const float* o1 = out1 + b * N_;
  float p2 = 0.f;
  for (int i = t; i < NN; i += TPB) { const float d = sF[i] - sadj[i]; p2 += d * d; }
  float p1 = 0.f;
  if (t < N_) {
    float a = 0.f;
    for (int n = 0; n < N_; ++n) a += o1[n] * sF[n * N_ + t];
    const float d = o1[t] - a * (1.0f / N_);
    p1 = d * d;
  }
  rl[t] = p2; rh[t] = p1;
  __syncthreads();
  for (int o = 128; o > 0; o >>= 1) {
    if (t < o) { rl[t] += rl[t + o]; rh[t] += rh[t + o]; }
    __syncthreads();
  }
  if (t == 0) atomicAdd(lossa, sqrtf(rl[0]) + sqrtf(rh[0]));
}

// ---------------------------------------------------------------------------
// K-FOLD (barrier-free streaming, ALL loads hoisted before any MFMA):
//   out[(b*80+n)*1024 + c] (bf16, B,N,C) = sum_m adj[n,m] * X[b,c,m]
// 21 operand fragments (3 kk x {5 B + 2 A}) issued as one load burst ->
// one latency wait instead of 3 serial rounds.  Templated on MODE so the
// fp32-convert path (mode 0) doesn't inflate mode 1's register allocation.
// ---------------------------------------------------------------------------
template <int MODE>
__global__ __launch_bounds__(256) void k_fold(const float* __restrict__ Xf32,
                                              const ushort* __restrict__ Xbf,
                                              const ushort* __restrict__ adjb,
                                              ushort* __restrict__ outp) {
  const int t = threadIdx.x;
  const int b  = blockIdx.x >> 3;
  const int c0 = (blockIdx.x & 7) * 128;
  const int lane = t & 63, wid = t >> 6;
  const int l16 = lane & 15, lq = lane >> 4;
  const ushort* ab = adjb + (MODE ? (size_t)b * ADJP : 0);

  bf16x8 b5[3][5], a2[3][2];

  // ---- load burst: all B frags (L2-resident) + all A frags (global) ----
#pragma unroll
  for (int kk = 0; kk < 3; ++kk) {
    const int mf = kk * 32 + lq * 8;
#pragma unroll
    for (int j = 0; j < 5; ++j)
      b5[kk][j] = *(const bf16x8*)&ab[(j * 16 + l16) * 96 + mf];
  }
#pragma unroll
  for (int kk = 0; kk < 3; ++kk) {
    const int mf = kk * 32 + lq * 8;
#pragma unroll
    for (int i = 0; i < 2; ++i) {
      const int row = wid * 32 + i * 16 + l16;
      if (mf >= N_) {
        union { bf16x8 v; uint4 u; } z; z.u = make_uint4(0, 0, 0, 0);
        a2[kk][i] = z.v;
      } else if (MODE == 0) {
        const float* src = Xf32 + ((size_t)b * C_ + c0 + row) * N_ + mf;
        float4 v0 = *(const float4*)src;
        float4 v1 = *(const float4*)(src + 4);
        union { bf16x8 v; ushort u[8]; } tmp;
        tmp.u[0] = f2bf(v0.x); tmp.u[1] = f2bf(v0.y); tmp.u[2] = f2bf(v0.z); tmp.u[3] = f2bf(v0.w);
        tmp.u[4] = f2bf(v1.x); tmp.u[5] = f2bf(v1.y); tmp.u[6] = f2bf(v1.z); tmp.u[7] = f2bf(v1.w);
        a2[kk][i] = tmp.v;
      } else {
        a2[kk][i] = *(const bf16x8*)&Xbf[((size_t)b * C_ + c0 + row) * N_ + mf];
      }
    }
  }

  // ---- compute: 30 MFMAs on fully-resident operands ----
  f32x4 acc[2][5];
#pragma unroll
  for (int i = 0; i < 2; ++i)
#pragma unroll
    for (int j = 0; j < 5; ++j) { f32x4 z = {0.f, 0.f, 0.f, 0.f}; acc[i][j] = z; }
#pragma unroll
  for (int kk = 0; kk < 3; ++kk)
#pragma unroll
    for (int i = 0; i < 2; ++i)
#pragma unroll
      for (int j = 0; j < 5; ++j)
        acc[i][j] = __builtin_amdgcn_mfma_f32_16x16x32_bf16(a2[kk][i], b5[kk][j], acc[i][j], 0, 0, 0);

  // ---- epilogue: D[row=c_local (lq*4+reg)][col=n (l16)] -> (B,N,C) ushort4 ----
  ushort* ob = outp + (size_t)b * CN;
#pragma unroll
  for (int i = 0; i < 2; ++i) {
    const int c = c0 + wid * 32 + i * 16 + lq * 4;
#pragma unroll
    for (int j = 0; j < 5; ++j) {
      const int n = j * 16 + l16;
      ushort4 u;
      u.x = f2bf(acc[i][j][0]); u.y = f2bf(acc[i][j][1]);
      u.z = f2bf(acc[i][j][2]); u.w = f2bf(acc[i][j][3]);
      *(ushort4*)&ob[(size_t)n * C_ + c] = u;
    }
  }
}

// ---------------------------------------------------------------------------
// K2: 160x128x64 2-phase dbuf MFMA GEMM, 2 blocks/CU (verified r10/r11).
// + fused per-channel BN stats ([128ch][8slot] LDS).
// ---------------------------------------------------------------------------
__global__ __launch_bounds__(256, 2) void k_gemm_160(const ushort* __restrict__ A,
                                                     const ushort* __restrict__ Bt,
                                                     void* __restrict__ outp, int out_bf,
                                                     float* __restrict__ bnsum,
                                                     float* __restrict__ bnsq) {
  __shared__ ushort sA[2][160 * 64];   // 2 x 20 KB
  __shared__ ushort sB[2][128 * 64];   // 2 x 16 KB
  const int t = threadIdx.x;
  const int lane = t & 63, wid = t >> 6;       // 4 waves
  const int wm = wid >> 1, wn = wid & 1;       // 2M x 2N
  const int l16 = lane & 15, lq = lane >> 4;

  // XCD-chunked swizzle: 1024 blocks; each XCD: tm in [xcd*16, xcd*16+16), tn 0..7.
  const int lin = blockIdx.x;
  const int xcd = lin & 7, bi = lin >> 3;      // bi in 0..127
  const int tm = xcd * 16 + (bi >> 3);
  const int tn = bi & 7;
  const int m0 = tm * 160, o0 = tn * 128;

  const int srow = t >> 3;                           // 0..31 (32 rows per call)
  const int sswz = ((t & 7) ^ ((t >> 3) & 7)) * 8;   // pre-swizzled source slot

  f32x4 acc[5][4];
#pragma unroll
  for (int i = 0; i < 5; ++i)
#pragma unroll
    for (int j = 0; j < 4; ++j) { f32x4 z = {0.f, 0.f, 0.f, 0.f}; acc[i][j] = z; }

#define STA(PAR, ROWB, KT) load_lds16(A  + (size_t)(m0 + (ROWB) + srow) * C_ + (KT) * 64 + sswz, \
                                      &sA[PAR][((ROWB) + (wid << 3)) * 64])
#define STB(PAR, ROWB, KT) load_lds16(Bt + (size_t)(o0 + (ROWB) + srow) * C_ + (KT) * 64 + sswz, \
                                      &sB[PAR][((ROWB) + (wid << 3)) * 64])
#define STAGE_T(PAR, KT) { STA(PAR, 0, KT); STA(PAR, 32, KT); STA(PAR, 64, KT); \
                           STA(PAR, 96, KT); STA(PAR, 128, KT); \
                           STB(PAR, 0, KT); STB(PAR, 32, KT); STB(PAR, 64, KT); STB(PAR, 96, KT); }

#define PH(PAR, KK, STAGES, VMW)                                                          \
  {                                                                                       \
    STAGES                                                                                \
    bf16x8 afr[5], bfr[4];                                                                \
    _Pragma("unroll") for (int fi = 0; fi < 5; ++fi)                                      \
      afr[fi] = *(const bf16x8*)&sA[PAR][(wm * 80 + fi * 16 + l16) * 64 +                 \
                                         (((KK) * 4 + lq) ^ (l16 & 7)) * 8];              \
    _Pragma("unroll") for (int gi = 0; gi < 4; ++gi)                                      \
      bfr[gi] = *(const bf16x8*)&sB[PAR][(wn * 64 + gi * 16 + l16) * 64 +                 \
                                         (((KK) * 4 + lq) ^ (l16 & 7)) * 8];              \
    asm volatile("s_barrier" ::: "memory");                                               \
    asm volatile("s_waitcnt lgkmcnt(0)" ::: "memory");                                    \
    __builtin_amdgcn_s_setprio(1);                                                        \
    _Pragma("unroll") for (int fi = 0; fi < 5; ++fi)                                      \
      _Pragma("unroll") for (int gi = 0; gi < 4; ++gi)                                    \
        acc[fi][gi] = __builtin_amdgcn_mfma_f32_16x16x32_bf16(afr[fi], bfr[gi],           \
                                                              acc[fi][gi], 0, 0, 0);      \
    __builtin_amdgcn_s_setprio(0);                                                        \
    VMW                                                                                   \
    asm volatile("s_barrier" ::: "memory");                                               \
  }

  // prologue: stage T0 into par0, drain, sync.
  STAGE_T(0, 0);
  asm volatile("s_waitcnt vmcnt(0)" ::: "memory");
  asm volatile("s_barrier" ::: "memory");

  for (int i = 0; i < 8; ++i) {
    const int t1 = 2 * i + 1, t2 = 2 * i + 2;
    // tile 2i in par0; stage T(2i+1) -> par1 (par1's last reads ended at prior barrier)
    PH(0, 0, { STAGE_T(1, t1); }, {})
    PH(0, 1, {}, { asm volatile("s_waitcnt vmcnt(0)" ::: "memory"); })
    // tile 2i+1 in par1; stage T(2i+2) -> par0
    PH(1, 0, { if (i < 7) STAGE_T(0, t2); }, {})
    PH(1, 1, {}, { if (i < 7) { asm volatile("s_waitcnt vmcnt(0)" ::: "memory"); } })
  }

  // epilogue: row = lq*4+reg -> m; col = l16 -> o. (B,C,N) store, 4 consecutive n.
#pragma unroll
  for (int fi = 0; fi < 5; ++fi) {
    const int mg = m0 + wm * 80 + fi * 16 + lq * 4;
    const int b  = mg / 80;
    const int n0 = mg - b * 80;
#pragma unroll
    for (int gi = 0; gi < 4; ++gi) {
      const int og = o0 + wn * 64 + gi * 16 + l16;
      const size_t off = (size_t)b * CN + (size_t)og * N_ + n0;
      if (out_bf) {
        ushort4 u;
        u.x = f2bf(acc[fi][gi][0]); u.y = f2bf(acc[fi][gi][1]);
        u.z = f2bf(acc[fi][gi][2]); u.w = f2bf(acc[fi][gi][3]);
        *(ushort4*)((ushort*)outp + off) = u;
      } else {
        *(f32x4*)((float*)outp + off) = acc[fi][gi];
      }
    }
  }

  // ---- fused BN partial stats (sA free after last phase barrier) ----
  {
    float* redS = (float*)&sA[0][0];           // [128][8]
    float* redQ = redS + 1024;                 // [128][8]
    const int slot = wm * 4 + lq;              // 0..7
#pragma unroll
    for (int gi = 0; gi < 4; ++gi) {
      float s = 0.f, q = 0.f;
#pragma unroll
      for (int fi = 0; fi < 5; ++fi)
#pragma unroll
        for (int r = 0; r < 4; ++r) { const float v = acc[fi][gi][r]; s += v; q += v * v; }
      const int ol = wn * 64 + gi * 16 + l16;  // 0..127, unique per (wn,gi,l16)
      redS[ol * 8 + slot] = s;
      redQ[ol * 8 + slot] = q;
    }
    __syncthreads();
    if (t < 128) {
      float s = 0.f, q = 0.f;
#pragma unroll
      for (int k = 0; k < 8; ++k) { s += redS[t * 8 + k]; q += redQ[t * 8 + k]; }
      atomicAdd(&bnsum[o0 + t], s);
      atomicAdd(&bnsq[o0 + t], q);
    }
  }
#undef STA
#undef STB
#undef STAGE_T
#undef PH
}

// ---------------------------------------------------------------------------
// K2b: dadj MFMA GEMM. A: x2t bf16 (M=20480, K=1024). Bw: Wco2t bf16 (80,1024).
// dadj[b,o,n] = go[b,o] + bco[o] + sum_k A[m=(b,n)][k]*Bw[o][k].
// Fused per-block min/max -> bmin/bmax[160].
// ---------------------------------------------------------------------------
__global__ __launch_bounds__(256) void k_dadj_mfma(const ushort* __restrict__ A,
                                                   const ushort* __restrict__ Bw,
                                                   const float* __restrict__ go,
                                                   const float* __restrict__ bco,
                                                   float* __restrict__ dadj,
                                                   float* __restrict__ bmin,
                                                   float* __restrict__ bmax) {
  __shared__ ushort smA[128 * 32];
  __shared__ ushort smB[80 * 32];
  const int t = threadIdx.x;
  const int lane = t & 63, wid = t >> 6;
  const int m0 = blockIdx.x * 128;
  const int rto = t >> 2, ch = t & 3;
  const size_t gA0 = (size_t)(m0 + rto) * C_ + (size_t)ch * 8;
  ushort* ldsA = smA + wid * 512;
  const int l16 = lane & 15, lq = lane >> 4;
  const int wrow = wid * 32;
  f32x4 zero = {0.f, 0.f, 0.f, 0.f};
  f32x4 acc[2][5];
#pragma unroll
  for (int i = 0; i < 2; ++i)
#pragma unroll
    for (int j = 0; j < 5; ++j) acc[i][j] = zero;
  for (int k0 = 0; k0 < C_; k0 += 32) {
    load_lds16(A + gA0 + k0,            ldsA);
    load_lds16(A + gA0 + 64 * C_ + k0,  ldsA + 2048);
    {
      const int idx = t;                               // 320 chunks of 16B
      uint4 v = *(const uint4*)&Bw[(size_t)(idx >> 2) * C_ + k0 + (idx & 3) * 8];
      *(uint4*)&smB[idx * 8] = v;
      if (t < 64) {
        const int idx2 = 256 + t;
        uint4 v2 = *(const uint4*)&Bw[(size_t)(idx2 >> 2) * C_ + k0 + (idx2 & 3) * 8];
        *(uint4*)&smB[idx2 * 8] = v2;
      }
    }
    __syncthreads();
    bf16x8 af[2], bfr[5];
#pragma unroll
    for (int i = 0; i < 2; ++i) af[i]  = *(const bf16x8*)&smA[(wrow + i * 16 + l16) * 32 + lq * 8];
#pragma unroll
    for (int j = 0; j < 5; ++j) bfr[j] = *(const bf16x8*)&smB[(j * 16 + l16) * 32 + lq * 8];
#pragma unroll
    for (int i = 0; i < 2; ++i)
#pragma unroll
      for (int j = 0; j < 5; ++j)
        acc[i][j] = __builtin_amdgcn_mfma_f32_16x16x32_bf16(af[i], bfr[j], acc[i][j], 0, 0, 0);
    __syncthreads();
  }
  float vlo = 3.4e38f, vhi = -3.4e38f;
#pragma unroll
  for (int i = 0; i < 2; ++i) {
    const int mg = m0 + wrow + i * 16 + lq * 4;
    const int b  = mg / 80;
    const int n0 = mg - b * 80;
    const float* gob = go + b * N_;
#pragma unroll
    for (int j = 0; j < 5; ++j) {
      const int o = j * 16 + l16;
      const float g = gob[o] + bco[o];
      f32x4 v = acc[i][j];
      v[0] += g; v[1] += g; v[2] += g; v[3] += g;
      vlo = fminf(vlo, fminf(fminf(v[0], v[1]), fminf(v[2], v[3])));
      vhi = fmaxf(vhi, fmaxf(fmaxf(v[0], v[1]), fmaxf(v[2], v[3])));
      *(f32x4*)&dadj[(size_t)b * NN + (size_t)o * N_ + n0] = v;
    }
  }
  // block min/max reduce (reuse smA as float scratch; all LDS reads done)
  float* red = (float*)smA;
  red[t] = vlo; red[TPB + t] = vhi;
  __syncthreads();
  for (int o = 128; o > 0; o >>= 1) {
    if (t < o) {
      red[t] = fminf(red[t], red[t + o]);
      red[TPB + t] = fmaxf(red[TPB + t], red[TPB + t + o]);
    }
    __syncthreads();
  }
  if (t == 0) { bmin[blockIdx.x] = red[0]; bmax[blockIdx.x] = red[TPB]; }
}

// ---------------------------------------------------------------------------
// K2c: glb1 MFMA GEMM. A: glb0_bf (256 x 1024). Bw: Wg_bf (1024 x 1024, K-contig).
// + fused per-channel stats (sum/sumsq of glb1 incl. bias) -> gsum/gsq atomics.
// ---------------------------------------------------------------------------
__global__ __launch_bounds__(256) void k_glb_mfma(const ushort* __restrict__ A,
                                                  const ushort* __restrict__ Bw,
                                                  const float* __restrict__ bias,
                                                  float* __restrict__ outp,
                                                  float* __restrict__ gsum,
                                                  float* __restrict__ gsq) {
  __shared__ ushort smA[2][64 * 32];
  __shared__ ushort smB[2][64 * 32];
  const int t = threadIdx.x;
  const int lane = t & 63, wid = t >> 6;
  const int o0 = blockIdx.x * 64, m0 = blockIdx.y * 64;
  const int rto = t >> 2, ch = t & 3;
  const size_t gA0 = (size_t)(m0 + rto) * C_ + (size_t)ch * 8;
  const size_t gB0 = (size_t)(o0 + rto) * C_ + (size_t)ch * 8;
  const int l16 = lane & 15, lq = lane >> 4;
  const int wm = wid & 1, wn = wid >> 1;
  f32x4 zero = {0.f, 0.f, 0.f, 0.f};
  f32x4 acc[2][2];
#pragma unroll
  for (int i = 0; i < 2; ++i)
#pragma unroll
    for (int j = 0; j < 2; ++j) acc[i][j] = zero;
  for (int k0 = 0; k0 < C_; k0 += 64) {
    load_lds16(A  + gA0 + k0,       smA[0] + wid * 512);
    load_lds16(A  + gA0 + k0 + 32,  smA[1] + wid * 512);
    load_lds16(Bw + gB0 + k0,       smB[0] + wid * 512);
    load_lds16(Bw + gB0 + k0 + 32,  smB[1] + wid * 512);
    __syncthreads();
#pragma unroll
    for (int h = 0; h < 2; ++h) {
      bf16x8 af[2], bfr[2];
#pragma unroll
      for (int i = 0; i < 2; ++i) af[i]  = *(const bf16x8*)&smA[h][(wm * 32 + i * 16 + l16) * 32 + lq * 8];
#pragma unroll
      for (int j = 0; j < 2; ++j) bfr[j] = *(const bf16x8*)&smB[h][(wn * 32 + j * 16 + l16) * 32 + lq * 8];
#pragma unroll
      for (int i = 0; i < 2; ++i)
#pragma unroll
        for (int j = 0; j < 2; ++j)
          acc[i][j] = __builtin_amdgcn_mfma_f32_16x16x32_bf16(af[i], bfr[j], acc[i][j], 0, 0, 0);
    }
    __syncthreads();
  }
  float ssv[2] = {0.f, 0.f}, sqv[2] = {0.f, 0.f};
#pragma unroll
  for (int i = 0; i < 2; ++i) {
    const int mg = m0 + wm * 32 + i * 16 + lq * 4;
#pragma unroll
    for (int j = 0; j < 2; ++j) {
      const int og = o0 + wn * 32 + j * 16 + l16;
      const float bs = bias[og];
      f32x4 v = acc[i][j];
#pragma unroll
      for (int r = 0; r < 4; ++r) {
        const float val = v[r] + bs;
        outp[(size_t)(mg + r) * C_ + og] = val;
        ssv[j] += val; sqv[j] += val * val;
      }
    }
  }
  // stats reduce: [64 og_local][8 slots] in smA (free after last sync)
  {
    float* redS = (float*)&smA[0][0];
    float* redQ = redS + 512;
    const int slot = wm * 4 + lq;
#pragma unroll
    for (int j = 0; j < 2; ++j) {
      const int ol = wn * 32 + j * 16 + l16;   // 0..63
      redS[ol * 8 + slot] = ssv[j];
      redQ[ol * 8 + slot] = sqv[j];
    }
    __syncthreads();
    if (t < 64) {
      float s = 0.f, q = 0.f;
#pragma unroll
      for (int k = 0; k < 8; ++k) { s += redS[t * 8 + k]; q += redQ[t * 8 + k]; }
      atomicAdd(&gsum[o0 + t], s);
      atomicAdd(&gsq[o0 + t], q);
    }
  }
}

// ---------------------------------------------------------------------------
// K2d: go MFMA GEMM, split-K x8, BN+leaky applied inline from gsum/gsq while
// reg-staging A from fp32 glb1 (replaces k_bng + glbf buffer).
// ---------------------------------------------------------------------------
__global__ __launch_bounds__(256) void k_go_mfma(const float* __restrict__ glb1,
                                                 const ushort* __restrict__ Bw,
                                                 const float* __restrict__ gsum,
                                                 const float* __restrict__ gsq,
                                                 const float* __restrict__ gg,
                                                 const float* __restrict__ gb,
                                                 float* __restrict__ go) {
  __shared__ ushort smA[128 * 32];
  __shared__ ushort smB[80 * 32];
  __shared__ float pgm[C_], pmu[C_], pgb[C_];
  const int t = threadIdx.x;
  const int lane = t & 63, wid = t >> 6;
  const int kbase = blockIdx.x * 128;
  const int m0 = blockIdx.y * 128;
  const int rto = t >> 2, ch = t & 3;
  const int l16 = lane & 15, lq = lane >> 4;
  const int wrow = wid * 32;
  for (int c = t; c < C_; c += TPB) {
    const float mu = gsum[c] * (1.0f / B_);
    const float var = gsq[c] * (1.0f / B_) - mu * mu;
    pgm[c] = gg[c] * rsqrtf(var + EPSf); pmu[c] = mu; pgb[c] = gb[c];
  }
  __syncthreads();
  f32x4 zero = {0.f, 0.f, 0.f, 0.f};
  f32x4 acc[2][5];
#pragma unroll
  for (int i = 0; i < 2; ++i)
#pragma unroll
    for (int j = 0; j < 5; ++j) acc[i][j] = zero;
  for (int kk0 = 0; kk0 < 128; kk0 += 32) {
    const int k0 = kbase + kk0;
    // A: rows m0+h*64+rto, cols k0+ch*8..+8; BN+leaky+bf16 in registers
#pragma unroll
    for (int h = 0; h < 2; ++h) {
      const float* src = &glb1[(size_t)(m0 + h * 64 + rto) * C_ + k0 + ch * 8];
      float4 a0 = *(const float4*)src;
      float4 a1 = *(const float4*)(src + 4);
      float av[8] = {a0.x, a0.y, a0.z, a0.w, a1.x, a1.y, a1.z, a1.w};
      ushort4 u0, u1;
      const int cb = k0 + ch * 8;
      u0.x = f2bf(leakyf(pgm[cb+0]*(av[0]-pmu[cb+0])+pgb[cb+0]));
      u0.y = f2bf(leakyf(pgm[cb+1]*(av[1]-pmu[cb+1])+pgb[cb+1]));
      u0.z = f2bf(leakyf(pgm[cb+2]*(av[2]-pmu[cb+2])+pgb[cb+2]));
      u0.w = f2bf(leakyf(pgm[cb+3]*(av[3]-pmu[cb+3])+pgb[cb+3]));
      u1.x = f2bf(leakyf(pgm[cb+4]*(av[4]-pmu[cb+4])+pgb[cb+4]));
      u1.y = f2bf(leakyf(pgm[cb+5]*(av[5]-pmu[cb+5])+pgb[cb+5]));
      u1.z = f2bf(leakyf(pgm[cb+6]*(av[6]-pmu[cb+6])+pgb[cb+6]));
      u1.w = f2bf(leakyf(pgm[cb+7]*(av[7]-pmu[cb+7])+pgb[cb+7]));
      *(ushort4*)&smA[h * 2048 + t * 8]     = u0;
      *(ushort4*)&smA[h * 2048 + t * 8 + 4] = u1;
    }
    {
      const int idx = t;
      uint4 v = *(const uint4*)&Bw[(size_t)(idx >> 2) * C_ + k0 + (idx & 3) * 8];
      *(uint4*)&smB[idx * 8] = v;
      if (t < 64) {
        const int idx2 = 256 + t;
        uint4 v2 = *(const uint4*)&Bw[(size_t)(idx2 >> 2) * C_ + k0 + (idx2 & 3) * 8];
        *(uint4*)&smB[idx2 * 8] = v2;
      }
    }
    __syncthreads();
    bf16x8 af[2], bfr[5];
#pragma unroll
    for (int i = 0; i < 2; ++i) af[i]  = *(const bf16x8*)&smA[(wrow + i * 16 + l16) * 32 + lq * 8];
#pragma unroll
    for (int j = 0; j < 5; ++j) bfr[j] = *(const bf16x8*)&smB[(j * 16 + l16) * 32 + lq * 8];
#pragma unroll
    for (int i = 0; i < 2; ++i)
#pragma unroll
      for (int j = 0; j < 5; ++j)
        acc[i][j] = __builtin_amdgcn_mfma_f32_16x16x32_bf16(af[i], bfr[j], acc[i][j], 0, 0, 0);
    __syncthreads();
  }
#pragma unroll
  for (int i = 0; i < 2; ++i) {
    const int mg = m0 + wrow + i * 16 + lq * 4;
#pragma unroll
    for (int j = 0; j < 5; ++j) {
      const int o = j * 16 + l16;
#pragma unroll
      for (int r = 0; r < 4; ++r)
        atomicAdd(&go[(size_t)(mg + r) * N_ + o], acc[i][j][r]);
    }
  }
}

// ---------------------------------------------------------------------------
// K4f: fused x2 = x + leaky(bn(hT)) ; bf16 x2 written IN PLACE over hT ;
// x2t transpose (bf16, B,N,C) ; glb0 mean. BN stats from fused gemm sums.
// ---------------------------------------------------------------------------
__global__ __launch_bounds__(256) void k_x2_fused(
    const float* __restrict__ x, ushort* __restrict__ hx,
    const float* __restrict__ g, const float* __restrict__ be,
    const float* __restrict__ ssum, const float* __restrict__ ssq,
    ushort* __restrict__ x2t, ushort* __restrict__ glb0b) {
  __shared__ float s[64][85];
  __shared__ float pg[64], pm[64], pb[64];
  const int t = threadIdx.x;
  const long row0 = (long)blockIdx.x * 64;     // row = b*C + c
  const int b = (int)(row0 >> 10), c0 = (int)(row0 & 1023);
  if (t < 64) {
    const int c = c0 + t;
    const float mu = ssum[c] * (1.0f / BNr);
    const float var = ssq[c] * (1.0f / BNr) - mu * mu;
    const float rstd = rsqrtf(var + EPSf);
    pg[t] = g[c] * rstd; pm[t] = mu; pb[t] = be[c];
  }
  __syncthreads();
  const float* xb = x  + row0 * N_;
  ushort*      hb = hx + row0 * N_;
  for (int i4 = t; i4 < (64 * N_) / 4; i4 += TPB) {
    const int e = i4 * 4, r = e / N_, n = e % N_;
    float4 xv = *(const float4*)&xb[e];
    ushort4 hu = *(const ushort4*)&hb[e];
    const float gm = pg[r], m = pm[r], bb = pb[r];
    float4 o;
    o.x = xv.x + leakyf(gm * (b2f(hu.x) - m) + bb);
    o.y = xv.y + leakyf(gm * (b2f(hu.y) - m) + bb);
    o.z = xv.z + leakyf(gm * (b2f(hu.z) - m) + bb);
    o.w = xv.w + leakyf(gm * (b2f(hu.w) - m) + bb);
    *(float4*)&s[r][n] = o;
    ushort4 ou;
    ou.x = f2bf(o.x); ou.y = f2bf(o.y); ou.z = f2bf(o.z); ou.w = f2bf(o.w);
    *(ushort4*)&hb[e] = ou;                     // in-place bf16 x2 (hT dead)
  }
  __syncthreads();
  // transpose to (B,N,C) bf16
  const int tx = t % 16, ty = t / 16;
  ushort* tb = x2t + (size_t)b * CN + c0 + tx * 4;
#pragma unroll
  for (int u = 0; u < 5; ++u) {
    const int n = ty + 16 * u;
    ushort4 v;
    v.x = f2bf(s[tx * 4 + 0][n]); v.y = f2bf(s[tx * 4 + 1][n]);
    v.z = f2bf(s[tx * 4 + 2][n]); v.w = f2bf(s[tx * 4 + 3][n]);
    *(ushort4*)&tb[(size_t)n * C_] = v;
  }
  // glb0 mean over n — 4 threads per c-row, shfl-reduce the quad
  {
    const int r = t >> 2, q = t & 3;           // r in 0..63
    float sacc = 0.f;
    for (int n = q; n < N_; n += 4) sacc += s[r][n];
    sacc += __shfl_down(sacc, 1);
    sacc += __shfl_down(sacc, 2);
    if (q == 0) glb0b[(size_t)b * C_ + c0 + r] = f2bf(sacc * (1.0f / N_));
  }
}

// ---------------------------------------------------------------------------
// K14: final BN + leaky: reads h2 bf16 (B,C,N) + fused gemm sums,
// writes fp32 out + loss scalar.
// ---------------------------------------------------------------------------
__global__ void k_final(const ushort* __restrict__ h2, float* __restrict__ outp,
                        const float* __restrict__ g, const float* __restrict__ be,
                        const float* __restrict__ ssum, const float* __restrict__ ssq,
                        const float* __restrict__ lossa) {
  const long i = ((long)blockIdx.x * TPB + threadIdx.x) * 4;
  const int c = (int)((i / N_) % C_);
  ushort4 hu = *(const ushort4*)&h2[i];
  const float mu = ssum[c] * (1.0f / BNr);
  const float rstd = rsqrtf(ssq[c] * (1.0f / BNr) - mu * mu + EPSf);
  const float gm = g[c] * rstd, bb = be[c];
  float4 v;
  v.x = leakyf(gm * (b2f(hu.x) - mu) + bb);
  v.y = leakyf(gm * (b2f(hu.y) - mu) + bb);
  v.z = leakyf(gm * (b2f(hu.z) - mu) + bb);
  v.w = leakyf(gm * (b2f(hu.w) - mu) + bb);
  *(float4*)&outp[i] = v;
  if (blockIdx.x == 0 && threadIdx.x == 0) outp[BCN] = *lossa;
}

// ---------------------------------------------------------------------------
extern "C" void kernel_launch(void* const* d_in, const int* in_sizes, int n_in,
                              void* d_out, int out_size, void* d_ws, size_t ws_size,
                              hipStream_t stream) {
  const float* x    = (const float*)d_in[0];
  const float* out1 = (const float*)d_in[1];
  const float* ap   = (const float*)d_in[2];
  const float* Ws   = (const float*)d_in[3];
  const float* Wd   = (const float*)d_in[4];
  const float* Wg   = (const float*)d_in[5];
  const float* bg   = (const float*)d_in[6];
  const float* Wco  = (const float*)d_in[7];
  const float* bco  = (const float*)d_in[8];
  const float* bn_g  = (const float*)d_in[9];
  const float* bn_b  = (const float*)d_in[10];
  const float* bng_g = (const float*)d_in[11];
  const float* bng_b = (const float*)d_in[12];
  float* out = (float*)d_out;

  float* w = (float*)d_ws;
  float* sadj  = w;                    // 6400
  float* dadj  = sadj + NN;            // 1638400
  float* glb0  = dadj + BNN;           // 262144 (used as bf16 ushorts)
  float* glb1  = glb0 + B_ * C_;       // 262144
  float* go    = glb1 + B_ * C_;       // 20480 -- start of contiguous zero region
  float* ssum1 = go + BNr;             // 1024
  float* ssq1  = ssum1 + C_;           // 1024
  float* ssum2 = ssq1 + C_;            // 1024
  float* ssq2  = ssum2 + C_;           // 1024
  float* gsum  = ssq2 + C_;            // 1024
  float* gsq   = gsum + C_;            // 1024 -- end of zero region (26624 floats)
  float* bmin  = gsq + C_;             // 512 (160 used)
  float* bmax  = bmin + 512;           // 512 (160 used)
  float* lossa = bmax + 512;           // 1
  ushort* ub   = (ushort*)(((uintptr_t)(lossa + 1) + 255) & ~(uintptr_t)255);
  ushort* xa_bf  = ub;                    // BCN bf16 (B,N,C): fold out / x2t / fold2 out
  ushort* hT_bf  = xa_bf + BCN;           // BCN bf16 (B,C,N): h -> x2bf (in-place) -> h2
  ushort* Wts    = hT_bf + BCN;           // 1M bf16 (O,C)
  ushort* Wtd    = Wts + (size_t)C_ * C_; // 1M bf16 (O,C)
  ushort* Wco2t  = Wtd + (size_t)C_ * C_; // 80K bf16 (80,1024)
  ushort* adj_bf = Wco2t + (size_t)N_ * C_; // 80x96 bf16 prepadded
  ushort* tadj_bf = adj_bf + ADJP;        // B x 80x96 bf16 (3.93 MB)
  // bf16 aliases in regions dead at time of use:
  ushort* Wg_bf   = (ushort*)dadj;                      // 1M ushorts; dadj written later
  ushort* Wco1t   = (ushort*)dadj + (size_t)C_ * C_;    // 80K ushorts, same region
  ushort* glb0_bf = (ushort*)glb0;
  ushort* x2t_bf  = xa_bf;                              // xa dead after GEMM#1; x2t dead before fold#2

  // ---- prep (single merged launch: transposes, converts, zeroes, prep_adj) ----
  k_prep_all<<<3259, TPB, 0, stream>>>(Ws, Wd, Wco, Wg, Wts, Wtd, Wco1t, Wco2t, Wg_bf,
                                       go, ap, sadj, adj_bf, lossa);

  // ---- static GCN ----
  k_fold<0><<<B_ * 8, TPB, 0, stream>>>(x, hT_bf, adj_bf, xa_bf);
  k_gemm_160<<<1024, TPB, 0, stream>>>(xa_bf, Wts, hT_bf, 1, ssum1, ssq1);
  k_x2_fused<<<(B_ * C_) / 64, TPB, 0, stream>>>(x, hT_bf, bn_g, bn_b, ssum1, ssq1,
                                                 x2t_bf, glb0_bf);

  // ---- dynamic graph construction ----
  k_glb_mfma<<<dim3(C_ / 64, B_ / 64), TPB, 0, stream>>>(glb0_bf, Wg_bf, bg, glb1, gsum, gsq);
  k_go_mfma<<<dim3(8, B_ / 128), TPB, 0, stream>>>(glb1, Wco1t, gsum, gsq, bng_g, bng_b, go);
  k_dadj_mfma<<<BNr / 128, TPB, 0, stream>>>(x2t_bf, Wco2t, go, bco, dadj, bmin, bmax);

  // ---- tadj build (per-b normalize + rowsum) + fused adjacency loss ----
  k_tadj<<<B_, TPB, 0, stream>>>(dadj, bmin, bmax, sadj, out1, tadj_bf, lossa);

  // ---- dynamic GCN ----
  k_fold<1><<<B_ * 8, TPB, 0, stream>>>(x, hT_bf, tadj_bf, xa_bf);
  k_gemm_160<<<1024, TPB, 0, stream>>>(xa_bf, Wtd, hT_bf, 1, ssum2, ssq2);
  k_final<<<(int)(BCN / (4 * TPB)), TPB, 0, stream>>>(hT_bf, out, bn_g, bn_b, ssum2, ssq2, lossa);
}